// Round 21
// baseline (916.285 us; speedup 1.0000x reference)
//
#include <hip/hip_runtime.h>
#include <hip/hip_bf16.h>

typedef __hip_bfloat16 bf16;

constexpr int B  = 64, T = 120, N = 24, M = 3, D = 32;
constexpr int NH = 2, FD = 16, FF = 64, L = 3;
constexpr float SCALE = 0.25f;   // 1/sqrt(FD)
constexpr int SK  = 40;          // attnt Q/V LDS stride (bf16, 80B rows)
constexpr int SKF = 36;          // attnt K/O LDS stride (f32, 144B rows)
constexpr int CH2 = 30;          // attnt rows per chunk: 4 x 30 = 120 exactly
constexpr int NJ  = 30;          // max keys per lane slice (120/4)
constexpr int QR  = 64;          // qkvt rows per block (4 lanes/row)
constexpr int QCH = (B * T) / QR;// qkvt chunks = 120
constexpr int BG  = 2;           // spatial batches per block
constexpr int SR  = N * BG;      // spatial rows per block = 48
constexpr int SES = 40;          // Es bf16 stride (80B)
constexpr int SQS = 33;          // spatial Q/K/V f32 stride (no 32-way conflicts)
constexpr int FR  = 32;          // ff rows per block (8 lanes/row)
constexpr int AB  = B * N;       // attnt blocks = 1536
constexpr int SB  = T * (B / BG);// spatial blocks = 3840

__device__ __forceinline__ float b2f(bf16 x) { return __bfloat162float(x); }
__device__ __forceinline__ float blo(unsigned u) { return __uint_as_float(u << 16); }
__device__ __forceinline__ float bhi(unsigned u) { return __uint_as_float(u & 0xffff0000u); }
__device__ __forceinline__ unsigned pk2(float a, float b) {
  bf16 x = __float2bfloat16(a), y = __float2bfloat16(b);
  unsigned short ux = *reinterpret_cast<unsigned short*>(&x);
  unsigned short uy = *reinterpret_cast<unsigned short*>(&y);
  return (unsigned)ux | ((unsigned)uy << 16);
}

// ---------------------------------------------------------------------------
// Compose q/k/v chained linears: grid = 3*U blocks.  Wc = W1@W2, bc = b1@W2+b2.
// ---------------------------------------------------------------------------
__global__ __launch_bounds__(256) void compose3_kernel(
    const float* __restrict__ W1q, const float* __restrict__ b1q,
    const float* __restrict__ W2q, const float* __restrict__ b2q,
    const float* __restrict__ W1k, const float* __restrict__ b1k,
    const float* __restrict__ W2k, const float* __restrict__ b2k,
    const float* __restrict__ W1v, const float* __restrict__ b1v,
    const float* __restrict__ W2v, const float* __restrict__ b2v,
    float* __restrict__ Wc, float* __restrict__ bc, int U) {
  int fam = blockIdx.x / U;
  int n   = blockIdx.x % U;
  const float* W1 = (fam == 0) ? W1q : (fam == 1) ? W1k : W1v;
  const float* b1 = (fam == 0) ? b1q : (fam == 1) ? b1k : b1v;
  const float* W2 = (fam == 0) ? W2q : (fam == 1) ? W2k : W2v;
  const float* b2 = (fam == 0) ? b2q : (fam == 1) ? b2k : b2v;
  const float* w1 = W1 + n * D * D;
  const float* w2 = W2 + n * D * D;
  float* wc  = Wc + (size_t)(fam * U + n) * D * D;
  float* bcp = bc + (fam * U + n) * D;
  __shared__ float s1[D * D], s2[D * D];
  for (int i = threadIdx.x; i < D * D; i += 256) { s1[i] = w1[i]; s2[i] = w2[i]; }
  __syncthreads();
  for (int i = threadIdx.x; i < D * D; i += 256) {
    int d = i >> 5, f = i & 31;
    float acc = 0.f;
#pragma unroll
    for (int e = 0; e < D; ++e) acc += s1[d * D + e] * s2[e * D + f];
    wc[i] = acc;
  }
  if (threadIdx.x < D) {
    int f = threadIdx.x;
    float acc = b2[n * D + f];
#pragma unroll
    for (int e = 0; e < D; ++e) acc += b1[n * D + e] * s2[e * D + f];
    bcp[f] = acc;
  }
}

// ---------------------------------------------------------------------------
// E[b,t,n,d] = X@E_W + E_b + pe   (bf16 out)
// ---------------------------------------------------------------------------
__global__ __launch_bounds__(256) void embed_kernel(
    const float* __restrict__ X, const float* __restrict__ pe,
    const float* __restrict__ E_W, const float* __restrict__ E_b,
    bf16* __restrict__ E) {
  int idx = blockIdx.x * 256 + threadIdx.x;
  if (idx >= B * T * N * D) return;
  int d = idx & 31;
  int n = (idx >> 5) % N;
  int bt = idx / (D * N);
  int t = bt % T;
  const float* x = X + bt * (N * M) + n * M;
  float acc = E_b[n * D + d] + pe[t * D + d];
#pragma unroll
  for (int m = 0; m < M; ++m) acc += x[m] * E_W[(n * M + m) * D + d];
  E[idx] = __float2bfloat16(acc);
}

// ---------------------------------------------------------------------------
// qkvt v2: thread = (row, quarter); LDS-staged coalesced loads, one
// contiguous uint4 store per family.  Grid n-major for weight L2 reuse.
// ---------------------------------------------------------------------------
__global__ __launch_bounds__(256) void qkvt_kernel(
    const bf16* __restrict__ E, const float* __restrict__ WtC,
    const float* __restrict__ btC,
    bf16* __restrict__ Qt, bf16* __restrict__ Kt, bf16* __restrict__ Vt) {
  int n     = blockIdx.x / QCH;
  int chunk = blockIdx.x % QCH;
  __shared__ float wsh[3 * D * D];
  __shared__ float bsh[3 * D];
  __shared__ __align__(16) bf16 Es[QR * SES];
  int tid = threadIdx.x;
  for (int i = tid; i < 3 * D * D; i += 256) {
    int fam = i >> 10, idx = i & 1023;
    wsh[i] = WtC[(size_t)(fam * N + n) * D * D + idx];
  }
  if (tid < 3 * D) {
    int fam = tid >> 5, e = tid & 31;
    bsh[tid] = btC[(fam * N + n) * D + e];
  }
  {
    int row = tid >> 2, p = tid & 3;
    const bf16* er = E + ((size_t)(chunk * QR + row) * N + n) * D;
    *(uint4*)&Es[row * SES + p * 8] = *(const uint4*)&er[p * 8];
  }
  __syncthreads();

  int row = tid >> 2, q = tid & 3;
  int grow = chunk * QR + row;          // b*T + t
  int b = grow / T, t = grow % T;
  float x[D];
#pragma unroll
  for (int d = 0; d < D; ++d) x[d] = b2f(Es[row * SES + d]);
  size_t dsto = (((size_t)b * N + n) * T + t) * D + q * 8;
  bf16* dsts[3] = { Qt + dsto, Kt + dsto, Vt + dsto };
#pragma unroll
  for (int fam = 0; fam < 3; ++fam) {
    const float* w  = wsh + fam * D * D;
    const float* bi = bsh + fam * D;
    float a[8];
#pragma unroll
    for (int j = 0; j < 8; ++j) a[j] = bi[q * 8 + j];
#pragma unroll
    for (int d = 0; d < D; ++d) {
      float xv = x[d];
#pragma unroll
      for (int j = 0; j < 8; ++j) a[j] += xv * w[d * D + q * 8 + j];
    }
    uint4 o;
    o.x = pk2(a[0], a[1]); o.y = pk2(a[2], a[3]);
    o.z = pk2(a[4], a[5]); o.w = pk2(a[6], a[7]);
    *(uint4*)dsts[fam] = o;
  }
}

// ---------------------------------------------------------------------------
// attnt body (v9): one block per (b,n); K/V staged once; chunks looped.
// Shared memory carved from smem: Kl@0(17280) Vl@17280(9600) Ql@26880(2400)
// Ol@29280(4320) Wol@33600(4096) bol@37696 gl@37824 bbl@37952 -> 38080 B.
// ---------------------------------------------------------------------------
__device__ void attnt_body(
    char* smem, int bn,
    const bf16* __restrict__ Qt, const bf16* __restrict__ Kt,
    const bf16* __restrict__ Vt, const bf16* __restrict__ E,
    const float* __restrict__ tm_Wo, const float* __restrict__ tm_bo,
    const float* __restrict__ ln_g, const float* __restrict__ ln_b,
    bf16* __restrict__ Tn) {
  float* Kl  = (float*)smem;
  bf16*  Vl  = (bf16*)(smem + 17280);
  bf16*  Ql  = (bf16*)(smem + 26880);
  float* Ol  = (float*)(smem + 29280);
  float* Wol = (float*)(smem + 33600);
  float* bol = (float*)(smem + 37696);
  float* gl  = (float*)(smem + 37824);
  float* bbl = (float*)(smem + 37952);
  int n = bn % N, b = bn / N;
  int tid = threadIdx.x;

  const bf16* Kg = Kt + (size_t)bn * T * D;
  const bf16* Vg = Vt + (size_t)bn * T * D;
  const bf16* Qg = Qt + (size_t)bn * T * D;
  for (int i = tid; i < T * 4; i += 256) {
    int r = i >> 2, p = i & 3;
    uint4 ku = *(const uint4*)&Kg[r * D + p * 8];
    *(float4*)&Kl[r * SKF + p * 8]     = make_float4(blo(ku.x), bhi(ku.x), blo(ku.y), bhi(ku.y));
    *(float4*)&Kl[r * SKF + p * 8 + 4] = make_float4(blo(ku.z), bhi(ku.z), blo(ku.w), bhi(ku.w));
    *(uint4*)&Vl[r * SK + p * 8]       = *(const uint4*)&Vg[r * D + p * 8];
  }
  for (int i = tid; i < D * D; i += 256) Wol[i] = tm_Wo[(size_t)n * D * D + i];
  if (tid < D) {
    bol[tid] = tm_bo[n * D + tid];
    gl[tid]  = ln_g[tid];
    bbl[tid] = ln_b[tid];
  }
  __syncthreads();

#pragma unroll 1
  for (int c = 0; c < 4; ++c) {
    if (tid < CH2 * 4) {
      int r = tid >> 2, p = tid & 3;
      *(uint4*)&Ql[r * SK + p * 8] =
          *(const uint4*)&Qg[(CH2 * c + r) * D + p * 8];
    }
    __syncthreads();   // Ql ready; prior O-proj done -> Ol safe to overwrite

    {
      int task = tid >> 2, sl = tid & 3;
      if (task < 2 * CH2) {
        int rl = task >> 1, h = task & 1, ho = h * FD;
        int rg = CH2 * c + rl;
        uint4 q0 = *(const uint4*)&Ql[rl * SK + ho];
        uint4 q1 = *(const uint4*)&Ql[rl * SK + ho + 8];
        float qf[16];
        qf[0]  = blo(q0.x); qf[1]  = bhi(q0.x); qf[2]  = blo(q0.y); qf[3]  = bhi(q0.y);
        qf[4]  = blo(q0.z); qf[5]  = bhi(q0.z); qf[6]  = blo(q0.w); qf[7]  = bhi(q0.w);
        qf[8]  = blo(q1.x); qf[9]  = bhi(q1.x); qf[10] = blo(q1.y); qf[11] = bhi(q1.y);
        qf[12] = blo(q1.z); qf[13] = bhi(q1.z); qf[14] = blo(q1.w); qf[15] = bhi(q1.w);

        float sc[NJ];
        float mx = -3e38f;
#pragma unroll
        for (int j = 0; j < NJ; ++j) {
          int k = 4 * j + sl;
          sc[j] = -3e38f;
          if (k <= rg) {
            const float4 k0 = *(const float4*)&Kl[k * SKF + ho];
            const float4 k1 = *(const float4*)&Kl[k * SKF + ho + 4];
            const float4 k2 = *(const float4*)&Kl[k * SKF + ho + 8];
            const float4 k3 = *(const float4*)&Kl[k * SKF + ho + 12];
            float s0 = qf[0]*k0.x  + qf[1]*k0.y  + qf[2]*k0.z  + qf[3]*k0.w;
            float s1 = qf[4]*k1.x  + qf[5]*k1.y  + qf[6]*k1.z  + qf[7]*k1.w;
            float s2 = qf[8]*k2.x  + qf[9]*k2.y  + qf[10]*k2.z + qf[11]*k2.w;
            float s3 = qf[12]*k3.x + qf[13]*k3.y + qf[14]*k3.z + qf[15]*k3.w;
            float s = ((s0 + s1) + (s2 + s3)) * SCALE;
            sc[j] = s;
            mx = fmaxf(mx, s);
          }
        }
        mx = fmaxf(mx, __shfl_xor(mx, 1, 64));
        mx = fmaxf(mx, __shfl_xor(mx, 2, 64));
        float l = 0.f;
#pragma unroll
        for (int j = 0; j < NJ; ++j) {
          sc[j] = __expf(sc[j] - mx);   // invalid slots: exp(-inf) = 0
          l += sc[j];
        }
        l += __shfl_xor(l, 1, 64);
        l += __shfl_xor(l, 2, 64);
        float rli = 1.f / l;

        float acc[16];
#pragma unroll
        for (int f = 0; f < 16; ++f) acc[f] = 0.f;
#pragma unroll
        for (int j = 0; j < NJ; ++j) {
          int k = 4 * j + sl;
          if (k <= rg) {
            float p = sc[j];
            uint2 va = *(const uint2*)&Vl[k * SK + ho];
            uint2 vb = *(const uint2*)&Vl[k * SK + ho + 4];
            uint2 vc = *(const uint2*)&Vl[k * SK + ho + 8];
            uint2 vd = *(const uint2*)&Vl[k * SK + ho + 12];
            acc[0]  += p * blo(va.x); acc[1]  += p * bhi(va.x);
            acc[2]  += p * blo(va.y); acc[3]  += p * bhi(va.y);
            acc[4]  += p * blo(vb.x); acc[5]  += p * bhi(vb.x);
            acc[6]  += p * blo(vb.y); acc[7]  += p * bhi(vb.y);
            acc[8]  += p * blo(vc.x); acc[9]  += p * bhi(vc.x);
            acc[10] += p * blo(vc.y); acc[11] += p * bhi(vc.y);
            acc[12] += p * blo(vd.x); acc[13] += p * bhi(vd.x);
            acc[14] += p * blo(vd.y); acc[15] += p * bhi(vd.y);
          }
        }
#pragma unroll
        for (int f = 0; f < 16; ++f) {
          acc[f] += __shfl_xor(acc[f], 1, 64);
          acc[f] += __shfl_xor(acc[f], 2, 64);
        }
        if (sl == 0) {
#pragma unroll
          for (int f = 0; f < 16; ++f) Ol[rl * SKF + ho + f] = acc[f] * rli;
        }
      }
    }
    __syncthreads();

    {
      int rl = tid >> 3, q = tid & 7, e0 = q * 4;
      if (rl < CH2) {
        int rg = CH2 * c + rl;
        size_t rowo = ((size_t)(b * T + rg) * N + n) * D;
        uint2 eu = *(const uint2*)&E[rowo + e0];
        float res[4] = { blo(eu.x), bhi(eu.x), blo(eu.y), bhi(eu.y) };
        float o[4], s1 = 0.f, s2 = 0.f;
#pragma unroll
        for (int j = 0; j < 4; ++j) {
          int e = e0 + j;
          float aa = 0.f, ab = 0.f;
#pragma unroll
          for (int d = 0; d < D; d += 2) {
            aa += Ol[rl * SKF + d]     * Wol[d * D + e];
            ab += Ol[rl * SKF + d + 1] * Wol[(d + 1) * D + e];
          }
          float a = bol[e] + aa + ab + res[j];
          o[j] = a; s1 += a; s2 += a * a;
        }
        s1 += __shfl_xor(s1, 1, 64); s2 += __shfl_xor(s2, 1, 64);
        s1 += __shfl_xor(s1, 2, 64); s2 += __shfl_xor(s2, 2, 64);
        s1 += __shfl_xor(s1, 4, 64); s2 += __shfl_xor(s2, 4, 64);
        float mu  = s1 * (1.f / D);
        float var = s2 * (1.f / D) - mu * mu;
        float r = rsqrtf(var + 1e-5f);
        uint2 ou;
        ou.x = pk2((o[0]-mu)*r*gl[e0]+bbl[e0],    (o[1]-mu)*r*gl[e0+1]+bbl[e0+1]);
        ou.y = pk2((o[2]-mu)*r*gl[e0+2]+bbl[e0+2],(o[3]-mu)*r*gl[e0+3]+bbl[e0+3]);
        *(uint2*)&Tn[rowo + e0] = ou;
      }
    }
  }
}

// ---------------------------------------------------------------------------
// spatial body (v3, SQS=33): Wq@0 Wk@4096 Wv@8192 Wo@12288 biases@16384(768)
// Es@17152(3840) Qs@20992 Ks@27328 Vs@33664 -> 40000 B.
// ---------------------------------------------------------------------------
__device__ void spatial_body(
    char* smem, int sb,
    const bf16* __restrict__ E, const float* __restrict__ WsC,
    const float* __restrict__ bsC, const float* __restrict__ sm_Wo,
    const float* __restrict__ sm_bo, const float* __restrict__ ln_g,
    const float* __restrict__ ln_b, bf16* __restrict__ Sn) {
  float* Wq  = (float*)smem;
  float* Wk  = (float*)(smem + 4096);
  float* Wv  = (float*)(smem + 8192);
  float* Wo  = (float*)(smem + 12288);
  float* bqs = (float*)(smem + 16384);
  float* bks = (float*)(smem + 16512);
  float* bvs = (float*)(smem + 16640);
  float* bos = (float*)(smem + 16768);
  float* gs  = (float*)(smem + 16896);
  float* bbs = (float*)(smem + 17024);
  bf16*  Es  = (bf16*)(smem + 17152);
  float* Qs  = (float*)(smem + 20992);
  float* Ks  = (float*)(smem + 27328);
  float* Vs  = (float*)(smem + 33664);
  int t  = sb >> 5;                  // B/BG = 32 groups per t
  int bg = sb & 31;
  int b0 = bg * BG;
  int tid = threadIdx.x;

  for (int i = tid; i < D * D; i += 256) {
    Wq[i] = WsC[(size_t)(0 * T + t) * D * D + i];
    Wk[i] = WsC[(size_t)(1 * T + t) * D * D + i];
    Wv[i] = WsC[(size_t)(2 * T + t) * D * D + i];
    Wo[i] = sm_Wo[(size_t)t * D * D + i];
  }
  if (tid < D) {
    bqs[tid] = bsC[(0 * T + t) * D + tid];
    bks[tid] = bsC[(1 * T + t) * D + tid];
    bvs[tid] = bsC[(2 * T + t) * D + tid];
    bos[tid] = sm_bo[t * D + tid];
    gs[tid]  = ln_g[tid];
    bbs[tid] = ln_b[tid];
  }
  if (tid < SR * 4) {
    int r = tid >> 2, p = tid & 3;
    int b = b0 + r / N, n = r % N;
    *(uint4*)&Es[r * SES + p * 8] =
        *(const uint4*)&E[(((size_t)b * T + t) * N + n) * D + p * 8];
  }
  __syncthreads();

#pragma unroll 1
  for (int i = tid; i < SR * D; i += 256) {
    int r = i >> 5, e = i & 31;
    float aq = bqs[e], ak = bks[e], av = bvs[e];
#pragma unroll
    for (int d = 0; d < D; ++d) {
      float x = b2f(Es[r * SES + d]);
      aq += x * Wq[d * D + e];
      ak += x * Wk[d * D + e];
      av += x * Wv[d * D + e];
    }
    Qs[r * SQS + e] = aq;
    Ks[r * SQS + e] = ak;
    Vs[r * SQS + e] = av;
  }
  __syncthreads();

  if (tid < SR * NH) {
    int r = tid >> 1, h = tid & 1, ho = h * FD;
    int kb = (r >= N) ? N : 0;
    float q[FD];
#pragma unroll
    for (int f = 0; f < FD; ++f) q[f] = Qs[r * SQS + ho + f];
    float sc[N];
    float m = -1e30f;
#pragma unroll
    for (int k = 0; k < N; ++k) {
      float sa = 0.f, sb2 = 0.f;
#pragma unroll
      for (int f = 0; f < FD; f += 2) {
        sa  += q[f]     * Ks[(kb + k) * SQS + ho + f];
        sb2 += q[f + 1] * Ks[(kb + k) * SQS + ho + f + 1];
      }
      float s = (sa + sb2) * SCALE;
      sc[k] = s;
      m = fmaxf(m, s);
    }
    float l = 0.f;
#pragma unroll
    for (int k = 0; k < N; ++k) { sc[k] = __expf(sc[k] - m); l += sc[k]; }
    float rl = 1.f / l;
#pragma unroll
    for (int f = 0; f < FD; ++f) {
      float a = 0.f;
#pragma unroll
      for (int k = 0; k < N; ++k) a += sc[k] * Vs[(kb + k) * SQS + ho + f];
      Qs[r * SQS + ho + f] = a * rl;
    }
  }
  __syncthreads();

#pragma unroll 1
  for (int it = 0; it < SR * D / 256; ++it) {
    int i = it * 256 + tid;
    int r = i >> 5, e = i & 31;
    float aa = 0.f, ab = 0.f;
#pragma unroll
    for (int d = 0; d < D; d += 2) {
      aa += Qs[r * SQS + d]     * Wo[d * D + e];
      ab += Qs[r * SQS + d + 1] * Wo[(d + 1) * D + e];
    }
    float o = bos[e] + aa + ab + b2f(Es[r * SES + e]);
    float s1 = o, s2 = o * o;
    s1 += __shfl_xor(s1, 1, 64);  s2 += __shfl_xor(s2, 1, 64);
    s1 += __shfl_xor(s1, 2, 64);  s2 += __shfl_xor(s2, 2, 64);
    s1 += __shfl_xor(s1, 4, 64);  s2 += __shfl_xor(s2, 4, 64);
    s1 += __shfl_xor(s1, 8, 64);  s2 += __shfl_xor(s2, 8, 64);
    s1 += __shfl_xor(s1, 16, 64); s2 += __shfl_xor(s2, 16, 64);
    float mu  = s1 * (1.f / D);
    float var = s2 * (1.f / D) - mu * mu;
    float rr = rsqrtf(var + 1e-5f);
    int b = b0 + r / N, n = r % N;
    Sn[(((size_t)b * T + t) * N + n) * D + e] =
        __float2bfloat16((o - mu) * rr * gs[e] + bbs[e]);
  }
}

// ---------------------------------------------------------------------------
// fused attnt+spatial: both depend only on already-written buffers and write
// disjoint outputs (Tn vs Sn; Sn NO LONGER aliases Qt).  One dispatch lets
// spatial's blocks fill attnt's latency bubbles instead of running serially.
// attnt blocks first (long-running, launch early).
// ---------------------------------------------------------------------------
__global__ __launch_bounds__(256) void fused_ts_kernel(
    const bf16* __restrict__ Qt, const bf16* __restrict__ Kt,
    const bf16* __restrict__ Vt, const bf16* __restrict__ E,
    const float* __restrict__ tm_Wo, const float* __restrict__ tm_bo,
    const float* __restrict__ WsC, const float* __restrict__ bsC,
    const float* __restrict__ sm_Wo, const float* __restrict__ sm_bo,
    const float* __restrict__ ln_g, const float* __restrict__ ln_b,
    bf16* __restrict__ Tn, bf16* __restrict__ Sn) {
  __shared__ __align__(16) char smem[40000];
  if (blockIdx.x < AB) {
    attnt_body(smem, blockIdx.x, Qt, Kt, Vt, E, tm_Wo, tm_bo, ln_g, ln_b, Tn);
  } else {
    spatial_body(smem, blockIdx.x - AB, E, WsC, bsC, sm_Wo, sm_bo, ln_g, ln_b, Sn);
  }
}

// ---------------------------------------------------------------------------
// ff v2: block = 32 rows x 8 lanes/row (grid 240).
// ---------------------------------------------------------------------------
__global__ __launch_bounds__(256) void ff_kernel(
    const bf16* __restrict__ Tn, const bf16* __restrict__ Sn,
    const float* __restrict__ W1, const float* __restrict__ b1,
    const float* __restrict__ W2, const float* __restrict__ b2,
    const float* __restrict__ ln_g, const float* __restrict__ ln_b,
    bf16* __restrict__ E) {
  __shared__ float w1s[D * FF], w2s[FF * D];
  __shared__ float bb1[FF], bb2[D], gs[D], bbs[D];
  __shared__ float tsl[FR][D + 1];
  __shared__ float hl[FR][FF + 1];
  int tid = threadIdx.x;
  int r0 = blockIdx.x * FR;
  for (int i = tid; i < D * FF; i += 256) { w1s[i] = W1[i]; w2s[i] = W2[i]; }
  if (tid < FF) bb1[tid] = b1[tid];
  if (tid < D) { bb2[tid] = b2[tid]; gs[tid] = ln_g[tid]; bbs[tid] = ln_b[tid]; }
  int r = tid >> 3, s = tid & 7;
  {
    const bf16* tp = Tn + ((size_t)(r0 + r)) * D + s * 4;
    const bf16* sp = Sn + ((size_t)(r0 + r)) * D + s * 4;
    uint2 tu = *(const uint2*)tp;
    uint2 su = *(const uint2*)sp;
    tsl[r][s*4+0] = blo(tu.x) + blo(su.x);
    tsl[r][s*4+1] = bhi(tu.x) + bhi(su.x);
    tsl[r][s*4+2] = blo(tu.y) + blo(su.y);
    tsl[r][s*4+3] = bhi(tu.y) + bhi(su.y);
  }
  __syncthreads();
  {
    float hh[8];
#pragma unroll
    for (int j = 0; j < 8; ++j) {
      int jj = s * 8 + j;
      float aa = bb1[jj], ab = 0.f;
#pragma unroll
      for (int d = 0; d < D; d += 2) {
        aa += tsl[r][d]     * w1s[d * FF + jj];
        ab += tsl[r][d + 1] * w1s[(d + 1) * FF + jj];
      }
      hh[j] = fmaxf(aa + ab, 0.f);
    }
#pragma unroll
    for (int j = 0; j < 8; ++j) hl[r][s * 8 + j] = hh[j];
  }
  __syncthreads();
  {
    float x[4];
    float s1 = 0.f, s2 = 0.f;
#pragma unroll
    for (int j4 = 0; j4 < 4; ++j4) {
      int e = s * 4 + j4;
      float aa = 0.f, ab = 0.f;
#pragma unroll
      for (int k = 0; k < FF; k += 2) {
        aa += hl[r][k]     * w2s[k * D + e];
        ab += hl[r][k + 1] * w2s[(k + 1) * D + e];
      }
      float a = bb2[e] + tsl[r][e] + aa + ab;
      x[j4] = a; s1 += a; s2 += a * a;
    }
    s1 += __shfl_xor(s1, 1, 64); s2 += __shfl_xor(s2, 1, 64);
    s1 += __shfl_xor(s1, 2, 64); s2 += __shfl_xor(s2, 2, 64);
    s1 += __shfl_xor(s1, 4, 64); s2 += __shfl_xor(s2, 4, 64);
    float mu  = s1 * (1.f / D);
    float var = s2 * (1.f / D) - mu * mu;
    float rr = rsqrtf(var + 1e-5f);
    int e0 = s * 4;
    uint2 ou;
    ou.x = pk2((x[0]-mu)*rr*gs[e0]+bbs[e0],    (x[1]-mu)*rr*gs[e0+1]+bbs[e0+1]);
    ou.y = pk2((x[2]-mu)*rr*gs[e0+2]+bbs[e0+2],(x[3]-mu)*rr*gs[e0+3]+bbs[e0+3]);
    *(uint2*)&E[((size_t)(r0 + r)) * D + e0] = ou;
  }
}

// ---------------------------------------------------------------------------
// out = E@op_W + op_b + X   (f32 out)
// ---------------------------------------------------------------------------
__global__ __launch_bounds__(256) void out_kernel(
    const bf16* __restrict__ E, const float* __restrict__ op_W,
    const float* __restrict__ op_b, const float* __restrict__ X,
    float* __restrict__ out) {
  int idx = blockIdx.x * 256 + threadIdx.x;
  if (idx >= B * T * N * M) return;
  int m  = idx % M;
  int n  = (idx / M) % N;
  int bt = idx / (M * N);
  float acc = op_b[n * M + m];
  const bf16* e = E + ((size_t)bt * N + n) * D;
#pragma unroll
  for (int d = 0; d < D; ++d) acc += b2f(e[d]) * op_W[(n * D + d) * M + m];
  acc += X[idx];
  out[idx] = acc;
}

// ---------------------------------------------------------------------------
extern "C" void kernel_launch(void* const* d_in, const int* in_sizes, int n_in,
                              void* d_out, int out_size, void* d_ws, size_t ws_size,
                              hipStream_t stream) {
  const float* X     = (const float*)d_in[0];
  const float* pe    = (const float*)d_in[1];
  const float* E_W   = (const float*)d_in[2];
  const float* E_b   = (const float*)d_in[3];
  const float* tq_W  = (const float*)d_in[4];
  const float* tq_b  = (const float*)d_in[5];
  const float* tk_W  = (const float*)d_in[6];
  const float* tk_b  = (const float*)d_in[7];
  const float* tv_W  = (const float*)d_in[8];
  const float* tv_b  = (const float*)d_in[9];
  const float* tm_Wq = (const float*)d_in[10];
  const float* tm_bq = (const float*)d_in[11];
  const float* tm_Wk = (const float*)d_in[12];
  const float* tm_bk = (const float*)d_in[13];
  const float* tm_Wv = (const float*)d_in[14];
  const float* tm_bv = (const float*)d_in[15];
  const float* tm_Wo = (const float*)d_in[16];
  const float* tm_bo = (const float*)d_in[17];
  const float* sq_W  = (const float*)d_in[18];
  const float* sq_b  = (const float*)d_in[19];
  const float* sk_W  = (const float*)d_in[20];
  const float* sk_b  = (const float*)d_in[21];
  const float* sv_W  = (const float*)d_in[22];
  const float* sv_b  = (const float*)d_in[23];
  const float* sm_Wq = (const float*)d_in[24];
  const float* sm_bq = (const float*)d_in[25];
  const float* sm_Wk = (const float*)d_in[26];
  const float* sm_bk = (const float*)d_in[27];
  const float* sm_Wv = (const float*)d_in[28];
  const float* sm_bv = (const float*)d_in[29];
  const float* sm_Wo = (const float*)d_in[30];
  const float* sm_bo = (const float*)d_in[31];
  const float* ff1_W = (const float*)d_in[32];
  const float* ff1_b = (const float*)d_in[33];
  const float* ff2_W = (const float*)d_in[34];
  const float* ff2_b = (const float*)d_in[35];
  const float* ln_g  = (const float*)d_in[36];
  const float* ln_b  = (const float*)d_in[37];
  const float* op_W  = (const float*)d_in[38];
  const float* op_b  = (const float*)d_in[39];
  float* out = (float*)d_out;

  float* WtC = (float*)d_ws;                         // 3*N*D*D
  float* btC = WtC + 3 * N * D * D;                  // 3*N*D
  float* WsC = btC + 3 * N * D;                      // 3*T*D*D
  float* bsC = WsC + 3 * T * D * D;                  // 3*T*D
  size_t act = (size_t)B * T * N * D;
  bf16* Ebuf = (bf16*)(bsC + 3 * T * D);
  bf16* Tn   = Ebuf + act;
  bf16* Qt   = Tn + act;
  bf16* Kt   = Qt + act;
  bf16* Vt   = Kt + act;
  bf16* Sn   = Vt + act;     // own buffer (Qt alias would race in fused kernel)
  // total ~68.2 MB

  compose3_kernel<<<3 * N, 256, 0, stream>>>(
      tq_W, tq_b, tm_Wq, tm_bq, tk_W, tk_b, tm_Wk, tm_bk,
      tv_W, tv_b, tm_Wv, tm_bv, WtC, btC, N);
  compose3_kernel<<<3 * T, 256, 0, stream>>>(
      sq_W, sq_b, sm_Wq, sm_bq, sk_W, sk_b, sm_Wk, sm_bk,
      sv_W, sv_b, sm_Wv, sm_bv, WsC, bsC, T);

  embed_kernel<<<(B * T * N * D) / 256, 256, 0, stream>>>(X, pe, E_W, E_b, Ebuf);

  for (int l = 0; l < L; ++l) {
    qkvt_kernel<<<N * QCH, 256, 0, stream>>>(Ebuf, WtC, btC, Qt, Kt, Vt);
    fused_ts_kernel<<<AB + SB, 256, 0, stream>>>(
        Qt, Kt, Vt, Ebuf, tm_Wo, tm_bo, WsC, bsC, sm_Wo, sm_bo,
        ln_g, ln_b, Tn, Sn);
    ff_kernel<<<(B * T * N) / FR, 256, 0, stream>>>(Tn, Sn, ff1_W, ff1_b, ff2_W, ff2_b, ln_g, ln_b, Ebuf);
  }

  out_kernel<<<(B * T * N * M + 255) / 256, 256, 0, stream>>>(Ebuf, op_W, op_b, X, out);
}

// Round 22
// 794.590 us; speedup vs baseline: 1.1532x; 1.1532x over previous
//
#include <hip/hip_runtime.h>
#include <hip/hip_bf16.h>

typedef __hip_bfloat16 bf16;

constexpr int B  = 64, T = 120, N = 24, M = 3, D = 32;
constexpr int NH = 2, FD = 16, FF = 64, L = 3;
constexpr float SCALE = 0.25f;   // 1/sqrt(FD)
constexpr int SK  = 40;          // attnt Q/V LDS stride (bf16, 80B rows)
constexpr int SKF = 36;          // attnt K/O LDS stride (f32, 144B rows)
constexpr int CH2 = 30;          // attnt rows per chunk: 4 x 30 = 120 exactly
constexpr int NJ  = 30;          // max keys per lane slice (120/4)
constexpr int QR  = 64;          // qkvt rows per block (4 lanes/row)
constexpr int QCH = (B * T) / QR;// qkvt chunks = 120
constexpr int BG  = 2;           // spatial batches per block
constexpr int SR  = N * BG;      // spatial rows per block = 48
constexpr int SES = 40;          // Es bf16 stride (80B)
constexpr int SQS = 33;          // spatial Q/K/V f32 stride (no 32-way conflicts)
constexpr int FR  = 32;          // ff rows per block (8 lanes/row)

__device__ __forceinline__ float b2f(bf16 x) { return __bfloat162float(x); }
__device__ __forceinline__ float blo(unsigned u) { return __uint_as_float(u << 16); }
__device__ __forceinline__ float bhi(unsigned u) { return __uint_as_float(u & 0xffff0000u); }
__device__ __forceinline__ unsigned pk2(float a, float b) {
  bf16 x = __float2bfloat16(a), y = __float2bfloat16(b);
  unsigned short ux = *reinterpret_cast<unsigned short*>(&x);
  unsigned short uy = *reinterpret_cast<unsigned short*>(&y);
  return (unsigned)ux | ((unsigned)uy << 16);
}

// ---------------------------------------------------------------------------
// Compose q/k/v chained linears: grid = 3*U blocks.  Wc = W1@W2, bc = b1@W2+b2.
// ---------------------------------------------------------------------------
__global__ __launch_bounds__(256) void compose3_kernel(
    const float* __restrict__ W1q, const float* __restrict__ b1q,
    const float* __restrict__ W2q, const float* __restrict__ b2q,
    const float* __restrict__ W1k, const float* __restrict__ b1k,
    const float* __restrict__ W2k, const float* __restrict__ b2k,
    const float* __restrict__ W1v, const float* __restrict__ b1v,
    const float* __restrict__ W2v, const float* __restrict__ b2v,
    float* __restrict__ Wc, float* __restrict__ bc, int U) {
  int fam = blockIdx.x / U;
  int n   = blockIdx.x % U;
  const float* W1 = (fam == 0) ? W1q : (fam == 1) ? W1k : W1v;
  const float* b1 = (fam == 0) ? b1q : (fam == 1) ? b1k : b1v;
  const float* W2 = (fam == 0) ? W2q : (fam == 1) ? W2k : W2v;
  const float* b2 = (fam == 0) ? b2q : (fam == 1) ? b2k : b2v;
  const float* w1 = W1 + n * D * D;
  const float* w2 = W2 + n * D * D;
  float* wc  = Wc + (size_t)(fam * U + n) * D * D;
  float* bcp = bc + (fam * U + n) * D;
  __shared__ float s1[D * D], s2[D * D];
  for (int i = threadIdx.x; i < D * D; i += 256) { s1[i] = w1[i]; s2[i] = w2[i]; }
  __syncthreads();
  for (int i = threadIdx.x; i < D * D; i += 256) {
    int d = i >> 5, f = i & 31;
    float acc = 0.f;
#pragma unroll
    for (int e = 0; e < D; ++e) acc += s1[d * D + e] * s2[e * D + f];
    wc[i] = acc;
  }
  if (threadIdx.x < D) {
    int f = threadIdx.x;
    float acc = b2[n * D + f];
#pragma unroll
    for (int e = 0; e < D; ++e) acc += b1[n * D + e] * s2[e * D + f];
    bcp[f] = acc;
  }
}

// ---------------------------------------------------------------------------
// E[b,t,n,d] = X@E_W + E_b + pe   (bf16 out)
// ---------------------------------------------------------------------------
__global__ __launch_bounds__(256) void embed_kernel(
    const float* __restrict__ X, const float* __restrict__ pe,
    const float* __restrict__ E_W, const float* __restrict__ E_b,
    bf16* __restrict__ E) {
  int idx = blockIdx.x * 256 + threadIdx.x;
  if (idx >= B * T * N * D) return;
  int d = idx & 31;
  int n = (idx >> 5) % N;
  int bt = idx / (D * N);
  int t = bt % T;
  const float* x = X + bt * (N * M) + n * M;
  float acc = E_b[n * D + d] + pe[t * D + d];
#pragma unroll
  for (int m = 0; m < M; ++m) acc += x[m] * E_W[(n * M + m) * D + d];
  E[idx] = __float2bfloat16(acc);
}

// ---------------------------------------------------------------------------
// qkvt v2: thread = (row, quarter); LDS-staged coalesced loads, one
// contiguous uint4 store per family.  Grid n-major for weight L2 reuse.
// ---------------------------------------------------------------------------
__global__ __launch_bounds__(256) void qkvt_kernel(
    const bf16* __restrict__ E, const float* __restrict__ WtC,
    const float* __restrict__ btC,
    bf16* __restrict__ Qt, bf16* __restrict__ Kt, bf16* __restrict__ Vt) {
  int n     = blockIdx.x / QCH;
  int chunk = blockIdx.x % QCH;
  __shared__ float wsh[3 * D * D];
  __shared__ float bsh[3 * D];
  __shared__ __align__(16) bf16 Es[QR * SES];
  int tid = threadIdx.x;
  for (int i = tid; i < 3 * D * D; i += 256) {
    int fam = i >> 10, idx = i & 1023;
    wsh[i] = WtC[(size_t)(fam * N + n) * D * D + idx];
  }
  if (tid < 3 * D) {
    int fam = tid >> 5, e = tid & 31;
    bsh[tid] = btC[(fam * N + n) * D + e];
  }
  {
    int row = tid >> 2, p = tid & 3;
    const bf16* er = E + ((size_t)(chunk * QR + row) * N + n) * D;
    *(uint4*)&Es[row * SES + p * 8] = *(const uint4*)&er[p * 8];
  }
  __syncthreads();

  int row = tid >> 2, q = tid & 3;
  int grow = chunk * QR + row;          // b*T + t
  int b = grow / T, t = grow % T;
  float x[D];
#pragma unroll
  for (int d = 0; d < D; ++d) x[d] = b2f(Es[row * SES + d]);
  size_t dsto = (((size_t)b * N + n) * T + t) * D + q * 8;
  bf16* dsts[3] = { Qt + dsto, Kt + dsto, Vt + dsto };
#pragma unroll
  for (int fam = 0; fam < 3; ++fam) {
    const float* w  = wsh + fam * D * D;
    const float* bi = bsh + fam * D;
    float a[8];
#pragma unroll
    for (int j = 0; j < 8; ++j) a[j] = bi[q * 8 + j];
#pragma unroll
    for (int d = 0; d < D; ++d) {
      float xv = x[d];
#pragma unroll
      for (int j = 0; j < 8; ++j) a[j] += xv * w[d * D + q * 8 + j];
    }
    uint4 o;
    o.x = pk2(a[0], a[1]); o.y = pk2(a[2], a[3]);
    o.z = pk2(a[4], a[5]); o.w = pk2(a[6], a[7]);
    *(uint4*)dsts[fam] = o;
  }
}

// ---------------------------------------------------------------------------
// attnt v9: ONE block per (b,n); K/V staged ONCE, chunks looped with
// {stage Ql; barrier; attention; barrier; O-proj}.  Measured R20: 118us,
// FETCH 29MB, VGPR 116, 4 blocks/CU.  (R21 fusion with spatial regressed:
// 40.4KB LDS -> 3 blocks/CU + heterogeneous-block load imbalance.)
// ---------------------------------------------------------------------------
__global__ __launch_bounds__(256) void attnt_kernel(
    const bf16* __restrict__ Qt, const bf16* __restrict__ Kt,
    const bf16* __restrict__ Vt, const bf16* __restrict__ E,
    const float* __restrict__ tm_Wo, const float* __restrict__ tm_bo,
    const float* __restrict__ ln_g, const float* __restrict__ ln_b,
    bf16* __restrict__ Tn) {
  int bn = blockIdx.x;
  int n  = bn % N, b = bn / N;
  __shared__ __align__(16) float Kl[T * SKF];
  __shared__ __align__(16) bf16  Vl[T * SK];
  __shared__ __align__(16) bf16  Ql[CH2 * SK];
  __shared__ __align__(16) float Ol[CH2 * SKF];
  __shared__ float Wol[D * D], bol[D], gl[D], bbl[D];
  int tid = threadIdx.x;

  const bf16* Kg = Kt + (size_t)bn * T * D;
  const bf16* Vg = Vt + (size_t)bn * T * D;
  const bf16* Qg = Qt + (size_t)bn * T * D;
  for (int i = tid; i < T * 4; i += 256) {
    int r = i >> 2, p = i & 3;
    uint4 ku = *(const uint4*)&Kg[r * D + p * 8];
    *(float4*)&Kl[r * SKF + p * 8]     = make_float4(blo(ku.x), bhi(ku.x), blo(ku.y), bhi(ku.y));
    *(float4*)&Kl[r * SKF + p * 8 + 4] = make_float4(blo(ku.z), bhi(ku.z), blo(ku.w), bhi(ku.w));
    *(uint4*)&Vl[r * SK + p * 8]       = *(const uint4*)&Vg[r * D + p * 8];
  }
  for (int i = tid; i < D * D; i += 256) Wol[i] = tm_Wo[(size_t)n * D * D + i];
  if (tid < D) {
    bol[tid] = tm_bo[n * D + tid];
    gl[tid]  = ln_g[tid];
    bbl[tid] = ln_b[tid];
  }
  __syncthreads();

#pragma unroll 1
  for (int c = 0; c < 4; ++c) {
    // stage this chunk's Q (30 rows); races only with prior O-proj (no reader)
    if (tid < CH2 * 4) {
      int r = tid >> 2, p = tid & 3;
      *(uint4*)&Ql[r * SK + p * 8] =
          *(const uint4*)&Qg[(CH2 * c + r) * D + p * 8];
    }
    __syncthreads();   // Ql ready; prior O-proj done -> Ol safe to overwrite

    // ---- attention: task = (row, head), 4 lanes per task ----
    {
      int task = tid >> 2, sl = tid & 3;
      if (task < 2 * CH2) {
        int rl = task >> 1, h = task & 1, ho = h * FD;
        int rg = CH2 * c + rl;
        uint4 q0 = *(const uint4*)&Ql[rl * SK + ho];
        uint4 q1 = *(const uint4*)&Ql[rl * SK + ho + 8];
        float qf[16];
        qf[0]  = blo(q0.x); qf[1]  = bhi(q0.x); qf[2]  = blo(q0.y); qf[3]  = bhi(q0.y);
        qf[4]  = blo(q0.z); qf[5]  = bhi(q0.z); qf[6]  = blo(q0.w); qf[7]  = bhi(q0.w);
        qf[8]  = blo(q1.x); qf[9]  = bhi(q1.x); qf[10] = blo(q1.y); qf[11] = bhi(q1.y);
        qf[12] = blo(q1.z); qf[13] = bhi(q1.z); qf[14] = blo(q1.w); qf[15] = bhi(q1.w);

        float sc[NJ];
        float mx = -3e38f;
#pragma unroll
        for (int j = 0; j < NJ; ++j) {
          int k = 4 * j + sl;
          sc[j] = -3e38f;
          if (k <= rg) {
            const float4 k0 = *(const float4*)&Kl[k * SKF + ho];
            const float4 k1 = *(const float4*)&Kl[k * SKF + ho + 4];
            const float4 k2 = *(const float4*)&Kl[k * SKF + ho + 8];
            const float4 k3 = *(const float4*)&Kl[k * SKF + ho + 12];
            float s0 = qf[0]*k0.x  + qf[1]*k0.y  + qf[2]*k0.z  + qf[3]*k0.w;
            float s1 = qf[4]*k1.x  + qf[5]*k1.y  + qf[6]*k1.z  + qf[7]*k1.w;
            float s2 = qf[8]*k2.x  + qf[9]*k2.y  + qf[10]*k2.z + qf[11]*k2.w;
            float s3 = qf[12]*k3.x + qf[13]*k3.y + qf[14]*k3.z + qf[15]*k3.w;
            float s = ((s0 + s1) + (s2 + s3)) * SCALE;
            sc[j] = s;
            mx = fmaxf(mx, s);
          }
        }
        mx = fmaxf(mx, __shfl_xor(mx, 1, 64));
        mx = fmaxf(mx, __shfl_xor(mx, 2, 64));
        float l = 0.f;
#pragma unroll
        for (int j = 0; j < NJ; ++j) {
          sc[j] = __expf(sc[j] - mx);   // invalid slots: exp(-inf) = 0
          l += sc[j];
        }
        l += __shfl_xor(l, 1, 64);
        l += __shfl_xor(l, 2, 64);
        float rli = 1.f / l;

        float acc[16];
#pragma unroll
        for (int f = 0; f < 16; ++f) acc[f] = 0.f;
#pragma unroll
        for (int j = 0; j < NJ; ++j) {
          int k = 4 * j + sl;
          if (k <= rg) {
            float p = sc[j];
            uint2 va = *(const uint2*)&Vl[k * SK + ho];
            uint2 vb = *(const uint2*)&Vl[k * SK + ho + 4];
            uint2 vc = *(const uint2*)&Vl[k * SK + ho + 8];
            uint2 vd = *(const uint2*)&Vl[k * SK + ho + 12];
            acc[0]  += p * blo(va.x); acc[1]  += p * bhi(va.x);
            acc[2]  += p * blo(va.y); acc[3]  += p * bhi(va.y);
            acc[4]  += p * blo(vb.x); acc[5]  += p * bhi(vb.x);
            acc[6]  += p * blo(vb.y); acc[7]  += p * bhi(vb.y);
            acc[8]  += p * blo(vc.x); acc[9]  += p * bhi(vc.x);
            acc[10] += p * blo(vc.y); acc[11] += p * bhi(vc.y);
            acc[12] += p * blo(vd.x); acc[13] += p * bhi(vd.x);
            acc[14] += p * blo(vd.y); acc[15] += p * bhi(vd.y);
          }
        }
#pragma unroll
        for (int f = 0; f < 16; ++f) {
          acc[f] += __shfl_xor(acc[f], 1, 64);
          acc[f] += __shfl_xor(acc[f], 2, 64);
        }
        if (sl == 0) {
#pragma unroll
          for (int f = 0; f < 16; ++f) Ol[rl * SKF + ho + f] = acc[f] * rli;
        }
      }
    }
    __syncthreads();

    // ---- O-proj + residual + LN: thread = (row, e-quad) ----
    {
      int rl = tid >> 3, q = tid & 7, e0 = q * 4;
      if (rl < CH2) {
        int rg = CH2 * c + rl;
        size_t rowo = ((size_t)(b * T + rg) * N + n) * D;
        uint2 eu = *(const uint2*)&E[rowo + e0];
        float res[4] = { blo(eu.x), bhi(eu.x), blo(eu.y), bhi(eu.y) };
        float o[4], s1 = 0.f, s2 = 0.f;
#pragma unroll
        for (int j = 0; j < 4; ++j) {
          int e = e0 + j;
          float aa = 0.f, ab = 0.f;
#pragma unroll
          for (int d = 0; d < D; d += 2) {
            aa += Ol[rl * SKF + d]     * Wol[d * D + e];
            ab += Ol[rl * SKF + d + 1] * Wol[(d + 1) * D + e];
          }
          float a = bol[e] + aa + ab + res[j];
          o[j] = a; s1 += a; s2 += a * a;
        }
        s1 += __shfl_xor(s1, 1, 64); s2 += __shfl_xor(s2, 1, 64);
        s1 += __shfl_xor(s1, 2, 64); s2 += __shfl_xor(s2, 2, 64);
        s1 += __shfl_xor(s1, 4, 64); s2 += __shfl_xor(s2, 4, 64);
        float mu  = s1 * (1.f / D);
        float var = s2 * (1.f / D) - mu * mu;
        float r = rsqrtf(var + 1e-5f);
        uint2 ou;
        ou.x = pk2((o[0]-mu)*r*gl[e0]+bbl[e0],    (o[1]-mu)*r*gl[e0+1]+bbl[e0+1]);
        ou.y = pk2((o[2]-mu)*r*gl[e0+2]+bbl[e0+2],(o[3]-mu)*r*gl[e0+3]+bbl[e0+3]);
        *(uint2*)&Tn[rowo + e0] = ou;
      }
    }
  }
}

// ---------------------------------------------------------------------------
// spatial v3: SQS=33 (stride-32 f32 rows were a 32-way bank conflict).
// ---------------------------------------------------------------------------
__global__ __launch_bounds__(256) void spatial_kernel(
    const bf16* __restrict__ E, const float* __restrict__ WsC,
    const float* __restrict__ bsC, const float* __restrict__ sm_Wo,
    const float* __restrict__ sm_bo, const float* __restrict__ ln_g,
    const float* __restrict__ ln_b, bf16* __restrict__ Sn) {
  int t  = blockIdx.x >> 5;          // B/BG = 32 groups per t
  int bg = blockIdx.x & 31;
  int b0 = bg * BG;
  __shared__ float Wq[D * D], Wk[D * D], Wv[D * D], Wo[D * D];
  __shared__ float bqs[D], bks[D], bvs[D], bos[D], gs[D], bbs[D];
  __shared__ __align__(16) bf16  Es[SR * SES];
  __shared__ float Qs[SR * SQS], Ks[SR * SQS], Vs[SR * SQS];
  int tid = threadIdx.x;

  for (int i = tid; i < D * D; i += 256) {
    Wq[i] = WsC[(size_t)(0 * T + t) * D * D + i];
    Wk[i] = WsC[(size_t)(1 * T + t) * D * D + i];
    Wv[i] = WsC[(size_t)(2 * T + t) * D * D + i];
    Wo[i] = sm_Wo[(size_t)t * D * D + i];
  }
  if (tid < D) {
    bqs[tid] = bsC[(0 * T + t) * D + tid];
    bks[tid] = bsC[(1 * T + t) * D + tid];
    bvs[tid] = bsC[(2 * T + t) * D + tid];
    bos[tid] = sm_bo[t * D + tid];
    gs[tid]  = ln_g[tid];
    bbs[tid] = ln_b[tid];
  }
  if (tid < SR * 4) {
    int r = tid >> 2, p = tid & 3;
    int b = b0 + r / N, n = r % N;
    *(uint4*)&Es[r * SES + p * 8] =
        *(const uint4*)&E[(((size_t)b * T + t) * N + n) * D + p * 8];
  }
  __syncthreads();

#pragma unroll 1
  for (int i = tid; i < SR * D; i += 256) {
    int r = i >> 5, e = i & 31;
    float aq = bqs[e], ak = bks[e], av = bvs[e];
#pragma unroll
    for (int d = 0; d < D; ++d) {
      float x = b2f(Es[r * SES + d]);
      aq += x * Wq[d * D + e];
      ak += x * Wk[d * D + e];
      av += x * Wv[d * D + e];
    }
    Qs[r * SQS + e] = aq;
    Ks[r * SQS + e] = ak;
    Vs[r * SQS + e] = av;
  }
  __syncthreads();

  if (tid < SR * NH) {
    int r = tid >> 1, h = tid & 1, ho = h * FD;
    int kb = (r >= N) ? N : 0;
    float q[FD];
#pragma unroll
    for (int f = 0; f < FD; ++f) q[f] = Qs[r * SQS + ho + f];
    float sc[N];
    float m = -1e30f;
#pragma unroll
    for (int k = 0; k < N; ++k) {
      float sa = 0.f, sb = 0.f;
#pragma unroll
      for (int f = 0; f < FD; f += 2) {
        sa += q[f]     * Ks[(kb + k) * SQS + ho + f];
        sb += q[f + 1] * Ks[(kb + k) * SQS + ho + f + 1];
      }
      float s = (sa + sb) * SCALE;
      sc[k] = s;
      m = fmaxf(m, s);
    }
    float l = 0.f;
#pragma unroll
    for (int k = 0; k < N; ++k) { sc[k] = __expf(sc[k] - m); l += sc[k]; }
    float rl = 1.f / l;
#pragma unroll
    for (int f = 0; f < FD; ++f) {
      float a = 0.f;
#pragma unroll
      for (int k = 0; k < N; ++k) a += sc[k] * Vs[(kb + k) * SQS + ho + f];
      Qs[r * SQS + ho + f] = a * rl;
    }
  }
  __syncthreads();

#pragma unroll 1
  for (int it = 0; it < SR * D / 256; ++it) {
    int i = it * 256 + tid;
    int r = i >> 5, e = i & 31;
    float aa = 0.f, ab = 0.f;
#pragma unroll
    for (int d = 0; d < D; d += 2) {
      aa += Qs[r * SQS + d]     * Wo[d * D + e];
      ab += Qs[r * SQS + d + 1] * Wo[(d + 1) * D + e];
    }
    float o = bos[e] + aa + ab + b2f(Es[r * SES + e]);
    float s1 = o, s2 = o * o;
    s1 += __shfl_xor(s1, 1, 64);  s2 += __shfl_xor(s2, 1, 64);
    s1 += __shfl_xor(s1, 2, 64);  s2 += __shfl_xor(s2, 2, 64);
    s1 += __shfl_xor(s1, 4, 64);  s2 += __shfl_xor(s2, 4, 64);
    s1 += __shfl_xor(s1, 8, 64);  s2 += __shfl_xor(s2, 8, 64);
    s1 += __shfl_xor(s1, 16, 64); s2 += __shfl_xor(s2, 16, 64);
    float mu  = s1 * (1.f / D);
    float var = s2 * (1.f / D) - mu * mu;
    float rr = rsqrtf(var + 1e-5f);
    int b = b0 + r / N, n = r % N;
    Sn[(((size_t)b * T + t) * N + n) * D + e] =
        __float2bfloat16((o - mu) * rr * gs[e] + bbs[e]);
  }
}

// ---------------------------------------------------------------------------
// ff v2: block = 32 rows x 8 lanes/row (grid 240).
// ---------------------------------------------------------------------------
__global__ __launch_bounds__(256) void ff_kernel(
    const bf16* __restrict__ Tn, const bf16* __restrict__ Sn,
    const float* __restrict__ W1, const float* __restrict__ b1,
    const float* __restrict__ W2, const float* __restrict__ b2,
    const float* __restrict__ ln_g, const float* __restrict__ ln_b,
    bf16* __restrict__ E) {
  __shared__ float w1s[D * FF], w2s[FF * D];
  __shared__ float bb1[FF], bb2[D], gs[D], bbs[D];
  __shared__ float tsl[FR][D + 1];
  __shared__ float hl[FR][FF + 1];
  int tid = threadIdx.x;
  int r0 = blockIdx.x * FR;
  for (int i = tid; i < D * FF; i += 256) { w1s[i] = W1[i]; w2s[i] = W2[i]; }
  if (tid < FF) bb1[tid] = b1[tid];
  if (tid < D) { bb2[tid] = b2[tid]; gs[tid] = ln_g[tid]; bbs[tid] = ln_b[tid]; }
  int r = tid >> 3, s = tid & 7;
  {
    const bf16* tp = Tn + ((size_t)(r0 + r)) * D + s * 4;
    const bf16* sp = Sn + ((size_t)(r0 + r)) * D + s * 4;
    uint2 tu = *(const uint2*)tp;
    uint2 su = *(const uint2*)sp;
    tsl[r][s*4+0] = blo(tu.x) + blo(su.x);
    tsl[r][s*4+1] = bhi(tu.x) + bhi(su.x);
    tsl[r][s*4+2] = blo(tu.y) + blo(su.y);
    tsl[r][s*4+3] = bhi(tu.y) + bhi(su.y);
  }
  __syncthreads();
  {
    float hh[8];
#pragma unroll
    for (int j = 0; j < 8; ++j) {
      int jj = s * 8 + j;
      float aa = bb1[jj], ab = 0.f;
#pragma unroll
      for (int d = 0; d < D; d += 2) {
        aa += tsl[r][d]     * w1s[d * FF + jj];
        ab += tsl[r][d + 1] * w1s[(d + 1) * FF + jj];
      }
      hh[j] = fmaxf(aa + ab, 0.f);
    }
#pragma unroll
    for (int j = 0; j < 8; ++j) hl[r][s * 8 + j] = hh[j];
  }
  __syncthreads();
  {
    float x[4];
    float s1 = 0.f, s2 = 0.f;
#pragma unroll
    for (int j4 = 0; j4 < 4; ++j4) {
      int e = s * 4 + j4;
      float aa = 0.f, ab = 0.f;
#pragma unroll
      for (int k = 0; k < FF; k += 2) {
        aa += hl[r][k]     * w2s[k * D + e];
        ab += hl[r][k + 1] * w2s[(k + 1) * D + e];
      }
      float a = bb2[e] + tsl[r][e] + aa + ab;
      x[j4] = a; s1 += a; s2 += a * a;
    }
    s1 += __shfl_xor(s1, 1, 64); s2 += __shfl_xor(s2, 1, 64);
    s1 += __shfl_xor(s1, 2, 64); s2 += __shfl_xor(s2, 2, 64);
    s1 += __shfl_xor(s1, 4, 64); s2 += __shfl_xor(s2, 4, 64);
    float mu  = s1 * (1.f / D);
    float var = s2 * (1.f / D) - mu * mu;
    float rr = rsqrtf(var + 1e-5f);
    int e0 = s * 4;
    uint2 ou;
    ou.x = pk2((x[0]-mu)*rr*gs[e0]+bbs[e0],    (x[1]-mu)*rr*gs[e0+1]+bbs[e0+1]);
    ou.y = pk2((x[2]-mu)*rr*gs[e0+2]+bbs[e0+2],(x[3]-mu)*rr*gs[e0+3]+bbs[e0+3]);
    *(uint2*)&E[((size_t)(r0 + r)) * D + e0] = ou;
  }
}

// ---------------------------------------------------------------------------
// out = E@op_W + op_b + X   (f32 out)
// ---------------------------------------------------------------------------
__global__ __launch_bounds__(256) void out_kernel(
    const bf16* __restrict__ E, const float* __restrict__ op_W,
    const float* __restrict__ op_b, const float* __restrict__ X,
    float* __restrict__ out) {
  int idx = blockIdx.x * 256 + threadIdx.x;
  if (idx >= B * T * N * M) return;
  int m  = idx % M;
  int n  = (idx / M) % N;
  int bt = idx / (M * N);
  float acc = op_b[n * M + m];
  const bf16* e = E + ((size_t)bt * N + n) * D;
#pragma unroll
  for (int d = 0; d < D; ++d) acc += b2f(e[d]) * op_W[(n * D + d) * M + m];
  acc += X[idx];
  out[idx] = acc;
}

// ---------------------------------------------------------------------------
extern "C" void kernel_launch(void* const* d_in, const int* in_sizes, int n_in,
                              void* d_out, int out_size, void* d_ws, size_t ws_size,
                              hipStream_t stream) {
  const float* X     = (const float*)d_in[0];
  const float* pe    = (const float*)d_in[1];
  const float* E_W   = (const float*)d_in[2];
  const float* E_b   = (const float*)d_in[3];
  const float* tq_W  = (const float*)d_in[4];
  const float* tq_b  = (const float*)d_in[5];
  const float* tk_W  = (const float*)d_in[6];
  const float* tk_b  = (const float*)d_in[7];
  const float* tv_W  = (const float*)d_in[8];
  const float* tv_b  = (const float*)d_in[9];
  const float* tm_Wq = (const float*)d_in[10];
  const float* tm_bq = (const float*)d_in[11];
  const float* tm_Wk = (const float*)d_in[12];
  const float* tm_bk = (const float*)d_in[13];
  const float* tm_Wv = (const float*)d_in[14];
  const float* tm_bv = (const float*)d_in[15];
  const float* tm_Wo = (const float*)d_in[16];
  const float* tm_bo = (const float*)d_in[17];
  const float* sq_W  = (const float*)d_in[18];
  const float* sq_b  = (const float*)d_in[19];
  const float* sk_W  = (const float*)d_in[20];
  const float* sk_b  = (const float*)d_in[21];
  const float* sv_W  = (const float*)d_in[22];
  const float* sv_b  = (const float*)d_in[23];
  const float* sm_Wq = (const float*)d_in[24];
  const float* sm_bq = (const float*)d_in[25];
  const float* sm_Wk = (const float*)d_in[26];
  const float* sm_bk = (const float*)d_in[27];
  const float* sm_Wv = (const float*)d_in[28];
  const float* sm_bv = (const float*)d_in[29];
  const float* sm_Wo = (const float*)d_in[30];
  const float* sm_bo = (const float*)d_in[31];
  const float* ff1_W = (const float*)d_in[32];
  const float* ff1_b = (const float*)d_in[33];
  const float* ff2_W = (const float*)d_in[34];
  const float* ff2_b = (const float*)d_in[35];
  const float* ln_g  = (const float*)d_in[36];
  const float* ln_b  = (const float*)d_in[37];
  const float* op_W  = (const float*)d_in[38];
  const float* op_b  = (const float*)d_in[39];
  float* out = (float*)d_out;

  float* WtC = (float*)d_ws;                         // 3*N*D*D
  float* btC = WtC + 3 * N * D * D;                  // 3*N*D
  float* WsC = btC + 3 * N * D;                      // 3*T*D*D
  float* bsC = WsC + 3 * T * D * D;                  // 3*T*D
  size_t act = (size_t)B * T * N * D;
  bf16* Ebuf = (bf16*)(bsC + 3 * T * D);
  bf16* Tn   = Ebuf + act;
  bf16* Qt   = Tn + act;
  bf16* Kt   = Qt + act;
  bf16* Vt   = Kt + act;
  bf16* Sn   = Qt;                                   // alias (safe: serial schedule)

  compose3_kernel<<<3 * N, 256, 0, stream>>>(
      tq_W, tq_b, tm_Wq, tm_bq, tk_W, tk_b, tm_Wk, tm_bk,
      tv_W, tv_b, tm_Wv, tm_bv, WtC, btC, N);
  compose3_kernel<<<3 * T, 256, 0, stream>>>(
      sq_W, sq_b, sm_Wq, sm_bq, sk_W, sk_b, sm_Wk, sm_bk,
      sv_W, sv_b, sm_Wv, sm_bv, WsC, bsC, T);

  embed_kernel<<<(B * T * N * D) / 256, 256, 0, stream>>>(X, pe, E_W, E_b, Ebuf);

  for (int l = 0; l < L; ++l) {
    qkvt_kernel<<<N * QCH, 256, 0, stream>>>(Ebuf, WtC, btC, Qt, Kt, Vt);
    attnt_kernel<<<B * N, 256, 0, stream>>>(Qt, Kt, Vt, Ebuf, tm_Wo, tm_bo, ln_g, ln_b, Tn);
    spatial_kernel<<<T * (B / BG), 256, 0, stream>>>(Ebuf, WsC, bsC, sm_Wo, sm_bo, ln_g, ln_b, Sn);
    ff_kernel<<<(B * T * N) / FR, 256, 0, stream>>>(Tn, Sn, ff1_W, ff1_b, ff2_W, ff2_b, ln_g, ln_b, Ebuf);
  }

  out_kernel<<<(B * T * N * M + 255) / 256, 256, 0, stream>>>(Ebuf, op_W, op_b, X, out);
}

// Round 24
// 753.270 us; speedup vs baseline: 1.2164x; 1.0549x over previous
//
#include <hip/hip_runtime.h>
#include <hip/hip_bf16.h>

typedef __hip_bfloat16 bf16;
typedef __fp16 h2 __attribute__((ext_vector_type(2)));   // matches amdgcn builtin 'V2h'

constexpr int B  = 64, T = 120, N = 24, M = 3, D = 32;
constexpr int NH = 2, FD = 16, FF = 64, L = 3;
constexpr float SCALE = 0.25f;   // 1/sqrt(FD)
constexpr int SK  = 40;          // attnt K/Q f16 LDS stride (80B rows)
constexpr int SKF = 36;          // attnt V/O f32 LDS stride (144B rows)
constexpr int CH2 = 30;          // attnt rows per chunk: 4 x 30 = 120 exactly
constexpr int NJ  = 30;          // max keys per lane slice (120/4)
constexpr int QR  = 64;          // qkvt rows per block (4 lanes/row)
constexpr int QCH = (B * T) / QR;// qkvt chunks = 120
constexpr int BG  = 2;           // spatial batches per block
constexpr int SR  = N * BG;      // spatial rows per block = 48
constexpr int SES = 40;          // Es bf16 stride (80B)
constexpr int SQS = 33;          // spatial Q/K/V f32 stride (no 32-way conflicts)
constexpr int FR  = 32;          // ff rows per block (8 lanes/row)

__device__ __forceinline__ float b2f(bf16 x) { return __bfloat162float(x); }
__device__ __forceinline__ float blo(unsigned u) { return __uint_as_float(u << 16); }
__device__ __forceinline__ float bhi(unsigned u) { return __uint_as_float(u & 0xffff0000u); }
__device__ __forceinline__ unsigned pk2(float a, float b) {
  bf16 x = __float2bfloat16(a), y = __float2bfloat16(b);
  unsigned short ux = *reinterpret_cast<unsigned short*>(&x);
  unsigned short uy = *reinterpret_cast<unsigned short*>(&y);
  return (unsigned)ux | ((unsigned)uy << 16);
}
__device__ __forceinline__ unsigned pkh2(float a, float b) {
  h2 r = __builtin_amdgcn_cvt_pkrtz(a, b);     // v_cvt_pkrtz_f16_f32
  return *reinterpret_cast<unsigned*>(&r);
}
__device__ __forceinline__ h2 u2h(unsigned u) { return *reinterpret_cast<h2*>(&u); }

// ---------------------------------------------------------------------------
// Compose q/k/v chained linears: grid = 3*U blocks.  Wc = W1@W2, bc = b1@W2+b2.
// ---------------------------------------------------------------------------
__global__ __launch_bounds__(256) void compose3_kernel(
    const float* __restrict__ W1q, const float* __restrict__ b1q,
    const float* __restrict__ W2q, const float* __restrict__ b2q,
    const float* __restrict__ W1k, const float* __restrict__ b1k,
    const float* __restrict__ W2k, const float* __restrict__ b2k,
    const float* __restrict__ W1v, const float* __restrict__ b1v,
    const float* __restrict__ W2v, const float* __restrict__ b2v,
    float* __restrict__ Wc, float* __restrict__ bc, int U) {
  int fam = blockIdx.x / U;
  int n   = blockIdx.x % U;
  const float* W1 = (fam == 0) ? W1q : (fam == 1) ? W1k : W1v;
  const float* b1 = (fam == 0) ? b1q : (fam == 1) ? b1k : b1v;
  const float* W2 = (fam == 0) ? W2q : (fam == 1) ? W2k : W2v;
  const float* b2 = (fam == 0) ? b2q : (fam == 1) ? b2k : b2v;
  const float* w1 = W1 + n * D * D;
  const float* w2 = W2 + n * D * D;
  float* wc  = Wc + (size_t)(fam * U + n) * D * D;
  float* bcp = bc + (fam * U + n) * D;
  __shared__ float s1[D * D], s2[D * D];
  for (int i = threadIdx.x; i < D * D; i += 256) { s1[i] = w1[i]; s2[i] = w2[i]; }
  __syncthreads();
  for (int i = threadIdx.x; i < D * D; i += 256) {
    int d = i >> 5, f = i & 31;
    float acc = 0.f;
#pragma unroll
    for (int e = 0; e < D; ++e) acc += s1[d * D + e] * s2[e * D + f];
    wc[i] = acc;
  }
  if (threadIdx.x < D) {
    int f = threadIdx.x;
    float acc = b2[n * D + f];
#pragma unroll
    for (int e = 0; e < D; ++e) acc += b1[n * D + e] * s2[e * D + f];
    bcp[f] = acc;
  }
}

// ---------------------------------------------------------------------------
// E[b,t,n,d] = X@E_W + E_b + pe   (bf16 out)
// ---------------------------------------------------------------------------
__global__ __launch_bounds__(256) void embed_kernel(
    const float* __restrict__ X, const float* __restrict__ pe,
    const float* __restrict__ E_W, const float* __restrict__ E_b,
    bf16* __restrict__ E) {
  int idx = blockIdx.x * 256 + threadIdx.x;
  if (idx >= B * T * N * D) return;
  int d = idx & 31;
  int n = (idx >> 5) % N;
  int bt = idx / (D * N);
  int t = bt % T;
  const float* x = X + bt * (N * M) + n * M;
  float acc = E_b[n * D + d] + pe[t * D + d];
#pragma unroll
  for (int m = 0; m < M; ++m) acc += x[m] * E_W[(n * M + m) * D + d];
  E[idx] = __float2bfloat16(acc);
}

// ---------------------------------------------------------------------------
// qkvt v2: thread = (row, quarter); LDS-staged coalesced loads, one
// contiguous uint4 store per family.  Grid n-major for weight L2 reuse.
// ---------------------------------------------------------------------------
__global__ __launch_bounds__(256) void qkvt_kernel(
    const bf16* __restrict__ E, const float* __restrict__ WtC,
    const float* __restrict__ btC,
    bf16* __restrict__ Qt, bf16* __restrict__ Kt, bf16* __restrict__ Vt) {
  int n     = blockIdx.x / QCH;
  int chunk = blockIdx.x % QCH;
  __shared__ float wsh[3 * D * D];
  __shared__ float bsh[3 * D];
  __shared__ __align__(16) bf16 Es[QR * SES];
  int tid = threadIdx.x;
  for (int i = tid; i < 3 * D * D; i += 256) {
    int fam = i >> 10, idx = i & 1023;
    wsh[i] = WtC[(size_t)(fam * N + n) * D * D + idx];
  }
  if (tid < 3 * D) {
    int fam = tid >> 5, e = tid & 31;
    bsh[tid] = btC[(fam * N + n) * D + e];
  }
  {
    int row = tid >> 2, p = tid & 3;
    const bf16* er = E + ((size_t)(chunk * QR + row) * N + n) * D;
    *(uint4*)&Es[row * SES + p * 8] = *(const uint4*)&er[p * 8];
  }
  __syncthreads();

  int row = tid >> 2, q = tid & 3;
  int grow = chunk * QR + row;          // b*T + t
  int b = grow / T, t = grow % T;
  float x[D];
#pragma unroll
  for (int d = 0; d < D; ++d) x[d] = b2f(Es[row * SES + d]);
  size_t dsto = (((size_t)b * N + n) * T + t) * D + q * 8;
  bf16* dsts[3] = { Qt + dsto, Kt + dsto, Vt + dsto };
#pragma unroll
  for (int fam = 0; fam < 3; ++fam) {
    const float* w  = wsh + fam * D * D;
    const float* bi = bsh + fam * D;
    float a[8];
#pragma unroll
    for (int j = 0; j < 8; ++j) a[j] = bi[q * 8 + j];
#pragma unroll
    for (int d = 0; d < D; ++d) {
      float xv = x[d];
#pragma unroll
      for (int j = 0; j < 8; ++j) a[j] += xv * w[d * D + q * 8 + j];
    }
    uint4 o;
    o.x = pk2(a[0], a[1]); o.y = pk2(a[2], a[3]);
    o.z = pk2(a[4], a[5]); o.w = pk2(a[6], a[7]);
    *(uint4*)dsts[fam] = o;
  }
}

// ---------------------------------------------------------------------------
// attnt v10 = v9 + packed f16 dot-product scores.
//  - K,Q stored f16 in LDS (cvt_pkrtz at staging); score = 8 v_dot2_f32_f16
//    per key (was 16 FMA + 16 unpacks).
//  - V stored f32 (stride 36): PV loses its 8 per-key unpacks.
//  - LDS total unchanged (38,080B) -> 4 blocks/CU kept.
// ---------------------------------------------------------------------------
__global__ __launch_bounds__(256) void attnt_kernel(
    const bf16* __restrict__ Qt, const bf16* __restrict__ Kt,
    const bf16* __restrict__ Vt, const bf16* __restrict__ E,
    const float* __restrict__ tm_Wo, const float* __restrict__ tm_bo,
    const float* __restrict__ ln_g, const float* __restrict__ ln_b,
    bf16* __restrict__ Tn) {
  int bn = blockIdx.x;
  int n  = bn % N, b = bn / N;
  __shared__ __align__(16) __fp16 Klh[T * SK];    // 9600 B
  __shared__ __align__(16) float  Vlf[T * SKF];   // 17280 B
  __shared__ __align__(16) __fp16 Qlh[CH2 * SK];  // 2400 B
  __shared__ __align__(16) float  Ol[CH2 * SKF];  // 4320 B
  __shared__ float Wol[D * D], bol[D], gl[D], bbl[D];
  int tid = threadIdx.x;

  const bf16* Kg = Kt + (size_t)bn * T * D;
  const bf16* Vg = Vt + (size_t)bn * T * D;
  const bf16* Qg = Qt + (size_t)bn * T * D;
  for (int i = tid; i < T * 4; i += 256) {
    int r = i >> 2, p = i & 3;
    uint4 ku = *(const uint4*)&Kg[r * D + p * 8];
    uint4 kh;
    kh.x = pkh2(blo(ku.x), bhi(ku.x));
    kh.y = pkh2(blo(ku.y), bhi(ku.y));
    kh.z = pkh2(blo(ku.z), bhi(ku.z));
    kh.w = pkh2(blo(ku.w), bhi(ku.w));
    *(uint4*)&Klh[r * SK + p * 8] = kh;
    uint4 vu = *(const uint4*)&Vg[r * D + p * 8];
    *(float4*)&Vlf[r * SKF + p * 8]     = make_float4(blo(vu.x), bhi(vu.x), blo(vu.y), bhi(vu.y));
    *(float4*)&Vlf[r * SKF + p * 8 + 4] = make_float4(blo(vu.z), bhi(vu.z), blo(vu.w), bhi(vu.w));
  }
  for (int i = tid; i < D * D; i += 256) Wol[i] = tm_Wo[(size_t)n * D * D + i];
  if (tid < D) {
    bol[tid] = tm_bo[n * D + tid];
    gl[tid]  = ln_g[tid];
    bbl[tid] = ln_b[tid];
  }
  __syncthreads();

#pragma unroll 1
  for (int c = 0; c < 4; ++c) {
    // stage this chunk's Q (30 rows, bf16 -> f16); races only with prior O-proj
    if (tid < CH2 * 4) {
      int r = tid >> 2, p = tid & 3;
      uint4 qu = *(const uint4*)&Qg[(CH2 * c + r) * D + p * 8];
      uint4 qh;
      qh.x = pkh2(blo(qu.x), bhi(qu.x));
      qh.y = pkh2(blo(qu.y), bhi(qu.y));
      qh.z = pkh2(blo(qu.z), bhi(qu.z));
      qh.w = pkh2(blo(qu.w), bhi(qu.w));
      *(uint4*)&Qlh[r * SK + p * 8] = qh;
    }
    __syncthreads();   // Qlh ready; prior O-proj done -> Ol safe to overwrite

    // ---- attention: task = (row, head), 4 lanes per task ----
    {
      int task = tid >> 2, sl = tid & 3;
      if (task < 2 * CH2) {
        int rl = task >> 1, h = task & 1, ho = h * FD;
        int rg = CH2 * c + rl;
        uint4 q0 = *(const uint4*)&Qlh[rl * SK + ho];
        uint4 q1 = *(const uint4*)&Qlh[rl * SK + ho + 8];
        unsigned qh[8] = { q0.x, q0.y, q0.z, q0.w, q1.x, q1.y, q1.z, q1.w };

        float sc[NJ];
        float mx = -3e38f;
#pragma unroll
        for (int j = 0; j < NJ; ++j) {
          int k = 4 * j + sl;
          sc[j] = -3e38f;
          if (k <= rg) {
            const uint4 ka = *(const uint4*)&Klh[k * SK + ho];
            const uint4 kb = *(const uint4*)&Klh[k * SK + ho + 8];
            float s0 = __builtin_amdgcn_fdot2(u2h(qh[0]), u2h(ka.x), 0.f, false);
            float s1 = __builtin_amdgcn_fdot2(u2h(qh[1]), u2h(ka.y), 0.f, false);
            float s2 = __builtin_amdgcn_fdot2(u2h(qh[2]), u2h(ka.z), 0.f, false);
            float s3 = __builtin_amdgcn_fdot2(u2h(qh[3]), u2h(ka.w), 0.f, false);
            s0 = __builtin_amdgcn_fdot2(u2h(qh[4]), u2h(kb.x), s0, false);
            s1 = __builtin_amdgcn_fdot2(u2h(qh[5]), u2h(kb.y), s1, false);
            s2 = __builtin_amdgcn_fdot2(u2h(qh[6]), u2h(kb.z), s2, false);
            s3 = __builtin_amdgcn_fdot2(u2h(qh[7]), u2h(kb.w), s3, false);
            float s = ((s0 + s1) + (s2 + s3)) * SCALE;
            sc[j] = s;
            mx = fmaxf(mx, s);
          }
        }
        mx = fmaxf(mx, __shfl_xor(mx, 1, 64));
        mx = fmaxf(mx, __shfl_xor(mx, 2, 64));
        float l = 0.f;
#pragma unroll
        for (int j = 0; j < NJ; ++j) {
          sc[j] = __expf(sc[j] - mx);   // invalid slots: exp(-inf) = 0
          l += sc[j];
        }
        l += __shfl_xor(l, 1, 64);
        l += __shfl_xor(l, 2, 64);
        float rli = 1.f / l;

        float acc[16];
#pragma unroll
        for (int f = 0; f < 16; ++f) acc[f] = 0.f;
#pragma unroll
        for (int j = 0; j < NJ; ++j) {
          int k = 4 * j + sl;
          if (k <= rg) {
            float p = sc[j];
            const float4 v0 = *(const float4*)&Vlf[k * SKF + ho];
            const float4 v1 = *(const float4*)&Vlf[k * SKF + ho + 4];
            const float4 v2 = *(const float4*)&Vlf[k * SKF + ho + 8];
            const float4 v3 = *(const float4*)&Vlf[k * SKF + ho + 12];
            acc[0]  += p * v0.x; acc[1]  += p * v0.y;
            acc[2]  += p * v0.z; acc[3]  += p * v0.w;
            acc[4]  += p * v1.x; acc[5]  += p * v1.y;
            acc[6]  += p * v1.z; acc[7]  += p * v1.w;
            acc[8]  += p * v2.x; acc[9]  += p * v2.y;
            acc[10] += p * v2.z; acc[11] += p * v2.w;
            acc[12] += p * v3.x; acc[13] += p * v3.y;
            acc[14] += p * v3.z; acc[15] += p * v3.w;
          }
        }
#pragma unroll
        for (int f = 0; f < 16; ++f) {
          acc[f] += __shfl_xor(acc[f], 1, 64);
          acc[f] += __shfl_xor(acc[f], 2, 64);
        }
        if (sl == 0) {
#pragma unroll
          for (int f = 0; f < 16; ++f) Ol[rl * SKF + ho + f] = acc[f] * rli;
        }
      }
    }
    __syncthreads();

    // ---- O-proj + residual + LN: thread = (row, e-quad) ----
    {
      int rl = tid >> 3, q = tid & 7, e0 = q * 4;
      if (rl < CH2) {
        int rg = CH2 * c + rl;
        size_t rowo = ((size_t)(b * T + rg) * N + n) * D;
        uint2 eu = *(const uint2*)&E[rowo + e0];
        float res[4] = { blo(eu.x), bhi(eu.x), blo(eu.y), bhi(eu.y) };
        float o[4], s1 = 0.f, s2 = 0.f;
#pragma unroll
        for (int j = 0; j < 4; ++j) {
          int e = e0 + j;
          float aa = 0.f, ab = 0.f;
#pragma unroll
          for (int d = 0; d < D; d += 2) {
            aa += Ol[rl * SKF + d]     * Wol[d * D + e];
            ab += Ol[rl * SKF + d + 1] * Wol[(d + 1) * D + e];
          }
          float a = bol[e] + aa + ab + res[j];
          o[j] = a; s1 += a; s2 += a * a;
        }
        s1 += __shfl_xor(s1, 1, 64); s2 += __shfl_xor(s2, 1, 64);
        s1 += __shfl_xor(s1, 2, 64); s2 += __shfl_xor(s2, 2, 64);
        s1 += __shfl_xor(s1, 4, 64); s2 += __shfl_xor(s2, 4, 64);
        float mu  = s1 * (1.f / D);
        float var = s2 * (1.f / D) - mu * mu;
        float r = rsqrtf(var + 1e-5f);
        uint2 ou;
        ou.x = pk2((o[0]-mu)*r*gl[e0]+bbl[e0],    (o[1]-mu)*r*gl[e0+1]+bbl[e0+1]);
        ou.y = pk2((o[2]-mu)*r*gl[e0+2]+bbl[e0+2],(o[3]-mu)*r*gl[e0+3]+bbl[e0+3]);
        *(uint2*)&Tn[rowo + e0] = ou;
      }
    }
  }
}

// ---------------------------------------------------------------------------
// spatial v3: SQS=33 (stride-32 f32 rows were a 32-way bank conflict).
// ---------------------------------------------------------------------------
__global__ __launch_bounds__(256) void spatial_kernel(
    const bf16* __restrict__ E, const float* __restrict__ WsC,
    const float* __restrict__ bsC, const float* __restrict__ sm_Wo,
    const float* __restrict__ sm_bo, const float* __restrict__ ln_g,
    const float* __restrict__ ln_b, bf16* __restrict__ Sn) {
  int t  = blockIdx.x >> 5;          // B/BG = 32 groups per t
  int bg = blockIdx.x & 31;
  int b0 = bg * BG;
  __shared__ float Wq[D * D], Wk[D * D], Wv[D * D], Wo[D * D];
  __shared__ float bqs[D], bks[D], bvs[D], bos[D], gs[D], bbs[D];
  __shared__ __align__(16) bf16  Es[SR * SES];
  __shared__ float Qs[SR * SQS], Ks[SR * SQS], Vs[SR * SQS];
  int tid = threadIdx.x;

  for (int i = tid; i < D * D; i += 256) {
    Wq[i] = WsC[(size_t)(0 * T + t) * D * D + i];
    Wk[i] = WsC[(size_t)(1 * T + t) * D * D + i];
    Wv[i] = WsC[(size_t)(2 * T + t) * D * D + i];
    Wo[i] = sm_Wo[(size_t)t * D * D + i];
  }
  if (tid < D) {
    bqs[tid] = bsC[(0 * T + t) * D + tid];
    bks[tid] = bsC[(1 * T + t) * D + tid];
    bvs[tid] = bsC[(2 * T + t) * D + tid];
    bos[tid] = sm_bo[t * D + tid];
    gs[tid]  = ln_g[tid];
    bbs[tid] = ln_b[tid];
  }
  if (tid < SR * 4) {
    int r = tid >> 2, p = tid & 3;
    int b = b0 + r / N, n = r % N;
    *(uint4*)&Es[r * SES + p * 8] =
        *(const uint4*)&E[(((size_t)b * T + t) * N + n) * D + p * 8];
  }
  __syncthreads();

#pragma unroll 1
  for (int i = tid; i < SR * D; i += 256) {
    int r = i >> 5, e = i & 31;
    float aq = bqs[e], ak = bks[e], av = bvs[e];
#pragma unroll
    for (int d = 0; d < D; ++d) {
      float x = b2f(Es[r * SES + d]);
      aq += x * Wq[d * D + e];
      ak += x * Wk[d * D + e];
      av += x * Wv[d * D + e];
    }
    Qs[r * SQS + e] = aq;
    Ks[r * SQS + e] = ak;
    Vs[r * SQS + e] = av;
  }
  __syncthreads();

  if (tid < SR * NH) {
    int r = tid >> 1, h = tid & 1, ho = h * FD;
    int kb = (r >= N) ? N : 0;
    float q[FD];
#pragma unroll
    for (int f = 0; f < FD; ++f) q[f] = Qs[r * SQS + ho + f];
    float sc[N];
    float m = -1e30f;
#pragma unroll
    for (int k = 0; k < N; ++k) {
      float sa = 0.f, sb = 0.f;
#pragma unroll
      for (int f = 0; f < FD; f += 2) {
        sa += q[f]     * Ks[(kb + k) * SQS + ho + f];
        sb += q[f + 1] * Ks[(kb + k) * SQS + ho + f + 1];
      }
      float s = (sa + sb) * SCALE;
      sc[k] = s;
      m = fmaxf(m, s);
    }
    float l = 0.f;
#pragma unroll
    for (int k = 0; k < N; ++k) { sc[k] = __expf(sc[k] - m); l += sc[k]; }
    float rl = 1.f / l;
#pragma unroll
    for (int f = 0; f < FD; ++f) {
      float a = 0.f;
#pragma unroll
      for (int k = 0; k < N; ++k) a += sc[k] * Vs[(kb + k) * SQS + ho + f];
      Qs[r * SQS + ho + f] = a * rl;
    }
  }
  __syncthreads();

#pragma unroll 1
  for (int it = 0; it < SR * D / 256; ++it) {
    int i = it * 256 + tid;
    int r = i >> 5, e = i & 31;
    float aa = 0.f, ab = 0.f;
#pragma unroll
    for (int d = 0; d < D; d += 2) {
      aa += Qs[r * SQS + d]     * Wo[d * D + e];
      ab += Qs[r * SQS + d + 1] * Wo[(d + 1) * D + e];
    }
    float o = bos[e] + aa + ab + b2f(Es[r * SES + e]);
    float s1 = o, s2 = o * o;
    s1 += __shfl_xor(s1, 1, 64);  s2 += __shfl_xor(s2, 1, 64);
    s1 += __shfl_xor(s1, 2, 64);  s2 += __shfl_xor(s2, 2, 64);
    s1 += __shfl_xor(s1, 4, 64);  s2 += __shfl_xor(s2, 4, 64);
    s1 += __shfl_xor(s1, 8, 64);  s2 += __shfl_xor(s2, 8, 64);
    s1 += __shfl_xor(s1, 16, 64); s2 += __shfl_xor(s2, 16, 64);
    float mu  = s1 * (1.f / D);
    float var = s2 * (1.f / D) - mu * mu;
    float rr = rsqrtf(var + 1e-5f);
    int b = b0 + r / N, n = r % N;
    Sn[(((size_t)b * T + t) * N + n) * D + e] =
        __float2bfloat16((o - mu) * rr * gs[e] + bbs[e]);
  }
}

// ---------------------------------------------------------------------------
// ff v2: block = 32 rows x 8 lanes/row (grid 240).
// ---------------------------------------------------------------------------
__global__ __launch_bounds__(256) void ff_kernel(
    const bf16* __restrict__ Tn, const bf16* __restrict__ Sn,
    const float* __restrict__ W1, const float* __restrict__ b1,
    const float* __restrict__ W2, const float* __restrict__ b2,
    const float* __restrict__ ln_g, const float* __restrict__ ln_b,
    bf16* __restrict__ E) {
  __shared__ float w1s[D * FF], w2s[FF * D];
  __shared__ float bb1[FF], bb2[D], gs[D], bbs[D];
  __shared__ float tsl[FR][D + 1];
  __shared__ float hl[FR][FF + 1];
  int tid = threadIdx.x;
  int r0 = blockIdx.x * FR;
  for (int i = tid; i < D * FF; i += 256) { w1s[i] = W1[i]; w2s[i] = W2[i]; }
  if (tid < FF) bb1[tid] = b1[tid];
  if (tid < D) { bb2[tid] = b2[tid]; gs[tid] = ln_g[tid]; bbs[tid] = ln_b[tid]; }
  int r = tid >> 3, s = tid & 7;
  {
    const bf16* tp = Tn + ((size_t)(r0 + r)) * D + s * 4;
    const bf16* sp = Sn + ((size_t)(r0 + r)) * D + s * 4;
    uint2 tu = *(const uint2*)tp;
    uint2 su = *(const uint2*)sp;
    tsl[r][s*4+0] = blo(tu.x) + blo(su.x);
    tsl[r][s*4+1] = bhi(tu.x) + bhi(su.x);
    tsl[r][s*4+2] = blo(tu.y) + blo(su.y);
    tsl[r][s*4+3] = bhi(tu.y) + bhi(su.y);
  }
  __syncthreads();
  {
    float hh[8];
#pragma unroll
    for (int j = 0; j < 8; ++j) {
      int jj = s * 8 + j;
      float aa = bb1[jj], ab = 0.f;
#pragma unroll
      for (int d = 0; d < D; d += 2) {
        aa += tsl[r][d]     * w1s[d * FF + jj];
        ab += tsl[r][d + 1] * w1s[(d + 1) * FF + jj];
      }
      hh[j] = fmaxf(aa + ab, 0.f);
    }
#pragma unroll
    for (int j = 0; j < 8; ++j) hl[r][s * 8 + j] = hh[j];
  }
  __syncthreads();
  {
    float x[4];
    float s1 = 0.f, s2 = 0.f;
#pragma unroll
    for (int j4 = 0; j4 < 4; ++j4) {
      int e = s * 4 + j4;
      float aa = 0.f, ab = 0.f;
#pragma unroll
      for (int k = 0; k < FF; k += 2) {
        aa += hl[r][k]     * w2s[k * D + e];
        ab += hl[r][k + 1] * w2s[(k + 1) * D + e];
      }
      float a = bb2[e] + tsl[r][e] + aa + ab;
      x[j4] = a; s1 += a; s2 += a * a;
    }
    s1 += __shfl_xor(s1, 1, 64); s2 += __shfl_xor(s2, 1, 64);
    s1 += __shfl_xor(s1, 2, 64); s2 += __shfl_xor(s2, 2, 64);
    s1 += __shfl_xor(s1, 4, 64); s2 += __shfl_xor(s2, 4, 64);
    float mu  = s1 * (1.f / D);
    float var = s2 * (1.f / D) - mu * mu;
    float rr = rsqrtf(var + 1e-5f);
    int e0 = s * 4;
    uint2 ou;
    ou.x = pk2((x[0]-mu)*rr*gs[e0]+bbs[e0],    (x[1]-mu)*rr*gs[e0+1]+bbs[e0+1]);
    ou.y = pk2((x[2]-mu)*rr*gs[e0+2]+bbs[e0+2],(x[3]-mu)*rr*gs[e0+3]+bbs[e0+3]);
    *(uint2*)&E[((size_t)(r0 + r)) * D + e0] = ou;
  }
}

// ---------------------------------------------------------------------------
// out = E@op_W + op_b + X   (f32 out)
// ---------------------------------------------------------------------------
__global__ __launch_bounds__(256) void out_kernel(
    const bf16* __restrict__ E, const float* __restrict__ op_W,
    const float* __restrict__ op_b, const float* __restrict__ X,
    float* __restrict__ out) {
  int idx = blockIdx.x * 256 + threadIdx.x;
  if (idx >= B * T * N * M) return;
  int m  = idx % M;
  int n  = (idx / M) % N;
  int bt = idx / (M * N);
  float acc = op_b[n * M + m];
  const bf16* e = E + ((size_t)bt * N + n) * D;
#pragma unroll
  for (int d = 0; d < D; ++d) acc += b2f(e[d]) * op_W[(n * D + d) * M + m];
  acc += X[idx];
  out[idx] = acc;
}

// ---------------------------------------------------------------------------
extern "C" void kernel_launch(void* const* d_in, const int* in_sizes, int n_in,
                              void* d_out, int out_size, void* d_ws, size_t ws_size,
                              hipStream_t stream) {
  const float* X     = (const float*)d_in[0];
  const float* pe    = (const float*)d_in[1];
  const float* E_W   = (const float*)d_in[2];
  const float* E_b   = (const float*)d_in[3];
  const float* tq_W  = (const float*)d_in[4];
  const float* tq_b  = (const float*)d_in[5];
  const float* tk_W  = (const float*)d_in[6];
  const float* tk_b  = (const float*)d_in[7];
  const float* tv_W  = (const float*)d_in[8];
  const float* tv_b  = (const float*)d_in[9];
  const float* tm_Wq = (const float*)d_in[10];
  const float* tm_bq = (const float*)d_in[11];
  const float* tm_Wk = (const float*)d_in[12];
  const float* tm_bk = (const float*)d_in[13];
  const float* tm_Wv = (const float*)d_in[14];
  const float* tm_bv = (const float*)d_in[15];
  const float* tm_Wo = (const float*)d_in[16];
  const float* tm_bo = (const float*)d_in[17];
  const float* sq_W  = (const float*)d_in[18];
  const float* sq_b  = (const float*)d_in[19];
  const float* sk_W  = (const float*)d_in[20];
  const float* sk_b  = (const float*)d_in[21];
  const float* sv_W  = (const float*)d_in[22];
  const float* sv_b  = (const float*)d_in[23];
  const float* sm_Wq = (const float*)d_in[24];
  const float* sm_bq = (const float*)d_in[25];
  const float* sm_Wk = (const float*)d_in[26];
  const float* sm_bk = (const float*)d_in[27];
  const float* sm_Wv = (const float*)d_in[28];
  const float* sm_bv = (const float*)d_in[29];
  const float* sm_Wo = (const float*)d_in[30];
  const float* sm_bo = (const float*)d_in[31];
  const float* ff1_W = (const float*)d_in[32];
  const float* ff1_b = (const float*)d_in[33];
  const float* ff2_W = (const float*)d_in[34];
  const float* ff2_b = (const float*)d_in[35];
  const float* ln_g  = (const float*)d_in[36];
  const float* ln_b  = (const float*)d_in[37];
  const float* op_W  = (const float*)d_in[38];
  const float* op_b  = (const float*)d_in[39];
  float* out = (float*)d_out;

  float* WtC = (float*)d_ws;                         // 3*N*D*D
  float* btC = WtC + 3 * N * D * D;                  // 3*N*D
  float* WsC = btC + 3 * N * D;                      // 3*T*D*D
  float* bsC = WsC + 3 * T * D * D;                  // 3*T*D
  size_t act = (size_t)B * T * N * D;
  bf16* Ebuf = (bf16*)(bsC + 3 * T * D);
  bf16* Tn   = Ebuf + act;
  bf16* Qt   = Tn + act;
  bf16* Kt   = Qt + act;
  bf16* Vt   = Kt + act;
  bf16* Sn   = Qt;                                   // alias (safe: serial schedule)

  compose3_kernel<<<3 * N, 256, 0, stream>>>(
      tq_W, tq_b, tm_Wq, tm_bq, tk_W, tk_b, tm_Wk, tm_bk,
      tv_W, tv_b, tm_Wv, tm_bv, WtC, btC, N);
  compose3_kernel<<<3 * T, 256, 0, stream>>>(
      sq_W, sq_b, sm_Wq, sm_bq, sk_W, sk_b, sm_Wk, sm_bk,
      sv_W, sv_b, sm_Wv, sm_bv, WsC, bsC, T);

  embed_kernel<<<(B * T * N * D) / 256, 256, 0, stream>>>(X, pe, E_W, E_b, Ebuf);

  for (int l = 0; l < L; ++l) {
    qkvt_kernel<<<N * QCH, 256, 0, stream>>>(Ebuf, WtC, btC, Qt, Kt, Vt);
    attnt_kernel<<<B * N, 256, 0, stream>>>(Qt, Kt, Vt, Ebuf, tm_Wo, tm_bo, ln_g, ln_b, Tn);
    spatial_kernel<<<T * (B / BG), 256, 0, stream>>>(Ebuf, WsC, bsC, sm_Wo, sm_bo, ln_g, ln_b, Sn);
    ff_kernel<<<(B * T * N) / FR, 256, 0, stream>>>(Tn, Sn, ff1_W, ff1_b, ff2_W, ff2_b, ln_g, ln_b, Ebuf);
  }

  out_kernel<<<(B * T * N * M + 255) / 256, 256, 0, stream>>>(Ebuf, op_W, op_b, X, out);
}

// Round 25
// 750.532 us; speedup vs baseline: 1.2208x; 1.0036x over previous
//
#include <hip/hip_runtime.h>
#include <hip/hip_bf16.h>

typedef __hip_bfloat16 bf16;
typedef __fp16 h2 __attribute__((ext_vector_type(2)));   // matches amdgcn builtin 'V2h'

constexpr int B  = 64, T = 120, N = 24, M = 3, D = 32;
constexpr int NH = 2, FD = 16, FF = 64, L = 3;
constexpr float SCALE = 0.25f;   // 1/sqrt(FD)
constexpr int SK  = 40;          // attnt K/Q f16 LDS stride (80B rows)
constexpr int SKF = 36;          // attnt V/O f32 LDS stride (144B rows)
constexpr int CH2 = 30;          // attnt rows per chunk: 4 x 30 = 120 exactly
constexpr int NJ  = 30;          // max keys per lane slice (120/4)
constexpr int QR  = 64;          // qkvt rows per block (4 lanes/row)
constexpr int QCH = (B * T) / QR;// qkvt chunks = 120
constexpr int BG  = 2;           // spatial batches per block
constexpr int SR  = N * BG;      // spatial rows per block = 48
constexpr int SES = 40;          // Es bf16 stride (qkvt, 80B)
constexpr int SEH = 20;          // spatial packed-f16 Es stride (uints, 80B)
constexpr int SQS = 33;          // spatial Q/K/V f32 stride (no 32-way conflicts)
constexpr int FR  = 32;          // ff rows per block (8 lanes/row)

__device__ __forceinline__ float b2f(bf16 x) { return __bfloat162float(x); }
__device__ __forceinline__ float blo(unsigned u) { return __uint_as_float(u << 16); }
__device__ __forceinline__ float bhi(unsigned u) { return __uint_as_float(u & 0xffff0000u); }
__device__ __forceinline__ unsigned pk2(float a, float b) {
  bf16 x = __float2bfloat16(a), y = __float2bfloat16(b);
  unsigned short ux = *reinterpret_cast<unsigned short*>(&x);
  unsigned short uy = *reinterpret_cast<unsigned short*>(&y);
  return (unsigned)ux | ((unsigned)uy << 16);
}
__device__ __forceinline__ unsigned pkh2(float a, float b) {
  h2 r = __builtin_amdgcn_cvt_pkrtz(a, b);     // v_cvt_pkrtz_f16_f32
  return *reinterpret_cast<unsigned*>(&r);
}
__device__ __forceinline__ h2 u2h(unsigned u) { return *reinterpret_cast<h2*>(&u); }

// ---------------------------------------------------------------------------
// Compose q/k/v chained linears: grid = 3*U blocks.  Wc = W1@W2, bc = b1@W2+b2.
// ---------------------------------------------------------------------------
__global__ __launch_bounds__(256) void compose3_kernel(
    const float* __restrict__ W1q, const float* __restrict__ b1q,
    const float* __restrict__ W2q, const float* __restrict__ b2q,
    const float* __restrict__ W1k, const float* __restrict__ b1k,
    const float* __restrict__ W2k, const float* __restrict__ b2k,
    const float* __restrict__ W1v, const float* __restrict__ b1v,
    const float* __restrict__ W2v, const float* __restrict__ b2v,
    float* __restrict__ Wc, float* __restrict__ bc, int U) {
  int fam = blockIdx.x / U;
  int n   = blockIdx.x % U;
  const float* W1 = (fam == 0) ? W1q : (fam == 1) ? W1k : W1v;
  const float* b1 = (fam == 0) ? b1q : (fam == 1) ? b1k : b1v;
  const float* W2 = (fam == 0) ? W2q : (fam == 1) ? W2k : W2v;
  const float* b2 = (fam == 0) ? b2q : (fam == 1) ? b2k : b2v;
  const float* w1 = W1 + n * D * D;
  const float* w2 = W2 + n * D * D;
  float* wc  = Wc + (size_t)(fam * U + n) * D * D;
  float* bcp = bc + (fam * U + n) * D;
  __shared__ float s1[D * D], s2[D * D];
  for (int i = threadIdx.x; i < D * D; i += 256) { s1[i] = w1[i]; s2[i] = w2[i]; }
  __syncthreads();
  for (int i = threadIdx.x; i < D * D; i += 256) {
    int d = i >> 5, f = i & 31;
    float acc = 0.f;
#pragma unroll
    for (int e = 0; e < D; ++e) acc += s1[d * D + e] * s2[e * D + f];
    wc[i] = acc;
  }
  if (threadIdx.x < D) {
    int f = threadIdx.x;
    float acc = b2[n * D + f];
#pragma unroll
    for (int e = 0; e < D; ++e) acc += b1[n * D + e] * s2[e * D + f];
    bcp[f] = acc;
  }
}

// ---------------------------------------------------------------------------
// E[b,t,n,d] = X@E_W + E_b + pe   (bf16 out)
// ---------------------------------------------------------------------------
__global__ __launch_bounds__(256) void embed_kernel(
    const float* __restrict__ X, const float* __restrict__ pe,
    const float* __restrict__ E_W, const float* __restrict__ E_b,
    bf16* __restrict__ E) {
  int idx = blockIdx.x * 256 + threadIdx.x;
  if (idx >= B * T * N * D) return;
  int d = idx & 31;
  int n = (idx >> 5) % N;
  int bt = idx / (D * N);
  int t = bt % T;
  const float* x = X + bt * (N * M) + n * M;
  float acc = E_b[n * D + d] + pe[t * D + d];
#pragma unroll
  for (int m = 0; m < M; ++m) acc += x[m] * E_W[(n * M + m) * D + d];
  E[idx] = __float2bfloat16(acc);
}

// ---------------------------------------------------------------------------
// qkvt v2: thread = (row, quarter); LDS-staged coalesced loads, one
// contiguous uint4 store per family.  Grid n-major for weight L2 reuse.
// ---------------------------------------------------------------------------
__global__ __launch_bounds__(256) void qkvt_kernel(
    const bf16* __restrict__ E, const float* __restrict__ WtC,
    const float* __restrict__ btC,
    bf16* __restrict__ Qt, bf16* __restrict__ Kt, bf16* __restrict__ Vt) {
  int n     = blockIdx.x / QCH;
  int chunk = blockIdx.x % QCH;
  __shared__ float wsh[3 * D * D];
  __shared__ float bsh[3 * D];
  __shared__ __align__(16) bf16 Es[QR * SES];
  int tid = threadIdx.x;
  for (int i = tid; i < 3 * D * D; i += 256) {
    int fam = i >> 10, idx = i & 1023;
    wsh[i] = WtC[(size_t)(fam * N + n) * D * D + idx];
  }
  if (tid < 3 * D) {
    int fam = tid >> 5, e = tid & 31;
    bsh[tid] = btC[(fam * N + n) * D + e];
  }
  {
    int row = tid >> 2, p = tid & 3;
    const bf16* er = E + ((size_t)(chunk * QR + row) * N + n) * D;
    *(uint4*)&Es[row * SES + p * 8] = *(const uint4*)&er[p * 8];
  }
  __syncthreads();

  int row = tid >> 2, q = tid & 3;
  int grow = chunk * QR + row;          // b*T + t
  int b = grow / T, t = grow % T;
  float x[D];
#pragma unroll
  for (int d = 0; d < D; ++d) x[d] = b2f(Es[row * SES + d]);
  size_t dsto = (((size_t)b * N + n) * T + t) * D + q * 8;
  bf16* dsts[3] = { Qt + dsto, Kt + dsto, Vt + dsto };
#pragma unroll
  for (int fam = 0; fam < 3; ++fam) {
    const float* w  = wsh + fam * D * D;
    const float* bi = bsh + fam * D;
    float a[8];
#pragma unroll
    for (int j = 0; j < 8; ++j) a[j] = bi[q * 8 + j];
#pragma unroll
    for (int d = 0; d < D; ++d) {
      float xv = x[d];
#pragma unroll
      for (int j = 0; j < 8; ++j) a[j] += xv * w[d * D + q * 8 + j];
    }
    uint4 o;
    o.x = pk2(a[0], a[1]); o.y = pk2(a[2], a[3]);
    o.z = pk2(a[4], a[5]); o.w = pk2(a[6], a[7]);
    *(uint4*)dsts[fam] = o;
  }
}

// ---------------------------------------------------------------------------
// attnt v10: packed f16 dot-product scores (measured R24: 100.7us, was 118).
// ---------------------------------------------------------------------------
__global__ __launch_bounds__(256) void attnt_kernel(
    const bf16* __restrict__ Qt, const bf16* __restrict__ Kt,
    const bf16* __restrict__ Vt, const bf16* __restrict__ E,
    const float* __restrict__ tm_Wo, const float* __restrict__ tm_bo,
    const float* __restrict__ ln_g, const float* __restrict__ ln_b,
    bf16* __restrict__ Tn) {
  int bn = blockIdx.x;
  int n  = bn % N, b = bn / N;
  __shared__ __align__(16) __fp16 Klh[T * SK];    // 9600 B
  __shared__ __align__(16) float  Vlf[T * SKF];   // 17280 B
  __shared__ __align__(16) __fp16 Qlh[CH2 * SK];  // 2400 B
  __shared__ __align__(16) float  Ol[CH2 * SKF];  // 4320 B
  __shared__ float Wol[D * D], bol[D], gl[D], bbl[D];
  int tid = threadIdx.x;

  const bf16* Kg = Kt + (size_t)bn * T * D;
  const bf16* Vg = Vt + (size_t)bn * T * D;
  const bf16* Qg = Qt + (size_t)bn * T * D;
  for (int i = tid; i < T * 4; i += 256) {
    int r = i >> 2, p = i & 3;
    uint4 ku = *(const uint4*)&Kg[r * D + p * 8];
    uint4 kh;
    kh.x = pkh2(blo(ku.x), bhi(ku.x));
    kh.y = pkh2(blo(ku.y), bhi(ku.y));
    kh.z = pkh2(blo(ku.z), bhi(ku.z));
    kh.w = pkh2(blo(ku.w), bhi(ku.w));
    *(uint4*)&Klh[r * SK + p * 8] = kh;
    uint4 vu = *(const uint4*)&Vg[r * D + p * 8];
    *(float4*)&Vlf[r * SKF + p * 8]     = make_float4(blo(vu.x), bhi(vu.x), blo(vu.y), bhi(vu.y));
    *(float4*)&Vlf[r * SKF + p * 8 + 4] = make_float4(blo(vu.z), bhi(vu.z), blo(vu.w), bhi(vu.w));
  }
  for (int i = tid; i < D * D; i += 256) Wol[i] = tm_Wo[(size_t)n * D * D + i];
  if (tid < D) {
    bol[tid] = tm_bo[n * D + tid];
    gl[tid]  = ln_g[tid];
    bbl[tid] = ln_b[tid];
  }
  __syncthreads();

#pragma unroll 1
  for (int c = 0; c < 4; ++c) {
    if (tid < CH2 * 4) {
      int r = tid >> 2, p = tid & 3;
      uint4 qu = *(const uint4*)&Qg[(CH2 * c + r) * D + p * 8];
      uint4 qh;
      qh.x = pkh2(blo(qu.x), bhi(qu.x));
      qh.y = pkh2(blo(qu.y), bhi(qu.y));
      qh.z = pkh2(blo(qu.z), bhi(qu.z));
      qh.w = pkh2(blo(qu.w), bhi(qu.w));
      *(uint4*)&Qlh[r * SK + p * 8] = qh;
    }
    __syncthreads();   // Qlh ready; prior O-proj done -> Ol safe to overwrite

    {
      int task = tid >> 2, sl = tid & 3;
      if (task < 2 * CH2) {
        int rl = task >> 1, h = task & 1, ho = h * FD;
        int rg = CH2 * c + rl;
        uint4 q0 = *(const uint4*)&Qlh[rl * SK + ho];
        uint4 q1 = *(const uint4*)&Qlh[rl * SK + ho + 8];
        unsigned qh[8] = { q0.x, q0.y, q0.z, q0.w, q1.x, q1.y, q1.z, q1.w };

        float sc[NJ];
        float mx = -3e38f;
#pragma unroll
        for (int j = 0; j < NJ; ++j) {
          int k = 4 * j + sl;
          sc[j] = -3e38f;
          if (k <= rg) {
            const uint4 ka = *(const uint4*)&Klh[k * SK + ho];
            const uint4 kb = *(const uint4*)&Klh[k * SK + ho + 8];
            float s0 = __builtin_amdgcn_fdot2(u2h(qh[0]), u2h(ka.x), 0.f, false);
            float s1 = __builtin_amdgcn_fdot2(u2h(qh[1]), u2h(ka.y), 0.f, false);
            float s2 = __builtin_amdgcn_fdot2(u2h(qh[2]), u2h(ka.z), 0.f, false);
            float s3 = __builtin_amdgcn_fdot2(u2h(qh[3]), u2h(ka.w), 0.f, false);
            s0 = __builtin_amdgcn_fdot2(u2h(qh[4]), u2h(kb.x), s0, false);
            s1 = __builtin_amdgcn_fdot2(u2h(qh[5]), u2h(kb.y), s1, false);
            s2 = __builtin_amdgcn_fdot2(u2h(qh[6]), u2h(kb.z), s2, false);
            s3 = __builtin_amdgcn_fdot2(u2h(qh[7]), u2h(kb.w), s3, false);
            float s = ((s0 + s1) + (s2 + s3)) * SCALE;
            sc[j] = s;
            mx = fmaxf(mx, s);
          }
        }
        mx = fmaxf(mx, __shfl_xor(mx, 1, 64));
        mx = fmaxf(mx, __shfl_xor(mx, 2, 64));
        float l = 0.f;
#pragma unroll
        for (int j = 0; j < NJ; ++j) {
          sc[j] = __expf(sc[j] - mx);   // invalid slots: exp(-inf) = 0
          l += sc[j];
        }
        l += __shfl_xor(l, 1, 64);
        l += __shfl_xor(l, 2, 64);
        float rli = 1.f / l;

        float acc[16];
#pragma unroll
        for (int f = 0; f < 16; ++f) acc[f] = 0.f;
#pragma unroll
        for (int j = 0; j < NJ; ++j) {
          int k = 4 * j + sl;
          if (k <= rg) {
            float p = sc[j];
            const float4 v0 = *(const float4*)&Vlf[k * SKF + ho];
            const float4 v1 = *(const float4*)&Vlf[k * SKF + ho + 4];
            const float4 v2 = *(const float4*)&Vlf[k * SKF + ho + 8];
            const float4 v3 = *(const float4*)&Vlf[k * SKF + ho + 12];
            acc[0]  += p * v0.x; acc[1]  += p * v0.y;
            acc[2]  += p * v0.z; acc[3]  += p * v0.w;
            acc[4]  += p * v1.x; acc[5]  += p * v1.y;
            acc[6]  += p * v1.z; acc[7]  += p * v1.w;
            acc[8]  += p * v2.x; acc[9]  += p * v2.y;
            acc[10] += p * v2.z; acc[11] += p * v2.w;
            acc[12] += p * v3.x; acc[13] += p * v3.y;
            acc[14] += p * v3.z; acc[15] += p * v3.w;
          }
        }
#pragma unroll
        for (int f = 0; f < 16; ++f) {
          acc[f] += __shfl_xor(acc[f], 1, 64);
          acc[f] += __shfl_xor(acc[f], 2, 64);
        }
        if (sl == 0) {
#pragma unroll
          for (int f = 0; f < 16; ++f) Ol[rl * SKF + ho + f] = acc[f] * rli;
        }
      }
    }
    __syncthreads();

    {
      int rl = tid >> 3, q = tid & 7, e0 = q * 4;
      if (rl < CH2) {
        int rg = CH2 * c + rl;
        size_t rowo = ((size_t)(b * T + rg) * N + n) * D;
        uint2 eu = *(const uint2*)&E[rowo + e0];
        float res[4] = { blo(eu.x), bhi(eu.x), blo(eu.y), bhi(eu.y) };
        float o[4], s1 = 0.f, s2 = 0.f;
#pragma unroll
        for (int j = 0; j < 4; ++j) {
          int e = e0 + j;
          float aa = 0.f, ab = 0.f;
#pragma unroll
          for (int d = 0; d < D; d += 2) {
            aa += Ol[rl * SKF + d]     * Wol[d * D + e];
            ab += Ol[rl * SKF + d + 1] * Wol[(d + 1) * D + e];
          }
          float a = bol[e] + aa + ab + res[j];
          o[j] = a; s1 += a; s2 += a * a;
        }
        s1 += __shfl_xor(s1, 1, 64); s2 += __shfl_xor(s2, 1, 64);
        s1 += __shfl_xor(s1, 2, 64); s2 += __shfl_xor(s2, 2, 64);
        s1 += __shfl_xor(s1, 4, 64); s2 += __shfl_xor(s2, 4, 64);
        float mu  = s1 * (1.f / D);
        float var = s2 * (1.f / D) - mu * mu;
        float r = rsqrtf(var + 1e-5f);
        uint2 ou;
        ou.x = pk2((o[0]-mu)*r*gl[e0]+bbl[e0],    (o[1]-mu)*r*gl[e0+1]+bbl[e0+1]);
        ou.y = pk2((o[2]-mu)*r*gl[e0+2]+bbl[e0+2],(o[3]-mu)*r*gl[e0+3]+bbl[e0+3]);
        *(uint2*)&Tn[rowo + e0] = ou;
      }
    }
  }
}

// ---------------------------------------------------------------------------
// spatial v4 = v3 + packed-f16 gemv (fdot2).  Es staged as packed f16
// (stride 20 uints); Wq/Wk/Wv packed as f16 d-pairs per column
// (Wh[fam][d2][e] — lanes e consecutive, conflict-free).  Gemv: 48 fdot2,
// zero unpacks (was 32 unpacks + 96 FMA).  Attention/O-proj stay f32.
// LDS 39.4 -> 33.9 KB.
// ---------------------------------------------------------------------------
__global__ __launch_bounds__(256) void spatial_kernel(
    const bf16* __restrict__ E, const float* __restrict__ WsC,
    const float* __restrict__ bsC, const float* __restrict__ sm_Wo,
    const float* __restrict__ sm_bo, const float* __restrict__ ln_g,
    const float* __restrict__ ln_b, bf16* __restrict__ Sn) {
  int t  = blockIdx.x >> 5;          // B/BG = 32 groups per t
  int bg = blockIdx.x & 31;
  int b0 = bg * BG;
  __shared__ unsigned Wh[3 * (D / 2) * D];          // packed f16 pairs, 6144 B
  __shared__ float Wo[D * D];
  __shared__ float bqs[D], bks[D], bvs[D], bos[D], gs[D], bbs[D];
  __shared__ __align__(16) unsigned Esh[SR * SEH];  // packed f16 Es, 3840 B
  __shared__ float Qs[SR * SQS], Ks[SR * SQS], Vs[SR * SQS];
  int tid = threadIdx.x;

  for (int i = tid; i < 3 * (D / 2) * D; i += 256) {
    int fam = i / ((D / 2) * D);
    int idx = i % ((D / 2) * D);
    int d2 = idx >> 5, e = idx & 31;
    const float* wg = WsC + (size_t)(fam * T + t) * D * D;
    Wh[i] = pkh2(wg[(2 * d2) * D + e], wg[(2 * d2 + 1) * D + e]);
  }
  for (int i = tid; i < D * D; i += 256) Wo[i] = sm_Wo[(size_t)t * D * D + i];
  if (tid < D) {
    bqs[tid] = bsC[(0 * T + t) * D + tid];
    bks[tid] = bsC[(1 * T + t) * D + tid];
    bvs[tid] = bsC[(2 * T + t) * D + tid];
    bos[tid] = sm_bo[t * D + tid];
    gs[tid]  = ln_g[tid];
    bbs[tid] = ln_b[tid];
  }
  if (tid < SR * 4) {
    int r = tid >> 2, p = tid & 3;
    int b = b0 + r / N, n = r % N;
    uint4 u = *(const uint4*)&E[(((size_t)b * T + t) * N + n) * D + p * 8];
    uint4 o;
    o.x = pkh2(blo(u.x), bhi(u.x));
    o.y = pkh2(blo(u.y), bhi(u.y));
    o.z = pkh2(blo(u.z), bhi(u.z));
    o.w = pkh2(blo(u.w), bhi(u.w));
    *(uint4*)&Esh[r * SEH + p * 4] = o;
  }
  __syncthreads();

  // ---- QKV gemv: 48 fdot2 per (row, e) thread ----
#pragma unroll 1
  for (int i = tid; i < SR * D; i += 256) {
    int r = i >> 5, e = i & 31;
    float aq = bqs[e], ak = bks[e], av = bvs[e];
#pragma unroll
    for (int d2 = 0; d2 < D / 2; ++d2) {
      h2 x = u2h(Esh[r * SEH + d2]);
      aq = __builtin_amdgcn_fdot2(x, u2h(Wh[0 * 512 + d2 * 32 + e]), aq, false);
      ak = __builtin_amdgcn_fdot2(x, u2h(Wh[1 * 512 + d2 * 32 + e]), ak, false);
      av = __builtin_amdgcn_fdot2(x, u2h(Wh[2 * 512 + d2 * 32 + e]), av, false);
    }
    Qs[r * SQS + e] = aq;
    Ks[r * SQS + e] = ak;
    Vs[r * SQS + e] = av;
  }
  __syncthreads();

  if (tid < SR * NH) {
    int r = tid >> 1, h = tid & 1, ho = h * FD;
    int kb = (r >= N) ? N : 0;
    float q[FD];
#pragma unroll
    for (int f = 0; f < FD; ++f) q[f] = Qs[r * SQS + ho + f];
    float sc[N];
    float m = -1e30f;
#pragma unroll
    for (int k = 0; k < N; ++k) {
      float sa = 0.f, sb = 0.f;
#pragma unroll
      for (int f = 0; f < FD; f += 2) {
        sa += q[f]     * Ks[(kb + k) * SQS + ho + f];
        sb += q[f + 1] * Ks[(kb + k) * SQS + ho + f + 1];
      }
      float s = (sa + sb) * SCALE;
      sc[k] = s;
      m = fmaxf(m, s);
    }
    float l = 0.f;
#pragma unroll
    for (int k = 0; k < N; ++k) { sc[k] = __expf(sc[k] - m); l += sc[k]; }
    float rl = 1.f / l;
#pragma unroll
    for (int f = 0; f < FD; ++f) {
      float a = 0.f;
#pragma unroll
      for (int k = 0; k < N; ++k) a += sc[k] * Vs[(kb + k) * SQS + ho + f];
      Qs[r * SQS + ho + f] = a * rl;
    }
  }
  __syncthreads();

#pragma unroll 1
  for (int it = 0; it < SR * D / 256; ++it) {
    int i = it * 256 + tid;
    int r = i >> 5, e = i & 31;
    float aa = 0.f, ab = 0.f;
#pragma unroll
    for (int d = 0; d < D; d += 2) {
      aa += Qs[r * SQS + d]     * Wo[d * D + e];
      ab += Qs[r * SQS + d + 1] * Wo[(d + 1) * D + e];
    }
    h2 ex = u2h(Esh[r * SEH + (e >> 1)]);
    float res = (float)ex[e & 1];
    float o = bos[e] + aa + ab + res;
    float s1 = o, s2 = o * o;
    s1 += __shfl_xor(s1, 1, 64);  s2 += __shfl_xor(s2, 1, 64);
    s1 += __shfl_xor(s1, 2, 64);  s2 += __shfl_xor(s2, 2, 64);
    s1 += __shfl_xor(s1, 4, 64);  s2 += __shfl_xor(s2, 4, 64);
    s1 += __shfl_xor(s1, 8, 64);  s2 += __shfl_xor(s2, 8, 64);
    s1 += __shfl_xor(s1, 16, 64); s2 += __shfl_xor(s2, 16, 64);
    float mu  = s1 * (1.f / D);
    float var = s2 * (1.f / D) - mu * mu;
    float rr = rsqrtf(var + 1e-5f);
    int b = b0 + r / N, n = r % N;
    Sn[(((size_t)b * T + t) * N + n) * D + e] =
        __float2bfloat16((o - mu) * rr * gs[e] + bbs[e]);
  }
}

// ---------------------------------------------------------------------------
// ff v2: block = 32 rows x 8 lanes/row (grid 240).
// ---------------------------------------------------------------------------
__global__ __launch_bounds__(256) void ff_kernel(
    const bf16* __restrict__ Tn, const bf16* __restrict__ Sn,
    const float* __restrict__ W1, const float* __restrict__ b1,
    const float* __restrict__ W2, const float* __restrict__ b2,
    const float* __restrict__ ln_g, const float* __restrict__ ln_b,
    bf16* __restrict__ E) {
  __shared__ float w1s[D * FF], w2s[FF * D];
  __shared__ float bb1[FF], bb2[D], gs[D], bbs[D];
  __shared__ float tsl[FR][D + 1];
  __shared__ float hl[FR][FF + 1];
  int tid = threadIdx.x;
  int r0 = blockIdx.x * FR;
  for (int i = tid; i < D * FF; i += 256) { w1s[i] = W1[i]; w2s[i] = W2[i]; }
  if (tid < FF) bb1[tid] = b1[tid];
  if (tid < D) { bb2[tid] = b2[tid]; gs[tid] = ln_g[tid]; bbs[tid] = ln_b[tid]; }
  int r = tid >> 3, s = tid & 7;
  {
    const bf16* tp = Tn + ((size_t)(r0 + r)) * D + s * 4;
    const bf16* sp = Sn + ((size_t)(r0 + r)) * D + s * 4;
    uint2 tu = *(const uint2*)tp;
    uint2 su = *(const uint2*)sp;
    tsl[r][s*4+0] = blo(tu.x) + blo(su.x);
    tsl[r][s*4+1] = bhi(tu.x) + bhi(su.x);
    tsl[r][s*4+2] = blo(tu.y) + blo(su.y);
    tsl[r][s*4+3] = bhi(tu.y) + bhi(su.y);
  }
  __syncthreads();
  {
    float hh[8];
#pragma unroll
    for (int j = 0; j < 8; ++j) {
      int jj = s * 8 + j;
      float aa = bb1[jj], ab = 0.f;
#pragma unroll
      for (int d = 0; d < D; d += 2) {
        aa += tsl[r][d]     * w1s[d * FF + jj];
        ab += tsl[r][d + 1] * w1s[(d + 1) * FF + jj];
      }
      hh[j] = fmaxf(aa + ab, 0.f);
    }
#pragma unroll
    for (int j = 0; j < 8; ++j) hl[r][s * 8 + j] = hh[j];
  }
  __syncthreads();
  {
    float x[4];
    float s1 = 0.f, s2 = 0.f;
#pragma unroll
    for (int j4 = 0; j4 < 4; ++j4) {
      int e = s * 4 + j4;
      float aa = 0.f, ab = 0.f;
#pragma unroll
      for (int k = 0; k < FF; k += 2) {
        aa += hl[r][k]     * w2s[k * D + e];
        ab += hl[r][k + 1] * w2s[(k + 1) * D + e];
      }
      float a = bb2[e] + tsl[r][e] + aa + ab;
      x[j4] = a; s1 += a; s2 += a * a;
    }
    s1 += __shfl_xor(s1, 1, 64); s2 += __shfl_xor(s2, 1, 64);
    s1 += __shfl_xor(s1, 2, 64); s2 += __shfl_xor(s2, 2, 64);
    s1 += __shfl_xor(s1, 4, 64); s2 += __shfl_xor(s2, 4, 64);
    float mu  = s1 * (1.f / D);
    float var = s2 * (1.f / D) - mu * mu;
    float rr = rsqrtf(var + 1e-5f);
    int e0 = s * 4;
    uint2 ou;
    ou.x = pk2((x[0]-mu)*rr*gs[e0]+bbs[e0],    (x[1]-mu)*rr*gs[e0+1]+bbs[e0+1]);
    ou.y = pk2((x[2]-mu)*rr*gs[e0+2]+bbs[e0+2],(x[3]-mu)*rr*gs[e0+3]+bbs[e0+3]);
    *(uint2*)&E[((size_t)(r0 + r)) * D + e0] = ou;
  }
}

// ---------------------------------------------------------------------------
// out = E@op_W + op_b + X   (f32 out)
// ---------------------------------------------------------------------------
__global__ __launch_bounds__(256) void out_kernel(
    const bf16* __restrict__ E, const float* __restrict__ op_W,
    const float* __restrict__ op_b, const float* __restrict__ X,
    float* __restrict__ out) {
  int idx = blockIdx.x * 256 + threadIdx.x;
  if (idx >= B * T * N * M) return;
  int m  = idx % M;
  int n  = (idx / M) % N;
  int bt = idx / (M * N);
  float acc = op_b[n * M + m];
  const bf16* e = E + ((size_t)bt * N + n) * D;
#pragma unroll
  for (int d = 0; d < D; ++d) acc += b2f(e[d]) * op_W[(n * D + d) * M + m];
  acc += X[idx];
  out[idx] = acc;
}

// ---------------------------------------------------------------------------
extern "C" void kernel_launch(void* const* d_in, const int* in_sizes, int n_in,
                              void* d_out, int out_size, void* d_ws, size_t ws_size,
                              hipStream_t stream) {
  const float* X     = (const float*)d_in[0];
  const float* pe    = (const float*)d_in[1];
  const float* E_W   = (const float*)d_in[2];
  const float* E_b   = (const float*)d_in[3];
  const float* tq_W  = (const float*)d_in[4];
  const float* tq_b  = (const float*)d_in[5];
  const float* tk_W  = (const float*)d_in[6];
  const float* tk_b  = (const float*)d_in[7];
  const float* tv_W  = (const float*)d_in[8];
  const float* tv_b  = (const float*)d_in[9];
  const float* tm_Wq = (const float*)d_in[10];
  const float* tm_bq = (const float*)d_in[11];
  const float* tm_Wk = (const float*)d_in[12];
  const float* tm_bk = (const float*)d_in[13];
  const float* tm_Wv = (const float*)d_in[14];
  const float* tm_bv = (const float*)d_in[15];
  const float* tm_Wo = (const float*)d_in[16];
  const float* tm_bo = (const float*)d_in[17];
  const float* sq_W  = (const float*)d_in[18];
  const float* sq_b  = (const float*)d_in[19];
  const float* sk_W  = (const float*)d_in[20];
  const float* sk_b  = (const float*)d_in[21];
  const float* sv_W  = (const float*)d_in[22];
  const float* sv_b  = (const float*)d_in[23];
  const float* sm_Wq = (const float*)d_in[24];
  const float* sm_bq = (const float*)d_in[25];
  const float* sm_Wk = (const float*)d_in[26];
  const float* sm_bk = (const float*)d_in[27];
  const float* sm_Wv = (const float*)d_in[28];
  const float* sm_bv = (const float*)d_in[29];
  const float* sm_Wo = (const float*)d_in[30];
  const float* sm_bo = (const float*)d_in[31];
  const float* ff1_W = (const float*)d_in[32];
  const float* ff1_b = (const float*)d_in[33];
  const float* ff2_W = (const float*)d_in[34];
  const float* ff2_b = (const float*)d_in[35];
  const float* ln_g  = (const float*)d_in[36];
  const float* ln_b  = (const float*)d_in[37];
  const float* op_W  = (const float*)d_in[38];
  const float* op_b  = (const float*)d_in[39];
  float* out = (float*)d_out;

  float* WtC = (float*)d_ws;                         // 3*N*D*D
  float* btC = WtC + 3 * N * D * D;                  // 3*N*D
  float* WsC = btC + 3 * N * D;                      // 3*T*D*D
  float* bsC = WsC + 3 * T * D * D;                  // 3*T*D
  size_t act = (size_t)B * T * N * D;
  bf16* Ebuf = (bf16*)(bsC + 3 * T * D);
  bf16* Tn   = Ebuf + act;
  bf16* Qt   = Tn + act;
  bf16* Kt   = Qt + act;
  bf16* Vt   = Kt + act;
  bf16* Sn   = Qt;                                   // alias (safe: serial schedule)

  compose3_kernel<<<3 * N, 256, 0, stream>>>(
      tq_W, tq_b, tm_Wq, tm_bq, tk_W, tk_b, tm_Wk, tm_bk,
      tv_W, tv_b, tm_Wv, tm_bv, WtC, btC, N);
  compose3_kernel<<<3 * T, 256, 0, stream>>>(
      sq_W, sq_b, sm_Wq, sm_bq, sk_W, sk_b, sm_Wk, sm_bk,
      sv_W, sv_b, sm_Wv, sm_bv, WsC, bsC, T);

  embed_kernel<<<(B * T * N * D) / 256, 256, 0, stream>>>(X, pe, E_W, E_b, Ebuf);

  for (int l = 0; l < L; ++l) {
    qkvt_kernel<<<N * QCH, 256, 0, stream>>>(Ebuf, WtC, btC, Qt, Kt, Vt);
    attnt_kernel<<<B * N, 256, 0, stream>>>(Qt, Kt, Vt, Ebuf, tm_Wo, tm_bo, ln_g, ln_b, Tn);
    spatial_kernel<<<T * (B / BG), 256, 0, stream>>>(Ebuf, WsC, bsC, sm_Wo, sm_bo, ln_g, ln_b, Sn);
    ff_kernel<<<(B * T * N) / FR, 256, 0, stream>>>(Tn, Sn, ff1_W, ff1_b, ff2_W, ff2_b, ln_g, ln_b, Ebuf);
  }

  out_kernel<<<(B * T * N * M + 255) / 256, 256, 0, stream>>>(Ebuf, op_W, op_b, X, out);
}

// Round 26
// 679.128 us; speedup vs baseline: 1.3492x; 1.1051x over previous
//
#include <hip/hip_runtime.h>
#include <hip/hip_bf16.h>

typedef __hip_bfloat16 bf16;
typedef __fp16 h2 __attribute__((ext_vector_type(2)));   // matches amdgcn builtin 'V2h'

constexpr int B  = 64, T = 120, N = 24, M = 3, D = 32;
constexpr int NH = 2, FD = 16, FF = 64, L = 3;
constexpr float SCALE = 0.25f;   // 1/sqrt(FD)
constexpr int SK  = 40;          // attnt K/Q f16 LDS stride (80B rows)
constexpr int SKF = 36;          // attnt V/O f32 LDS stride (144B rows)
constexpr int CH2 = 30;          // attnt rows per chunk: 4 x 30 = 120 exactly
constexpr int NJ  = 30;          // max keys per lane slice (120/4)
constexpr int QR  = 64;          // qkvt rows per block (4 lanes/row)
constexpr int QCH = (B * T) / QR;// qkvt chunks = 120
constexpr int BG  = 2;           // spatial batches per block
constexpr int SR  = N * BG;      // spatial rows per block = 48
constexpr int SES = 40;          // Es bf16 stride (qkvt, 80B)
constexpr int SEH = 20;          // spatial packed-f16 Es stride (uints, 80B)
constexpr int SQS = 33;          // spatial Q/K/V f32 stride (no 32-way conflicts)
constexpr int FR  = 32;          // ff rows per block (8 lanes/row)

__device__ __forceinline__ float b2f(bf16 x) { return __bfloat162float(x); }
__device__ __forceinline__ float blo(unsigned u) { return __uint_as_float(u << 16); }
__device__ __forceinline__ float bhi(unsigned u) { return __uint_as_float(u & 0xffff0000u); }
__device__ __forceinline__ unsigned pk2(float a, float b) {
  bf16 x = __float2bfloat16(a), y = __float2bfloat16(b);
  unsigned short ux = *reinterpret_cast<unsigned short*>(&x);
  unsigned short uy = *reinterpret_cast<unsigned short*>(&y);
  return (unsigned)ux | ((unsigned)uy << 16);
}
__device__ __forceinline__ unsigned pkh2(float a, float b) {
  h2 r = __builtin_amdgcn_cvt_pkrtz(a, b);     // v_cvt_pkrtz_f16_f32
  return *reinterpret_cast<unsigned*>(&r);
}
__device__ __forceinline__ h2 u2h(unsigned u) { return *reinterpret_cast<h2*>(&u); }

// ---------------------------------------------------------------------------
// Compose q/k/v chained linears: grid = 3*U blocks.  Wc = W1@W2, bc = b1@W2+b2.
// ---------------------------------------------------------------------------
__global__ __launch_bounds__(256) void compose3_kernel(
    const float* __restrict__ W1q, const float* __restrict__ b1q,
    const float* __restrict__ W2q, const float* __restrict__ b2q,
    const float* __restrict__ W1k, const float* __restrict__ b1k,
    const float* __restrict__ W2k, const float* __restrict__ b2k,
    const float* __restrict__ W1v, const float* __restrict__ b1v,
    const float* __restrict__ W2v, const float* __restrict__ b2v,
    float* __restrict__ Wc, float* __restrict__ bc, int U) {
  int fam = blockIdx.x / U;
  int n   = blockIdx.x % U;
  const float* W1 = (fam == 0) ? W1q : (fam == 1) ? W1k : W1v;
  const float* b1 = (fam == 0) ? b1q : (fam == 1) ? b1k : b1v;
  const float* W2 = (fam == 0) ? W2q : (fam == 1) ? W2k : W2v;
  const float* b2 = (fam == 0) ? b2q : (fam == 1) ? b2k : b2v;
  const float* w1 = W1 + n * D * D;
  const float* w2 = W2 + n * D * D;
  float* wc  = Wc + (size_t)(fam * U + n) * D * D;
  float* bcp = bc + (fam * U + n) * D;
  __shared__ float s1[D * D], s2[D * D];
  for (int i = threadIdx.x; i < D * D; i += 256) { s1[i] = w1[i]; s2[i] = w2[i]; }
  __syncthreads();
  for (int i = threadIdx.x; i < D * D; i += 256) {
    int d = i >> 5, f = i & 31;
    float acc = 0.f;
#pragma unroll
    for (int e = 0; e < D; ++e) acc += s1[d * D + e] * s2[e * D + f];
    wc[i] = acc;
  }
  if (threadIdx.x < D) {
    int f = threadIdx.x;
    float acc = b2[n * D + f];
#pragma unroll
    for (int e = 0; e < D; ++e) acc += b1[n * D + e] * s2[e * D + f];
    bcp[f] = acc;
  }
}

// ---------------------------------------------------------------------------
// E[b,t,n,d] = X@E_W + E_b + pe   (bf16 out)
// ---------------------------------------------------------------------------
__global__ __launch_bounds__(256) void embed_kernel(
    const float* __restrict__ X, const float* __restrict__ pe,
    const float* __restrict__ E_W, const float* __restrict__ E_b,
    bf16* __restrict__ E) {
  int idx = blockIdx.x * 256 + threadIdx.x;
  if (idx >= B * T * N * D) return;
  int d = idx & 31;
  int n = (idx >> 5) % N;
  int bt = idx / (D * N);
  int t = bt % T;
  const float* x = X + bt * (N * M) + n * M;
  float acc = E_b[n * D + d] + pe[t * D + d];
#pragma unroll
  for (int m = 0; m < M; ++m) acc += x[m] * E_W[(n * M + m) * D + d];
  E[idx] = __float2bfloat16(acc);
}

// ---------------------------------------------------------------------------
// qkvt v2: thread = (row, quarter); LDS-staged coalesced loads, one
// contiguous uint4 store per family.  Grid n-major for weight L2 reuse.
// ---------------------------------------------------------------------------
__global__ __launch_bounds__(256) void qkvt_kernel(
    const bf16* __restrict__ E, const float* __restrict__ WtC,
    const float* __restrict__ btC,
    bf16* __restrict__ Qt, bf16* __restrict__ Kt, bf16* __restrict__ Vt) {
  int n     = blockIdx.x / QCH;
  int chunk = blockIdx.x % QCH;
  __shared__ float wsh[3 * D * D];
  __shared__ float bsh[3 * D];
  __shared__ __align__(16) bf16 Es[QR * SES];
  int tid = threadIdx.x;
  for (int i = tid; i < 3 * D * D; i += 256) {
    int fam = i >> 10, idx = i & 1023;
    wsh[i] = WtC[(size_t)(fam * N + n) * D * D + idx];
  }
  if (tid < 3 * D) {
    int fam = tid >> 5, e = tid & 31;
    bsh[tid] = btC[(fam * N + n) * D + e];
  }
  {
    int row = tid >> 2, p = tid & 3;
    const bf16* er = E + ((size_t)(chunk * QR + row) * N + n) * D;
    *(uint4*)&Es[row * SES + p * 8] = *(const uint4*)&er[p * 8];
  }
  __syncthreads();

  int row = tid >> 2, q = tid & 3;
  int grow = chunk * QR + row;          // b*T + t
  int b = grow / T, t = grow % T;
  float x[D];
#pragma unroll
  for (int d = 0; d < D; ++d) x[d] = b2f(Es[row * SES + d]);
  size_t dsto = (((size_t)b * N + n) * T + t) * D + q * 8;
  bf16* dsts[3] = { Qt + dsto, Kt + dsto, Vt + dsto };
#pragma unroll
  for (int fam = 0; fam < 3; ++fam) {
    const float* w  = wsh + fam * D * D;
    const float* bi = bsh + fam * D;
    float a[8];
#pragma unroll
    for (int j = 0; j < 8; ++j) a[j] = bi[q * 8 + j];
#pragma unroll
    for (int d = 0; d < D; ++d) {
      float xv = x[d];
#pragma unroll
      for (int j = 0; j < 8; ++j) a[j] += xv * w[d * D + q * 8 + j];
    }
    uint4 o;
    o.x = pk2(a[0], a[1]); o.y = pk2(a[2], a[3]);
    o.z = pk2(a[4], a[5]); o.w = pk2(a[6], a[7]);
    *(uint4*)dsts[fam] = o;
  }
}

// ---------------------------------------------------------------------------
// attnt v10: packed f16 dot-product scores (measured R24: 100.7us, was 118).
// ---------------------------------------------------------------------------
__global__ __launch_bounds__(256) void attnt_kernel(
    const bf16* __restrict__ Qt, const bf16* __restrict__ Kt,
    const bf16* __restrict__ Vt, const bf16* __restrict__ E,
    const float* __restrict__ tm_Wo, const float* __restrict__ tm_bo,
    const float* __restrict__ ln_g, const float* __restrict__ ln_b,
    bf16* __restrict__ Tn) {
  int bn = blockIdx.x;
  int n  = bn % N, b = bn / N;
  __shared__ __align__(16) __fp16 Klh[T * SK];    // 9600 B
  __shared__ __align__(16) float  Vlf[T * SKF];   // 17280 B
  __shared__ __align__(16) __fp16 Qlh[CH2 * SK];  // 2400 B
  __shared__ __align__(16) float  Ol[CH2 * SKF];  // 4320 B
  __shared__ float Wol[D * D], bol[D], gl[D], bbl[D];
  int tid = threadIdx.x;

  const bf16* Kg = Kt + (size_t)bn * T * D;
  const bf16* Vg = Vt + (size_t)bn * T * D;
  const bf16* Qg = Qt + (size_t)bn * T * D;
  for (int i = tid; i < T * 4; i += 256) {
    int r = i >> 2, p = i & 3;
    uint4 ku = *(const uint4*)&Kg[r * D + p * 8];
    uint4 kh;
    kh.x = pkh2(blo(ku.x), bhi(ku.x));
    kh.y = pkh2(blo(ku.y), bhi(ku.y));
    kh.z = pkh2(blo(ku.z), bhi(ku.z));
    kh.w = pkh2(blo(ku.w), bhi(ku.w));
    *(uint4*)&Klh[r * SK + p * 8] = kh;
    uint4 vu = *(const uint4*)&Vg[r * D + p * 8];
    *(float4*)&Vlf[r * SKF + p * 8]     = make_float4(blo(vu.x), bhi(vu.x), blo(vu.y), bhi(vu.y));
    *(float4*)&Vlf[r * SKF + p * 8 + 4] = make_float4(blo(vu.z), bhi(vu.z), blo(vu.w), bhi(vu.w));
  }
  for (int i = tid; i < D * D; i += 256) Wol[i] = tm_Wo[(size_t)n * D * D + i];
  if (tid < D) {
    bol[tid] = tm_bo[n * D + tid];
    gl[tid]  = ln_g[tid];
    bbl[tid] = ln_b[tid];
  }
  __syncthreads();

#pragma unroll 1
  for (int c = 0; c < 4; ++c) {
    if (tid < CH2 * 4) {
      int r = tid >> 2, p = tid & 3;
      uint4 qu = *(const uint4*)&Qg[(CH2 * c + r) * D + p * 8];
      uint4 qh;
      qh.x = pkh2(blo(qu.x), bhi(qu.x));
      qh.y = pkh2(blo(qu.y), bhi(qu.y));
      qh.z = pkh2(blo(qu.z), bhi(qu.z));
      qh.w = pkh2(blo(qu.w), bhi(qu.w));
      *(uint4*)&Qlh[r * SK + p * 8] = qh;
    }
    __syncthreads();   // Qlh ready; prior O-proj done -> Ol safe to overwrite

    {
      int task = tid >> 2, sl = tid & 3;
      if (task < 2 * CH2) {
        int rl = task >> 1, h = task & 1, ho = h * FD;
        int rg = CH2 * c + rl;
        uint4 q0 = *(const uint4*)&Qlh[rl * SK + ho];
        uint4 q1 = *(const uint4*)&Qlh[rl * SK + ho + 8];
        unsigned qh[8] = { q0.x, q0.y, q0.z, q0.w, q1.x, q1.y, q1.z, q1.w };

        float sc[NJ];
        float mx = -3e38f;
#pragma unroll
        for (int j = 0; j < NJ; ++j) {
          int k = 4 * j + sl;
          sc[j] = -3e38f;
          if (k <= rg) {
            const uint4 ka = *(const uint4*)&Klh[k * SK + ho];
            const uint4 kb = *(const uint4*)&Klh[k * SK + ho + 8];
            float s0 = __builtin_amdgcn_fdot2(u2h(qh[0]), u2h(ka.x), 0.f, false);
            float s1 = __builtin_amdgcn_fdot2(u2h(qh[1]), u2h(ka.y), 0.f, false);
            float s2 = __builtin_amdgcn_fdot2(u2h(qh[2]), u2h(ka.z), 0.f, false);
            float s3 = __builtin_amdgcn_fdot2(u2h(qh[3]), u2h(ka.w), 0.f, false);
            s0 = __builtin_amdgcn_fdot2(u2h(qh[4]), u2h(kb.x), s0, false);
            s1 = __builtin_amdgcn_fdot2(u2h(qh[5]), u2h(kb.y), s1, false);
            s2 = __builtin_amdgcn_fdot2(u2h(qh[6]), u2h(kb.z), s2, false);
            s3 = __builtin_amdgcn_fdot2(u2h(qh[7]), u2h(kb.w), s3, false);
            float s = ((s0 + s1) + (s2 + s3)) * SCALE;
            sc[j] = s;
            mx = fmaxf(mx, s);
          }
        }
        mx = fmaxf(mx, __shfl_xor(mx, 1, 64));
        mx = fmaxf(mx, __shfl_xor(mx, 2, 64));
        float l = 0.f;
#pragma unroll
        for (int j = 0; j < NJ; ++j) {
          sc[j] = __expf(sc[j] - mx);   // invalid slots: exp(-inf) = 0
          l += sc[j];
        }
        l += __shfl_xor(l, 1, 64);
        l += __shfl_xor(l, 2, 64);
        float rli = 1.f / l;

        float acc[16];
#pragma unroll
        for (int f = 0; f < 16; ++f) acc[f] = 0.f;
#pragma unroll
        for (int j = 0; j < NJ; ++j) {
          int k = 4 * j + sl;
          if (k <= rg) {
            float p = sc[j];
            const float4 v0 = *(const float4*)&Vlf[k * SKF + ho];
            const float4 v1 = *(const float4*)&Vlf[k * SKF + ho + 4];
            const float4 v2 = *(const float4*)&Vlf[k * SKF + ho + 8];
            const float4 v3 = *(const float4*)&Vlf[k * SKF + ho + 12];
            acc[0]  += p * v0.x; acc[1]  += p * v0.y;
            acc[2]  += p * v0.z; acc[3]  += p * v0.w;
            acc[4]  += p * v1.x; acc[5]  += p * v1.y;
            acc[6]  += p * v1.z; acc[7]  += p * v1.w;
            acc[8]  += p * v2.x; acc[9]  += p * v2.y;
            acc[10] += p * v2.z; acc[11] += p * v2.w;
            acc[12] += p * v3.x; acc[13] += p * v3.y;
            acc[14] += p * v3.z; acc[15] += p * v3.w;
          }
        }
#pragma unroll
        for (int f = 0; f < 16; ++f) {
          acc[f] += __shfl_xor(acc[f], 1, 64);
          acc[f] += __shfl_xor(acc[f], 2, 64);
        }
        if (sl == 0) {
#pragma unroll
          for (int f = 0; f < 16; ++f) Ol[rl * SKF + ho + f] = acc[f] * rli;
        }
      }
    }
    __syncthreads();

    {
      int rl = tid >> 3, q = tid & 7, e0 = q * 4;
      if (rl < CH2) {
        int rg = CH2 * c + rl;
        size_t rowo = ((size_t)(b * T + rg) * N + n) * D;
        uint2 eu = *(const uint2*)&E[rowo + e0];
        float res[4] = { blo(eu.x), bhi(eu.x), blo(eu.y), bhi(eu.y) };
        float o[4], s1 = 0.f, s2 = 0.f;
#pragma unroll
        for (int j = 0; j < 4; ++j) {
          int e = e0 + j;
          float aa = 0.f, ab = 0.f;
#pragma unroll
          for (int d = 0; d < D; d += 2) {
            aa += Ol[rl * SKF + d]     * Wol[d * D + e];
            ab += Ol[rl * SKF + d + 1] * Wol[(d + 1) * D + e];
          }
          float a = bol[e] + aa + ab + res[j];
          o[j] = a; s1 += a; s2 += a * a;
        }
        s1 += __shfl_xor(s1, 1, 64); s2 += __shfl_xor(s2, 1, 64);
        s1 += __shfl_xor(s1, 2, 64); s2 += __shfl_xor(s2, 2, 64);
        s1 += __shfl_xor(s1, 4, 64); s2 += __shfl_xor(s2, 4, 64);
        float mu  = s1 * (1.f / D);
        float var = s2 * (1.f / D) - mu * mu;
        float r = rsqrtf(var + 1e-5f);
        uint2 ou;
        ou.x = pk2((o[0]-mu)*r*gl[e0]+bbl[e0],    (o[1]-mu)*r*gl[e0+1]+bbl[e0+1]);
        ou.y = pk2((o[2]-mu)*r*gl[e0+2]+bbl[e0+2],(o[3]-mu)*r*gl[e0+3]+bbl[e0+3]);
        *(uint2*)&Tn[rowo + e0] = ou;
      }
    }
  }
}

// ---------------------------------------------------------------------------
// spatial v4: packed-f16 gemv (fdot2).  Measured R25: ~neutral-to-+1us.
// ---------------------------------------------------------------------------
__global__ __launch_bounds__(256) void spatial_kernel(
    const bf16* __restrict__ E, const float* __restrict__ WsC,
    const float* __restrict__ bsC, const float* __restrict__ sm_Wo,
    const float* __restrict__ sm_bo, const float* __restrict__ ln_g,
    const float* __restrict__ ln_b, bf16* __restrict__ Sn) {
  int t  = blockIdx.x >> 5;          // B/BG = 32 groups per t
  int bg = blockIdx.x & 31;
  int b0 = bg * BG;
  __shared__ unsigned Wh[3 * (D / 2) * D];          // packed f16 pairs, 6144 B
  __shared__ float Wo[D * D];
  __shared__ float bqs[D], bks[D], bvs[D], bos[D], gs[D], bbs[D];
  __shared__ __align__(16) unsigned Esh[SR * SEH];  // packed f16 Es, 3840 B
  __shared__ float Qs[SR * SQS], Ks[SR * SQS], Vs[SR * SQS];
  int tid = threadIdx.x;

  for (int i = tid; i < 3 * (D / 2) * D; i += 256) {
    int fam = i / ((D / 2) * D);
    int idx = i % ((D / 2) * D);
    int d2 = idx >> 5, e = idx & 31;
    const float* wg = WsC + (size_t)(fam * T + t) * D * D;
    Wh[i] = pkh2(wg[(2 * d2) * D + e], wg[(2 * d2 + 1) * D + e]);
  }
  for (int i = tid; i < D * D; i += 256) Wo[i] = sm_Wo[(size_t)t * D * D + i];
  if (tid < D) {
    bqs[tid] = bsC[(0 * T + t) * D + tid];
    bks[tid] = bsC[(1 * T + t) * D + tid];
    bvs[tid] = bsC[(2 * T + t) * D + tid];
    bos[tid] = sm_bo[t * D + tid];
    gs[tid]  = ln_g[tid];
    bbs[tid] = ln_b[tid];
  }
  if (tid < SR * 4) {
    int r = tid >> 2, p = tid & 3;
    int b = b0 + r / N, n = r % N;
    uint4 u = *(const uint4*)&E[(((size_t)b * T + t) * N + n) * D + p * 8];
    uint4 o;
    o.x = pkh2(blo(u.x), bhi(u.x));
    o.y = pkh2(blo(u.y), bhi(u.y));
    o.z = pkh2(blo(u.z), bhi(u.z));
    o.w = pkh2(blo(u.w), bhi(u.w));
    *(uint4*)&Esh[r * SEH + p * 4] = o;
  }
  __syncthreads();

#pragma unroll 1
  for (int i = tid; i < SR * D; i += 256) {
    int r = i >> 5, e = i & 31;
    float aq = bqs[e], ak = bks[e], av = bvs[e];
#pragma unroll
    for (int d2 = 0; d2 < D / 2; ++d2) {
      h2 x = u2h(Esh[r * SEH + d2]);
      aq = __builtin_amdgcn_fdot2(x, u2h(Wh[0 * 512 + d2 * 32 + e]), aq, false);
      ak = __builtin_amdgcn_fdot2(x, u2h(Wh[1 * 512 + d2 * 32 + e]), ak, false);
      av = __builtin_amdgcn_fdot2(x, u2h(Wh[2 * 512 + d2 * 32 + e]), av, false);
    }
    Qs[r * SQS + e] = aq;
    Ks[r * SQS + e] = ak;
    Vs[r * SQS + e] = av;
  }
  __syncthreads();

  if (tid < SR * NH) {
    int r = tid >> 1, h = tid & 1, ho = h * FD;
    int kb = (r >= N) ? N : 0;
    float q[FD];
#pragma unroll
    for (int f = 0; f < FD; ++f) q[f] = Qs[r * SQS + ho + f];
    float sc[N];
    float m = -1e30f;
#pragma unroll
    for (int k = 0; k < N; ++k) {
      float sa = 0.f, sb = 0.f;
#pragma unroll
      for (int f = 0; f < FD; f += 2) {
        sa += q[f]     * Ks[(kb + k) * SQS + ho + f];
        sb += q[f + 1] * Ks[(kb + k) * SQS + ho + f + 1];
      }
      float s = (sa + sb) * SCALE;
      sc[k] = s;
      m = fmaxf(m, s);
    }
    float l = 0.f;
#pragma unroll
    for (int k = 0; k < N; ++k) { sc[k] = __expf(sc[k] - m); l += sc[k]; }
    float rl = 1.f / l;
#pragma unroll
    for (int f = 0; f < FD; ++f) {
      float a = 0.f;
#pragma unroll
      for (int k = 0; k < N; ++k) a += sc[k] * Vs[(kb + k) * SQS + ho + f];
      Qs[r * SQS + ho + f] = a * rl;
    }
  }
  __syncthreads();

#pragma unroll 1
  for (int it = 0; it < SR * D / 256; ++it) {
    int i = it * 256 + tid;
    int r = i >> 5, e = i & 31;
    float aa = 0.f, ab = 0.f;
#pragma unroll
    for (int d = 0; d < D; d += 2) {
      aa += Qs[r * SQS + d]     * Wo[d * D + e];
      ab += Qs[r * SQS + d + 1] * Wo[(d + 1) * D + e];
    }
    h2 ex = u2h(Esh[r * SEH + (e >> 1)]);
    float res = (float)ex[e & 1];
    float o = bos[e] + aa + ab + res;
    float s1 = o, s2 = o * o;
    s1 += __shfl_xor(s1, 1, 64);  s2 += __shfl_xor(s2, 1, 64);
    s1 += __shfl_xor(s1, 2, 64);  s2 += __shfl_xor(s2, 2, 64);
    s1 += __shfl_xor(s1, 4, 64);  s2 += __shfl_xor(s2, 4, 64);
    s1 += __shfl_xor(s1, 8, 64);  s2 += __shfl_xor(s2, 8, 64);
    s1 += __shfl_xor(s1, 16, 64); s2 += __shfl_xor(s2, 16, 64);
    float mu  = s1 * (1.f / D);
    float var = s2 * (1.f / D) - mu * mu;
    float rr = rsqrtf(var + 1e-5f);
    int b = b0 + r / N, n = r % N;
    Sn[(((size_t)b * T + t) * N + n) * D + e] =
        __float2bfloat16((o - mu) * rr * gs[e] + bbs[e]);
  }
}

// ---------------------------------------------------------------------------
// ff v3 = v2 + packed-f16 fdot2 gemvs.  ts packed (tslp, stride 17), h packed
// (hlp, stride 33), w1/w2 packed by input-pairs.  Pass1: 16 fdot2/hidden
// (was 32 FMA); pass2: 32 fdot2/output (was 64 FMA).  Residual from packed
// ts (tv[j4&1] — compile-time element index).
// ---------------------------------------------------------------------------
__global__ __launch_bounds__(256) void ff_kernel(
    const bf16* __restrict__ Tn, const bf16* __restrict__ Sn,
    const float* __restrict__ W1, const float* __restrict__ b1,
    const float* __restrict__ W2, const float* __restrict__ b2,
    const float* __restrict__ ln_g, const float* __restrict__ ln_b,
    bf16* __restrict__ E) {
  __shared__ unsigned w1h[(D / 2) * FF];   // 1024 uints, 4KB
  __shared__ unsigned w2h[(FF / 2) * D];   // 1024 uints, 4KB
  __shared__ float bb1[FF], bb2[D], gs[D], bbs[D];
  __shared__ unsigned tslp[FR][D / 2 + 1]; // 32 x 17 (stride 17: conflict-free)
  __shared__ unsigned hlp[FR][FF / 2 + 1]; // 32 x 33 (stride 33: conflict-free)
  int tid = threadIdx.x;
  int r0 = blockIdx.x * FR;
  for (int i = tid; i < (D / 2) * FF; i += 256) {
    int d2 = i / FF, jj = i % FF;
    w1h[i] = pkh2(W1[(2 * d2) * FF + jj], W1[(2 * d2 + 1) * FF + jj]);
  }
  for (int i = tid; i < (FF / 2) * D; i += 256) {
    int k2 = i / D, e = i % D;
    w2h[i] = pkh2(W2[(2 * k2) * D + e], W2[(2 * k2 + 1) * D + e]);
  }
  if (tid < FF) bb1[tid] = b1[tid];
  if (tid < D) { bb2[tid] = b2[tid]; gs[tid] = ln_g[tid]; bbs[tid] = ln_b[tid]; }
  int r = tid >> 3, s = tid & 7;
  {
    const bf16* tp = Tn + ((size_t)(r0 + r)) * D + s * 4;
    const bf16* sp = Sn + ((size_t)(r0 + r)) * D + s * 4;
    uint2 tu = *(const uint2*)tp;
    uint2 su = *(const uint2*)sp;
    float t0 = blo(tu.x) + blo(su.x);
    float t1 = bhi(tu.x) + bhi(su.x);
    float t2 = blo(tu.y) + blo(su.y);
    float t3 = bhi(tu.y) + bhi(su.y);
    tslp[r][s * 2]     = pkh2(t0, t1);
    tslp[r][s * 2 + 1] = pkh2(t2, t3);
  }
  __syncthreads();
  // pass1: 8 hidden units per lane via fdot2
  {
    float hh[8];
#pragma unroll
    for (int j = 0; j < 8; ++j) {
      int jj = s * 8 + j;
      float a = bb1[jj];
#pragma unroll
      for (int d2 = 0; d2 < D / 2; ++d2)
        a = __builtin_amdgcn_fdot2(u2h(tslp[r][d2]), u2h(w1h[d2 * FF + jj]), a, false);
      hh[j] = fmaxf(a, 0.f);
    }
#pragma unroll
    for (int j = 0; j < 4; ++j)
      hlp[r][s * 4 + j] = pkh2(hh[2 * j], hh[2 * j + 1]);
  }
  __syncthreads();
  // pass2: 4 outputs per lane via fdot2 + LN (3-level shfl reduce)
  {
    float x[4];
    float s1 = 0.f, s2 = 0.f;
#pragma unroll
    for (int j4 = 0; j4 < 4; ++j4) {
      int e = s * 4 + j4;
      h2 tv = u2h(tslp[r][e >> 1]);
      float a = bb2[e] + (float)tv[j4 & 1];   // s*4 even -> e&1 == j4&1
#pragma unroll
      for (int k2 = 0; k2 < FF / 2; ++k2)
        a = __builtin_amdgcn_fdot2(u2h(hlp[r][k2]), u2h(w2h[k2 * D + e]), a, false);
      x[j4] = a; s1 += a; s2 += a * a;
    }
    s1 += __shfl_xor(s1, 1, 64); s2 += __shfl_xor(s2, 1, 64);
    s1 += __shfl_xor(s1, 2, 64); s2 += __shfl_xor(s2, 2, 64);
    s1 += __shfl_xor(s1, 4, 64); s2 += __shfl_xor(s2, 4, 64);
    float mu  = s1 * (1.f / D);
    float var = s2 * (1.f / D) - mu * mu;
    float rr = rsqrtf(var + 1e-5f);
    int e0 = s * 4;
    uint2 ou;
    ou.x = pk2((x[0]-mu)*rr*gs[e0]+bbs[e0],    (x[1]-mu)*rr*gs[e0+1]+bbs[e0+1]);
    ou.y = pk2((x[2]-mu)*rr*gs[e0+2]+bbs[e0+2],(x[3]-mu)*rr*gs[e0+3]+bbs[e0+3]);
    *(uint2*)&E[((size_t)(r0 + r)) * D + e0] = ou;
  }
}

// ---------------------------------------------------------------------------
// out = E@op_W + op_b + X   (f32 out)
// ---------------------------------------------------------------------------
__global__ __launch_bounds__(256) void out_kernel(
    const bf16* __restrict__ E, const float* __restrict__ op_W,
    const float* __restrict__ op_b, const float* __restrict__ X,
    float* __restrict__ out) {
  int idx = blockIdx.x * 256 + threadIdx.x;
  if (idx >= B * T * N * M) return;
  int m  = idx % M;
  int n  = (idx / M) % N;
  int bt = idx / (M * N);
  float acc = op_b[n * M + m];
  const bf16* e = E + ((size_t)bt * N + n) * D;
#pragma unroll
  for (int d = 0; d < D; ++d) acc += b2f(e[d]) * op_W[(n * D + d) * M + m];
  acc += X[idx];
  out[idx] = acc;
}

// ---------------------------------------------------------------------------
extern "C" void kernel_launch(void* const* d_in, const int* in_sizes, int n_in,
                              void* d_out, int out_size, void* d_ws, size_t ws_size,
                              hipStream_t stream) {
  const float* X     = (const float*)d_in[0];
  const float* pe    = (const float*)d_in[1];
  const float* E_W   = (const float*)d_in[2];
  const float* E_b   = (const float*)d_in[3];
  const float* tq_W  = (const float*)d_in[4];
  const float* tq_b  = (const float*)d_in[5];
  const float* tk_W  = (const float*)d_in[6];
  const float* tk_b  = (const float*)d_in[7];
  const float* tv_W  = (const float*)d_in[8];
  const float* tv_b  = (const float*)d_in[9];
  const float* tm_Wq = (const float*)d_in[10];
  const float* tm_bq = (const float*)d_in[11];
  const float* tm_Wk = (const float*)d_in[12];
  const float* tm_bk = (const float*)d_in[13];
  const float* tm_Wv = (const float*)d_in[14];
  const float* tm_bv = (const float*)d_in[15];
  const float* tm_Wo = (const float*)d_in[16];
  const float* tm_bo = (const float*)d_in[17];
  const float* sq_W  = (const float*)d_in[18];
  const float* sq_b  = (const float*)d_in[19];
  const float* sk_W  = (const float*)d_in[20];
  const float* sk_b  = (const float*)d_in[21];
  const float* sv_W  = (const float*)d_in[22];
  const float* sv_b  = (const float*)d_in[23];
  const float* sm_Wq = (const float*)d_in[24];
  const float* sm_bq = (const float*)d_in[25];
  const float* sm_Wk = (const float*)d_in[26];
  const float* sm_bk = (const float*)d_in[27];
  const float* sm_Wv = (const float*)d_in[28];
  const float* sm_bv = (const float*)d_in[29];
  const float* sm_Wo = (const float*)d_in[30];
  const float* sm_bo = (const float*)d_in[31];
  const float* ff1_W = (const float*)d_in[32];
  const float* ff1_b = (const float*)d_in[33];
  const float* ff2_W = (const float*)d_in[34];
  const float* ff2_b = (const float*)d_in[35];
  const float* ln_g  = (const float*)d_in[36];
  const float* ln_b  = (const float*)d_in[37];
  const float* op_W  = (const float*)d_in[38];
  const float* op_b  = (const float*)d_in[39];
  float* out = (float*)d_out;

  float* WtC = (float*)d_ws;                         // 3*N*D*D
  float* btC = WtC + 3 * N * D * D;                  // 3*N*D
  float* WsC = btC + 3 * N * D;                      // 3*T*D*D
  float* bsC = WsC + 3 * T * D * D;                  // 3*T*D
  size_t act = (size_t)B * T * N * D;
  bf16* Ebuf = (bf16*)(bsC + 3 * T * D);
  bf16* Tn   = Ebuf + act;
  bf16* Qt   = Tn + act;
  bf16* Kt   = Qt + act;
  bf16* Vt   = Kt + act;
  bf16* Sn   = Qt;                                   // alias (safe: serial schedule)

  compose3_kernel<<<3 * N, 256, 0, stream>>>(
      tq_W, tq_b, tm_Wq, tm_bq, tk_W, tk_b, tm_Wk, tm_bk,
      tv_W, tv_b, tm_Wv, tm_bv, WtC, btC, N);
  compose3_kernel<<<3 * T, 256, 0, stream>>>(
      sq_W, sq_b, sm_Wq, sm_bq, sk_W, sk_b, sm_Wk, sm_bk,
      sv_W, sv_b, sm_Wv, sm_bv, WsC, bsC, T);

  embed_kernel<<<(B * T * N * D) / 256, 256, 0, stream>>>(X, pe, E_W, E_b, Ebuf);

  for (int l = 0; l < L; ++l) {
    qkvt_kernel<<<N * QCH, 256, 0, stream>>>(Ebuf, WtC, btC, Qt, Kt, Vt);
    attnt_kernel<<<B * N, 256, 0, stream>>>(Qt, Kt, Vt, Ebuf, tm_Wo, tm_bo, ln_g, ln_b, Tn);
    spatial_kernel<<<T * (B / BG), 256, 0, stream>>>(Ebuf, WsC, bsC, sm_Wo, sm_bo, ln_g, ln_b, Sn);
    ff_kernel<<<(B * T * N) / FR, 256, 0, stream>>>(Tn, Sn, ff1_W, ff1_b, ff2_W, ff2_b, ln_g, ln_b, Ebuf);
  }

  out_kernel<<<(B * T * N * M + 255) / 256, 256, 0, stream>>>(Ebuf, op_W, op_b, X, out);
}

// Round 27
// 627.940 us; speedup vs baseline: 1.4592x; 1.0815x over previous
//
#include <hip/hip_runtime.h>
#include <hip/hip_bf16.h>

typedef __hip_bfloat16 bf16;
typedef __fp16 h2 __attribute__((ext_vector_type(2)));   // matches amdgcn builtin 'V2h'

constexpr int B  = 64, T = 120, N = 24, M = 3, D = 32;
constexpr int NH = 2, FD = 16, FF = 64, L = 3;
constexpr float SCALE = 0.25f;   // 1/sqrt(FD)
constexpr int SK  = 40;          // attnt K/Q f16 LDS stride (80B rows)
constexpr int SKF = 36;          // attnt V/O f32 LDS stride (144B rows)
constexpr int CH2 = 30;          // attnt rows per chunk: 4 x 30 = 120 exactly
constexpr int NJ  = 30;          // max keys per lane slice (120/4)
constexpr int QR  = 64;          // qkvt rows per block (4 lanes/row)
constexpr int QCH = (B * T) / QR;// qkvt chunks = 120
constexpr int QEH = 20;          // qkvt packed-f16 Es stride (uints, 80B)
constexpr int BG  = 2;           // spatial batches per block
constexpr int SR  = N * BG;      // spatial rows per block = 48
constexpr int SEH = 20;          // spatial packed-f16 Es stride (uints, 80B)
constexpr int SQS = 33;          // spatial Q/K/V f32 stride (no 32-way conflicts)
constexpr int FR  = 32;          // ff rows per block (8 lanes/row)

__device__ __forceinline__ float b2f(bf16 x) { return __bfloat162float(x); }
__device__ __forceinline__ float blo(unsigned u) { return __uint_as_float(u << 16); }
__device__ __forceinline__ float bhi(unsigned u) { return __uint_as_float(u & 0xffff0000u); }
__device__ __forceinline__ unsigned pk2(float a, float b) {
  bf16 x = __float2bfloat16(a), y = __float2bfloat16(b);
  unsigned short ux = *reinterpret_cast<unsigned short*>(&x);
  unsigned short uy = *reinterpret_cast<unsigned short*>(&y);
  return (unsigned)ux | ((unsigned)uy << 16);
}
__device__ __forceinline__ unsigned pkh2(float a, float b) {
  h2 r = __builtin_amdgcn_cvt_pkrtz(a, b);     // v_cvt_pkrtz_f16_f32
  return *reinterpret_cast<unsigned*>(&r);
}
__device__ __forceinline__ h2 u2h(unsigned u) { return *reinterpret_cast<h2*>(&u); }

// ---------------------------------------------------------------------------
// Compose q/k/v chained linears: grid = 3*U blocks.  Wc = W1@W2, bc = b1@W2+b2.
// ---------------------------------------------------------------------------
__global__ __launch_bounds__(256) void compose3_kernel(
    const float* __restrict__ W1q, const float* __restrict__ b1q,
    const float* __restrict__ W2q, const float* __restrict__ b2q,
    const float* __restrict__ W1k, const float* __restrict__ b1k,
    const float* __restrict__ W2k, const float* __restrict__ b2k,
    const float* __restrict__ W1v, const float* __restrict__ b1v,
    const float* __restrict__ W2v, const float* __restrict__ b2v,
    float* __restrict__ Wc, float* __restrict__ bc, int U) {
  int fam = blockIdx.x / U;
  int n   = blockIdx.x % U;
  const float* W1 = (fam == 0) ? W1q : (fam == 1) ? W1k : W1v;
  const float* b1 = (fam == 0) ? b1q : (fam == 1) ? b1k : b1v;
  const float* W2 = (fam == 0) ? W2q : (fam == 1) ? W2k : W2v;
  const float* b2 = (fam == 0) ? b2q : (fam == 1) ? b2k : b2v;
  const float* w1 = W1 + n * D * D;
  const float* w2 = W2 + n * D * D;
  float* wc  = Wc + (size_t)(fam * U + n) * D * D;
  float* bcp = bc + (fam * U + n) * D;
  __shared__ float s1[D * D], s2[D * D];
  for (int i = threadIdx.x; i < D * D; i += 256) { s1[i] = w1[i]; s2[i] = w2[i]; }
  __syncthreads();
  for (int i = threadIdx.x; i < D * D; i += 256) {
    int d = i >> 5, f = i & 31;
    float acc = 0.f;
#pragma unroll
    for (int e = 0; e < D; ++e) acc += s1[d * D + e] * s2[e * D + f];
    wc[i] = acc;
  }
  if (threadIdx.x < D) {
    int f = threadIdx.x;
    float acc = b2[n * D + f];
#pragma unroll
    for (int e = 0; e < D; ++e) acc += b1[n * D + e] * s2[e * D + f];
    bcp[f] = acc;
  }
}

// ---------------------------------------------------------------------------
// E[b,t,n,d] = X@E_W + E_b + pe   (bf16 out)
// ---------------------------------------------------------------------------
__global__ __launch_bounds__(256) void embed_kernel(
    const float* __restrict__ X, const float* __restrict__ pe,
    const float* __restrict__ E_W, const float* __restrict__ E_b,
    bf16* __restrict__ E) {
  int idx = blockIdx.x * 256 + threadIdx.x;
  if (idx >= B * T * N * D) return;
  int d = idx & 31;
  int n = (idx >> 5) % N;
  int bt = idx / (D * N);
  int t = bt % T;
  const float* x = X + bt * (N * M) + n * M;
  float acc = E_b[n * D + d] + pe[t * D + d];
#pragma unroll
  for (int m = 0; m < M; ++m) acc += x[m] * E_W[(n * M + m) * D + d];
  E[idx] = __float2bfloat16(acc);
}

// ---------------------------------------------------------------------------
// qkvt v3 = v2 + packed-f16 fdot2 gemv.  Es staged as packed f16 (16 uints/
// row, stride 20); weights packed by d-pairs whh[fam][d2][j] (spatial-proven
// layout).  Inner loop: 384 fdot2, zero unpacks (was 32 unpacks + 768 FMA).
// LDS 17.4 -> 11.6 KB.  Q/K/V are consumed as f16 in attnt anyway.
// ---------------------------------------------------------------------------
__global__ __launch_bounds__(256) void qkvt_kernel(
    const bf16* __restrict__ E, const float* __restrict__ WtC,
    const float* __restrict__ btC,
    bf16* __restrict__ Qt, bf16* __restrict__ Kt, bf16* __restrict__ Vt) {
  int n     = blockIdx.x / QCH;
  int chunk = blockIdx.x % QCH;
  __shared__ unsigned whh[3 * (D / 2) * D];        // 1536 uints, 6 KB
  __shared__ float bsh[3 * D];
  __shared__ __align__(16) unsigned Esp[QR * QEH]; // packed f16 Es, 5 KB
  int tid = threadIdx.x;
  for (int i = tid; i < 3 * (D / 2) * D; i += 256) {
    int fam = i / ((D / 2) * D);
    int idx = i % ((D / 2) * D);
    int d2 = idx >> 5, j = idx & 31;
    const float* wg = WtC + (size_t)(fam * N + n) * D * D;
    whh[i] = pkh2(wg[(2 * d2) * D + j], wg[(2 * d2 + 1) * D + j]);
  }
  if (tid < 3 * D) {
    int fam = tid >> 5, e = tid & 31;
    bsh[tid] = btC[(fam * N + n) * D + e];
  }
  {
    int row = tid >> 2, p = tid & 3;
    const bf16* er = E + ((size_t)(chunk * QR + row) * N + n) * D;
    uint4 u = *(const uint4*)&er[p * 8];
    uint4 o;
    o.x = pkh2(blo(u.x), bhi(u.x));
    o.y = pkh2(blo(u.y), bhi(u.y));
    o.z = pkh2(blo(u.z), bhi(u.z));
    o.w = pkh2(blo(u.w), bhi(u.w));
    *(uint4*)&Esp[row * QEH + p * 4] = o;
  }
  __syncthreads();

  int row = tid >> 2, q = tid & 3;
  int grow = chunk * QR + row;          // b*T + t
  int b = grow / T, t = grow % T;
  unsigned xp[D / 2];
#pragma unroll
  for (int d2 = 0; d2 < D / 2; ++d2) xp[d2] = Esp[row * QEH + d2];
  size_t dsto = (((size_t)b * N + n) * T + t) * D + q * 8;
  bf16* dsts[3] = { Qt + dsto, Kt + dsto, Vt + dsto };
#pragma unroll
  for (int fam = 0; fam < 3; ++fam) {
    const unsigned* wf = whh + fam * (D / 2) * D;
    const float* bi = bsh + fam * D;
    float a[8];
#pragma unroll
    for (int j = 0; j < 8; ++j) a[j] = bi[q * 8 + j];
#pragma unroll
    for (int d2 = 0; d2 < D / 2; ++d2) {
      h2 x = u2h(xp[d2]);
#pragma unroll
      for (int j = 0; j < 8; ++j)
        a[j] = __builtin_amdgcn_fdot2(x, u2h(wf[d2 * D + q * 8 + j]), a[j], false);
    }
    uint4 o;
    o.x = pk2(a[0], a[1]); o.y = pk2(a[2], a[3]);
    o.z = pk2(a[4], a[5]); o.w = pk2(a[6], a[7]);
    *(uint4*)dsts[fam] = o;
  }
}

// ---------------------------------------------------------------------------
// attnt v10: packed f16 dot-product scores (measured R24: 100.7us, was 118).
// ---------------------------------------------------------------------------
__global__ __launch_bounds__(256) void attnt_kernel(
    const bf16* __restrict__ Qt, const bf16* __restrict__ Kt,
    const bf16* __restrict__ Vt, const bf16* __restrict__ E,
    const float* __restrict__ tm_Wo, const float* __restrict__ tm_bo,
    const float* __restrict__ ln_g, const float* __restrict__ ln_b,
    bf16* __restrict__ Tn) {
  int bn = blockIdx.x;
  int n  = bn % N, b = bn / N;
  __shared__ __align__(16) __fp16 Klh[T * SK];    // 9600 B
  __shared__ __align__(16) float  Vlf[T * SKF];   // 17280 B
  __shared__ __align__(16) __fp16 Qlh[CH2 * SK];  // 2400 B
  __shared__ __align__(16) float  Ol[CH2 * SKF];  // 4320 B
  __shared__ float Wol[D * D], bol[D], gl[D], bbl[D];
  int tid = threadIdx.x;

  const bf16* Kg = Kt + (size_t)bn * T * D;
  const bf16* Vg = Vt + (size_t)bn * T * D;
  const bf16* Qg = Qt + (size_t)bn * T * D;
  for (int i = tid; i < T * 4; i += 256) {
    int r = i >> 2, p = i & 3;
    uint4 ku = *(const uint4*)&Kg[r * D + p * 8];
    uint4 kh;
    kh.x = pkh2(blo(ku.x), bhi(ku.x));
    kh.y = pkh2(blo(ku.y), bhi(ku.y));
    kh.z = pkh2(blo(ku.z), bhi(ku.z));
    kh.w = pkh2(blo(ku.w), bhi(ku.w));
    *(uint4*)&Klh[r * SK + p * 8] = kh;
    uint4 vu = *(const uint4*)&Vg[r * D + p * 8];
    *(float4*)&Vlf[r * SKF + p * 8]     = make_float4(blo(vu.x), bhi(vu.x), blo(vu.y), bhi(vu.y));
    *(float4*)&Vlf[r * SKF + p * 8 + 4] = make_float4(blo(vu.z), bhi(vu.z), blo(vu.w), bhi(vu.w));
  }
  for (int i = tid; i < D * D; i += 256) Wol[i] = tm_Wo[(size_t)n * D * D + i];
  if (tid < D) {
    bol[tid] = tm_bo[n * D + tid];
    gl[tid]  = ln_g[tid];
    bbl[tid] = ln_b[tid];
  }
  __syncthreads();

#pragma unroll 1
  for (int c = 0; c < 4; ++c) {
    if (tid < CH2 * 4) {
      int r = tid >> 2, p = tid & 3;
      uint4 qu = *(const uint4*)&Qg[(CH2 * c + r) * D + p * 8];
      uint4 qh;
      qh.x = pkh2(blo(qu.x), bhi(qu.x));
      qh.y = pkh2(blo(qu.y), bhi(qu.y));
      qh.z = pkh2(blo(qu.z), bhi(qu.z));
      qh.w = pkh2(blo(qu.w), bhi(qu.w));
      *(uint4*)&Qlh[r * SK + p * 8] = qh;
    }
    __syncthreads();   // Qlh ready; prior O-proj done -> Ol safe to overwrite

    {
      int task = tid >> 2, sl = tid & 3;
      if (task < 2 * CH2) {
        int rl = task >> 1, h = task & 1, ho = h * FD;
        int rg = CH2 * c + rl;
        uint4 q0 = *(const uint4*)&Qlh[rl * SK + ho];
        uint4 q1 = *(const uint4*)&Qlh[rl * SK + ho + 8];
        unsigned qh[8] = { q0.x, q0.y, q0.z, q0.w, q1.x, q1.y, q1.z, q1.w };

        float sc[NJ];
        float mx = -3e38f;
#pragma unroll
        for (int j = 0; j < NJ; ++j) {
          int k = 4 * j + sl;
          sc[j] = -3e38f;
          if (k <= rg) {
            const uint4 ka = *(const uint4*)&Klh[k * SK + ho];
            const uint4 kb = *(const uint4*)&Klh[k * SK + ho + 8];
            float s0 = __builtin_amdgcn_fdot2(u2h(qh[0]), u2h(ka.x), 0.f, false);
            float s1 = __builtin_amdgcn_fdot2(u2h(qh[1]), u2h(ka.y), 0.f, false);
            float s2 = __builtin_amdgcn_fdot2(u2h(qh[2]), u2h(ka.z), 0.f, false);
            float s3 = __builtin_amdgcn_fdot2(u2h(qh[3]), u2h(ka.w), 0.f, false);
            s0 = __builtin_amdgcn_fdot2(u2h(qh[4]), u2h(kb.x), s0, false);
            s1 = __builtin_amdgcn_fdot2(u2h(qh[5]), u2h(kb.y), s1, false);
            s2 = __builtin_amdgcn_fdot2(u2h(qh[6]), u2h(kb.z), s2, false);
            s3 = __builtin_amdgcn_fdot2(u2h(qh[7]), u2h(kb.w), s3, false);
            float s = ((s0 + s1) + (s2 + s3)) * SCALE;
            sc[j] = s;
            mx = fmaxf(mx, s);
          }
        }
        mx = fmaxf(mx, __shfl_xor(mx, 1, 64));
        mx = fmaxf(mx, __shfl_xor(mx, 2, 64));
        float l = 0.f;
#pragma unroll
        for (int j = 0; j < NJ; ++j) {
          sc[j] = __expf(sc[j] - mx);   // invalid slots: exp(-inf) = 0
          l += sc[j];
        }
        l += __shfl_xor(l, 1, 64);
        l += __shfl_xor(l, 2, 64);
        float rli = 1.f / l;

        float acc[16];
#pragma unroll
        for (int f = 0; f < 16; ++f) acc[f] = 0.f;
#pragma unroll
        for (int j = 0; j < NJ; ++j) {
          int k = 4 * j + sl;
          if (k <= rg) {
            float p = sc[j];
            const float4 v0 = *(const float4*)&Vlf[k * SKF + ho];
            const float4 v1 = *(const float4*)&Vlf[k * SKF + ho + 4];
            const float4 v2 = *(const float4*)&Vlf[k * SKF + ho + 8];
            const float4 v3 = *(const float4*)&Vlf[k * SKF + ho + 12];
            acc[0]  += p * v0.x; acc[1]  += p * v0.y;
            acc[2]  += p * v0.z; acc[3]  += p * v0.w;
            acc[4]  += p * v1.x; acc[5]  += p * v1.y;
            acc[6]  += p * v1.z; acc[7]  += p * v1.w;
            acc[8]  += p * v2.x; acc[9]  += p * v2.y;
            acc[10] += p * v2.z; acc[11] += p * v2.w;
            acc[12] += p * v3.x; acc[13] += p * v3.y;
            acc[14] += p * v3.z; acc[15] += p * v3.w;
          }
        }
#pragma unroll
        for (int f = 0; f < 16; ++f) {
          acc[f] += __shfl_xor(acc[f], 1, 64);
          acc[f] += __shfl_xor(acc[f], 2, 64);
        }
        if (sl == 0) {
#pragma unroll
          for (int f = 0; f < 16; ++f) Ol[rl * SKF + ho + f] = acc[f] * rli;
        }
      }
    }
    __syncthreads();

    {
      int rl = tid >> 3, q = tid & 7, e0 = q * 4;
      if (rl < CH2) {
        int rg = CH2 * c + rl;
        size_t rowo = ((size_t)(b * T + rg) * N + n) * D;
        uint2 eu = *(const uint2*)&E[rowo + e0];
        float res[4] = { blo(eu.x), bhi(eu.x), blo(eu.y), bhi(eu.y) };
        float o[4], s1 = 0.f, s2 = 0.f;
#pragma unroll
        for (int j = 0; j < 4; ++j) {
          int e = e0 + j;
          float aa = 0.f, ab = 0.f;
#pragma unroll
          for (int d = 0; d < D; d += 2) {
            aa += Ol[rl * SKF + d]     * Wol[d * D + e];
            ab += Ol[rl * SKF + d + 1] * Wol[(d + 1) * D + e];
          }
          float a = bol[e] + aa + ab + res[j];
          o[j] = a; s1 += a; s2 += a * a;
        }
        s1 += __shfl_xor(s1, 1, 64); s2 += __shfl_xor(s2, 1, 64);
        s1 += __shfl_xor(s1, 2, 64); s2 += __shfl_xor(s2, 2, 64);
        s1 += __shfl_xor(s1, 4, 64); s2 += __shfl_xor(s2, 4, 64);
        float mu  = s1 * (1.f / D);
        float var = s2 * (1.f / D) - mu * mu;
        float r = rsqrtf(var + 1e-5f);
        uint2 ou;
        ou.x = pk2((o[0]-mu)*r*gl[e0]+bbl[e0],    (o[1]-mu)*r*gl[e0+1]+bbl[e0+1]);
        ou.y = pk2((o[2]-mu)*r*gl[e0+2]+bbl[e0+2],(o[3]-mu)*r*gl[e0+3]+bbl[e0+3]);
        *(uint2*)&Tn[rowo + e0] = ou;
      }
    }
  }
}

// ---------------------------------------------------------------------------
// spatial v4: packed-f16 gemv (fdot2).
// ---------------------------------------------------------------------------
__global__ __launch_bounds__(256) void spatial_kernel(
    const bf16* __restrict__ E, const float* __restrict__ WsC,
    const float* __restrict__ bsC, const float* __restrict__ sm_Wo,
    const float* __restrict__ sm_bo, const float* __restrict__ ln_g,
    const float* __restrict__ ln_b, bf16* __restrict__ Sn) {
  int t  = blockIdx.x >> 5;          // B/BG = 32 groups per t
  int bg = blockIdx.x & 31;
  int b0 = bg * BG;
  __shared__ unsigned Wh[3 * (D / 2) * D];          // packed f16 pairs, 6144 B
  __shared__ float Wo[D * D];
  __shared__ float bqs[D], bks[D], bvs[D], bos[D], gs[D], bbs[D];
  __shared__ __align__(16) unsigned Esh[SR * SEH];  // packed f16 Es, 3840 B
  __shared__ float Qs[SR * SQS], Ks[SR * SQS], Vs[SR * SQS];
  int tid = threadIdx.x;

  for (int i = tid; i < 3 * (D / 2) * D; i += 256) {
    int fam = i / ((D / 2) * D);
    int idx = i % ((D / 2) * D);
    int d2 = idx >> 5, e = idx & 31;
    const float* wg = WsC + (size_t)(fam * T + t) * D * D;
    Wh[i] = pkh2(wg[(2 * d2) * D + e], wg[(2 * d2 + 1) * D + e]);
  }
  for (int i = tid; i < D * D; i += 256) Wo[i] = sm_Wo[(size_t)t * D * D + i];
  if (tid < D) {
    bqs[tid] = bsC[(0 * T + t) * D + tid];
    bks[tid] = bsC[(1 * T + t) * D + tid];
    bvs[tid] = bsC[(2 * T + t) * D + tid];
    bos[tid] = sm_bo[t * D + tid];
    gs[tid]  = ln_g[tid];
    bbs[tid] = ln_b[tid];
  }
  if (tid < SR * 4) {
    int r = tid >> 2, p = tid & 3;
    int b = b0 + r / N, n = r % N;
    uint4 u = *(const uint4*)&E[(((size_t)b * T + t) * N + n) * D + p * 8];
    uint4 o;
    o.x = pkh2(blo(u.x), bhi(u.x));
    o.y = pkh2(blo(u.y), bhi(u.y));
    o.z = pkh2(blo(u.z), bhi(u.z));
    o.w = pkh2(blo(u.w), bhi(u.w));
    *(uint4*)&Esh[r * SEH + p * 4] = o;
  }
  __syncthreads();

#pragma unroll 1
  for (int i = tid; i < SR * D; i += 256) {
    int r = i >> 5, e = i & 31;
    float aq = bqs[e], ak = bks[e], av = bvs[e];
#pragma unroll
    for (int d2 = 0; d2 < D / 2; ++d2) {
      h2 x = u2h(Esh[r * SEH + d2]);
      aq = __builtin_amdgcn_fdot2(x, u2h(Wh[0 * 512 + d2 * 32 + e]), aq, false);
      ak = __builtin_amdgcn_fdot2(x, u2h(Wh[1 * 512 + d2 * 32 + e]), ak, false);
      av = __builtin_amdgcn_fdot2(x, u2h(Wh[2 * 512 + d2 * 32 + e]), av, false);
    }
    Qs[r * SQS + e] = aq;
    Ks[r * SQS + e] = ak;
    Vs[r * SQS + e] = av;
  }
  __syncthreads();

  if (tid < SR * NH) {
    int r = tid >> 1, h = tid & 1, ho = h * FD;
    int kb = (r >= N) ? N : 0;
    float q[FD];
#pragma unroll
    for (int f = 0; f < FD; ++f) q[f] = Qs[r * SQS + ho + f];
    float sc[N];
    float m = -1e30f;
#pragma unroll
    for (int k = 0; k < N; ++k) {
      float sa = 0.f, sb = 0.f;
#pragma unroll
      for (int f = 0; f < FD; f += 2) {
        sa += q[f]     * Ks[(kb + k) * SQS + ho + f];
        sb += q[f + 1] * Ks[(kb + k) * SQS + ho + f + 1];
      }
      float s = (sa + sb) * SCALE;
      sc[k] = s;
      m = fmaxf(m, s);
    }
    float l = 0.f;
#pragma unroll
    for (int k = 0; k < N; ++k) { sc[k] = __expf(sc[k] - m); l += sc[k]; }
    float rl = 1.f / l;
#pragma unroll
    for (int f = 0; f < FD; ++f) {
      float a = 0.f;
#pragma unroll
      for (int k = 0; k < N; ++k) a += sc[k] * Vs[(kb + k) * SQS + ho + f];
      Qs[r * SQS + ho + f] = a * rl;
    }
  }
  __syncthreads();

#pragma unroll 1
  for (int it = 0; it < SR * D / 256; ++it) {
    int i = it * 256 + tid;
    int r = i >> 5, e = i & 31;
    float aa = 0.f, ab = 0.f;
#pragma unroll
    for (int d = 0; d < D; d += 2) {
      aa += Qs[r * SQS + d]     * Wo[d * D + e];
      ab += Qs[r * SQS + d + 1] * Wo[(d + 1) * D + e];
    }
    h2 ex = u2h(Esh[r * SEH + (e >> 1)]);
    float res = (float)ex[e & 1];
    float o = bos[e] + aa + ab + res;
    float s1 = o, s2 = o * o;
    s1 += __shfl_xor(s1, 1, 64);  s2 += __shfl_xor(s2, 1, 64);
    s1 += __shfl_xor(s1, 2, 64);  s2 += __shfl_xor(s2, 2, 64);
    s1 += __shfl_xor(s1, 4, 64);  s2 += __shfl_xor(s2, 4, 64);
    s1 += __shfl_xor(s1, 8, 64);  s2 += __shfl_xor(s2, 8, 64);
    s1 += __shfl_xor(s1, 16, 64); s2 += __shfl_xor(s2, 16, 64);
    float mu  = s1 * (1.f / D);
    float var = s2 * (1.f / D) - mu * mu;
    float rr = rsqrtf(var + 1e-5f);
    int b = b0 + r / N, n = r % N;
    Sn[(((size_t)b * T + t) * N + n) * D + e] =
        __float2bfloat16((o - mu) * rr * gs[e] + bbs[e]);
  }
}

// ---------------------------------------------------------------------------
// ff v3: packed-f16 fdot2 gemvs (measured R26: ~-24us/dispatch).
// ---------------------------------------------------------------------------
__global__ __launch_bounds__(256) void ff_kernel(
    const bf16* __restrict__ Tn, const bf16* __restrict__ Sn,
    const float* __restrict__ W1, const float* __restrict__ b1,
    const float* __restrict__ W2, const float* __restrict__ b2,
    const float* __restrict__ ln_g, const float* __restrict__ ln_b,
    bf16* __restrict__ E) {
  __shared__ unsigned w1h[(D / 2) * FF];   // 1024 uints, 4KB
  __shared__ unsigned w2h[(FF / 2) * D];   // 1024 uints, 4KB
  __shared__ float bb1[FF], bb2[D], gs[D], bbs[D];
  __shared__ unsigned tslp[FR][D / 2 + 1]; // 32 x 17 (stride 17: conflict-free)
  __shared__ unsigned hlp[FR][FF / 2 + 1]; // 32 x 33 (stride 33: conflict-free)
  int tid = threadIdx.x;
  int r0 = blockIdx.x * FR;
  for (int i = tid; i < (D / 2) * FF; i += 256) {
    int d2 = i / FF, jj = i % FF;
    w1h[i] = pkh2(W1[(2 * d2) * FF + jj], W1[(2 * d2 + 1) * FF + jj]);
  }
  for (int i = tid; i < (FF / 2) * D; i += 256) {
    int k2 = i / D, e = i % D;
    w2h[i] = pkh2(W2[(2 * k2) * D + e], W2[(2 * k2 + 1) * D + e]);
  }
  if (tid < FF) bb1[tid] = b1[tid];
  if (tid < D) { bb2[tid] = b2[tid]; gs[tid] = ln_g[tid]; bbs[tid] = ln_b[tid]; }
  int r = tid >> 3, s = tid & 7;
  {
    const bf16* tp = Tn + ((size_t)(r0 + r)) * D + s * 4;
    const bf16* sp = Sn + ((size_t)(r0 + r)) * D + s * 4;
    uint2 tu = *(const uint2*)tp;
    uint2 su = *(const uint2*)sp;
    float t0 = blo(tu.x) + blo(su.x);
    float t1 = bhi(tu.x) + bhi(su.x);
    float t2 = blo(tu.y) + blo(su.y);
    float t3 = bhi(tu.y) + bhi(su.y);
    tslp[r][s * 2]     = pkh2(t0, t1);
    tslp[r][s * 2 + 1] = pkh2(t2, t3);
  }
  __syncthreads();
  // pass1: 8 hidden units per lane via fdot2
  {
    float hh[8];
#pragma unroll
    for (int j = 0; j < 8; ++j) {
      int jj = s * 8 + j;
      float a = bb1[jj];
#pragma unroll
      for (int d2 = 0; d2 < D / 2; ++d2)
        a = __builtin_amdgcn_fdot2(u2h(tslp[r][d2]), u2h(w1h[d2 * FF + jj]), a, false);
      hh[j] = fmaxf(a, 0.f);
    }
#pragma unroll
    for (int j = 0; j < 4; ++j)
      hlp[r][s * 4 + j] = pkh2(hh[2 * j], hh[2 * j + 1]);
  }
  __syncthreads();
  // pass2: 4 outputs per lane via fdot2 + LN (3-level shfl reduce)
  {
    float x[4];
    float s1 = 0.f, s2 = 0.f;
#pragma unroll
    for (int j4 = 0; j4 < 4; ++j4) {
      int e = s * 4 + j4;
      h2 tv = u2h(tslp[r][e >> 1]);
      float a = bb2[e] + (float)tv[j4 & 1];   // s*4 even -> e&1 == j4&1
#pragma unroll
      for (int k2 = 0; k2 < FF / 2; ++k2)
        a = __builtin_amdgcn_fdot2(u2h(hlp[r][k2]), u2h(w2h[k2 * D + e]), a, false);
      x[j4] = a; s1 += a; s2 += a * a;
    }
    s1 += __shfl_xor(s1, 1, 64); s2 += __shfl_xor(s2, 1, 64);
    s1 += __shfl_xor(s1, 2, 64); s2 += __shfl_xor(s2, 2, 64);
    s1 += __shfl_xor(s1, 4, 64); s2 += __shfl_xor(s2, 4, 64);
    float mu  = s1 * (1.f / D);
    float var = s2 * (1.f / D) - mu * mu;
    float rr = rsqrtf(var + 1e-5f);
    int e0 = s * 4;
    uint2 ou;
    ou.x = pk2((x[0]-mu)*rr*gs[e0]+bbs[e0],    (x[1]-mu)*rr*gs[e0+1]+bbs[e0+1]);
    ou.y = pk2((x[2]-mu)*rr*gs[e0+2]+bbs[e0+2],(x[3]-mu)*rr*gs[e0+3]+bbs[e0+3]);
    *(uint2*)&E[((size_t)(r0 + r)) * D + e0] = ou;
  }
}

// ---------------------------------------------------------------------------
// out = E@op_W + op_b + X   (f32 out)
// ---------------------------------------------------------------------------
__global__ __launch_bounds__(256) void out_kernel(
    const bf16* __restrict__ E, const float* __restrict__ op_W,
    const float* __restrict__ op_b, const float* __restrict__ X,
    float* __restrict__ out) {
  int idx = blockIdx.x * 256 + threadIdx.x;
  if (idx >= B * T * N * M) return;
  int m  = idx % M;
  int n  = (idx / M) % N;
  int bt = idx / (M * N);
  float acc = op_b[n * M + m];
  const bf16* e = E + ((size_t)bt * N + n) * D;
#pragma unroll
  for (int d = 0; d < D; ++d) acc += b2f(e[d]) * op_W[(n * D + d) * M + m];
  acc += X[idx];
  out[idx] = acc;
}

// ---------------------------------------------------------------------------
extern "C" void kernel_launch(void* const* d_in, const int* in_sizes, int n_in,
                              void* d_out, int out_size, void* d_ws, size_t ws_size,
                              hipStream_t stream) {
  const float* X     = (const float*)d_in[0];
  const float* pe    = (const float*)d_in[1];
  const float* E_W   = (const float*)d_in[2];
  const float* E_b   = (const float*)d_in[3];
  const float* tq_W  = (const float*)d_in[4];
  const float* tq_b  = (const float*)d_in[5];
  const float* tk_W  = (const float*)d_in[6];
  const float* tk_b  = (const float*)d_in[7];
  const float* tv_W  = (const float*)d_in[8];
  const float* tv_b  = (const float*)d_in[9];
  const float* tm_Wq = (const float*)d_in[10];
  const float* tm_bq = (const float*)d_in[11];
  const float* tm_Wk = (const float*)d_in[12];
  const float* tm_bk = (const float*)d_in[13];
  const float* tm_Wv = (const float*)d_in[14];
  const float* tm_bv = (const float*)d_in[15];
  const float* tm_Wo = (const float*)d_in[16];
  const float* tm_bo = (const float*)d_in[17];
  const float* sq_W  = (const float*)d_in[18];
  const float* sq_b  = (const float*)d_in[19];
  const float* sk_W  = (const float*)d_in[20];
  const float* sk_b  = (const float*)d_in[21];
  const float* sv_W  = (const float*)d_in[22];
  const float* sv_b  = (const float*)d_in[23];
  const float* sm_Wq = (const float*)d_in[24];
  const float* sm_bq = (const float*)d_in[25];
  const float* sm_Wk = (const float*)d_in[26];
  const float* sm_bk = (const float*)d_in[27];
  const float* sm_Wv = (const float*)d_in[28];
  const float* sm_bv = (const float*)d_in[29];
  const float* sm_Wo = (const float*)d_in[30];
  const float* sm_bo = (const float*)d_in[31];
  const float* ff1_W = (const float*)d_in[32];
  const float* ff1_b = (const float*)d_in[33];
  const float* ff2_W = (const float*)d_in[34];
  const float* ff2_b = (const float*)d_in[35];
  const float* ln_g  = (const float*)d_in[36];
  const float* ln_b  = (const float*)d_in[37];
  const float* op_W  = (const float*)d_in[38];
  const float* op_b  = (const float*)d_in[39];
  float* out = (float*)d_out;

  float* WtC = (float*)d_ws;                         // 3*N*D*D
  float* btC = WtC + 3 * N * D * D;                  // 3*N*D
  float* WsC = btC + 3 * N * D;                      // 3*T*D*D
  float* bsC = WsC + 3 * T * D * D;                  // 3*T*D
  size_t act = (size_t)B * T * N * D;
  bf16* Ebuf = (bf16*)(bsC + 3 * T * D);
  bf16* Tn   = Ebuf + act;
  bf16* Qt   = Tn + act;
  bf16* Kt   = Qt + act;
  bf16* Vt   = Kt + act;
  bf16* Sn   = Qt;                                   // alias (safe: serial schedule)

  compose3_kernel<<<3 * N, 256, 0, stream>>>(
      tq_W, tq_b, tm_Wq, tm_bq, tk_W, tk_b, tm_Wk, tm_bk,
      tv_W, tv_b, tm_Wv, tm_bv, WtC, btC, N);
  compose3_kernel<<<3 * T, 256, 0, stream>>>(
      sq_W, sq_b, sm_Wq, sm_bq, sk_W, sk_b, sm_Wk, sm_bk,
      sv_W, sv_b, sm_Wv, sm_bv, WsC, bsC, T);

  embed_kernel<<<(B * T * N * D) / 256, 256, 0, stream>>>(X, pe, E_W, E_b, Ebuf);

  for (int l = 0; l < L; ++l) {
    qkvt_kernel<<<N * QCH, 256, 0, stream>>>(Ebuf, WtC, btC, Qt, Kt, Vt);
    attnt_kernel<<<B * N, 256, 0, stream>>>(Qt, Kt, Vt, Ebuf, tm_Wo, tm_bo, ln_g, ln_b, Tn);
    spatial_kernel<<<T * (B / BG), 256, 0, stream>>>(Ebuf, WsC, bsC, sm_Wo, sm_bo, ln_g, ln_b, Sn);
    ff_kernel<<<(B * T * N) / FR, 256, 0, stream>>>(Tn, Sn, ff1_W, ff1_b, ff2_W, ff2_b, ln_g, ln_b, Ebuf);
  }

  out_kernel<<<(B * T * N * M + 255) / 256, 256, 0, stream>>>(Ebuf, op_W, op_b, X, out);
}

// Round 28
// 610.267 us; speedup vs baseline: 1.5014x; 1.0290x over previous
//
#include <hip/hip_runtime.h>
#include <hip/hip_bf16.h>

typedef __hip_bfloat16 bf16;
typedef __fp16 h2 __attribute__((ext_vector_type(2)));   // matches amdgcn builtin 'V2h'

constexpr int B  = 64, T = 120, N = 24, M = 3, D = 32;
constexpr int NH = 2, FD = 16, FF = 64, L = 3;
constexpr float SCALE = 0.25f;   // 1/sqrt(FD)
constexpr int SK  = 40;          // attnt K/Q f16 LDS stride (80B rows)
constexpr int SKF = 36;          // attnt V f32 LDS stride (144B rows)
constexpr int SOH = 20;          // attnt packed-f16 O stride (uints, 80B)
constexpr int CH2 = 30;          // attnt rows per chunk: 4 x 30 = 120 exactly
constexpr int NJ  = 30;          // max keys per lane slice (120/4)
constexpr int QR  = 64;          // qkvt rows per block (4 lanes/row)
constexpr int QCH = (B * T) / QR;// qkvt chunks = 120
constexpr int QEH = 20;          // qkvt packed-f16 Es stride (uints, 80B)
constexpr int BG  = 2;           // spatial batches per block
constexpr int SR  = N * BG;      // spatial rows per block = 48
constexpr int SEH = 20;          // spatial packed-f16 Es stride (uints, 80B)
constexpr int SQS = 33;          // spatial Q/K/V f32 stride (no 32-way conflicts)
constexpr int FR  = 32;          // ff rows per block (8 lanes/row)

__device__ __forceinline__ float b2f(bf16 x) { return __bfloat162float(x); }
__device__ __forceinline__ float blo(unsigned u) { return __uint_as_float(u << 16); }
__device__ __forceinline__ float bhi(unsigned u) { return __uint_as_float(u & 0xffff0000u); }
__device__ __forceinline__ unsigned pk2(float a, float b) {
  bf16 x = __float2bfloat16(a), y = __float2bfloat16(b);
  unsigned short ux = *reinterpret_cast<unsigned short*>(&x);
  unsigned short uy = *reinterpret_cast<unsigned short*>(&y);
  return (unsigned)ux | ((unsigned)uy << 16);
}
__device__ __forceinline__ unsigned pkh2(float a, float b) {
  h2 r = __builtin_amdgcn_cvt_pkrtz(a, b);     // v_cvt_pkrtz_f16_f32
  return *reinterpret_cast<unsigned*>(&r);
}
__device__ __forceinline__ h2 u2h(unsigned u) { return *reinterpret_cast<h2*>(&u); }

// ---------------------------------------------------------------------------
// Compose q/k/v chained linears: grid = 3*U blocks.  Wc = W1@W2, bc = b1@W2+b2.
// ---------------------------------------------------------------------------
__global__ __launch_bounds__(256) void compose3_kernel(
    const float* __restrict__ W1q, const float* __restrict__ b1q,
    const float* __restrict__ W2q, const float* __restrict__ b2q,
    const float* __restrict__ W1k, const float* __restrict__ b1k,
    const float* __restrict__ W2k, const float* __restrict__ b2k,
    const float* __restrict__ W1v, const float* __restrict__ b1v,
    const float* __restrict__ W2v, const float* __restrict__ b2v,
    float* __restrict__ Wc, float* __restrict__ bc, int U) {
  int fam = blockIdx.x / U;
  int n   = blockIdx.x % U;
  const float* W1 = (fam == 0) ? W1q : (fam == 1) ? W1k : W1v;
  const float* b1 = (fam == 0) ? b1q : (fam == 1) ? b1k : b1v;
  const float* W2 = (fam == 0) ? W2q : (fam == 1) ? W2k : W2v;
  const float* b2 = (fam == 0) ? b2q : (fam == 1) ? b2k : b2v;
  const float* w1 = W1 + n * D * D;
  const float* w2 = W2 + n * D * D;
  float* wc  = Wc + (size_t)(fam * U + n) * D * D;
  float* bcp = bc + (fam * U + n) * D;
  __shared__ float s1[D * D], s2[D * D];
  for (int i = threadIdx.x; i < D * D; i += 256) { s1[i] = w1[i]; s2[i] = w2[i]; }
  __syncthreads();
  for (int i = threadIdx.x; i < D * D; i += 256) {
    int d = i >> 5, f = i & 31;
    float acc = 0.f;
#pragma unroll
    for (int e = 0; e < D; ++e) acc += s1[d * D + e] * s2[e * D + f];
    wc[i] = acc;
  }
  if (threadIdx.x < D) {
    int f = threadIdx.x;
    float acc = b2[n * D + f];
#pragma unroll
    for (int e = 0; e < D; ++e) acc += b1[n * D + e] * s2[e * D + f];
    bcp[f] = acc;
  }
}

// ---------------------------------------------------------------------------
// E[b,t,n,d] = X@E_W + E_b + pe   (bf16 out)
// ---------------------------------------------------------------------------
__global__ __launch_bounds__(256) void embed_kernel(
    const float* __restrict__ X, const float* __restrict__ pe,
    const float* __restrict__ E_W, const float* __restrict__ E_b,
    bf16* __restrict__ E) {
  int idx = blockIdx.x * 256 + threadIdx.x;
  if (idx >= B * T * N * D) return;
  int d = idx & 31;
  int n = (idx >> 5) % N;
  int bt = idx / (D * N);
  int t = bt % T;
  const float* x = X + bt * (N * M) + n * M;
  float acc = E_b[n * D + d] + pe[t * D + d];
#pragma unroll
  for (int m = 0; m < M; ++m) acc += x[m] * E_W[(n * M + m) * D + d];
  E[idx] = __float2bfloat16(acc);
}

// ---------------------------------------------------------------------------
// qkvt v3: packed-f16 fdot2 gemv (measured R27: -17us/dispatch).
// ---------------------------------------------------------------------------
__global__ __launch_bounds__(256) void qkvt_kernel(
    const bf16* __restrict__ E, const float* __restrict__ WtC,
    const float* __restrict__ btC,
    bf16* __restrict__ Qt, bf16* __restrict__ Kt, bf16* __restrict__ Vt) {
  int n     = blockIdx.x / QCH;
  int chunk = blockIdx.x % QCH;
  __shared__ unsigned whh[3 * (D / 2) * D];        // 1536 uints, 6 KB
  __shared__ float bsh[3 * D];
  __shared__ __align__(16) unsigned Esp[QR * QEH]; // packed f16 Es, 5 KB
  int tid = threadIdx.x;
  for (int i = tid; i < 3 * (D / 2) * D; i += 256) {
    int fam = i / ((D / 2) * D);
    int idx = i % ((D / 2) * D);
    int d2 = idx >> 5, j = idx & 31;
    const float* wg = WtC + (size_t)(fam * N + n) * D * D;
    whh[i] = pkh2(wg[(2 * d2) * D + j], wg[(2 * d2 + 1) * D + j]);
  }
  if (tid < 3 * D) {
    int fam = tid >> 5, e = tid & 31;
    bsh[tid] = btC[(fam * N + n) * D + e];
  }
  {
    int row = tid >> 2, p = tid & 3;
    const bf16* er = E + ((size_t)(chunk * QR + row) * N + n) * D;
    uint4 u = *(const uint4*)&er[p * 8];
    uint4 o;
    o.x = pkh2(blo(u.x), bhi(u.x));
    o.y = pkh2(blo(u.y), bhi(u.y));
    o.z = pkh2(blo(u.z), bhi(u.z));
    o.w = pkh2(blo(u.w), bhi(u.w));
    *(uint4*)&Esp[row * QEH + p * 4] = o;
  }
  __syncthreads();

  int row = tid >> 2, q = tid & 3;
  int grow = chunk * QR + row;          // b*T + t
  int b = grow / T, t = grow % T;
  unsigned xp[D / 2];
#pragma unroll
  for (int d2 = 0; d2 < D / 2; ++d2) xp[d2] = Esp[row * QEH + d2];
  size_t dsto = (((size_t)b * N + n) * T + t) * D + q * 8;
  bf16* dsts[3] = { Qt + dsto, Kt + dsto, Vt + dsto };
#pragma unroll
  for (int fam = 0; fam < 3; ++fam) {
    const unsigned* wf = whh + fam * (D / 2) * D;
    const float* bi = bsh + fam * D;
    float a[8];
#pragma unroll
    for (int j = 0; j < 8; ++j) a[j] = bi[q * 8 + j];
#pragma unroll
    for (int d2 = 0; d2 < D / 2; ++d2) {
      h2 x = u2h(xp[d2]);
#pragma unroll
      for (int j = 0; j < 8; ++j)
        a[j] = __builtin_amdgcn_fdot2(x, u2h(wf[d2 * D + q * 8 + j]), a[j], false);
    }
    uint4 o;
    o.x = pk2(a[0], a[1]); o.y = pk2(a[2], a[3]);
    o.z = pk2(a[4], a[5]); o.w = pk2(a[6], a[7]);
    *(uint4*)dsts[fam] = o;
  }
}

// ---------------------------------------------------------------------------
// attnt v11 = v10 + packed-f16 O-proj (fdot2).  After PV merge, O packed to
// f16 pairs (Olh, stride 20 uints — distinct banks across the 8 rows/wave,
// broadcast within a row's 8 lanes).  Wol packed by d-pairs (woh, spatial-
// proven layout).  O-proj: 64 fdot2/thread (was 128 FMA).  LDS 38.4->34.1KB.
// ---------------------------------------------------------------------------
__global__ __launch_bounds__(256) void attnt_kernel(
    const bf16* __restrict__ Qt, const bf16* __restrict__ Kt,
    const bf16* __restrict__ Vt, const bf16* __restrict__ E,
    const float* __restrict__ tm_Wo, const float* __restrict__ tm_bo,
    const float* __restrict__ ln_g, const float* __restrict__ ln_b,
    bf16* __restrict__ Tn) {
  int bn = blockIdx.x;
  int n  = bn % N, b = bn / N;
  __shared__ __align__(16) __fp16 Klh[T * SK];        // 9600 B
  __shared__ __align__(16) float  Vlf[T * SKF];       // 17280 B
  __shared__ __align__(16) __fp16 Qlh[CH2 * SK];      // 2400 B
  __shared__ __align__(16) unsigned Olh[CH2 * SOH];   // packed f16 O, 2400 B
  __shared__ unsigned woh[(D / 2) * D];               // packed Wol, 2048 B
  __shared__ float bol[D], gl[D], bbl[D];
  int tid = threadIdx.x;

  const bf16* Kg = Kt + (size_t)bn * T * D;
  const bf16* Vg = Vt + (size_t)bn * T * D;
  const bf16* Qg = Qt + (size_t)bn * T * D;
  for (int i = tid; i < T * 4; i += 256) {
    int r = i >> 2, p = i & 3;
    uint4 ku = *(const uint4*)&Kg[r * D + p * 8];
    uint4 kh;
    kh.x = pkh2(blo(ku.x), bhi(ku.x));
    kh.y = pkh2(blo(ku.y), bhi(ku.y));
    kh.z = pkh2(blo(ku.z), bhi(ku.z));
    kh.w = pkh2(blo(ku.w), bhi(ku.w));
    *(uint4*)&Klh[r * SK + p * 8] = kh;
    uint4 vu = *(const uint4*)&Vg[r * D + p * 8];
    *(float4*)&Vlf[r * SKF + p * 8]     = make_float4(blo(vu.x), bhi(vu.x), blo(vu.y), bhi(vu.y));
    *(float4*)&Vlf[r * SKF + p * 8 + 4] = make_float4(blo(vu.z), bhi(vu.z), blo(vu.w), bhi(vu.w));
  }
  {
    const float* wg = tm_Wo + (size_t)n * D * D;
    for (int i = tid; i < (D / 2) * D; i += 256) {
      int d2 = i >> 5, e = i & 31;
      woh[i] = pkh2(wg[(2 * d2) * D + e], wg[(2 * d2 + 1) * D + e]);
    }
  }
  if (tid < D) {
    bol[tid] = tm_bo[n * D + tid];
    gl[tid]  = ln_g[tid];
    bbl[tid] = ln_b[tid];
  }
  __syncthreads();

#pragma unroll 1
  for (int c = 0; c < 4; ++c) {
    if (tid < CH2 * 4) {
      int r = tid >> 2, p = tid & 3;
      uint4 qu = *(const uint4*)&Qg[(CH2 * c + r) * D + p * 8];
      uint4 qh;
      qh.x = pkh2(blo(qu.x), bhi(qu.x));
      qh.y = pkh2(blo(qu.y), bhi(qu.y));
      qh.z = pkh2(blo(qu.z), bhi(qu.z));
      qh.w = pkh2(blo(qu.w), bhi(qu.w));
      *(uint4*)&Qlh[r * SK + p * 8] = qh;
    }
    __syncthreads();   // Qlh ready; prior O-proj done -> Olh safe to overwrite

    {
      int task = tid >> 2, sl = tid & 3;
      if (task < 2 * CH2) {
        int rl = task >> 1, h = task & 1, ho = h * FD;
        int rg = CH2 * c + rl;
        uint4 q0 = *(const uint4*)&Qlh[rl * SK + ho];
        uint4 q1 = *(const uint4*)&Qlh[rl * SK + ho + 8];
        unsigned qh[8] = { q0.x, q0.y, q0.z, q0.w, q1.x, q1.y, q1.z, q1.w };

        float sc[NJ];
        float mx = -3e38f;
#pragma unroll
        for (int j = 0; j < NJ; ++j) {
          int k = 4 * j + sl;
          sc[j] = -3e38f;
          if (k <= rg) {
            const uint4 ka = *(const uint4*)&Klh[k * SK + ho];
            const uint4 kb = *(const uint4*)&Klh[k * SK + ho + 8];
            float s0 = __builtin_amdgcn_fdot2(u2h(qh[0]), u2h(ka.x), 0.f, false);
            float s1 = __builtin_amdgcn_fdot2(u2h(qh[1]), u2h(ka.y), 0.f, false);
            float s2 = __builtin_amdgcn_fdot2(u2h(qh[2]), u2h(ka.z), 0.f, false);
            float s3 = __builtin_amdgcn_fdot2(u2h(qh[3]), u2h(ka.w), 0.f, false);
            s0 = __builtin_amdgcn_fdot2(u2h(qh[4]), u2h(kb.x), s0, false);
            s1 = __builtin_amdgcn_fdot2(u2h(qh[5]), u2h(kb.y), s1, false);
            s2 = __builtin_amdgcn_fdot2(u2h(qh[6]), u2h(kb.z), s2, false);
            s3 = __builtin_amdgcn_fdot2(u2h(qh[7]), u2h(kb.w), s3, false);
            float s = ((s0 + s1) + (s2 + s3)) * SCALE;
            sc[j] = s;
            mx = fmaxf(mx, s);
          }
        }
        mx = fmaxf(mx, __shfl_xor(mx, 1, 64));
        mx = fmaxf(mx, __shfl_xor(mx, 2, 64));
        float l = 0.f;
#pragma unroll
        for (int j = 0; j < NJ; ++j) {
          sc[j] = __expf(sc[j] - mx);   // invalid slots: exp(-inf) = 0
          l += sc[j];
        }
        l += __shfl_xor(l, 1, 64);
        l += __shfl_xor(l, 2, 64);
        float rli = 1.f / l;

        float acc[16];
#pragma unroll
        for (int f = 0; f < 16; ++f) acc[f] = 0.f;
#pragma unroll
        for (int j = 0; j < NJ; ++j) {
          int k = 4 * j + sl;
          if (k <= rg) {
            float p = sc[j];
            const float4 v0 = *(const float4*)&Vlf[k * SKF + ho];
            const float4 v1 = *(const float4*)&Vlf[k * SKF + ho + 4];
            const float4 v2 = *(const float4*)&Vlf[k * SKF + ho + 8];
            const float4 v3 = *(const float4*)&Vlf[k * SKF + ho + 12];
            acc[0]  += p * v0.x; acc[1]  += p * v0.y;
            acc[2]  += p * v0.z; acc[3]  += p * v0.w;
            acc[4]  += p * v1.x; acc[5]  += p * v1.y;
            acc[6]  += p * v1.z; acc[7]  += p * v1.w;
            acc[8]  += p * v2.x; acc[9]  += p * v2.y;
            acc[10] += p * v2.z; acc[11] += p * v2.w;
            acc[12] += p * v3.x; acc[13] += p * v3.y;
            acc[14] += p * v3.z; acc[15] += p * v3.w;
          }
        }
#pragma unroll
        for (int f = 0; f < 16; ++f) {
          acc[f] += __shfl_xor(acc[f], 1, 64);
          acc[f] += __shfl_xor(acc[f], 2, 64);
        }
        if (sl == 0) {
#pragma unroll
          for (int j = 0; j < 8; ++j)
            Olh[rl * SOH + h * 8 + j] = pkh2(acc[2 * j] * rli, acc[2 * j + 1] * rli);
        }
      }
    }
    __syncthreads();

    // ---- O-proj (fdot2) + residual + LN: thread = (row, e-quad) ----
    {
      int rl = tid >> 3, q = tid & 7, e0 = q * 4;
      if (rl < CH2) {
        int rg = CH2 * c + rl;
        size_t rowo = ((size_t)(b * T + rg) * N + n) * D;
        uint2 eu = *(const uint2*)&E[rowo + e0];
        float res[4] = { blo(eu.x), bhi(eu.x), blo(eu.y), bhi(eu.y) };
        float o[4], s1 = 0.f, s2 = 0.f;
#pragma unroll
        for (int j = 0; j < 4; ++j) {
          int e = e0 + j;
          float a = bol[e] + res[j];
#pragma unroll
          for (int d2 = 0; d2 < D / 2; ++d2)
            a = __builtin_amdgcn_fdot2(u2h(Olh[rl * SOH + d2]),
                                       u2h(woh[d2 * D + e]), a, false);
          o[j] = a; s1 += a; s2 += a * a;
        }
        s1 += __shfl_xor(s1, 1, 64); s2 += __shfl_xor(s2, 1, 64);
        s1 += __shfl_xor(s1, 2, 64); s2 += __shfl_xor(s2, 2, 64);
        s1 += __shfl_xor(s1, 4, 64); s2 += __shfl_xor(s2, 4, 64);
        float mu  = s1 * (1.f / D);
        float var = s2 * (1.f / D) - mu * mu;
        float r = rsqrtf(var + 1e-5f);
        uint2 ou;
        ou.x = pk2((o[0]-mu)*r*gl[e0]+bbl[e0],    (o[1]-mu)*r*gl[e0+1]+bbl[e0+1]);
        ou.y = pk2((o[2]-mu)*r*gl[e0+2]+bbl[e0+2],(o[3]-mu)*r*gl[e0+3]+bbl[e0+3]);
        *(uint2*)&Tn[rowo + e0] = ou;
      }
    }
  }
}

// ---------------------------------------------------------------------------
// spatial v4: packed-f16 gemv (fdot2).
// ---------------------------------------------------------------------------
__global__ __launch_bounds__(256) void spatial_kernel(
    const bf16* __restrict__ E, const float* __restrict__ WsC,
    const float* __restrict__ bsC, const float* __restrict__ sm_Wo,
    const float* __restrict__ sm_bo, const float* __restrict__ ln_g,
    const float* __restrict__ ln_b, bf16* __restrict__ Sn) {
  int t  = blockIdx.x >> 5;          // B/BG = 32 groups per t
  int bg = blockIdx.x & 31;
  int b0 = bg * BG;
  __shared__ unsigned Wh[3 * (D / 2) * D];          // packed f16 pairs, 6144 B
  __shared__ float Wo[D * D];
  __shared__ float bqs[D], bks[D], bvs[D], bos[D], gs[D], bbs[D];
  __shared__ __align__(16) unsigned Esh[SR * SEH];  // packed f16 Es, 3840 B
  __shared__ float Qs[SR * SQS], Ks[SR * SQS], Vs[SR * SQS];
  int tid = threadIdx.x;

  for (int i = tid; i < 3 * (D / 2) * D; i += 256) {
    int fam = i / ((D / 2) * D);
    int idx = i % ((D / 2) * D);
    int d2 = idx >> 5, e = idx & 31;
    const float* wg = WsC + (size_t)(fam * T + t) * D * D;
    Wh[i] = pkh2(wg[(2 * d2) * D + e], wg[(2 * d2 + 1) * D + e]);
  }
  for (int i = tid; i < D * D; i += 256) Wo[i] = sm_Wo[(size_t)t * D * D + i];
  if (tid < D) {
    bqs[tid] = bsC[(0 * T + t) * D + tid];
    bks[tid] = bsC[(1 * T + t) * D + tid];
    bvs[tid] = bsC[(2 * T + t) * D + tid];
    bos[tid] = sm_bo[t * D + tid];
    gs[tid]  = ln_g[tid];
    bbs[tid] = ln_b[tid];
  }
  if (tid < SR * 4) {
    int r = tid >> 2, p = tid & 3;
    int b = b0 + r / N, n = r % N;
    uint4 u = *(const uint4*)&E[(((size_t)b * T + t) * N + n) * D + p * 8];
    uint4 o;
    o.x = pkh2(blo(u.x), bhi(u.x));
    o.y = pkh2(blo(u.y), bhi(u.y));
    o.z = pkh2(blo(u.z), bhi(u.z));
    o.w = pkh2(blo(u.w), bhi(u.w));
    *(uint4*)&Esh[r * SEH + p * 4] = o;
  }
  __syncthreads();

#pragma unroll 1
  for (int i = tid; i < SR * D; i += 256) {
    int r = i >> 5, e = i & 31;
    float aq = bqs[e], ak = bks[e], av = bvs[e];
#pragma unroll
    for (int d2 = 0; d2 < D / 2; ++d2) {
      h2 x = u2h(Esh[r * SEH + d2]);
      aq = __builtin_amdgcn_fdot2(x, u2h(Wh[0 * 512 + d2 * 32 + e]), aq, false);
      ak = __builtin_amdgcn_fdot2(x, u2h(Wh[1 * 512 + d2 * 32 + e]), ak, false);
      av = __builtin_amdgcn_fdot2(x, u2h(Wh[2 * 512 + d2 * 32 + e]), av, false);
    }
    Qs[r * SQS + e] = aq;
    Ks[r * SQS + e] = ak;
    Vs[r * SQS + e] = av;
  }
  __syncthreads();

  if (tid < SR * NH) {
    int r = tid >> 1, h = tid & 1, ho = h * FD;
    int kb = (r >= N) ? N : 0;
    float q[FD];
#pragma unroll
    for (int f = 0; f < FD; ++f) q[f] = Qs[r * SQS + ho + f];
    float sc[N];
    float m = -1e30f;
#pragma unroll
    for (int k = 0; k < N; ++k) {
      float sa = 0.f, sb = 0.f;
#pragma unroll
      for (int f = 0; f < FD; f += 2) {
        sa += q[f]     * Ks[(kb + k) * SQS + ho + f];
        sb += q[f + 1] * Ks[(kb + k) * SQS + ho + f + 1];
      }
      float s = (sa + sb) * SCALE;
      sc[k] = s;
      m = fmaxf(m, s);
    }
    float l = 0.f;
#pragma unroll
    for (int k = 0; k < N; ++k) { sc[k] = __expf(sc[k] - m); l += sc[k]; }
    float rl = 1.f / l;
#pragma unroll
    for (int f = 0; f < FD; ++f) {
      float a = 0.f;
#pragma unroll
      for (int k = 0; k < N; ++k) a += sc[k] * Vs[(kb + k) * SQS + ho + f];
      Qs[r * SQS + ho + f] = a * rl;
    }
  }
  __syncthreads();

#pragma unroll 1
  for (int it = 0; it < SR * D / 256; ++it) {
    int i = it * 256 + tid;
    int r = i >> 5, e = i & 31;
    float aa = 0.f, ab = 0.f;
#pragma unroll
    for (int d = 0; d < D; d += 2) {
      aa += Qs[r * SQS + d]     * Wo[d * D + e];
      ab += Qs[r * SQS + d + 1] * Wo[(d + 1) * D + e];
    }
    h2 ex = u2h(Esh[r * SEH + (e >> 1)]);
    float res = (float)ex[e & 1];
    float o = bos[e] + aa + ab + res;
    float s1 = o, s2 = o * o;
    s1 += __shfl_xor(s1, 1, 64);  s2 += __shfl_xor(s2, 1, 64);
    s1 += __shfl_xor(s1, 2, 64);  s2 += __shfl_xor(s2, 2, 64);
    s1 += __shfl_xor(s1, 4, 64);  s2 += __shfl_xor(s2, 4, 64);
    s1 += __shfl_xor(s1, 8, 64);  s2 += __shfl_xor(s2, 8, 64);
    s1 += __shfl_xor(s1, 16, 64); s2 += __shfl_xor(s2, 16, 64);
    float mu  = s1 * (1.f / D);
    float var = s2 * (1.f / D) - mu * mu;
    float rr = rsqrtf(var + 1e-5f);
    int b = b0 + r / N, n = r % N;
    Sn[(((size_t)b * T + t) * N + n) * D + e] =
        __float2bfloat16((o - mu) * rr * gs[e] + bbs[e]);
  }
}

// ---------------------------------------------------------------------------
// ff v3: packed-f16 fdot2 gemvs (measured R26: ~-24us/dispatch).
// ---------------------------------------------------------------------------
__global__ __launch_bounds__(256) void ff_kernel(
    const bf16* __restrict__ Tn, const bf16* __restrict__ Sn,
    const float* __restrict__ W1, const float* __restrict__ b1,
    const float* __restrict__ W2, const float* __restrict__ b2,
    const float* __restrict__ ln_g, const float* __restrict__ ln_b,
    bf16* __restrict__ E) {
  __shared__ unsigned w1h[(D / 2) * FF];   // 1024 uints, 4KB
  __shared__ unsigned w2h[(FF / 2) * D];   // 1024 uints, 4KB
  __shared__ float bb1[FF], bb2[D], gs[D], bbs[D];
  __shared__ unsigned tslp[FR][D / 2 + 1]; // 32 x 17 (stride 17: conflict-free)
  __shared__ unsigned hlp[FR][FF / 2 + 1]; // 32 x 33 (stride 33: conflict-free)
  int tid = threadIdx.x;
  int r0 = blockIdx.x * FR;
  for (int i = tid; i < (D / 2) * FF; i += 256) {
    int d2 = i / FF, jj = i % FF;
    w1h[i] = pkh2(W1[(2 * d2) * FF + jj], W1[(2 * d2 + 1) * FF + jj]);
  }
  for (int i = tid; i < (FF / 2) * D; i += 256) {
    int k2 = i / D, e = i % D;
    w2h[i] = pkh2(W2[(2 * k2) * D + e], W2[(2 * k2 + 1) * D + e]);
  }
  if (tid < FF) bb1[tid] = b1[tid];
  if (tid < D) { bb2[tid] = b2[tid]; gs[tid] = ln_g[tid]; bbs[tid] = ln_b[tid]; }
  int r = tid >> 3, s = tid & 7;
  {
    const bf16* tp = Tn + ((size_t)(r0 + r)) * D + s * 4;
    const bf16* sp = Sn + ((size_t)(r0 + r)) * D + s * 4;
    uint2 tu = *(const uint2*)tp;
    uint2 su = *(const uint2*)sp;
    float t0 = blo(tu.x) + blo(su.x);
    float t1 = bhi(tu.x) + bhi(su.x);
    float t2 = blo(tu.y) + blo(su.y);
    float t3 = bhi(tu.y) + bhi(su.y);
    tslp[r][s * 2]     = pkh2(t0, t1);
    tslp[r][s * 2 + 1] = pkh2(t2, t3);
  }
  __syncthreads();
  // pass1: 8 hidden units per lane via fdot2
  {
    float hh[8];
#pragma unroll
    for (int j = 0; j < 8; ++j) {
      int jj = s * 8 + j;
      float a = bb1[jj];
#pragma unroll
      for (int d2 = 0; d2 < D / 2; ++d2)
        a = __builtin_amdgcn_fdot2(u2h(tslp[r][d2]), u2h(w1h[d2 * FF + jj]), a, false);
      hh[j] = fmaxf(a, 0.f);
    }
#pragma unroll
    for (int j = 0; j < 4; ++j)
      hlp[r][s * 4 + j] = pkh2(hh[2 * j], hh[2 * j + 1]);
  }
  __syncthreads();
  // pass2: 4 outputs per lane via fdot2 + LN (3-level shfl reduce)
  {
    float x[4];
    float s1 = 0.f, s2 = 0.f;
#pragma unroll
    for (int j4 = 0; j4 < 4; ++j4) {
      int e = s * 4 + j4;
      h2 tv = u2h(tslp[r][e >> 1]);
      float a = bb2[e] + (float)tv[j4 & 1];   // s*4 even -> e&1 == j4&1
#pragma unroll
      for (int k2 = 0; k2 < FF / 2; ++k2)
        a = __builtin_amdgcn_fdot2(u2h(hlp[r][k2]), u2h(w2h[k2 * D + e]), a, false);
      x[j4] = a; s1 += a; s2 += a * a;
    }
    s1 += __shfl_xor(s1, 1, 64); s2 += __shfl_xor(s2, 1, 64);
    s1 += __shfl_xor(s1, 2, 64); s2 += __shfl_xor(s2, 2, 64);
    s1 += __shfl_xor(s1, 4, 64); s2 += __shfl_xor(s2, 4, 64);
    float mu  = s1 * (1.f / D);
    float var = s2 * (1.f / D) - mu * mu;
    float rr = rsqrtf(var + 1e-5f);
    int e0 = s * 4;
    uint2 ou;
    ou.x = pk2((x[0]-mu)*rr*gs[e0]+bbs[e0],    (x[1]-mu)*rr*gs[e0+1]+bbs[e0+1]);
    ou.y = pk2((x[2]-mu)*rr*gs[e0+2]+bbs[e0+2],(x[3]-mu)*rr*gs[e0+3]+bbs[e0+3]);
    *(uint2*)&E[((size_t)(r0 + r)) * D + e0] = ou;
  }
}

// ---------------------------------------------------------------------------
// out = E@op_W + op_b + X   (f32 out)
// ---------------------------------------------------------------------------
__global__ __launch_bounds__(256) void out_kernel(
    const bf16* __restrict__ E, const float* __restrict__ op_W,
    const float* __restrict__ op_b, const float* __restrict__ X,
    float* __restrict__ out) {
  int idx = blockIdx.x * 256 + threadIdx.x;
  if (idx >= B * T * N * M) return;
  int m  = idx % M;
  int n  = (idx / M) % N;
  int bt = idx / (M * N);
  float acc = op_b[n * M + m];
  const bf16* e = E + ((size_t)bt * N + n) * D;
#pragma unroll
  for (int d = 0; d < D; ++d) acc += b2f(e[d]) * op_W[(n * D + d) * M + m];
  acc += X[idx];
  out[idx] = acc;
}

// ---------------------------------------------------------------------------
extern "C" void kernel_launch(void* const* d_in, const int* in_sizes, int n_in,
                              void* d_out, int out_size, void* d_ws, size_t ws_size,
                              hipStream_t stream) {
  const float* X     = (const float*)d_in[0];
  const float* pe    = (const float*)d_in[1];
  const float* E_W   = (const float*)d_in[2];
  const float* E_b   = (const float*)d_in[3];
  const float* tq_W  = (const float*)d_in[4];
  const float* tq_b  = (const float*)d_in[5];
  const float* tk_W  = (const float*)d_in[6];
  const float* tk_b  = (const float*)d_in[7];
  const float* tv_W  = (const float*)d_in[8];
  const float* tv_b  = (const float*)d_in[9];
  const float* tm_Wq = (const float*)d_in[10];
  const float* tm_bq = (const float*)d_in[11];
  const float* tm_Wk = (const float*)d_in[12];
  const float* tm_bk = (const float*)d_in[13];
  const float* tm_Wv = (const float*)d_in[14];
  const float* tm_bv = (const float*)d_in[15];
  const float* tm_Wo = (const float*)d_in[16];
  const float* tm_bo = (const float*)d_in[17];
  const float* sq_W  = (const float*)d_in[18];
  const float* sq_b  = (const float*)d_in[19];
  const float* sk_W  = (const float*)d_in[20];
  const float* sk_b  = (const float*)d_in[21];
  const float* sv_W  = (const float*)d_in[22];
  const float* sv_b  = (const float*)d_in[23];
  const float* sm_Wq = (const float*)d_in[24];
  const float* sm_bq = (const float*)d_in[25];
  const float* sm_Wk = (const float*)d_in[26];
  const float* sm_bk = (const float*)d_in[27];
  const float* sm_Wv = (const float*)d_in[28];
  const float* sm_bv = (const float*)d_in[29];
  const float* sm_Wo = (const float*)d_in[30];
  const float* sm_bo = (const float*)d_in[31];
  const float* ff1_W = (const float*)d_in[32];
  const float* ff1_b = (const float*)d_in[33];
  const float* ff2_W = (const float*)d_in[34];
  const float* ff2_b = (const float*)d_in[35];
  const float* ln_g  = (const float*)d_in[36];
  const float* ln_b  = (const float*)d_in[37];
  const float* op_W  = (const float*)d_in[38];
  const float* op_b  = (const float*)d_in[39];
  float* out = (float*)d_out;

  float* WtC = (float*)d_ws;                         // 3*N*D*D
  float* btC = WtC + 3 * N * D * D;                  // 3*N*D
  float* WsC = btC + 3 * N * D;                      // 3*T*D*D
  float* bsC = WsC + 3 * T * D * D;                  // 3*T*D
  size_t act = (size_t)B * T * N * D;
  bf16* Ebuf = (bf16*)(bsC + 3 * T * D);
  bf16* Tn   = Ebuf + act;
  bf16* Qt   = Tn + act;
  bf16* Kt   = Qt + act;
  bf16* Vt   = Kt + act;
  bf16* Sn   = Qt;                                   // alias (safe: serial schedule)

  compose3_kernel<<<3 * N, 256, 0, stream>>>(
      tq_W, tq_b, tm_Wq, tm_bq, tk_W, tk_b, tm_Wk, tm_bk,
      tv_W, tv_b, tm_Wv, tm_bv, WtC, btC, N);
  compose3_kernel<<<3 * T, 256, 0, stream>>>(
      sq_W, sq_b, sm_Wq, sm_bq, sk_W, sk_b, sm_Wk, sm_bk,
      sv_W, sv_b, sm_Wv, sm_bv, WsC, bsC, T);

  embed_kernel<<<(B * T * N * D) / 256, 256, 0, stream>>>(X, pe, E_W, E_b, Ebuf);

  for (int l = 0; l < L; ++l) {
    qkvt_kernel<<<N * QCH, 256, 0, stream>>>(Ebuf, WtC, btC, Qt, Kt, Vt);
    attnt_kernel<<<B * N, 256, 0, stream>>>(Qt, Kt, Vt, Ebuf, tm_Wo, tm_bo, ln_g, ln_b, Tn);
    spatial_kernel<<<T * (B / BG), 256, 0, stream>>>(Ebuf, WsC, bsC, sm_Wo, sm_bo, ln_g, ln_b, Sn);
    ff_kernel<<<(B * T * N) / FR, 256, 0, stream>>>(Tn, Sn, ff1_W, ff1_b, ff2_W, ff2_b, ln_g, ln_b, Ebuf);
  }

  out_kernel<<<(B * T * N * M + 255) / 256, 256, 0, stream>>>(Ebuf, op_W, op_b, X, out);
}

// Round 29
// 558.419 us; speedup vs baseline: 1.6409x; 1.0928x over previous
//
#include <hip/hip_runtime.h>
#include <hip/hip_bf16.h>

typedef __hip_bfloat16 bf16;
typedef __fp16 h2 __attribute__((ext_vector_type(2)));      // matches amdgcn builtin 'V2h'
typedef _Float16 f16x2 __attribute__((ext_vector_type(2))); // arithmetic (v_pk_*_f16)

constexpr int B  = 64, T = 120, N = 24, M = 3, D = 32;
constexpr int NH = 2, FD = 16, FF = 64, L = 3;
constexpr float SCALE = 0.25f;   // 1/sqrt(FD)
constexpr int SK  = 40;          // attnt K/Q/V f16 LDS stride (80B rows)
constexpr int SOH = 20;          // attnt packed-f16 O stride (uints, 80B)
constexpr int CH2 = 30;          // attnt rows per chunk: 4 x 30 = 120 exactly
constexpr int NJ  = 30;          // max keys per lane slice (120/4)
constexpr int QR  = 64;          // qkvt rows per block (4 lanes/row)
constexpr int QCH = (B * T) / QR;// qkvt chunks = 120
constexpr int QEH = 20;          // qkvt packed-f16 Es stride (uints, 80B)
constexpr int BG  = 2;           // spatial batches per block
constexpr int SR  = N * BG;      // spatial rows per block = 48
constexpr int SEH = 20;          // spatial packed-f16 Es stride (uints, 80B)
constexpr int SQS = 33;          // spatial Q/K/V f32 stride (no 32-way conflicts)
constexpr int FR  = 32;          // ff rows per block (8 lanes/row)

__device__ __forceinline__ float b2f(bf16 x) { return __bfloat162float(x); }
__device__ __forceinline__ float blo(unsigned u) { return __uint_as_float(u << 16); }
__device__ __forceinline__ float bhi(unsigned u) { return __uint_as_float(u & 0xffff0000u); }
__device__ __forceinline__ unsigned pk2(float a, float b) {
  bf16 x = __float2bfloat16(a), y = __float2bfloat16(b);
  unsigned short ux = *reinterpret_cast<unsigned short*>(&x);
  unsigned short uy = *reinterpret_cast<unsigned short*>(&y);
  return (unsigned)ux | ((unsigned)uy << 16);
}
__device__ __forceinline__ unsigned pkh2(float a, float b) {
  h2 r = __builtin_amdgcn_cvt_pkrtz(a, b);     // v_cvt_pkrtz_f16_f32
  return *reinterpret_cast<unsigned*>(&r);
}
__device__ __forceinline__ h2 u2h(unsigned u) { return *reinterpret_cast<h2*>(&u); }
__device__ __forceinline__ f16x2 u2f(unsigned u) { return *reinterpret_cast<f16x2*>(&u); }

// ---------------------------------------------------------------------------
// Compose q/k/v chained linears: grid = 3*U blocks.  Wc = W1@W2, bc = b1@W2+b2.
// ---------------------------------------------------------------------------
__global__ __launch_bounds__(256) void compose3_kernel(
    const float* __restrict__ W1q, const float* __restrict__ b1q,
    const float* __restrict__ W2q, const float* __restrict__ b2q,
    const float* __restrict__ W1k, const float* __restrict__ b1k,
    const float* __restrict__ W2k, const float* __restrict__ b2k,
    const float* __restrict__ W1v, const float* __restrict__ b1v,
    const float* __restrict__ W2v, const float* __restrict__ b2v,
    float* __restrict__ Wc, float* __restrict__ bc, int U) {
  int fam = blockIdx.x / U;
  int n   = blockIdx.x % U;
  const float* W1 = (fam == 0) ? W1q : (fam == 1) ? W1k : W1v;
  const float* b1 = (fam == 0) ? b1q : (fam == 1) ? b1k : b1v;
  const float* W2 = (fam == 0) ? W2q : (fam == 1) ? W2k : W2v;
  const float* b2 = (fam == 0) ? b2q : (fam == 1) ? b2k : b2v;
  const float* w1 = W1 + n * D * D;
  const float* w2 = W2 + n * D * D;
  float* wc  = Wc + (size_t)(fam * U + n) * D * D;
  float* bcp = bc + (fam * U + n) * D;
  __shared__ float s1[D * D], s2[D * D];
  for (int i = threadIdx.x; i < D * D; i += 256) { s1[i] = w1[i]; s2[i] = w2[i]; }
  __syncthreads();
  for (int i = threadIdx.x; i < D * D; i += 256) {
    int d = i >> 5, f = i & 31;
    float acc = 0.f;
#pragma unroll
    for (int e = 0; e < D; ++e) acc += s1[d * D + e] * s2[e * D + f];
    wc[i] = acc;
  }
  if (threadIdx.x < D) {
    int f = threadIdx.x;
    float acc = b2[n * D + f];
#pragma unroll
    for (int e = 0; e < D; ++e) acc += b1[n * D + e] * s2[e * D + f];
    bcp[f] = acc;
  }
}

// ---------------------------------------------------------------------------
// E[b,t,n,d] = X@E_W + E_b + pe   (bf16 out)
// ---------------------------------------------------------------------------
__global__ __launch_bounds__(256) void embed_kernel(
    const float* __restrict__ X, const float* __restrict__ pe,
    const float* __restrict__ E_W, const float* __restrict__ E_b,
    bf16* __restrict__ E) {
  int idx = blockIdx.x * 256 + threadIdx.x;
  if (idx >= B * T * N * D) return;
  int d = idx & 31;
  int n = (idx >> 5) % N;
  int bt = idx / (D * N);
  int t = bt % T;
  const float* x = X + bt * (N * M) + n * M;
  float acc = E_b[n * D + d] + pe[t * D + d];
#pragma unroll
  for (int m = 0; m < M; ++m) acc += x[m] * E_W[(n * M + m) * D + d];
  E[idx] = __float2bfloat16(acc);
}

// ---------------------------------------------------------------------------
// qkvt v3: packed-f16 fdot2 gemv (measured R27: -17us/dispatch).
// ---------------------------------------------------------------------------
__global__ __launch_bounds__(256) void qkvt_kernel(
    const bf16* __restrict__ E, const float* __restrict__ WtC,
    const float* __restrict__ btC,
    bf16* __restrict__ Qt, bf16* __restrict__ Kt, bf16* __restrict__ Vt) {
  int n     = blockIdx.x / QCH;
  int chunk = blockIdx.x % QCH;
  __shared__ unsigned whh[3 * (D / 2) * D];        // 1536 uints, 6 KB
  __shared__ float bsh[3 * D];
  __shared__ __align__(16) unsigned Esp[QR * QEH]; // packed f16 Es, 5 KB
  int tid = threadIdx.x;
  for (int i = tid; i < 3 * (D / 2) * D; i += 256) {
    int fam = i / ((D / 2) * D);
    int idx = i % ((D / 2) * D);
    int d2 = idx >> 5, j = idx & 31;
    const float* wg = WtC + (size_t)(fam * N + n) * D * D;
    whh[i] = pkh2(wg[(2 * d2) * D + j], wg[(2 * d2 + 1) * D + j]);
  }
  if (tid < 3 * D) {
    int fam = tid >> 5, e = tid & 31;
    bsh[tid] = btC[(fam * N + n) * D + e];
  }
  {
    int row = tid >> 2, p = tid & 3;
    const bf16* er = E + ((size_t)(chunk * QR + row) * N + n) * D;
    uint4 u = *(const uint4*)&er[p * 8];
    uint4 o;
    o.x = pkh2(blo(u.x), bhi(u.x));
    o.y = pkh2(blo(u.y), bhi(u.y));
    o.z = pkh2(blo(u.z), bhi(u.z));
    o.w = pkh2(blo(u.w), bhi(u.w));
    *(uint4*)&Esp[row * QEH + p * 4] = o;
  }
  __syncthreads();

  int row = tid >> 2, q = tid & 3;
  int grow = chunk * QR + row;          // b*T + t
  int b = grow / T, t = grow % T;
  unsigned xp[D / 2];
#pragma unroll
  for (int d2 = 0; d2 < D / 2; ++d2) xp[d2] = Esp[row * QEH + d2];
  size_t dsto = (((size_t)b * N + n) * T + t) * D + q * 8;
  bf16* dsts[3] = { Qt + dsto, Kt + dsto, Vt + dsto };
#pragma unroll
  for (int fam = 0; fam < 3; ++fam) {
    const unsigned* wf = whh + fam * (D / 2) * D;
    const float* bi = bsh + fam * D;
    float a[8];
#pragma unroll
    for (int j = 0; j < 8; ++j) a[j] = bi[q * 8 + j];
#pragma unroll
    for (int d2 = 0; d2 < D / 2; ++d2) {
      h2 x = u2h(xp[d2]);
#pragma unroll
      for (int j = 0; j < 8; ++j)
        a[j] = __builtin_amdgcn_fdot2(x, u2h(wf[d2 * D + q * 8 + j]), a[j], false);
    }
    uint4 o;
    o.x = pk2(a[0], a[1]); o.y = pk2(a[2], a[3]);
    o.z = pk2(a[4], a[5]); o.w = pk2(a[6], a[7]);
    *(uint4*)dsts[fam] = o;
  }
}

// ---------------------------------------------------------------------------
// attnt v12 = v11 + packed-f16 V & pk_fma PV.  V stored f16 (Vlh, stride 40
// halfs) -> LDS 34.3->26.6 KB (6 blocks/CU at VGPR<=85).  PV: 8 v_pk_fma_f16
// per key (was 16 f32 FMA), 8 packed accumulators (-8 VGPR), shfl merge on
// packed u32 + pk_add (16 shfl, was 32).  f16 accum err ~3e-3 rel, under the
// bf16 noise floor that follows.
// ---------------------------------------------------------------------------
__global__ __launch_bounds__(256) void attnt_kernel(
    const bf16* __restrict__ Qt, const bf16* __restrict__ Kt,
    const bf16* __restrict__ Vt, const bf16* __restrict__ E,
    const float* __restrict__ tm_Wo, const float* __restrict__ tm_bo,
    const float* __restrict__ ln_g, const float* __restrict__ ln_b,
    bf16* __restrict__ Tn) {
  int bn = blockIdx.x;
  int n  = bn % N, b = bn / N;
  __shared__ __align__(16) __fp16 Klh[T * SK];        // 9600 B
  __shared__ __align__(16) __fp16 Vlh[T * SK];        // 9600 B
  __shared__ __align__(16) __fp16 Qlh[CH2 * SK];      // 2400 B
  __shared__ __align__(16) unsigned Olh[CH2 * SOH];   // packed f16 O, 2400 B
  __shared__ unsigned woh[(D / 2) * D];               // packed Wol, 2048 B
  __shared__ float bol[D], gl[D], bbl[D];
  int tid = threadIdx.x;

  const bf16* Kg = Kt + (size_t)bn * T * D;
  const bf16* Vg = Vt + (size_t)bn * T * D;
  const bf16* Qg = Qt + (size_t)bn * T * D;
  for (int i = tid; i < T * 4; i += 256) {
    int r = i >> 2, p = i & 3;
    uint4 ku = *(const uint4*)&Kg[r * D + p * 8];
    uint4 kh;
    kh.x = pkh2(blo(ku.x), bhi(ku.x));
    kh.y = pkh2(blo(ku.y), bhi(ku.y));
    kh.z = pkh2(blo(ku.z), bhi(ku.z));
    kh.w = pkh2(blo(ku.w), bhi(ku.w));
    *(uint4*)&Klh[r * SK + p * 8] = kh;
    uint4 vu = *(const uint4*)&Vg[r * D + p * 8];
    uint4 vh;
    vh.x = pkh2(blo(vu.x), bhi(vu.x));
    vh.y = pkh2(blo(vu.y), bhi(vu.y));
    vh.z = pkh2(blo(vu.z), bhi(vu.z));
    vh.w = pkh2(blo(vu.w), bhi(vu.w));
    *(uint4*)&Vlh[r * SK + p * 8] = vh;
  }
  {
    const float* wg = tm_Wo + (size_t)n * D * D;
    for (int i = tid; i < (D / 2) * D; i += 256) {
      int d2 = i >> 5, e = i & 31;
      woh[i] = pkh2(wg[(2 * d2) * D + e], wg[(2 * d2 + 1) * D + e]);
    }
  }
  if (tid < D) {
    bol[tid] = tm_bo[n * D + tid];
    gl[tid]  = ln_g[tid];
    bbl[tid] = ln_b[tid];
  }
  __syncthreads();

#pragma unroll 1
  for (int c = 0; c < 4; ++c) {
    if (tid < CH2 * 4) {
      int r = tid >> 2, p = tid & 3;
      uint4 qu = *(const uint4*)&Qg[(CH2 * c + r) * D + p * 8];
      uint4 qh;
      qh.x = pkh2(blo(qu.x), bhi(qu.x));
      qh.y = pkh2(blo(qu.y), bhi(qu.y));
      qh.z = pkh2(blo(qu.z), bhi(qu.z));
      qh.w = pkh2(blo(qu.w), bhi(qu.w));
      *(uint4*)&Qlh[r * SK + p * 8] = qh;
    }
    __syncthreads();   // Qlh ready; prior O-proj done -> Olh safe to overwrite

    {
      int task = tid >> 2, sl = tid & 3;
      if (task < 2 * CH2) {
        int rl = task >> 1, h = task & 1, ho = h * FD;
        int rg = CH2 * c + rl;
        uint4 q0 = *(const uint4*)&Qlh[rl * SK + ho];
        uint4 q1 = *(const uint4*)&Qlh[rl * SK + ho + 8];
        unsigned qh[8] = { q0.x, q0.y, q0.z, q0.w, q1.x, q1.y, q1.z, q1.w };

        float sc[NJ];
        float mx = -3e38f;
#pragma unroll
        for (int j = 0; j < NJ; ++j) {
          int k = 4 * j + sl;
          sc[j] = -3e38f;
          if (k <= rg) {
            const uint4 ka = *(const uint4*)&Klh[k * SK + ho];
            const uint4 kb = *(const uint4*)&Klh[k * SK + ho + 8];
            float s0 = __builtin_amdgcn_fdot2(u2h(qh[0]), u2h(ka.x), 0.f, false);
            float s1 = __builtin_amdgcn_fdot2(u2h(qh[1]), u2h(ka.y), 0.f, false);
            float s2 = __builtin_amdgcn_fdot2(u2h(qh[2]), u2h(ka.z), 0.f, false);
            float s3 = __builtin_amdgcn_fdot2(u2h(qh[3]), u2h(ka.w), 0.f, false);
            s0 = __builtin_amdgcn_fdot2(u2h(qh[4]), u2h(kb.x), s0, false);
            s1 = __builtin_amdgcn_fdot2(u2h(qh[5]), u2h(kb.y), s1, false);
            s2 = __builtin_amdgcn_fdot2(u2h(qh[6]), u2h(kb.z), s2, false);
            s3 = __builtin_amdgcn_fdot2(u2h(qh[7]), u2h(kb.w), s3, false);
            float s = ((s0 + s1) + (s2 + s3)) * SCALE;
            sc[j] = s;
            mx = fmaxf(mx, s);
          }
        }
        mx = fmaxf(mx, __shfl_xor(mx, 1, 64));
        mx = fmaxf(mx, __shfl_xor(mx, 2, 64));
        float l = 0.f;
#pragma unroll
        for (int j = 0; j < NJ; ++j) {
          sc[j] = __expf(sc[j] - mx);   // invalid slots: exp(-inf) = 0
          l += sc[j];
        }
        l += __shfl_xor(l, 1, 64);
        l += __shfl_xor(l, 2, 64);
        float rli = 1.f / l;

        f16x2 acc2[8];
#pragma unroll
        for (int f = 0; f < 8; ++f) acc2[f] = f16x2{(_Float16)0.f, (_Float16)0.f};
#pragma unroll
        for (int j = 0; j < NJ; ++j) {
          int k = 4 * j + sl;
          if (k <= rg) {
            f16x2 pp = f16x2{(_Float16)sc[j], (_Float16)sc[j]};
            const uint4 va = *(const uint4*)&Vlh[k * SK + ho];
            const uint4 vb = *(const uint4*)&Vlh[k * SK + ho + 8];
            acc2[0] += pp * u2f(va.x);
            acc2[1] += pp * u2f(va.y);
            acc2[2] += pp * u2f(va.z);
            acc2[3] += pp * u2f(va.w);
            acc2[4] += pp * u2f(vb.x);
            acc2[5] += pp * u2f(vb.y);
            acc2[6] += pp * u2f(vb.z);
            acc2[7] += pp * u2f(vb.w);
          }
        }
#pragma unroll
        for (int f = 0; f < 8; ++f) {
          unsigned u = *reinterpret_cast<unsigned*>(&acc2[f]);
          unsigned u1 = __shfl_xor(u, 1, 64);
          acc2[f] += u2f(u1);
          u = *reinterpret_cast<unsigned*>(&acc2[f]);
          unsigned u2_ = __shfl_xor(u, 2, 64);
          acc2[f] += u2f(u2_);
        }
        if (sl == 0) {
#pragma unroll
          for (int j = 0; j < 8; ++j)
            Olh[rl * SOH + h * 8 + j] =
                pkh2((float)acc2[j][0] * rli, (float)acc2[j][1] * rli);
        }
      }
    }
    __syncthreads();

    // ---- O-proj (fdot2) + residual + LN: thread = (row, e-quad) ----
    {
      int rl = tid >> 3, q = tid & 7, e0 = q * 4;
      if (rl < CH2) {
        int rg = CH2 * c + rl;
        size_t rowo = ((size_t)(b * T + rg) * N + n) * D;
        uint2 eu = *(const uint2*)&E[rowo + e0];
        float res[4] = { blo(eu.x), bhi(eu.x), blo(eu.y), bhi(eu.y) };
        float o[4], s1 = 0.f, s2 = 0.f;
#pragma unroll
        for (int j = 0; j < 4; ++j) {
          int e = e0 + j;
          float a = bol[e] + res[j];
#pragma unroll
          for (int d2 = 0; d2 < D / 2; ++d2)
            a = __builtin_amdgcn_fdot2(u2h(Olh[rl * SOH + d2]),
                                       u2h(woh[d2 * D + e]), a, false);
          o[j] = a; s1 += a; s2 += a * a;
        }
        s1 += __shfl_xor(s1, 1, 64); s2 += __shfl_xor(s2, 1, 64);
        s1 += __shfl_xor(s1, 2, 64); s2 += __shfl_xor(s2, 2, 64);
        s1 += __shfl_xor(s1, 4, 64); s2 += __shfl_xor(s2, 4, 64);
        float mu  = s1 * (1.f / D);
        float var = s2 * (1.f / D) - mu * mu;
        float r = rsqrtf(var + 1e-5f);
        uint2 ou;
        ou.x = pk2((o[0]-mu)*r*gl[e0]+bbl[e0],    (o[1]-mu)*r*gl[e0+1]+bbl[e0+1]);
        ou.y = pk2((o[2]-mu)*r*gl[e0+2]+bbl[e0+2],(o[3]-mu)*r*gl[e0+3]+bbl[e0+3]);
        *(uint2*)&Tn[rowo + e0] = ou;
      }
    }
  }
}

// ---------------------------------------------------------------------------
// spatial v4: packed-f16 gemv (fdot2).
// ---------------------------------------------------------------------------
__global__ __launch_bounds__(256) void spatial_kernel(
    const bf16* __restrict__ E, const float* __restrict__ WsC,
    const float* __restrict__ bsC, const float* __restrict__ sm_Wo,
    const float* __restrict__ sm_bo, const float* __restrict__ ln_g,
    const float* __restrict__ ln_b, bf16* __restrict__ Sn) {
  int t  = blockIdx.x >> 5;          // B/BG = 32 groups per t
  int bg = blockIdx.x & 31;
  int b0 = bg * BG;
  __shared__ unsigned Wh[3 * (D / 2) * D];          // packed f16 pairs, 6144 B
  __shared__ float Wo[D * D];
  __shared__ float bqs[D], bks[D], bvs[D], bos[D], gs[D], bbs[D];
  __shared__ __align__(16) unsigned Esh[SR * SEH];  // packed f16 Es, 3840 B
  __shared__ float Qs[SR * SQS], Ks[SR * SQS], Vs[SR * SQS];
  int tid = threadIdx.x;

  for (int i = tid; i < 3 * (D / 2) * D; i += 256) {
    int fam = i / ((D / 2) * D);
    int idx = i % ((D / 2) * D);
    int d2 = idx >> 5, e = idx & 31;
    const float* wg = WsC + (size_t)(fam * T + t) * D * D;
    Wh[i] = pkh2(wg[(2 * d2) * D + e], wg[(2 * d2 + 1) * D + e]);
  }
  for (int i = tid; i < D * D; i += 256) Wo[i] = sm_Wo[(size_t)t * D * D + i];
  if (tid < D) {
    bqs[tid] = bsC[(0 * T + t) * D + tid];
    bks[tid] = bsC[(1 * T + t) * D + tid];
    bvs[tid] = bsC[(2 * T + t) * D + tid];
    bos[tid] = sm_bo[t * D + tid];
    gs[tid]  = ln_g[tid];
    bbs[tid] = ln_b[tid];
  }
  if (tid < SR * 4) {
    int r = tid >> 2, p = tid & 3;
    int b = b0 + r / N, n = r % N;
    uint4 u = *(const uint4*)&E[(((size_t)b * T + t) * N + n) * D + p * 8];
    uint4 o;
    o.x = pkh2(blo(u.x), bhi(u.x));
    o.y = pkh2(blo(u.y), bhi(u.y));
    o.z = pkh2(blo(u.z), bhi(u.z));
    o.w = pkh2(blo(u.w), bhi(u.w));
    *(uint4*)&Esh[r * SEH + p * 4] = o;
  }
  __syncthreads();

#pragma unroll 1
  for (int i = tid; i < SR * D; i += 256) {
    int r = i >> 5, e = i & 31;
    float aq = bqs[e], ak = bks[e], av = bvs[e];
#pragma unroll
    for (int d2 = 0; d2 < D / 2; ++d2) {
      h2 x = u2h(Esh[r * SEH + d2]);
      aq = __builtin_amdgcn_fdot2(x, u2h(Wh[0 * 512 + d2 * 32 + e]), aq, false);
      ak = __builtin_amdgcn_fdot2(x, u2h(Wh[1 * 512 + d2 * 32 + e]), ak, false);
      av = __builtin_amdgcn_fdot2(x, u2h(Wh[2 * 512 + d2 * 32 + e]), av, false);
    }
    Qs[r * SQS + e] = aq;
    Ks[r * SQS + e] = ak;
    Vs[r * SQS + e] = av;
  }
  __syncthreads();

  if (tid < SR * NH) {
    int r = tid >> 1, h = tid & 1, ho = h * FD;
    int kb = (r >= N) ? N : 0;
    float q[FD];
#pragma unroll
    for (int f = 0; f < FD; ++f) q[f] = Qs[r * SQS + ho + f];
    float sc[N];
    float m = -1e30f;
#pragma unroll
    for (int k = 0; k < N; ++k) {
      float sa = 0.f, sb = 0.f;
#pragma unroll
      for (int f = 0; f < FD; f += 2) {
        sa += q[f]     * Ks[(kb + k) * SQS + ho + f];
        sb += q[f + 1] * Ks[(kb + k) * SQS + ho + f + 1];
      }
      float s = (sa + sb) * SCALE;
      sc[k] = s;
      m = fmaxf(m, s);
    }
    float l = 0.f;
#pragma unroll
    for (int k = 0; k < N; ++k) { sc[k] = __expf(sc[k] - m); l += sc[k]; }
    float rl = 1.f / l;
#pragma unroll
    for (int f = 0; f < FD; ++f) {
      float a = 0.f;
#pragma unroll
      for (int k = 0; k < N; ++k) a += sc[k] * Vs[(kb + k) * SQS + ho + f];
      Qs[r * SQS + ho + f] = a * rl;
    }
  }
  __syncthreads();

#pragma unroll 1
  for (int it = 0; it < SR * D / 256; ++it) {
    int i = it * 256 + tid;
    int r = i >> 5, e = i & 31;
    float aa = 0.f, ab = 0.f;
#pragma unroll
    for (int d = 0; d < D; d += 2) {
      aa += Qs[r * SQS + d]     * Wo[d * D + e];
      ab += Qs[r * SQS + d + 1] * Wo[(d + 1) * D + e];
    }
    h2 ex = u2h(Esh[r * SEH + (e >> 1)]);
    float res = (float)ex[e & 1];
    float o = bos[e] + aa + ab + res;
    float s1 = o, s2 = o * o;
    s1 += __shfl_xor(s1, 1, 64);  s2 += __shfl_xor(s2, 1, 64);
    s1 += __shfl_xor(s1, 2, 64);  s2 += __shfl_xor(s2, 2, 64);
    s1 += __shfl_xor(s1, 4, 64);  s2 += __shfl_xor(s2, 4, 64);
    s1 += __shfl_xor(s1, 8, 64);  s2 += __shfl_xor(s2, 8, 64);
    s1 += __shfl_xor(s1, 16, 64); s2 += __shfl_xor(s2, 16, 64);
    float mu  = s1 * (1.f / D);
    float var = s2 * (1.f / D) - mu * mu;
    float rr = rsqrtf(var + 1e-5f);
    int b = b0 + r / N, n = r % N;
    Sn[(((size_t)b * T + t) * N + n) * D + e] =
        __float2bfloat16((o - mu) * rr * gs[e] + bbs[e]);
  }
}

// ---------------------------------------------------------------------------
// ff v3: packed-f16 fdot2 gemvs (measured R26: ~-24us/dispatch).
// ---------------------------------------------------------------------------
__global__ __launch_bounds__(256) void ff_kernel(
    const bf16* __restrict__ Tn, const bf16* __restrict__ Sn,
    const float* __restrict__ W1, const float* __restrict__ b1,
    const float* __restrict__ W2, const float* __restrict__ b2,
    const float* __restrict__ ln_g, const float* __restrict__ ln_b,
    bf16* __restrict__ E) {
  __shared__ unsigned w1h[(D / 2) * FF];   // 1024 uints, 4KB
  __shared__ unsigned w2h[(FF / 2) * D];   // 1024 uints, 4KB
  __shared__ float bb1[FF], bb2[D], gs[D], bbs[D];
  __shared__ unsigned tslp[FR][D / 2 + 1]; // 32 x 17 (stride 17: conflict-free)
  __shared__ unsigned hlp[FR][FF / 2 + 1]; // 32 x 33 (stride 33: conflict-free)
  int tid = threadIdx.x;
  int r0 = blockIdx.x * FR;
  for (int i = tid; i < (D / 2) * FF; i += 256) {
    int d2 = i / FF, jj = i % FF;
    w1h[i] = pkh2(W1[(2 * d2) * FF + jj], W1[(2 * d2 + 1) * FF + jj]);
  }
  for (int i = tid; i < (FF / 2) * D; i += 256) {
    int k2 = i / D, e = i % D;
    w2h[i] = pkh2(W2[(2 * k2) * D + e], W2[(2 * k2 + 1) * D + e]);
  }
  if (tid < FF) bb1[tid] = b1[tid];
  if (tid < D) { bb2[tid] = b2[tid]; gs[tid] = ln_g[tid]; bbs[tid] = ln_b[tid]; }
  int r = tid >> 3, s = tid & 7;
  {
    const bf16* tp = Tn + ((size_t)(r0 + r)) * D + s * 4;
    const bf16* sp = Sn + ((size_t)(r0 + r)) * D + s * 4;
    uint2 tu = *(const uint2*)tp;
    uint2 su = *(const uint2*)sp;
    float t0 = blo(tu.x) + blo(su.x);
    float t1 = bhi(tu.x) + bhi(su.x);
    float t2 = blo(tu.y) + blo(su.y);
    float t3 = bhi(tu.y) + bhi(su.y);
    tslp[r][s * 2]     = pkh2(t0, t1);
    tslp[r][s * 2 + 1] = pkh2(t2, t3);
  }
  __syncthreads();
  // pass1: 8 hidden units per lane via fdot2
  {
    float hh[8];
#pragma unroll
    for (int j = 0; j < 8; ++j) {
      int jj = s * 8 + j;
      float a = bb1[jj];
#pragma unroll
      for (int d2 = 0; d2 < D / 2; ++d2)
        a = __builtin_amdgcn_fdot2(u2h(tslp[r][d2]), u2h(w1h[d2 * FF + jj]), a, false);
      hh[j] = fmaxf(a, 0.f);
    }
#pragma unroll
    for (int j = 0; j < 4; ++j)
      hlp[r][s * 4 + j] = pkh2(hh[2 * j], hh[2 * j + 1]);
  }
  __syncthreads();
  // pass2: 4 outputs per lane via fdot2 + LN (3-level shfl reduce)
  {
    float x[4];
    float s1 = 0.f, s2 = 0.f;
#pragma unroll
    for (int j4 = 0; j4 < 4; ++j4) {
      int e = s * 4 + j4;
      h2 tv = u2h(tslp[r][e >> 1]);
      float a = bb2[e] + (float)tv[j4 & 1];   // s*4 even -> e&1 == j4&1
#pragma unroll
      for (int k2 = 0; k2 < FF / 2; ++k2)
        a = __builtin_amdgcn_fdot2(u2h(hlp[r][k2]), u2h(w2h[k2 * D + e]), a, false);
      x[j4] = a; s1 += a; s2 += a * a;
    }
    s1 += __shfl_xor(s1, 1, 64); s2 += __shfl_xor(s2, 1, 64);
    s1 += __shfl_xor(s1, 2, 64); s2 += __shfl_xor(s2, 2, 64);
    s1 += __shfl_xor(s1, 4, 64); s2 += __shfl_xor(s2, 4, 64);
    float mu  = s1 * (1.f / D);
    float var = s2 * (1.f / D) - mu * mu;
    float rr = rsqrtf(var + 1e-5f);
    int e0 = s * 4;
    uint2 ou;
    ou.x = pk2((x[0]-mu)*rr*gs[e0]+bbs[e0],    (x[1]-mu)*rr*gs[e0+1]+bbs[e0+1]);
    ou.y = pk2((x[2]-mu)*rr*gs[e0+2]+bbs[e0+2],(x[3]-mu)*rr*gs[e0+3]+bbs[e0+3]);
    *(uint2*)&E[((size_t)(r0 + r)) * D + e0] = ou;
  }
}

// ---------------------------------------------------------------------------
// out = E@op_W + op_b + X   (f32 out)
// ---------------------------------------------------------------------------
__global__ __launch_bounds__(256) void out_kernel(
    const bf16* __restrict__ E, const float* __restrict__ op_W,
    const float* __restrict__ op_b, const float* __restrict__ X,
    float* __restrict__ out) {
  int idx = blockIdx.x * 256 + threadIdx.x;
  if (idx >= B * T * N * M) return;
  int m  = idx % M;
  int n  = (idx / M) % N;
  int bt = idx / (M * N);
  float acc = op_b[n * M + m];
  const bf16* e = E + ((size_t)bt * N + n) * D;
#pragma unroll
  for (int d = 0; d < D; ++d) acc += b2f(e[d]) * op_W[(n * D + d) * M + m];
  acc += X[idx];
  out[idx] = acc;
}

// ---------------------------------------------------------------------------
extern "C" void kernel_launch(void* const* d_in, const int* in_sizes, int n_in,
                              void* d_out, int out_size, void* d_ws, size_t ws_size,
                              hipStream_t stream) {
  const float* X     = (const float*)d_in[0];
  const float* pe    = (const float*)d_in[1];
  const float* E_W   = (const float*)d_in[2];
  const float* E_b   = (const float*)d_in[3];
  const float* tq_W  = (const float*)d_in[4];
  const float* tq_b  = (const float*)d_in[5];
  const float* tk_W  = (const float*)d_in[6];
  const float* tk_b  = (const float*)d_in[7];
  const float* tv_W  = (const float*)d_in[8];
  const float* tv_b  = (const float*)d_in[9];
  const float* tm_Wq = (const float*)d_in[10];
  const float* tm_bq = (const float*)d_in[11];
  const float* tm_Wk = (const float*)d_in[12];
  const float* tm_bk = (const float*)d_in[13];
  const float* tm_Wv = (const float*)d_in[14];
  const float* tm_bv = (const float*)d_in[15];
  const float* tm_Wo = (const float*)d_in[16];
  const float* tm_bo = (const float*)d_in[17];
  const float* sq_W  = (const float*)d_in[18];
  const float* sq_b  = (const float*)d_in[19];
  const float* sk_W  = (const float*)d_in[20];
  const float* sk_b  = (const float*)d_in[21];
  const float* sv_W  = (const float*)d_in[22];
  const float* sv_b  = (const float*)d_in[23];
  const float* sm_Wq = (const float*)d_in[24];
  const float* sm_bq = (const float*)d_in[25];
  const float* sm_Wk = (const float*)d_in[26];
  const float* sm_bk = (const float*)d_in[27];
  const float* sm_Wv = (const float*)d_in[28];
  const float* sm_bv = (const float*)d_in[29];
  const float* sm_Wo = (const float*)d_in[30];
  const float* sm_bo = (const float*)d_in[31];
  const float* ff1_W = (const float*)d_in[32];
  const float* ff1_b = (const float*)d_in[33];
  const float* ff2_W = (const float*)d_in[34];
  const float* ff2_b = (const float*)d_in[35];
  const float* ln_g  = (const float*)d_in[36];
  const float* ln_b  = (const float*)d_in[37];
  const float* op_W  = (const float*)d_in[38];
  const float* op_b  = (const float*)d_in[39];
  float* out = (float*)d_out;

  float* WtC = (float*)d_ws;                         // 3*N*D*D
  float* btC = WtC + 3 * N * D * D;                  // 3*N*D
  float* WsC = btC + 3 * N * D;                      // 3*T*D*D
  float* bsC = WsC + 3 * T * D * D;                  // 3*T*D
  size_t act = (size_t)B * T * N * D;
  bf16* Ebuf = (bf16*)(bsC + 3 * T * D);
  bf16* Tn   = Ebuf + act;
  bf16* Qt   = Tn + act;
  bf16* Kt   = Qt + act;
  bf16* Vt   = Kt + act;
  bf16* Sn   = Qt;                                   // alias (safe: serial schedule)

  compose3_kernel<<<3 * N, 256, 0, stream>>>(
      tq_W, tq_b, tm_Wq, tm_bq, tk_W, tk_b, tm_Wk, tm_bk,
      tv_W, tv_b, tm_Wv, tm_bv, WtC, btC, N);
  compose3_kernel<<<3 * T, 256, 0, stream>>>(
      sq_W, sq_b, sm_Wq, sm_bq, sk_W, sk_b, sm_Wk, sm_bk,
      sv_W, sv_b, sm_Wv, sm_bv, WsC, bsC, T);

  embed_kernel<<<(B * T * N * D) / 256, 256, 0, stream>>>(X, pe, E_W, E_b, Ebuf);

  for (int l = 0; l < L; ++l) {
    qkvt_kernel<<<N * QCH, 256, 0, stream>>>(Ebuf, WtC, btC, Qt, Kt, Vt);
    attnt_kernel<<<B * N, 256, 0, stream>>>(Qt, Kt, Vt, Ebuf, tm_Wo, tm_bo, ln_g, ln_b, Tn);
    spatial_kernel<<<T * (B / BG), 256, 0, stream>>>(Ebuf, WsC, bsC, sm_Wo, sm_bo, ln_g, ln_b, Sn);
    ff_kernel<<<(B * T * N) / FR, 256, 0, stream>>>(Tn, Sn, ff1_W, ff1_b, ff2_W, ff2_b, ln_g, ln_b, Ebuf);
  }

  out_kernel<<<(B * T * N * M + 255) / 256, 256, 0, stream>>>(Ebuf, op_W, op_b, X, out);
}

// Round 30
// 477.769 us; speedup vs baseline: 1.9178x; 1.1688x over previous
//
#include <hip/hip_runtime.h>
#include <hip/hip_bf16.h>

typedef __hip_bfloat16 bf16;
typedef __fp16 h2 __attribute__((ext_vector_type(2)));      // matches amdgcn builtin 'V2h'
typedef _Float16 f16x2 __attribute__((ext_vector_type(2))); // arithmetic (v_pk_*_f16)

constexpr int B  = 64, T = 120, N = 24, M = 3, D = 32;
constexpr int NH = 2, FD = 16, FF = 64, L = 3;
constexpr float SCALE = 0.25f;   // 1/sqrt(FD)
constexpr int SK  = 40;          // f16 LDS stride (80B rows) — attnt & spatial
constexpr int SOH = 20;          // attnt packed-f16 O stride (uints, 80B)
constexpr int CH2 = 30;          // attnt rows per chunk: 4 x 30 = 120 exactly
constexpr int NJ  = 30;          // max keys per lane slice (120/4)
constexpr int QR  = 64;          // qkvt rows per block (4 lanes/row)
constexpr int QCH = (B * T) / QR;// qkvt chunks = 120
constexpr int QEH = 20;          // qkvt packed-f16 Es stride (uints, 80B)
constexpr int BG  = 2;           // spatial batches per block
constexpr int SR  = N * BG;      // spatial rows per block = 48
constexpr int SEH = 20;          // spatial packed-f16 Es stride (uints, 80B)
constexpr int FR  = 32;          // ff rows per block (8 lanes/row)

__device__ __forceinline__ float b2f(bf16 x) { return __bfloat162float(x); }
__device__ __forceinline__ float blo(unsigned u) { return __uint_as_float(u << 16); }
__device__ __forceinline__ float bhi(unsigned u) { return __uint_as_float(u & 0xffff0000u); }
__device__ __forceinline__ unsigned pk2(float a, float b) {
  bf16 x = __float2bfloat16(a), y = __float2bfloat16(b);
  unsigned short ux = *reinterpret_cast<unsigned short*>(&x);
  unsigned short uy = *reinterpret_cast<unsigned short*>(&y);
  return (unsigned)ux | ((unsigned)uy << 16);
}
__device__ __forceinline__ unsigned pkh2(float a, float b) {
  h2 r = __builtin_amdgcn_cvt_pkrtz(a, b);     // v_cvt_pkrtz_f16_f32
  return *reinterpret_cast<unsigned*>(&r);
}
__device__ __forceinline__ h2 u2h(unsigned u) { return *reinterpret_cast<h2*>(&u); }
__device__ __forceinline__ f16x2 u2f(unsigned u) { return *reinterpret_cast<f16x2*>(&u); }

// ---------------------------------------------------------------------------
// Compose q/k/v chained linears: grid = 3*U blocks.  Wc = W1@W2, bc = b1@W2+b2.
// ---------------------------------------------------------------------------
__global__ __launch_bounds__(256) void compose3_kernel(
    const float* __restrict__ W1q, const float* __restrict__ b1q,
    const float* __restrict__ W2q, const float* __restrict__ b2q,
    const float* __restrict__ W1k, const float* __restrict__ b1k,
    const float* __restrict__ W2k, const float* __restrict__ b2k,
    const float* __restrict__ W1v, const float* __restrict__ b1v,
    const float* __restrict__ W2v, const float* __restrict__ b2v,
    float* __restrict__ Wc, float* __restrict__ bc, int U) {
  int fam = blockIdx.x / U;
  int n   = blockIdx.x % U;
  const float* W1 = (fam == 0) ? W1q : (fam == 1) ? W1k : W1v;
  const float* b1 = (fam == 0) ? b1q : (fam == 1) ? b1k : b1v;
  const float* W2 = (fam == 0) ? W2q : (fam == 1) ? W2k : W2v;
  const float* b2 = (fam == 0) ? b2q : (fam == 1) ? b2k : b2v;
  const float* w1 = W1 + n * D * D;
  const float* w2 = W2 + n * D * D;
  float* wc  = Wc + (size_t)(fam * U + n) * D * D;
  float* bcp = bc + (fam * U + n) * D;
  __shared__ float s1[D * D], s2[D * D];
  for (int i = threadIdx.x; i < D * D; i += 256) { s1[i] = w1[i]; s2[i] = w2[i]; }
  __syncthreads();
  for (int i = threadIdx.x; i < D * D; i += 256) {
    int d = i >> 5, f = i & 31;
    float acc = 0.f;
#pragma unroll
    for (int e = 0; e < D; ++e) acc += s1[d * D + e] * s2[e * D + f];
    wc[i] = acc;
  }
  if (threadIdx.x < D) {
    int f = threadIdx.x;
    float acc = b2[n * D + f];
#pragma unroll
    for (int e = 0; e < D; ++e) acc += b1[n * D + e] * s2[e * D + f];
    bcp[f] = acc;
  }
}

// ---------------------------------------------------------------------------
// E[b,t,n,d] = X@E_W + E_b + pe   (bf16 out)
// ---------------------------------------------------------------------------
__global__ __launch_bounds__(256) void embed_kernel(
    const float* __restrict__ X, const float* __restrict__ pe,
    const float* __restrict__ E_W, const float* __restrict__ E_b,
    bf16* __restrict__ E) {
  int idx = blockIdx.x * 256 + threadIdx.x;
  if (idx >= B * T * N * D) return;
  int d = idx & 31;
  int n = (idx >> 5) % N;
  int bt = idx / (D * N);
  int t = bt % T;
  const float* x = X + bt * (N * M) + n * M;
  float acc = E_b[n * D + d] + pe[t * D + d];
#pragma unroll
  for (int m = 0; m < M; ++m) acc += x[m] * E_W[(n * M + m) * D + d];
  E[idx] = __float2bfloat16(acc);
}

// ---------------------------------------------------------------------------
// qkvt v3: packed-f16 fdot2 gemv (measured R27: -17us/dispatch).
// ---------------------------------------------------------------------------
__global__ __launch_bounds__(256) void qkvt_kernel(
    const bf16* __restrict__ E, const float* __restrict__ WtC,
    const float* __restrict__ btC,
    bf16* __restrict__ Qt, bf16* __restrict__ Kt, bf16* __restrict__ Vt) {
  int n     = blockIdx.x / QCH;
  int chunk = blockIdx.x % QCH;
  __shared__ unsigned whh[3 * (D / 2) * D];        // 1536 uints, 6 KB
  __shared__ float bsh[3 * D];
  __shared__ __align__(16) unsigned Esp[QR * QEH]; // packed f16 Es, 5 KB
  int tid = threadIdx.x;
  for (int i = tid; i < 3 * (D / 2) * D; i += 256) {
    int fam = i / ((D / 2) * D);
    int idx = i % ((D / 2) * D);
    int d2 = idx >> 5, j = idx & 31;
    const float* wg = WtC + (size_t)(fam * N + n) * D * D;
    whh[i] = pkh2(wg[(2 * d2) * D + j], wg[(2 * d2 + 1) * D + j]);
  }
  if (tid < 3 * D) {
    int fam = tid >> 5, e = tid & 31;
    bsh[tid] = btC[(fam * N + n) * D + e];
  }
  {
    int row = tid >> 2, p = tid & 3;
    const bf16* er = E + ((size_t)(chunk * QR + row) * N + n) * D;
    uint4 u = *(const uint4*)&er[p * 8];
    uint4 o;
    o.x = pkh2(blo(u.x), bhi(u.x));
    o.y = pkh2(blo(u.y), bhi(u.y));
    o.z = pkh2(blo(u.z), bhi(u.z));
    o.w = pkh2(blo(u.w), bhi(u.w));
    *(uint4*)&Esp[row * QEH + p * 4] = o;
  }
  __syncthreads();

  int row = tid >> 2, q = tid & 3;
  int grow = chunk * QR + row;          // b*T + t
  int b = grow / T, t = grow % T;
  unsigned xp[D / 2];
#pragma unroll
  for (int d2 = 0; d2 < D / 2; ++d2) xp[d2] = Esp[row * QEH + d2];
  size_t dsto = (((size_t)b * N + n) * T + t) * D + q * 8;
  bf16* dsts[3] = { Qt + dsto, Kt + dsto, Vt + dsto };
#pragma unroll
  for (int fam = 0; fam < 3; ++fam) {
    const unsigned* wf = whh + fam * (D / 2) * D;
    const float* bi = bsh + fam * D;
    float a[8];
#pragma unroll
    for (int j = 0; j < 8; ++j) a[j] = bi[q * 8 + j];
#pragma unroll
    for (int d2 = 0; d2 < D / 2; ++d2) {
      h2 x = u2h(xp[d2]);
#pragma unroll
      for (int j = 0; j < 8; ++j)
        a[j] = __builtin_amdgcn_fdot2(x, u2h(wf[d2 * D + q * 8 + j]), a[j], false);
    }
    uint4 o;
    o.x = pk2(a[0], a[1]); o.y = pk2(a[2], a[3]);
    o.z = pk2(a[4], a[5]); o.w = pk2(a[6], a[7]);
    *(uint4*)dsts[fam] = o;
  }
}

// ---------------------------------------------------------------------------
// attnt v12: packed-f16 V & pk_fma PV (measured R29: <83us, LDS 26.6KB).
// ---------------------------------------------------------------------------
__global__ __launch_bounds__(256) void attnt_kernel(
    const bf16* __restrict__ Qt, const bf16* __restrict__ Kt,
    const bf16* __restrict__ Vt, const bf16* __restrict__ E,
    const float* __restrict__ tm_Wo, const float* __restrict__ tm_bo,
    const float* __restrict__ ln_g, const float* __restrict__ ln_b,
    bf16* __restrict__ Tn) {
  int bn = blockIdx.x;
  int n  = bn % N, b = bn / N;
  __shared__ __align__(16) __fp16 Klh[T * SK];        // 9600 B
  __shared__ __align__(16) __fp16 Vlh[T * SK];        // 9600 B
  __shared__ __align__(16) __fp16 Qlh[CH2 * SK];      // 2400 B
  __shared__ __align__(16) unsigned Olh[CH2 * SOH];   // packed f16 O, 2400 B
  __shared__ unsigned woh[(D / 2) * D];               // packed Wol, 2048 B
  __shared__ float bol[D], gl[D], bbl[D];
  int tid = threadIdx.x;

  const bf16* Kg = Kt + (size_t)bn * T * D;
  const bf16* Vg = Vt + (size_t)bn * T * D;
  const bf16* Qg = Qt + (size_t)bn * T * D;
  for (int i = tid; i < T * 4; i += 256) {
    int r = i >> 2, p = i & 3;
    uint4 ku = *(const uint4*)&Kg[r * D + p * 8];
    uint4 kh;
    kh.x = pkh2(blo(ku.x), bhi(ku.x));
    kh.y = pkh2(blo(ku.y), bhi(ku.y));
    kh.z = pkh2(blo(ku.z), bhi(ku.z));
    kh.w = pkh2(blo(ku.w), bhi(ku.w));
    *(uint4*)&Klh[r * SK + p * 8] = kh;
    uint4 vu = *(const uint4*)&Vg[r * D + p * 8];
    uint4 vh;
    vh.x = pkh2(blo(vu.x), bhi(vu.x));
    vh.y = pkh2(blo(vu.y), bhi(vu.y));
    vh.z = pkh2(blo(vu.z), bhi(vu.z));
    vh.w = pkh2(blo(vu.w), bhi(vu.w));
    *(uint4*)&Vlh[r * SK + p * 8] = vh;
  }
  {
    const float* wg = tm_Wo + (size_t)n * D * D;
    for (int i = tid; i < (D / 2) * D; i += 256) {
      int d2 = i >> 5, e = i & 31;
      woh[i] = pkh2(wg[(2 * d2) * D + e], wg[(2 * d2 + 1) * D + e]);
    }
  }
  if (tid < D) {
    bol[tid] = tm_bo[n * D + tid];
    gl[tid]  = ln_g[tid];
    bbl[tid] = ln_b[tid];
  }
  __syncthreads();

#pragma unroll 1
  for (int c = 0; c < 4; ++c) {
    if (tid < CH2 * 4) {
      int r = tid >> 2, p = tid & 3;
      uint4 qu = *(const uint4*)&Qg[(CH2 * c + r) * D + p * 8];
      uint4 qh;
      qh.x = pkh2(blo(qu.x), bhi(qu.x));
      qh.y = pkh2(blo(qu.y), bhi(qu.y));
      qh.z = pkh2(blo(qu.z), bhi(qu.z));
      qh.w = pkh2(blo(qu.w), bhi(qu.w));
      *(uint4*)&Qlh[r * SK + p * 8] = qh;
    }
    __syncthreads();   // Qlh ready; prior O-proj done -> Olh safe to overwrite

    {
      int task = tid >> 2, sl = tid & 3;
      if (task < 2 * CH2) {
        int rl = task >> 1, h = task & 1, ho = h * FD;
        int rg = CH2 * c + rl;
        uint4 q0 = *(const uint4*)&Qlh[rl * SK + ho];
        uint4 q1 = *(const uint4*)&Qlh[rl * SK + ho + 8];
        unsigned qh[8] = { q0.x, q0.y, q0.z, q0.w, q1.x, q1.y, q1.z, q1.w };

        float sc[NJ];
        float mx = -3e38f;
#pragma unroll
        for (int j = 0; j < NJ; ++j) {
          int k = 4 * j + sl;
          sc[j] = -3e38f;
          if (k <= rg) {
            const uint4 ka = *(const uint4*)&Klh[k * SK + ho];
            const uint4 kb = *(const uint4*)&Klh[k * SK + ho + 8];
            float s0 = __builtin_amdgcn_fdot2(u2h(qh[0]), u2h(ka.x), 0.f, false);
            float s1 = __builtin_amdgcn_fdot2(u2h(qh[1]), u2h(ka.y), 0.f, false);
            float s2 = __builtin_amdgcn_fdot2(u2h(qh[2]), u2h(ka.z), 0.f, false);
            float s3 = __builtin_amdgcn_fdot2(u2h(qh[3]), u2h(ka.w), 0.f, false);
            s0 = __builtin_amdgcn_fdot2(u2h(qh[4]), u2h(kb.x), s0, false);
            s1 = __builtin_amdgcn_fdot2(u2h(qh[5]), u2h(kb.y), s1, false);
            s2 = __builtin_amdgcn_fdot2(u2h(qh[6]), u2h(kb.z), s2, false);
            s3 = __builtin_amdgcn_fdot2(u2h(qh[7]), u2h(kb.w), s3, false);
            float s = ((s0 + s1) + (s2 + s3)) * SCALE;
            sc[j] = s;
            mx = fmaxf(mx, s);
          }
        }
        mx = fmaxf(mx, __shfl_xor(mx, 1, 64));
        mx = fmaxf(mx, __shfl_xor(mx, 2, 64));
        float l = 0.f;
#pragma unroll
        for (int j = 0; j < NJ; ++j) {
          sc[j] = __expf(sc[j] - mx);   // invalid slots: exp(-inf) = 0
          l += sc[j];
        }
        l += __shfl_xor(l, 1, 64);
        l += __shfl_xor(l, 2, 64);
        float rli = 1.f / l;

        f16x2 acc2[8];
#pragma unroll
        for (int f = 0; f < 8; ++f) acc2[f] = f16x2{(_Float16)0.f, (_Float16)0.f};
#pragma unroll
        for (int j = 0; j < NJ; ++j) {
          int k = 4 * j + sl;
          if (k <= rg) {
            f16x2 pp = f16x2{(_Float16)sc[j], (_Float16)sc[j]};
            const uint4 va = *(const uint4*)&Vlh[k * SK + ho];
            const uint4 vb = *(const uint4*)&Vlh[k * SK + ho + 8];
            acc2[0] += pp * u2f(va.x);
            acc2[1] += pp * u2f(va.y);
            acc2[2] += pp * u2f(va.z);
            acc2[3] += pp * u2f(va.w);
            acc2[4] += pp * u2f(vb.x);
            acc2[5] += pp * u2f(vb.y);
            acc2[6] += pp * u2f(vb.z);
            acc2[7] += pp * u2f(vb.w);
          }
        }
#pragma unroll
        for (int f = 0; f < 8; ++f) {
          unsigned u = *reinterpret_cast<unsigned*>(&acc2[f]);
          unsigned u1 = __shfl_xor(u, 1, 64);
          acc2[f] += u2f(u1);
          u = *reinterpret_cast<unsigned*>(&acc2[f]);
          unsigned u2_ = __shfl_xor(u, 2, 64);
          acc2[f] += u2f(u2_);
        }
        if (sl == 0) {
#pragma unroll
          for (int j = 0; j < 8; ++j)
            Olh[rl * SOH + h * 8 + j] =
                pkh2((float)acc2[j][0] * rli, (float)acc2[j][1] * rli);
        }
      }
    }
    __syncthreads();

    // ---- O-proj (fdot2) + residual + LN: thread = (row, e-quad) ----
    {
      int rl = tid >> 3, q = tid & 7, e0 = q * 4;
      if (rl < CH2) {
        int rg = CH2 * c + rl;
        size_t rowo = ((size_t)(b * T + rg) * N + n) * D;
        uint2 eu = *(const uint2*)&E[rowo + e0];
        float res[4] = { blo(eu.x), bhi(eu.x), blo(eu.y), bhi(eu.y) };
        float o[4], s1 = 0.f, s2 = 0.f;
#pragma unroll
        for (int j = 0; j < 4; ++j) {
          int e = e0 + j;
          float a = bol[e] + res[j];
#pragma unroll
          for (int d2 = 0; d2 < D / 2; ++d2)
            a = __builtin_amdgcn_fdot2(u2h(Olh[rl * SOH + d2]),
                                       u2h(woh[d2 * D + e]), a, false);
          o[j] = a; s1 += a; s2 += a * a;
        }
        s1 += __shfl_xor(s1, 1, 64); s2 += __shfl_xor(s2, 1, 64);
        s1 += __shfl_xor(s1, 2, 64); s2 += __shfl_xor(s2, 2, 64);
        s1 += __shfl_xor(s1, 4, 64); s2 += __shfl_xor(s2, 4, 64);
        float mu  = s1 * (1.f / D);
        float var = s2 * (1.f / D) - mu * mu;
        float r = rsqrtf(var + 1e-5f);
        uint2 ou;
        ou.x = pk2((o[0]-mu)*r*gl[e0]+bbl[e0],    (o[1]-mu)*r*gl[e0+1]+bbl[e0+1]);
        ou.y = pk2((o[2]-mu)*r*gl[e0+2]+bbl[e0+2],(o[3]-mu)*r*gl[e0+3]+bbl[e0+3]);
        *(uint2*)&Tn[rowo + e0] = ou;
      }
    }
  }
}

// ---------------------------------------------------------------------------
// spatial v5 = v4 + full packed-f16 attention (attnt-v12 structure ported).
//  - Q/K/V stored packed f16 (stride SK=40 halfs): LDS 34.3 -> 24.3 KB
//    -> 6 blocks/CU (was 4).
//  - scores: uint4 + 8 fdot2/key;  PV: v_pk_fma_f16, O written back packed
//    into the Q slot;  O-proj: fdot2 vs packed woh (2-iter row split).
// ---------------------------------------------------------------------------
__global__ __launch_bounds__(256) void spatial_kernel(
    const bf16* __restrict__ E, const float* __restrict__ WsC,
    const float* __restrict__ bsC, const float* __restrict__ sm_Wo,
    const float* __restrict__ sm_bo, const float* __restrict__ ln_g,
    const float* __restrict__ ln_b, bf16* __restrict__ Sn) {
  int t  = blockIdx.x >> 5;          // B/BG = 32 groups per t
  int bg = blockIdx.x & 31;
  int b0 = bg * BG;
  __shared__ unsigned Wh[3 * (D / 2) * D];          // packed f16 pairs, 6144 B
  __shared__ unsigned woh[(D / 2) * D];             // packed Wo, 2048 B
  __shared__ float bqs[D], bks[D], bvs[D], bos[D], gs[D], bbs[D];
  __shared__ __align__(16) unsigned Esh[SR * SEH];  // packed f16 Es, 3840 B
  __shared__ __align__(16) __fp16 Qh[SR * SK];      // 3840 B (O overwrites)
  __shared__ __align__(16) __fp16 Kh[SR * SK];      // 3840 B
  __shared__ __align__(16) __fp16 Vh[SR * SK];      // 3840 B
  int tid = threadIdx.x;

  for (int i = tid; i < 3 * (D / 2) * D; i += 256) {
    int fam = i / ((D / 2) * D);
    int idx = i % ((D / 2) * D);
    int d2 = idx >> 5, e = idx & 31;
    const float* wg = WsC + (size_t)(fam * T + t) * D * D;
    Wh[i] = pkh2(wg[(2 * d2) * D + e], wg[(2 * d2 + 1) * D + e]);
  }
  {
    const float* wg = sm_Wo + (size_t)t * D * D;
    for (int i = tid; i < (D / 2) * D; i += 256) {
      int d2 = i >> 5, e = i & 31;
      woh[i] = pkh2(wg[(2 * d2) * D + e], wg[(2 * d2 + 1) * D + e]);
    }
  }
  if (tid < D) {
    bqs[tid] = bsC[(0 * T + t) * D + tid];
    bks[tid] = bsC[(1 * T + t) * D + tid];
    bvs[tid] = bsC[(2 * T + t) * D + tid];
    bos[tid] = sm_bo[t * D + tid];
    gs[tid]  = ln_g[tid];
    bbs[tid] = ln_b[tid];
  }
  if (tid < SR * 4) {
    int r = tid >> 2, p = tid & 3;
    int b = b0 + r / N, n = r % N;
    uint4 u = *(const uint4*)&E[(((size_t)b * T + t) * N + n) * D + p * 8];
    uint4 o;
    o.x = pkh2(blo(u.x), bhi(u.x));
    o.y = pkh2(blo(u.y), bhi(u.y));
    o.z = pkh2(blo(u.z), bhi(u.z));
    o.w = pkh2(blo(u.w), bhi(u.w));
    *(uint4*)&Esh[r * SEH + p * 4] = o;
  }
  __syncthreads();

  // ---- QKV gemv (fdot2) -> packed-f16 Q/K/V ----
#pragma unroll 1
  for (int i = tid; i < SR * D; i += 256) {
    int r = i >> 5, e = i & 31;
    float aq = bqs[e], ak = bks[e], av = bvs[e];
#pragma unroll
    for (int d2 = 0; d2 < D / 2; ++d2) {
      h2 x = u2h(Esh[r * SEH + d2]);
      aq = __builtin_amdgcn_fdot2(x, u2h(Wh[0 * 512 + d2 * 32 + e]), aq, false);
      ak = __builtin_amdgcn_fdot2(x, u2h(Wh[1 * 512 + d2 * 32 + e]), ak, false);
      av = __builtin_amdgcn_fdot2(x, u2h(Wh[2 * 512 + d2 * 32 + e]), av, false);
    }
    Qh[r * SK + e] = (__fp16)aq;
    Kh[r * SK + e] = (__fp16)ak;
    Vh[r * SK + e] = (__fp16)av;
  }
  __syncthreads();

  // ---- attention (96 threads): fdot2 scores + pk_fma PV, O -> Q slot ----
  if (tid < SR * NH) {
    int r = tid >> 1, h = tid & 1, ho = h * FD;
    int kb = (r >= N) ? N : 0;
    uint4 q0 = *(const uint4*)&Qh[r * SK + ho];
    uint4 q1 = *(const uint4*)&Qh[r * SK + ho + 8];
    unsigned qh[8] = { q0.x, q0.y, q0.z, q0.w, q1.x, q1.y, q1.z, q1.w };
    float sc[N];
    float m = -1e30f;
#pragma unroll
    for (int k = 0; k < N; ++k) {
      const uint4 ka = *(const uint4*)&Kh[(kb + k) * SK + ho];
      const uint4 kc = *(const uint4*)&Kh[(kb + k) * SK + ho + 8];
      float s0 = __builtin_amdgcn_fdot2(u2h(qh[0]), u2h(ka.x), 0.f, false);
      float s1 = __builtin_amdgcn_fdot2(u2h(qh[1]), u2h(ka.y), 0.f, false);
      float s2 = __builtin_amdgcn_fdot2(u2h(qh[2]), u2h(ka.z), 0.f, false);
      float s3 = __builtin_amdgcn_fdot2(u2h(qh[3]), u2h(ka.w), 0.f, false);
      s0 = __builtin_amdgcn_fdot2(u2h(qh[4]), u2h(kc.x), s0, false);
      s1 = __builtin_amdgcn_fdot2(u2h(qh[5]), u2h(kc.y), s1, false);
      s2 = __builtin_amdgcn_fdot2(u2h(qh[6]), u2h(kc.z), s2, false);
      s3 = __builtin_amdgcn_fdot2(u2h(qh[7]), u2h(kc.w), s3, false);
      float s = ((s0 + s1) + (s2 + s3)) * SCALE;
      sc[k] = s;
      m = fmaxf(m, s);
    }
    float l = 0.f;
#pragma unroll
    for (int k = 0; k < N; ++k) { sc[k] = __expf(sc[k] - m); l += sc[k]; }
    float rl = 1.f / l;

    f16x2 acc2[8];
#pragma unroll
    for (int f = 0; f < 8; ++f) acc2[f] = f16x2{(_Float16)0.f, (_Float16)0.f};
#pragma unroll
    for (int k = 0; k < N; ++k) {
      f16x2 pp = f16x2{(_Float16)sc[k], (_Float16)sc[k]};
      const uint4 va = *(const uint4*)&Vh[(kb + k) * SK + ho];
      const uint4 vb = *(const uint4*)&Vh[(kb + k) * SK + ho + 8];
      acc2[0] += pp * u2f(va.x);
      acc2[1] += pp * u2f(va.y);
      acc2[2] += pp * u2f(va.z);
      acc2[3] += pp * u2f(va.w);
      acc2[4] += pp * u2f(vb.x);
      acc2[5] += pp * u2f(vb.y);
      acc2[6] += pp * u2f(vb.z);
      acc2[7] += pp * u2f(vb.w);
    }
    unsigned* op = (unsigned*)&Qh[r * SK + ho];
#pragma unroll
    for (int j = 0; j < 8; ++j)
      op[j] = pkh2((float)acc2[j][0] * rl, (float)acc2[j][1] * rl);
  }
  __syncthreads();

  // ---- O-proj (fdot2) + residual + LN: thread = (row, e-quad), 2 iters ----
#pragma unroll 1
  for (int it = 0; it < 2; ++it) {
    int rl = it * 32 + (tid >> 3);
    int q = tid & 7, e0 = q * 4;
    if (rl < SR) {
      const unsigned* opk = (const unsigned*)&Qh[rl * SK];
      unsigned r0u = Esh[rl * SEH + (e0 >> 1)];
      unsigned r1u = Esh[rl * SEH + (e0 >> 1) + 1];
      h2 ra = u2h(r0u), rb = u2h(r1u);
      float res[4] = { (float)ra[0], (float)ra[1], (float)rb[0], (float)rb[1] };
      float o[4], s1 = 0.f, s2 = 0.f;
#pragma unroll
      for (int j = 0; j < 4; ++j) {
        int e = e0 + j;
        float a = bos[e] + res[j];
#pragma unroll
        for (int d2 = 0; d2 < D / 2; ++d2)
          a = __builtin_amdgcn_fdot2(u2h(opk[d2]), u2h(woh[d2 * D + e]), a, false);
        o[j] = a; s1 += a; s2 += a * a;
      }
      s1 += __shfl_xor(s1, 1, 64); s2 += __shfl_xor(s2, 1, 64);
      s1 += __shfl_xor(s1, 2, 64); s2 += __shfl_xor(s2, 2, 64);
      s1 += __shfl_xor(s1, 4, 64); s2 += __shfl_xor(s2, 4, 64);
      float mu  = s1 * (1.f / D);
      float var = s2 * (1.f / D) - mu * mu;
      float rr = rsqrtf(var + 1e-5f);
      int b = b0 + rl / N, n = rl % N;
      uint2 ou;
      ou.x = pk2((o[0]-mu)*rr*gs[e0]+bbs[e0],    (o[1]-mu)*rr*gs[e0+1]+bbs[e0+1]);
      ou.y = pk2((o[2]-mu)*rr*gs[e0+2]+bbs[e0+2],(o[3]-mu)*rr*gs[e0+3]+bbs[e0+3]);
      *(uint2*)&Sn[(((size_t)b * T + t) * N + n) * D + e0] = ou;
    }
  }
}

// ---------------------------------------------------------------------------
// ff v3: packed-f16 fdot2 gemvs (measured R26: ~-24us/dispatch).
// ---------------------------------------------------------------------------
__global__ __launch_bounds__(256) void ff_kernel(
    const bf16* __restrict__ Tn, const bf16* __restrict__ Sn,
    const float* __restrict__ W1, const float* __restrict__ b1,
    const float* __restrict__ W2, const float* __restrict__ b2,
    const float* __restrict__ ln_g, const float* __restrict__ ln_b,
    bf16* __restrict__ E) {
  __shared__ unsigned w1h[(D / 2) * FF];   // 1024 uints, 4KB
  __shared__ unsigned w2h[(FF / 2) * D];   // 1024 uints, 4KB
  __shared__ float bb1[FF], bb2[D], gs[D], bbs[D];
  __shared__ unsigned tslp[FR][D / 2 + 1]; // 32 x 17 (stride 17: conflict-free)
  __shared__ unsigned hlp[FR][FF / 2 + 1]; // 32 x 33 (stride 33: conflict-free)
  int tid = threadIdx.x;
  int r0 = blockIdx.x * FR;
  for (int i = tid; i < (D / 2) * FF; i += 256) {
    int d2 = i / FF, jj = i % FF;
    w1h[i] = pkh2(W1[(2 * d2) * FF + jj], W1[(2 * d2 + 1) * FF + jj]);
  }
  for (int i = tid; i < (FF / 2) * D; i += 256) {
    int k2 = i / D, e = i % D;
    w2h[i] = pkh2(W2[(2 * k2) * D + e], W2[(2 * k2 + 1) * D + e]);
  }
  if (tid < FF) bb1[tid] = b1[tid];
  if (tid < D) { bb2[tid] = b2[tid]; gs[tid] = ln_g[tid]; bbs[tid] = ln_b[tid]; }
  int r = tid >> 3, s = tid & 7;
  {
    const bf16* tp = Tn + ((size_t)(r0 + r)) * D + s * 4;
    const bf16* sp = Sn + ((size_t)(r0 + r)) * D + s * 4;
    uint2 tu = *(const uint2*)tp;
    uint2 su = *(const uint2*)sp;
    float t0 = blo(tu.x) + blo(su.x);
    float t1 = bhi(tu.x) + bhi(su.x);
    float t2 = blo(tu.y) + blo(su.y);
    float t3 = bhi(tu.y) + bhi(su.y);
    tslp[r][s * 2]     = pkh2(t0, t1);
    tslp[r][s * 2 + 1] = pkh2(t2, t3);
  }
  __syncthreads();
  // pass1: 8 hidden units per lane via fdot2
  {
    float hh[8];
#pragma unroll
    for (int j = 0; j < 8; ++j) {
      int jj = s * 8 + j;
      float a = bb1[jj];
#pragma unroll
      for (int d2 = 0; d2 < D / 2; ++d2)
        a = __builtin_amdgcn_fdot2(u2h(tslp[r][d2]), u2h(w1h[d2 * FF + jj]), a, false);
      hh[j] = fmaxf(a, 0.f);
    }
#pragma unroll
    for (int j = 0; j < 4; ++j)
      hlp[r][s * 4 + j] = pkh2(hh[2 * j], hh[2 * j + 1]);
  }
  __syncthreads();
  // pass2: 4 outputs per lane via fdot2 + LN (3-level shfl reduce)
  {
    float x[4];
    float s1 = 0.f, s2 = 0.f;
#pragma unroll
    for (int j4 = 0; j4 < 4; ++j4) {
      int e = s * 4 + j4;
      h2 tv = u2h(tslp[r][e >> 1]);
      float a = bb2[e] + (float)tv[j4 & 1];   // s*4 even -> e&1 == j4&1
#pragma unroll
      for (int k2 = 0; k2 < FF / 2; ++k2)
        a = __builtin_amdgcn_fdot2(u2h(hlp[r][k2]), u2h(w2h[k2 * D + e]), a, false);
      x[j4] = a; s1 += a; s2 += a * a;
    }
    s1 += __shfl_xor(s1, 1, 64); s2 += __shfl_xor(s2, 1, 64);
    s1 += __shfl_xor(s1, 2, 64); s2 += __shfl_xor(s2, 2, 64);
    s1 += __shfl_xor(s1, 4, 64); s2 += __shfl_xor(s2, 4, 64);
    float mu  = s1 * (1.f / D);
    float var = s2 * (1.f / D) - mu * mu;
    float rr = rsqrtf(var + 1e-5f);
    int e0 = s * 4;
    uint2 ou;
    ou.x = pk2((x[0]-mu)*rr*gs[e0]+bbs[e0],    (x[1]-mu)*rr*gs[e0+1]+bbs[e0+1]);
    ou.y = pk2((x[2]-mu)*rr*gs[e0+2]+bbs[e0+2],(x[3]-mu)*rr*gs[e0+3]+bbs[e0+3]);
    *(uint2*)&E[((size_t)(r0 + r)) * D + e0] = ou;
  }
}

// ---------------------------------------------------------------------------
// out = E@op_W + op_b + X   (f32 out)
// ---------------------------------------------------------------------------
__global__ __launch_bounds__(256) void out_kernel(
    const bf16* __restrict__ E, const float* __restrict__ op_W,
    const float* __restrict__ op_b, const float* __restrict__ X,
    float* __restrict__ out) {
  int idx = blockIdx.x * 256 + threadIdx.x;
  if (idx >= B * T * N * M) return;
  int m  = idx % M;
  int n  = (idx / M) % N;
  int bt = idx / (M * N);
  float acc = op_b[n * M + m];
  const bf16* e = E + ((size_t)bt * N + n) * D;
#pragma unroll
  for (int d = 0; d < D; ++d) acc += b2f(e[d]) * op_W[(n * D + d) * M + m];
  acc += X[idx];
  out[idx] = acc;
}

// ---------------------------------------------------------------------------
extern "C" void kernel_launch(void* const* d_in, const int* in_sizes, int n_in,
                              void* d_out, int out_size, void* d_ws, size_t ws_size,
                              hipStream_t stream) {
  const float* X     = (const float*)d_in[0];
  const float* pe    = (const float*)d_in[1];
  const float* E_W   = (const float*)d_in[2];
  const float* E_b   = (const float*)d_in[3];
  const float* tq_W  = (const float*)d_in[4];
  const float* tq_b  = (const float*)d_in[5];
  const float* tk_W  = (const float*)d_in[6];
  const float* tk_b  = (const float*)d_in[7];
  const float* tv_W  = (const float*)d_in[8];
  const float* tv_b  = (const float*)d_in[9];
  const float* tm_Wq = (const float*)d_in[10];
  const float* tm_bq = (const float*)d_in[11];
  const float* tm_Wk = (const float*)d_in[12];
  const float* tm_bk = (const float*)d_in[13];
  const float* tm_Wv = (const float*)d_in[14];
  const float* tm_bv = (const float*)d_in[15];
  const float* tm_Wo = (const float*)d_in[16];
  const float* tm_bo = (const float*)d_in[17];
  const float* sq_W  = (const float*)d_in[18];
  const float* sq_b  = (const float*)d_in[19];
  const float* sk_W  = (const float*)d_in[20];
  const float* sk_b  = (const float*)d_in[21];
  const float* sv_W  = (const float*)d_in[22];
  const float* sv_b  = (const float*)d_in[23];
  const float* sm_Wq = (const float*)d_in[24];
  const float* sm_bq = (const float*)d_in[25];
  const float* sm_Wk = (const float*)d_in[26];
  const float* sm_bk = (const float*)d_in[27];
  const float* sm_Wv = (const float*)d_in[28];
  const float* sm_bv = (const float*)d_in[29];
  const float* sm_Wo = (const float*)d_in[30];
  const float* sm_bo = (const float*)d_in[31];
  const float* ff1_W = (const float*)d_in[32];
  const float* ff1_b = (const float*)d_in[33];
  const float* ff2_W = (const float*)d_in[34];
  const float* ff2_b = (const float*)d_in[35];
  const float* ln_g  = (const float*)d_in[36];
  const float* ln_b  = (const float*)d_in[37];
  const float* op_W  = (const float*)d_in[38];
  const float* op_b  = (const float*)d_in[39];
  float* out = (float*)d_out;

  float* WtC = (float*)d_ws;                         // 3*N*D*D
  float* btC = WtC + 3 * N * D * D;                  // 3*N*D
  float* WsC = btC + 3 * N * D;                      // 3*T*D*D
  float* bsC = WsC + 3 * T * D * D;                  // 3*T*D
  size_t act = (size_t)B * T * N * D;
  bf16* Ebuf = (bf16*)(bsC + 3 * T * D);
  bf16* Tn   = Ebuf + act;
  bf16* Qt   = Tn + act;
  bf16* Kt   = Qt + act;
  bf16* Vt   = Kt + act;
  bf16* Sn   = Qt;                                   // alias (safe: serial schedule)

  compose3_kernel<<<3 * N, 256, 0, stream>>>(
      tq_W, tq_b, tm_Wq, tm_bq, tk_W, tk_b, tm_Wk, tm_bk,
      tv_W, tv_b, tm_Wv, tm_bv, WtC, btC, N);
  compose3_kernel<<<3 * T, 256, 0, stream>>>(
      sq_W, sq_b, sm_Wq, sm_bq, sk_W, sk_b, sm_Wk, sm_bk,
      sv_W, sv_b, sm_Wv, sm_bv, WsC, bsC, T);

  embed_kernel<<<(B * T * N * D) / 256, 256, 0, stream>>>(X, pe, E_W, E_b, Ebuf);

  for (int l = 0; l < L; ++l) {
    qkvt_kernel<<<N * QCH, 256, 0, stream>>>(Ebuf, WtC, btC, Qt, Kt, Vt);
    attnt_kernel<<<B * N, 256, 0, stream>>>(Qt, Kt, Vt, Ebuf, tm_Wo, tm_bo, ln_g, ln_b, Tn);
    spatial_kernel<<<T * (B / BG), 256, 0, stream>>>(Ebuf, WsC, bsC, sm_Wo, sm_bo, ln_g, ln_b, Sn);
    ff_kernel<<<(B * T * N) / FR, 256, 0, stream>>>(Tn, Sn, ff1_W, ff1_b, ff2_W, ff2_b, ln_g, ln_b, Ebuf);
  }

  out_kernel<<<(B * T * N * M + 255) / 256, 256, 0, stream>>>(Ebuf, op_W, op_b, X, out);
}

// Round 31
// 437.964 us; speedup vs baseline: 2.0921x; 1.0909x over previous
//
#include <hip/hip_runtime.h>
#include <hip/hip_bf16.h>

typedef __hip_bfloat16 bf16;
typedef __fp16 h2 __attribute__((ext_vector_type(2)));      // matches amdgcn builtin 'V2h'
typedef _Float16 f16x2 __attribute__((ext_vector_type(2))); // arithmetic (v_pk_*_f16)

constexpr int B  = 64, T = 120, N = 24, M = 3, D = 32;
constexpr int NH = 2, FD = 16, FF = 64, L = 3;
constexpr float SCALE = 0.25f;   // 1/sqrt(FD)
constexpr int SK  = 40;          // f16 LDS stride (80B rows) — attnt & spatial
constexpr int SOH = 20;          // attnt packed-f16 O stride (uints, 80B)
constexpr int CH2 = 30;          // attnt rows per chunk: 4 x 30 = 120 exactly
constexpr int NJ  = 30;          // max keys per lane slice (120/4)
constexpr int QR  = 64;          // qkvt rows per block (4 lanes/row)
constexpr int QCH = (B * T) / QR;// qkvt chunks = 120
constexpr int QEH = 20;          // qkvt packed-f16 Es stride (uints, 80B)
constexpr int BG  = 2;           // spatial batches per block
constexpr int SR  = N * BG;      // spatial rows per block = 48
constexpr int SEH = 20;          // spatial packed-f16 Es stride (uints, 80B)
constexpr int FR  = 32;          // ff rows per block (8 lanes/row)

__device__ __forceinline__ float b2f(bf16 x) { return __bfloat162float(x); }
__device__ __forceinline__ float blo(unsigned u) { return __uint_as_float(u << 16); }
__device__ __forceinline__ float bhi(unsigned u) { return __uint_as_float(u & 0xffff0000u); }
__device__ __forceinline__ unsigned pk2(float a, float b) {
  bf16 x = __float2bfloat16(a), y = __float2bfloat16(b);
  unsigned short ux = *reinterpret_cast<unsigned short*>(&x);
  unsigned short uy = *reinterpret_cast<unsigned short*>(&y);
  return (unsigned)ux | ((unsigned)uy << 16);
}
__device__ __forceinline__ unsigned pkh2(float a, float b) {
  h2 r = __builtin_amdgcn_cvt_pkrtz(a, b);     // v_cvt_pkrtz_f16_f32
  return *reinterpret_cast<unsigned*>(&r);
}
__device__ __forceinline__ h2 u2h(unsigned u) { return *reinterpret_cast<h2*>(&u); }
__device__ __forceinline__ f16x2 u2f(unsigned u) { return *reinterpret_cast<f16x2*>(&u); }

// ---------------------------------------------------------------------------
// Compose q/k/v chained linears: grid = 3*U blocks.  Wc = W1@W2, bc = b1@W2+b2.
// ---------------------------------------------------------------------------
__global__ __launch_bounds__(256) void compose3_kernel(
    const float* __restrict__ W1q, const float* __restrict__ b1q,
    const float* __restrict__ W2q, const float* __restrict__ b2q,
    const float* __restrict__ W1k, const float* __restrict__ b1k,
    const float* __restrict__ W2k, const float* __restrict__ b2k,
    const float* __restrict__ W1v, const float* __restrict__ b1v,
    const float* __restrict__ W2v, const float* __restrict__ b2v,
    float* __restrict__ Wc, float* __restrict__ bc, int U) {
  int fam = blockIdx.x / U;
  int n   = blockIdx.x % U;
  const float* W1 = (fam == 0) ? W1q : (fam == 1) ? W1k : W1v;
  const float* b1 = (fam == 0) ? b1q : (fam == 1) ? b1k : b1v;
  const float* W2 = (fam == 0) ? W2q : (fam == 1) ? W2k : W2v;
  const float* b2 = (fam == 0) ? b2q : (fam == 1) ? b2k : b2v;
  const float* w1 = W1 + n * D * D;
  const float* w2 = W2 + n * D * D;
  float* wc  = Wc + (size_t)(fam * U + n) * D * D;
  float* bcp = bc + (fam * U + n) * D;
  __shared__ float s1[D * D], s2[D * D];
  for (int i = threadIdx.x; i < D * D; i += 256) { s1[i] = w1[i]; s2[i] = w2[i]; }
  __syncthreads();
  for (int i = threadIdx.x; i < D * D; i += 256) {
    int d = i >> 5, f = i & 31;
    float acc = 0.f;
#pragma unroll
    for (int e = 0; e < D; ++e) acc += s1[d * D + e] * s2[e * D + f];
    wc[i] = acc;
  }
  if (threadIdx.x < D) {
    int f = threadIdx.x;
    float acc = b2[n * D + f];
#pragma unroll
    for (int e = 0; e < D; ++e) acc += b1[n * D + e] * s2[e * D + f];
    bcp[f] = acc;
  }
}

// ---------------------------------------------------------------------------
// E[b,t,n,d] = X@E_W + E_b + pe   (bf16 out)
// ---------------------------------------------------------------------------
__global__ __launch_bounds__(256) void embed_kernel(
    const float* __restrict__ X, const float* __restrict__ pe,
    const float* __restrict__ E_W, const float* __restrict__ E_b,
    bf16* __restrict__ E) {
  int idx = blockIdx.x * 256 + threadIdx.x;
  if (idx >= B * T * N * D) return;
  int d = idx & 31;
  int n = (idx >> 5) % N;
  int bt = idx / (D * N);
  int t = bt % T;
  const float* x = X + bt * (N * M) + n * M;
  float acc = E_b[n * D + d] + pe[t * D + d];
#pragma unroll
  for (int m = 0; m < M; ++m) acc += x[m] * E_W[(n * M + m) * D + d];
  E[idx] = __float2bfloat16(acc);
}

// ---------------------------------------------------------------------------
// qkvt v3: packed-f16 fdot2 gemv (measured R27: -17us/dispatch).
// ---------------------------------------------------------------------------
__global__ __launch_bounds__(256) void qkvt_kernel(
    const bf16* __restrict__ E, const float* __restrict__ WtC,
    const float* __restrict__ btC,
    bf16* __restrict__ Qt, bf16* __restrict__ Kt, bf16* __restrict__ Vt) {
  int n     = blockIdx.x / QCH;
  int chunk = blockIdx.x % QCH;
  __shared__ unsigned whh[3 * (D / 2) * D];        // 1536 uints, 6 KB
  __shared__ float bsh[3 * D];
  __shared__ __align__(16) unsigned Esp[QR * QEH]; // packed f16 Es, 5 KB
  int tid = threadIdx.x;
  for (int i = tid; i < 3 * (D / 2) * D; i += 256) {
    int fam = i / ((D / 2) * D);
    int idx = i % ((D / 2) * D);
    int d2 = idx >> 5, j = idx & 31;
    const float* wg = WtC + (size_t)(fam * N + n) * D * D;
    whh[i] = pkh2(wg[(2 * d2) * D + j], wg[(2 * d2 + 1) * D + j]);
  }
  if (tid < 3 * D) {
    int fam = tid >> 5, e = tid & 31;
    bsh[tid] = btC[(fam * N + n) * D + e];
  }
  {
    int row = tid >> 2, p = tid & 3;
    const bf16* er = E + ((size_t)(chunk * QR + row) * N + n) * D;
    uint4 u = *(const uint4*)&er[p * 8];
    uint4 o;
    o.x = pkh2(blo(u.x), bhi(u.x));
    o.y = pkh2(blo(u.y), bhi(u.y));
    o.z = pkh2(blo(u.z), bhi(u.z));
    o.w = pkh2(blo(u.w), bhi(u.w));
    *(uint4*)&Esp[row * QEH + p * 4] = o;
  }
  __syncthreads();

  int row = tid >> 2, q = tid & 3;
  int grow = chunk * QR + row;          // b*T + t
  int b = grow / T, t = grow % T;
  unsigned xp[D / 2];
#pragma unroll
  for (int d2 = 0; d2 < D / 2; ++d2) xp[d2] = Esp[row * QEH + d2];
  size_t dsto = (((size_t)b * N + n) * T + t) * D + q * 8;
  bf16* dsts[3] = { Qt + dsto, Kt + dsto, Vt + dsto };
#pragma unroll
  for (int fam = 0; fam < 3; ++fam) {
    const unsigned* wf = whh + fam * (D / 2) * D;
    const float* bi = bsh + fam * D;
    float a[8];
#pragma unroll
    for (int j = 0; j < 8; ++j) a[j] = bi[q * 8 + j];
#pragma unroll
    for (int d2 = 0; d2 < D / 2; ++d2) {
      h2 x = u2h(xp[d2]);
#pragma unroll
      for (int j = 0; j < 8; ++j)
        a[j] = __builtin_amdgcn_fdot2(x, u2h(wf[d2 * D + q * 8 + j]), a[j], false);
    }
    uint4 o;
    o.x = pk2(a[0], a[1]); o.y = pk2(a[2], a[3]);
    o.z = pk2(a[4], a[5]); o.w = pk2(a[6], a[7]);
    *(uint4*)dsts[fam] = o;
  }
}

// ---------------------------------------------------------------------------
// attnt v13 = v12 + causal-bounded chunk unroll.  The c-loop is fully
// unrolled so the per-chunk key bound JM = (CH2*(c+1)+3)>>2 = {8,15,23,30}
// folds at compile time: chunks 0/1/2 skip the 22/15/7 score+PV iterations
// that the causal mask kills anyway (120 -> 76 iterations, -37% VALU).
// Arithmetic identical (skipped slots were exp(-inf)=0 / predicated off).
// ---------------------------------------------------------------------------
__global__ __launch_bounds__(256) void attnt_kernel(
    const bf16* __restrict__ Qt, const bf16* __restrict__ Kt,
    const bf16* __restrict__ Vt, const bf16* __restrict__ E,
    const float* __restrict__ tm_Wo, const float* __restrict__ tm_bo,
    const float* __restrict__ ln_g, const float* __restrict__ ln_b,
    bf16* __restrict__ Tn) {
  int bn = blockIdx.x;
  int n  = bn % N, b = bn / N;
  __shared__ __align__(16) __fp16 Klh[T * SK];        // 9600 B
  __shared__ __align__(16) __fp16 Vlh[T * SK];        // 9600 B
  __shared__ __align__(16) __fp16 Qlh[CH2 * SK];      // 2400 B
  __shared__ __align__(16) unsigned Olh[CH2 * SOH];   // packed f16 O, 2400 B
  __shared__ unsigned woh[(D / 2) * D];               // packed Wol, 2048 B
  __shared__ float bol[D], gl[D], bbl[D];
  int tid = threadIdx.x;

  const bf16* Kg = Kt + (size_t)bn * T * D;
  const bf16* Vg = Vt + (size_t)bn * T * D;
  const bf16* Qg = Qt + (size_t)bn * T * D;
  for (int i = tid; i < T * 4; i += 256) {
    int r = i >> 2, p = i & 3;
    uint4 ku = *(const uint4*)&Kg[r * D + p * 8];
    uint4 kh;
    kh.x = pkh2(blo(ku.x), bhi(ku.x));
    kh.y = pkh2(blo(ku.y), bhi(ku.y));
    kh.z = pkh2(blo(ku.z), bhi(ku.z));
    kh.w = pkh2(blo(ku.w), bhi(ku.w));
    *(uint4*)&Klh[r * SK + p * 8] = kh;
    uint4 vu = *(const uint4*)&Vg[r * D + p * 8];
    uint4 vh;
    vh.x = pkh2(blo(vu.x), bhi(vu.x));
    vh.y = pkh2(blo(vu.y), bhi(vu.y));
    vh.z = pkh2(blo(vu.z), bhi(vu.z));
    vh.w = pkh2(blo(vu.w), bhi(vu.w));
    *(uint4*)&Vlh[r * SK + p * 8] = vh;
  }
  {
    const float* wg = tm_Wo + (size_t)n * D * D;
    for (int i = tid; i < (D / 2) * D; i += 256) {
      int d2 = i >> 5, e = i & 31;
      woh[i] = pkh2(wg[(2 * d2) * D + e], wg[(2 * d2 + 1) * D + e]);
    }
  }
  if (tid < D) {
    bol[tid] = tm_bo[n * D + tid];
    gl[tid]  = ln_g[tid];
    bbl[tid] = ln_b[tid];
  }
  __syncthreads();

#pragma unroll
  for (int c = 0; c < 4; ++c) {
    const int JM = (CH2 * (c + 1) + 3) >> 2;   // 8,15,23,30 (compile-time)
    if (tid < CH2 * 4) {
      int r = tid >> 2, p = tid & 3;
      uint4 qu = *(const uint4*)&Qg[(CH2 * c + r) * D + p * 8];
      uint4 qh;
      qh.x = pkh2(blo(qu.x), bhi(qu.x));
      qh.y = pkh2(blo(qu.y), bhi(qu.y));
      qh.z = pkh2(blo(qu.z), bhi(qu.z));
      qh.w = pkh2(blo(qu.w), bhi(qu.w));
      *(uint4*)&Qlh[r * SK + p * 8] = qh;
    }
    __syncthreads();   // Qlh ready; prior O-proj done -> Olh safe to overwrite

    {
      int task = tid >> 2, sl = tid & 3;
      if (task < 2 * CH2) {
        int rl = task >> 1, h = task & 1, ho = h * FD;
        int rg = CH2 * c + rl;
        uint4 q0 = *(const uint4*)&Qlh[rl * SK + ho];
        uint4 q1 = *(const uint4*)&Qlh[rl * SK + ho + 8];
        unsigned qh[8] = { q0.x, q0.y, q0.z, q0.w, q1.x, q1.y, q1.z, q1.w };

        float sc[NJ];
        float mx = -3e38f;
#pragma unroll
        for (int j = 0; j < JM; ++j) {
          int k = 4 * j + sl;
          sc[j] = -3e38f;
          if (k <= rg) {
            const uint4 ka = *(const uint4*)&Klh[k * SK + ho];
            const uint4 kb = *(const uint4*)&Klh[k * SK + ho + 8];
            float s0 = __builtin_amdgcn_fdot2(u2h(qh[0]), u2h(ka.x), 0.f, false);
            float s1 = __builtin_amdgcn_fdot2(u2h(qh[1]), u2h(ka.y), 0.f, false);
            float s2 = __builtin_amdgcn_fdot2(u2h(qh[2]), u2h(ka.z), 0.f, false);
            float s3 = __builtin_amdgcn_fdot2(u2h(qh[3]), u2h(ka.w), 0.f, false);
            s0 = __builtin_amdgcn_fdot2(u2h(qh[4]), u2h(kb.x), s0, false);
            s1 = __builtin_amdgcn_fdot2(u2h(qh[5]), u2h(kb.y), s1, false);
            s2 = __builtin_amdgcn_fdot2(u2h(qh[6]), u2h(kb.z), s2, false);
            s3 = __builtin_amdgcn_fdot2(u2h(qh[7]), u2h(kb.w), s3, false);
            float s = ((s0 + s1) + (s2 + s3)) * SCALE;
            sc[j] = s;
            mx = fmaxf(mx, s);
          }
        }
        mx = fmaxf(mx, __shfl_xor(mx, 1, 64));
        mx = fmaxf(mx, __shfl_xor(mx, 2, 64));
        float l = 0.f;
#pragma unroll
        for (int j = 0; j < JM; ++j) {
          sc[j] = __expf(sc[j] - mx);   // invalid slots: exp(-inf) = 0
          l += sc[j];
        }
        l += __shfl_xor(l, 1, 64);
        l += __shfl_xor(l, 2, 64);
        float rli = 1.f / l;

        f16x2 acc2[8];
#pragma unroll
        for (int f = 0; f < 8; ++f) acc2[f] = f16x2{(_Float16)0.f, (_Float16)0.f};
#pragma unroll
        for (int j = 0; j < JM; ++j) {
          int k = 4 * j + sl;
          if (k <= rg) {
            f16x2 pp = f16x2{(_Float16)sc[j], (_Float16)sc[j]};
            const uint4 va = *(const uint4*)&Vlh[k * SK + ho];
            const uint4 vb = *(const uint4*)&Vlh[k * SK + ho + 8];
            acc2[0] += pp * u2f(va.x);
            acc2[1] += pp * u2f(va.y);
            acc2[2] += pp * u2f(va.z);
            acc2[3] += pp * u2f(va.w);
            acc2[4] += pp * u2f(vb.x);
            acc2[5] += pp * u2f(vb.y);
            acc2[6] += pp * u2f(vb.z);
            acc2[7] += pp * u2f(vb.w);
          }
        }
#pragma unroll
        for (int f = 0; f < 8; ++f) {
          unsigned u = *reinterpret_cast<unsigned*>(&acc2[f]);
          unsigned u1 = __shfl_xor(u, 1, 64);
          acc2[f] += u2f(u1);
          u = *reinterpret_cast<unsigned*>(&acc2[f]);
          unsigned u2_ = __shfl_xor(u, 2, 64);
          acc2[f] += u2f(u2_);
        }
        if (sl == 0) {
#pragma unroll
          for (int j = 0; j < 8; ++j)
            Olh[rl * SOH + h * 8 + j] =
                pkh2((float)acc2[j][0] * rli, (float)acc2[j][1] * rli);
        }
      }
    }
    __syncthreads();

    // ---- O-proj (fdot2) + residual + LN: thread = (row, e-quad) ----
    {
      int rl = tid >> 3, q = tid & 7, e0 = q * 4;
      if (rl < CH2) {
        int rg = CH2 * c + rl;
        size_t rowo = ((size_t)(b * T + rg) * N + n) * D;
        uint2 eu = *(const uint2*)&E[rowo + e0];
        float res[4] = { blo(eu.x), bhi(eu.x), blo(eu.y), bhi(eu.y) };
        float o[4], s1 = 0.f, s2 = 0.f;
#pragma unroll
        for (int j = 0; j < 4; ++j) {
          int e = e0 + j;
          float a = bol[e] + res[j];
#pragma unroll
          for (int d2 = 0; d2 < D / 2; ++d2)
            a = __builtin_amdgcn_fdot2(u2h(Olh[rl * SOH + d2]),
                                       u2h(woh[d2 * D + e]), a, false);
          o[j] = a; s1 += a; s2 += a * a;
        }
        s1 += __shfl_xor(s1, 1, 64); s2 += __shfl_xor(s2, 1, 64);
        s1 += __shfl_xor(s1, 2, 64); s2 += __shfl_xor(s2, 2, 64);
        s1 += __shfl_xor(s1, 4, 64); s2 += __shfl_xor(s2, 4, 64);
        float mu  = s1 * (1.f / D);
        float var = s2 * (1.f / D) - mu * mu;
        float r = rsqrtf(var + 1e-5f);
        uint2 ou;
        ou.x = pk2((o[0]-mu)*r*gl[e0]+bbl[e0],    (o[1]-mu)*r*gl[e0+1]+bbl[e0+1]);
        ou.y = pk2((o[2]-mu)*r*gl[e0+2]+bbl[e0+2],(o[3]-mu)*r*gl[e0+3]+bbl[e0+3]);
        *(uint2*)&Tn[rowo + e0] = ou;
      }
    }
  }
}

// ---------------------------------------------------------------------------
// spatial v5: full packed-f16 attention (measured R30: <73us).
// ---------------------------------------------------------------------------
__global__ __launch_bounds__(256) void spatial_kernel(
    const bf16* __restrict__ E, const float* __restrict__ WsC,
    const float* __restrict__ bsC, const float* __restrict__ sm_Wo,
    const float* __restrict__ sm_bo, const float* __restrict__ ln_g,
    const float* __restrict__ ln_b, bf16* __restrict__ Sn) {
  int t  = blockIdx.x >> 5;          // B/BG = 32 groups per t
  int bg = blockIdx.x & 31;
  int b0 = bg * BG;
  __shared__ unsigned Wh[3 * (D / 2) * D];          // packed f16 pairs, 6144 B
  __shared__ unsigned woh[(D / 2) * D];             // packed Wo, 2048 B
  __shared__ float bqs[D], bks[D], bvs[D], bos[D], gs[D], bbs[D];
  __shared__ __align__(16) unsigned Esh[SR * SEH];  // packed f16 Es, 3840 B
  __shared__ __align__(16) __fp16 Qh[SR * SK];      // 3840 B (O overwrites)
  __shared__ __align__(16) __fp16 Kh[SR * SK];      // 3840 B
  __shared__ __align__(16) __fp16 Vh[SR * SK];      // 3840 B
  int tid = threadIdx.x;

  for (int i = tid; i < 3 * (D / 2) * D; i += 256) {
    int fam = i / ((D / 2) * D);
    int idx = i % ((D / 2) * D);
    int d2 = idx >> 5, e = idx & 31;
    const float* wg = WsC + (size_t)(fam * T + t) * D * D;
    Wh[i] = pkh2(wg[(2 * d2) * D + e], wg[(2 * d2 + 1) * D + e]);
  }
  {
    const float* wg = sm_Wo + (size_t)t * D * D;
    for (int i = tid; i < (D / 2) * D; i += 256) {
      int d2 = i >> 5, e = i & 31;
      woh[i] = pkh2(wg[(2 * d2) * D + e], wg[(2 * d2 + 1) * D + e]);
    }
  }
  if (tid < D) {
    bqs[tid] = bsC[(0 * T + t) * D + tid];
    bks[tid] = bsC[(1 * T + t) * D + tid];
    bvs[tid] = bsC[(2 * T + t) * D + tid];
    bos[tid] = sm_bo[t * D + tid];
    gs[tid]  = ln_g[tid];
    bbs[tid] = ln_b[tid];
  }
  if (tid < SR * 4) {
    int r = tid >> 2, p = tid & 3;
    int b = b0 + r / N, n = r % N;
    uint4 u = *(const uint4*)&E[(((size_t)b * T + t) * N + n) * D + p * 8];
    uint4 o;
    o.x = pkh2(blo(u.x), bhi(u.x));
    o.y = pkh2(blo(u.y), bhi(u.y));
    o.z = pkh2(blo(u.z), bhi(u.z));
    o.w = pkh2(blo(u.w), bhi(u.w));
    *(uint4*)&Esh[r * SEH + p * 4] = o;
  }
  __syncthreads();

  // ---- QKV gemv (fdot2) -> packed-f16 Q/K/V ----
#pragma unroll 1
  for (int i = tid; i < SR * D; i += 256) {
    int r = i >> 5, e = i & 31;
    float aq = bqs[e], ak = bks[e], av = bvs[e];
#pragma unroll
    for (int d2 = 0; d2 < D / 2; ++d2) {
      h2 x = u2h(Esh[r * SEH + d2]);
      aq = __builtin_amdgcn_fdot2(x, u2h(Wh[0 * 512 + d2 * 32 + e]), aq, false);
      ak = __builtin_amdgcn_fdot2(x, u2h(Wh[1 * 512 + d2 * 32 + e]), ak, false);
      av = __builtin_amdgcn_fdot2(x, u2h(Wh[2 * 512 + d2 * 32 + e]), av, false);
    }
    Qh[r * SK + e] = (__fp16)aq;
    Kh[r * SK + e] = (__fp16)ak;
    Vh[r * SK + e] = (__fp16)av;
  }
  __syncthreads();

  // ---- attention (96 threads): fdot2 scores + pk_fma PV, O -> Q slot ----
  if (tid < SR * NH) {
    int r = tid >> 1, h = tid & 1, ho = h * FD;
    int kb = (r >= N) ? N : 0;
    uint4 q0 = *(const uint4*)&Qh[r * SK + ho];
    uint4 q1 = *(const uint4*)&Qh[r * SK + ho + 8];
    unsigned qh[8] = { q0.x, q0.y, q0.z, q0.w, q1.x, q1.y, q1.z, q1.w };
    float sc[N];
    float m = -1e30f;
#pragma unroll
    for (int k = 0; k < N; ++k) {
      const uint4 ka = *(const uint4*)&Kh[(kb + k) * SK + ho];
      const uint4 kc = *(const uint4*)&Kh[(kb + k) * SK + ho + 8];
      float s0 = __builtin_amdgcn_fdot2(u2h(qh[0]), u2h(ka.x), 0.f, false);
      float s1 = __builtin_amdgcn_fdot2(u2h(qh[1]), u2h(ka.y), 0.f, false);
      float s2 = __builtin_amdgcn_fdot2(u2h(qh[2]), u2h(ka.z), 0.f, false);
      float s3 = __builtin_amdgcn_fdot2(u2h(qh[3]), u2h(ka.w), 0.f, false);
      s0 = __builtin_amdgcn_fdot2(u2h(qh[4]), u2h(kc.x), s0, false);
      s1 = __builtin_amdgcn_fdot2(u2h(qh[5]), u2h(kc.y), s1, false);
      s2 = __builtin_amdgcn_fdot2(u2h(qh[6]), u2h(kc.z), s2, false);
      s3 = __builtin_amdgcn_fdot2(u2h(qh[7]), u2h(kc.w), s3, false);
      float s = ((s0 + s1) + (s2 + s3)) * SCALE;
      sc[k] = s;
      m = fmaxf(m, s);
    }
    float l = 0.f;
#pragma unroll
    for (int k = 0; k < N; ++k) { sc[k] = __expf(sc[k] - m); l += sc[k]; }
    float rl = 1.f / l;

    f16x2 acc2[8];
#pragma unroll
    for (int f = 0; f < 8; ++f) acc2[f] = f16x2{(_Float16)0.f, (_Float16)0.f};
#pragma unroll
    for (int k = 0; k < N; ++k) {
      f16x2 pp = f16x2{(_Float16)sc[k], (_Float16)sc[k]};
      const uint4 va = *(const uint4*)&Vh[(kb + k) * SK + ho];
      const uint4 vb = *(const uint4*)&Vh[(kb + k) * SK + ho + 8];
      acc2[0] += pp * u2f(va.x);
      acc2[1] += pp * u2f(va.y);
      acc2[2] += pp * u2f(va.z);
      acc2[3] += pp * u2f(va.w);
      acc2[4] += pp * u2f(vb.x);
      acc2[5] += pp * u2f(vb.y);
      acc2[6] += pp * u2f(vb.z);
      acc2[7] += pp * u2f(vb.w);
    }
    unsigned* op = (unsigned*)&Qh[r * SK + ho];
#pragma unroll
    for (int j = 0; j < 8; ++j)
      op[j] = pkh2((float)acc2[j][0] * rl, (float)acc2[j][1] * rl);
  }
  __syncthreads();

  // ---- O-proj (fdot2) + residual + LN: thread = (row, e-quad), 2 iters ----
#pragma unroll 1
  for (int it = 0; it < 2; ++it) {
    int rl = it * 32 + (tid >> 3);
    int q = tid & 7, e0 = q * 4;
    if (rl < SR) {
      const unsigned* opk = (const unsigned*)&Qh[rl * SK];
      unsigned r0u = Esh[rl * SEH + (e0 >> 1)];
      unsigned r1u = Esh[rl * SEH + (e0 >> 1) + 1];
      h2 ra = u2h(r0u), rb = u2h(r1u);
      float res[4] = { (float)ra[0], (float)ra[1], (float)rb[0], (float)rb[1] };
      float o[4], s1 = 0.f, s2 = 0.f;
#pragma unroll
      for (int j = 0; j < 4; ++j) {
        int e = e0 + j;
        float a = bos[e] + res[j];
#pragma unroll
        for (int d2 = 0; d2 < D / 2; ++d2)
          a = __builtin_amdgcn_fdot2(u2h(opk[d2]), u2h(woh[d2 * D + e]), a, false);
        o[j] = a; s1 += a; s2 += a * a;
      }
      s1 += __shfl_xor(s1, 1, 64); s2 += __shfl_xor(s2, 1, 64);
      s1 += __shfl_xor(s1, 2, 64); s2 += __shfl_xor(s2, 2, 64);
      s1 += __shfl_xor(s1, 4, 64); s2 += __shfl_xor(s2, 4, 64);
      float mu  = s1 * (1.f / D);
      float var = s2 * (1.f / D) - mu * mu;
      float rr = rsqrtf(var + 1e-5f);
      int b = b0 + rl / N, n = rl % N;
      uint2 ou;
      ou.x = pk2((o[0]-mu)*rr*gs[e0]+bbs[e0],    (o[1]-mu)*rr*gs[e0+1]+bbs[e0+1]);
      ou.y = pk2((o[2]-mu)*rr*gs[e0+2]+bbs[e0+2],(o[3]-mu)*rr*gs[e0+3]+bbs[e0+3]);
      *(uint2*)&Sn[(((size_t)b * T + t) * N + n) * D + e0] = ou;
    }
  }
}

// ---------------------------------------------------------------------------
// ff v3: packed-f16 fdot2 gemvs (measured R26: ~-24us/dispatch).
// ---------------------------------------------------------------------------
__global__ __launch_bounds__(256) void ff_kernel(
    const bf16* __restrict__ Tn, const bf16* __restrict__ Sn,
    const float* __restrict__ W1, const float* __restrict__ b1,
    const float* __restrict__ W2, const float* __restrict__ b2,
    const float* __restrict__ ln_g, const float* __restrict__ ln_b,
    bf16* __restrict__ E) {
  __shared__ unsigned w1h[(D / 2) * FF];   // 1024 uints, 4KB
  __shared__ unsigned w2h[(FF / 2) * D];   // 1024 uints, 4KB
  __shared__ float bb1[FF], bb2[D], gs[D], bbs[D];
  __shared__ unsigned tslp[FR][D / 2 + 1]; // 32 x 17 (stride 17: conflict-free)
  __shared__ unsigned hlp[FR][FF / 2 + 1]; // 32 x 33 (stride 33: conflict-free)
  int tid = threadIdx.x;
  int r0 = blockIdx.x * FR;
  for (int i = tid; i < (D / 2) * FF; i += 256) {
    int d2 = i / FF, jj = i % FF;
    w1h[i] = pkh2(W1[(2 * d2) * FF + jj], W1[(2 * d2 + 1) * FF + jj]);
  }
  for (int i = tid; i < (FF / 2) * D; i += 256) {
    int k2 = i / D, e = i % D;
    w2h[i] = pkh2(W2[(2 * k2) * D + e], W2[(2 * k2 + 1) * D + e]);
  }
  if (tid < FF) bb1[tid] = b1[tid];
  if (tid < D) { bb2[tid] = b2[tid]; gs[tid] = ln_g[tid]; bbs[tid] = ln_b[tid]; }
  int r = tid >> 3, s = tid & 7;
  {
    const bf16* tp = Tn + ((size_t)(r0 + r)) * D + s * 4;
    const bf16* sp = Sn + ((size_t)(r0 + r)) * D + s * 4;
    uint2 tu = *(const uint2*)tp;
    uint2 su = *(const uint2*)sp;
    float t0 = blo(tu.x) + blo(su.x);
    float t1 = bhi(tu.x) + bhi(su.x);
    float t2 = blo(tu.y) + blo(su.y);
    float t3 = bhi(tu.y) + bhi(su.y);
    tslp[r][s * 2]     = pkh2(t0, t1);
    tslp[r][s * 2 + 1] = pkh2(t2, t3);
  }
  __syncthreads();
  // pass1: 8 hidden units per lane via fdot2
  {
    float hh[8];
#pragma unroll
    for (int j = 0; j < 8; ++j) {
      int jj = s * 8 + j;
      float a = bb1[jj];
#pragma unroll
      for (int d2 = 0; d2 < D / 2; ++d2)
        a = __builtin_amdgcn_fdot2(u2h(tslp[r][d2]), u2h(w1h[d2 * FF + jj]), a, false);
      hh[j] = fmaxf(a, 0.f);
    }
#pragma unroll
    for (int j = 0; j < 4; ++j)
      hlp[r][s * 4 + j] = pkh2(hh[2 * j], hh[2 * j + 1]);
  }
  __syncthreads();
  // pass2: 4 outputs per lane via fdot2 + LN (3-level shfl reduce)
  {
    float x[4];
    float s1 = 0.f, s2 = 0.f;
#pragma unroll
    for (int j4 = 0; j4 < 4; ++j4) {
      int e = s * 4 + j4;
      h2 tv = u2h(tslp[r][e >> 1]);
      float a = bb2[e] + (float)tv[j4 & 1];   // s*4 even -> e&1 == j4&1
#pragma unroll
      for (int k2 = 0; k2 < FF / 2; ++k2)
        a = __builtin_amdgcn_fdot2(u2h(hlp[r][k2]), u2h(w2h[k2 * D + e]), a, false);
      x[j4] = a; s1 += a; s2 += a * a;
    }
    s1 += __shfl_xor(s1, 1, 64); s2 += __shfl_xor(s2, 1, 64);
    s1 += __shfl_xor(s1, 2, 64); s2 += __shfl_xor(s2, 2, 64);
    s1 += __shfl_xor(s1, 4, 64); s2 += __shfl_xor(s2, 4, 64);
    float mu  = s1 * (1.f / D);
    float var = s2 * (1.f / D) - mu * mu;
    float rr = rsqrtf(var + 1e-5f);
    int e0 = s * 4;
    uint2 ou;
    ou.x = pk2((x[0]-mu)*rr*gs[e0]+bbs[e0],    (x[1]-mu)*rr*gs[e0+1]+bbs[e0+1]);
    ou.y = pk2((x[2]-mu)*rr*gs[e0+2]+bbs[e0+2],(x[3]-mu)*rr*gs[e0+3]+bbs[e0+3]);
    *(uint2*)&E[((size_t)(r0 + r)) * D + e0] = ou;
  }
}

// ---------------------------------------------------------------------------
// out = E@op_W + op_b + X   (f32 out)
// ---------------------------------------------------------------------------
__global__ __launch_bounds__(256) void out_kernel(
    const bf16* __restrict__ E, const float* __restrict__ op_W,
    const float* __restrict__ op_b, const float* __restrict__ X,
    float* __restrict__ out) {
  int idx = blockIdx.x * 256 + threadIdx.x;
  if (idx >= B * T * N * M) return;
  int m  = idx % M;
  int n  = (idx / M) % N;
  int bt = idx / (M * N);
  float acc = op_b[n * M + m];
  const bf16* e = E + ((size_t)bt * N + n) * D;
#pragma unroll
  for (int d = 0; d < D; ++d) acc += b2f(e[d]) * op_W[(n * D + d) * M + m];
  acc += X[idx];
  out[idx] = acc;
}

// ---------------------------------------------------------------------------
extern "C" void kernel_launch(void* const* d_in, const int* in_sizes, int n_in,
                              void* d_out, int out_size, void* d_ws, size_t ws_size,
                              hipStream_t stream) {
  const float* X     = (const float*)d_in[0];
  const float* pe    = (const float*)d_in[1];
  const float* E_W   = (const float*)d_in[2];
  const float* E_b   = (const float*)d_in[3];
  const float* tq_W  = (const float*)d_in[4];
  const float* tq_b  = (const float*)d_in[5];
  const float* tk_W  = (const float*)d_in[6];
  const float* tk_b  = (const float*)d_in[7];
  const float* tv_W  = (const float*)d_in[8];
  const float* tv_b  = (const float*)d_in[9];
  const float* tm_Wq = (const float*)d_in[10];
  const float* tm_bq = (const float*)d_in[11];
  const float* tm_Wk = (const float*)d_in[12];
  const float* tm_bk = (const float*)d_in[13];
  const float* tm_Wv = (const float*)d_in[14];
  const float* tm_bv = (const float*)d_in[15];
  const float* tm_Wo = (const float*)d_in[16];
  const float* tm_bo = (const float*)d_in[17];
  const float* sq_W  = (const float*)d_in[18];
  const float* sq_b  = (const float*)d_in[19];
  const float* sk_W  = (const float*)d_in[20];
  const float* sk_b  = (const float*)d_in[21];
  const float* sv_W  = (const float*)d_in[22];
  const float* sv_b  = (const float*)d_in[23];
  const float* sm_Wq = (const float*)d_in[24];
  const float* sm_bq = (const float*)d_in[25];
  const float* sm_Wk = (const float*)d_in[26];
  const float* sm_bk = (const float*)d_in[27];
  const float* sm_Wv = (const float*)d_in[28];
  const float* sm_bv = (const float*)d_in[29];
  const float* sm_Wo = (const float*)d_in[30];
  const float* sm_bo = (const float*)d_in[31];
  const float* ff1_W = (const float*)d_in[32];
  const float* ff1_b = (const float*)d_in[33];
  const float* ff2_W = (const float*)d_in[34];
  const float* ff2_b = (const float*)d_in[35];
  const float* ln_g  = (const float*)d_in[36];
  const float* ln_b  = (const float*)d_in[37];
  const float* op_W  = (const float*)d_in[38];
  const float* op_b  = (const float*)d_in[39];
  float* out = (float*)d_out;

  float* WtC = (float*)d_ws;                         // 3*N*D*D
  float* btC = WtC + 3 * N * D * D;                  // 3*N*D
  float* WsC = btC + 3 * N * D;                      // 3*T*D*D
  float* bsC = WsC + 3 * T * D * D;                  // 3*T*D
  size_t act = (size_t)B * T * N * D;
  bf16* Ebuf = (bf16*)(bsC + 3 * T * D);
  bf16* Tn   = Ebuf + act;
  bf16* Qt   = Tn + act;
  bf16* Kt   = Qt + act;
  bf16* Vt   = Kt + act;
  bf16* Sn   = Qt;                                   // alias (safe: serial schedule)

  compose3_kernel<<<3 * N, 256, 0, stream>>>(
      tq_W, tq_b, tm_Wq, tm_bq, tk_W, tk_b, tm_Wk, tm_bk,
      tv_W, tv_b, tm_Wv, tm_bv, WtC, btC, N);
  compose3_kernel<<<3 * T, 256, 0, stream>>>(
      sq_W, sq_b, sm_Wq, sm_bq, sk_W, sk_b, sm_Wk, sm_bk,
      sv_W, sv_b, sm_Wv, sm_bv, WsC, bsC, T);

  embed_kernel<<<(B * T * N * D) / 256, 256, 0, stream>>>(X, pe, E_W, E_b, Ebuf);

  for (int l = 0; l < L; ++l) {
    qkvt_kernel<<<N * QCH, 256, 0, stream>>>(Ebuf, WtC, btC, Qt, Kt, Vt);
    attnt_kernel<<<B * N, 256, 0, stream>>>(Qt, Kt, Vt, Ebuf, tm_Wo, tm_bo, ln_g, ln_b, Tn);
    spatial_kernel<<<T * (B / BG), 256, 0, stream>>>(Ebuf, WsC, bsC, sm_Wo, sm_bo, ln_g, ln_b, Sn);
    ff_kernel<<<(B * T * N) / FR, 256, 0, stream>>>(Tn, Sn, ff1_W, ff1_b, ff2_W, ff2_b, ln_g, ln_b, Ebuf);
  }

  out_kernel<<<(B * T * N * M + 255) / 256, 256, 0, stream>>>(Ebuf, op_W, op_b, X, out);
}

// Round 32
// 422.776 us; speedup vs baseline: 2.1673x; 1.0359x over previous
//
#include <hip/hip_runtime.h>
#include <hip/hip_bf16.h>

typedef __hip_bfloat16 bf16;
typedef __fp16 h2 __attribute__((ext_vector_type(2)));      // matches amdgcn builtin 'V2h'
typedef _Float16 f16x2 __attribute__((ext_vector_type(2))); // arithmetic (v_pk_*_f16)

constexpr int B  = 64, T = 120, N = 24, M = 3, D = 32;
constexpr int NH = 2, FD = 16, FF = 64, L = 3;
constexpr float SCALE = 0.25f;   // 1/sqrt(FD)
constexpr int SK  = 40;          // f16 LDS stride (80B rows) — attnt & spatial
constexpr int SOH = 20;          // attnt packed-f16 O stride (uints, 80B)
constexpr int CH2 = 30;          // attnt rows per chunk: 4 x 30 = 120 exactly
constexpr int NJ  = 30;          // max keys per lane slice (120/4)
constexpr int QR  = 64;          // qkvt rows per block (4 lanes/row)
constexpr int QCH = (B * T) / QR;// qkvt chunks = 120
constexpr int QEH = 20;          // qkvt packed-f16 Es stride (uints, 80B)
constexpr int BG  = 2;           // spatial batches per block
constexpr int SR  = N * BG;      // spatial rows per block = 48
constexpr int SEH = 20;          // spatial packed-f16 Es stride (uints, 80B)
constexpr int FR  = 32;          // ff rows per block (8 lanes/row)
constexpr int QG  = N * QCH;     // qkvt role blocks = 2880
constexpr int SG  = T * (B / BG);// spatial role blocks = 3840

__device__ __forceinline__ float b2f(bf16 x) { return __bfloat162float(x); }
__device__ __forceinline__ float blo(unsigned u) { return __uint_as_float(u << 16); }
__device__ __forceinline__ float bhi(unsigned u) { return __uint_as_float(u & 0xffff0000u); }
__device__ __forceinline__ unsigned pk2(float a, float b) {
  bf16 x = __float2bfloat16(a), y = __float2bfloat16(b);
  unsigned short ux = *reinterpret_cast<unsigned short*>(&x);
  unsigned short uy = *reinterpret_cast<unsigned short*>(&y);
  return (unsigned)ux | ((unsigned)uy << 16);
}
__device__ __forceinline__ unsigned pkh2(float a, float b) {
  h2 r = __builtin_amdgcn_cvt_pkrtz(a, b);     // v_cvt_pkrtz_f16_f32
  return *reinterpret_cast<unsigned*>(&r);
}
__device__ __forceinline__ h2 u2h(unsigned u) { return *reinterpret_cast<h2*>(&u); }
__device__ __forceinline__ f16x2 u2f(unsigned u) { return *reinterpret_cast<f16x2*>(&u); }

// ---------------------------------------------------------------------------
// Compose q/k/v chained linears: grid = 3*U blocks.  Wc = W1@W2, bc = b1@W2+b2.
// ---------------------------------------------------------------------------
__global__ __launch_bounds__(256) void compose3_kernel(
    const float* __restrict__ W1q, const float* __restrict__ b1q,
    const float* __restrict__ W2q, const float* __restrict__ b2q,
    const float* __restrict__ W1k, const float* __restrict__ b1k,
    const float* __restrict__ W2k, const float* __restrict__ b2k,
    const float* __restrict__ W1v, const float* __restrict__ b1v,
    const float* __restrict__ W2v, const float* __restrict__ b2v,
    float* __restrict__ Wc, float* __restrict__ bc, int U) {
  int fam = blockIdx.x / U;
  int n   = blockIdx.x % U;
  const float* W1 = (fam == 0) ? W1q : (fam == 1) ? W1k : W1v;
  const float* b1 = (fam == 0) ? b1q : (fam == 1) ? b1k : b1v;
  const float* W2 = (fam == 0) ? W2q : (fam == 1) ? W2k : W2v;
  const float* b2 = (fam == 0) ? b2q : (fam == 1) ? b2k : b2v;
  const float* w1 = W1 + n * D * D;
  const float* w2 = W2 + n * D * D;
  float* wc  = Wc + (size_t)(fam * U + n) * D * D;
  float* bcp = bc + (fam * U + n) * D;
  __shared__ float s1[D * D], s2[D * D];
  for (int i = threadIdx.x; i < D * D; i += 256) { s1[i] = w1[i]; s2[i] = w2[i]; }
  __syncthreads();
  for (int i = threadIdx.x; i < D * D; i += 256) {
    int d = i >> 5, f = i & 31;
    float acc = 0.f;
#pragma unroll
    for (int e = 0; e < D; ++e) acc += s1[d * D + e] * s2[e * D + f];
    wc[i] = acc;
  }
  if (threadIdx.x < D) {
    int f = threadIdx.x;
    float acc = b2[n * D + f];
#pragma unroll
    for (int e = 0; e < D; ++e) acc += b1[n * D + e] * s2[e * D + f];
    bcp[f] = acc;
  }
}

// ---------------------------------------------------------------------------
// E[b,t,n,d] = X@E_W + E_b + pe   (bf16 out)
// ---------------------------------------------------------------------------
__global__ __launch_bounds__(256) void embed_kernel(
    const float* __restrict__ X, const float* __restrict__ pe,
    const float* __restrict__ E_W, const float* __restrict__ E_b,
    bf16* __restrict__ E) {
  int idx = blockIdx.x * 256 + threadIdx.x;
  if (idx >= B * T * N * D) return;
  int d = idx & 31;
  int n = (idx >> 5) % N;
  int bt = idx / (D * N);
  int t = bt % T;
  const float* x = X + bt * (N * M) + n * M;
  float acc = E_b[n * D + d] + pe[t * D + d];
#pragma unroll
  for (int m = 0; m < M; ++m) acc += x[m] * E_W[(n * M + m) * D + d];
  E[idx] = __float2bfloat16(acc);
}

// ---------------------------------------------------------------------------
// qs_fused: role-split blocks — [0, qblocks) run qkvt v3, rest run spatial v5.
// Shared-LDS union (24.3 KB = spatial's footprint) keeps 6 blocks/CU for both.
// Launched with grid QG+SG (concurrent, needs distinct Sn) or as two partial
// grids (serial fallback, Sn may alias Qt).
// ---------------------------------------------------------------------------
struct QSmem {
  unsigned whh[3 * (D / 2) * D];   // 6144 B
  float bsh[3 * D];                // 384 B
  unsigned Esp[QR * QEH];          // 5120 B (offset 6528, 16B-aligned)
};
struct SSmem {
  unsigned Wh[3 * (D / 2) * D];    // 6144 B
  unsigned woh[(D / 2) * D];       // 2048 B
  float bqs[D], bks[D], bvs[D], bos[D], gs[D], bbs[D];  // 768 B
  unsigned Esh[SR * SEH];          // 3840 B (offset 8960, 16B-aligned)
  __fp16 Qh[SR * SK];              // 3840 B (offset 12800)
  __fp16 Kh[SR * SK];              // 3840 B
  __fp16 Vh[SR * SK];              // 3840 B  -> total 24320 B
};
constexpr size_t FUSED_SMEM =
    sizeof(SSmem) > sizeof(QSmem) ? sizeof(SSmem) : sizeof(QSmem);

__global__ __launch_bounds__(256) void qs_fused_kernel(
    const bf16* __restrict__ E, const float* __restrict__ WtC,
    const float* __restrict__ btC,
    bf16* __restrict__ Qt, bf16* __restrict__ Kt, bf16* __restrict__ Vt,
    const float* __restrict__ WsC, const float* __restrict__ bsC,
    const float* __restrict__ sm_Wo, const float* __restrict__ sm_bo,
    const float* __restrict__ ln_g, const float* __restrict__ ln_b,
    bf16* __restrict__ Sn, int qblocks) {
  __shared__ __align__(16) char smem[FUSED_SMEM];
  int tid = threadIdx.x;

  if ((int)blockIdx.x < qblocks) {
    // ================= qkvt role =================
    QSmem& q = *reinterpret_cast<QSmem*>(smem);
    int n     = blockIdx.x / QCH;
    int chunk = blockIdx.x % QCH;
    for (int i = tid; i < 3 * (D / 2) * D; i += 256) {
      int fam = i / ((D / 2) * D);
      int idx = i % ((D / 2) * D);
      int d2 = idx >> 5, j = idx & 31;
      const float* wg = WtC + (size_t)(fam * N + n) * D * D;
      q.whh[i] = pkh2(wg[(2 * d2) * D + j], wg[(2 * d2 + 1) * D + j]);
    }
    if (tid < 3 * D) {
      int fam = tid >> 5, e = tid & 31;
      q.bsh[tid] = btC[(fam * N + n) * D + e];
    }
    {
      int row = tid >> 2, p = tid & 3;
      const bf16* er = E + ((size_t)(chunk * QR + row) * N + n) * D;
      uint4 u = *(const uint4*)&er[p * 8];
      uint4 o;
      o.x = pkh2(blo(u.x), bhi(u.x));
      o.y = pkh2(blo(u.y), bhi(u.y));
      o.z = pkh2(blo(u.z), bhi(u.z));
      o.w = pkh2(blo(u.w), bhi(u.w));
      *(uint4*)&q.Esp[row * QEH + p * 4] = o;
    }
    __syncthreads();

    int row = tid >> 2, qd = tid & 3;
    int grow = chunk * QR + row;          // b*T + t
    int b = grow / T, t = grow % T;
    unsigned xp[D / 2];
#pragma unroll
    for (int d2 = 0; d2 < D / 2; ++d2) xp[d2] = q.Esp[row * QEH + d2];
    size_t dsto = (((size_t)b * N + n) * T + t) * D + qd * 8;
    bf16* dsts[3] = { Qt + dsto, Kt + dsto, Vt + dsto };
#pragma unroll
    for (int fam = 0; fam < 3; ++fam) {
      const unsigned* wf = q.whh + fam * (D / 2) * D;
      const float* bi = q.bsh + fam * D;
      float a[8];
#pragma unroll
      for (int j = 0; j < 8; ++j) a[j] = bi[qd * 8 + j];
#pragma unroll
      for (int d2 = 0; d2 < D / 2; ++d2) {
        h2 x = u2h(xp[d2]);
#pragma unroll
        for (int j = 0; j < 8; ++j)
          a[j] = __builtin_amdgcn_fdot2(x, u2h(wf[d2 * D + qd * 8 + j]), a[j], false);
      }
      uint4 o;
      o.x = pk2(a[0], a[1]); o.y = pk2(a[2], a[3]);
      o.z = pk2(a[4], a[5]); o.w = pk2(a[6], a[7]);
      *(uint4*)dsts[fam] = o;
    }
  } else {
    // ================= spatial role =================
    SSmem& s = *reinterpret_cast<SSmem*>(smem);
    int sb = blockIdx.x - qblocks;
    int t  = sb >> 5;          // B/BG = 32 groups per t
    int bg = sb & 31;
    int b0 = bg * BG;

    for (int i = tid; i < 3 * (D / 2) * D; i += 256) {
      int fam = i / ((D / 2) * D);
      int idx = i % ((D / 2) * D);
      int d2 = idx >> 5, e = idx & 31;
      const float* wg = WsC + (size_t)(fam * T + t) * D * D;
      s.Wh[i] = pkh2(wg[(2 * d2) * D + e], wg[(2 * d2 + 1) * D + e]);
    }
    {
      const float* wg = sm_Wo + (size_t)t * D * D;
      for (int i = tid; i < (D / 2) * D; i += 256) {
        int d2 = i >> 5, e = i & 31;
        s.woh[i] = pkh2(wg[(2 * d2) * D + e], wg[(2 * d2 + 1) * D + e]);
      }
    }
    if (tid < D) {
      s.bqs[tid] = bsC[(0 * T + t) * D + tid];
      s.bks[tid] = bsC[(1 * T + t) * D + tid];
      s.bvs[tid] = bsC[(2 * T + t) * D + tid];
      s.bos[tid] = sm_bo[t * D + tid];
      s.gs[tid]  = ln_g[tid];
      s.bbs[tid] = ln_b[tid];
    }
    if (tid < SR * 4) {
      int r = tid >> 2, p = tid & 3;
      int b = b0 + r / N, n = r % N;
      uint4 u = *(const uint4*)&E[(((size_t)b * T + t) * N + n) * D + p * 8];
      uint4 o;
      o.x = pkh2(blo(u.x), bhi(u.x));
      o.y = pkh2(blo(u.y), bhi(u.y));
      o.z = pkh2(blo(u.z), bhi(u.z));
      o.w = pkh2(blo(u.w), bhi(u.w));
      *(uint4*)&s.Esh[r * SEH + p * 4] = o;
    }
    __syncthreads();

    // ---- QKV gemv (fdot2) -> packed-f16 Q/K/V ----
#pragma unroll 1
    for (int i = tid; i < SR * D; i += 256) {
      int r = i >> 5, e = i & 31;
      float aq = s.bqs[e], ak = s.bks[e], av = s.bvs[e];
#pragma unroll
      for (int d2 = 0; d2 < D / 2; ++d2) {
        h2 x = u2h(s.Esh[r * SEH + d2]);
        aq = __builtin_amdgcn_fdot2(x, u2h(s.Wh[0 * 512 + d2 * 32 + e]), aq, false);
        ak = __builtin_amdgcn_fdot2(x, u2h(s.Wh[1 * 512 + d2 * 32 + e]), ak, false);
        av = __builtin_amdgcn_fdot2(x, u2h(s.Wh[2 * 512 + d2 * 32 + e]), av, false);
      }
      s.Qh[r * SK + e] = (__fp16)aq;
      s.Kh[r * SK + e] = (__fp16)ak;
      s.Vh[r * SK + e] = (__fp16)av;
    }
    __syncthreads();

    // ---- attention (96 threads): fdot2 scores + pk_fma PV, O -> Q slot ----
    if (tid < SR * NH) {
      int r = tid >> 1, h = tid & 1, ho = h * FD;
      int kb = (r >= N) ? N : 0;
      uint4 q0 = *(const uint4*)&s.Qh[r * SK + ho];
      uint4 q1 = *(const uint4*)&s.Qh[r * SK + ho + 8];
      unsigned qh[8] = { q0.x, q0.y, q0.z, q0.w, q1.x, q1.y, q1.z, q1.w };
      float sc[N];
      float m = -1e30f;
#pragma unroll
      for (int k = 0; k < N; ++k) {
        const uint4 ka = *(const uint4*)&s.Kh[(kb + k) * SK + ho];
        const uint4 kc = *(const uint4*)&s.Kh[(kb + k) * SK + ho + 8];
        float s0 = __builtin_amdgcn_fdot2(u2h(qh[0]), u2h(ka.x), 0.f, false);
        float s1 = __builtin_amdgcn_fdot2(u2h(qh[1]), u2h(ka.y), 0.f, false);
        float s2 = __builtin_amdgcn_fdot2(u2h(qh[2]), u2h(ka.z), 0.f, false);
        float s3 = __builtin_amdgcn_fdot2(u2h(qh[3]), u2h(ka.w), 0.f, false);
        s0 = __builtin_amdgcn_fdot2(u2h(qh[4]), u2h(kc.x), s0, false);
        s1 = __builtin_amdgcn_fdot2(u2h(qh[5]), u2h(kc.y), s1, false);
        s2 = __builtin_amdgcn_fdot2(u2h(qh[6]), u2h(kc.z), s2, false);
        s3 = __builtin_amdgcn_fdot2(u2h(qh[7]), u2h(kc.w), s3, false);
        float sv = ((s0 + s1) + (s2 + s3)) * SCALE;
        sc[k] = sv;
        m = fmaxf(m, sv);
      }
      float l = 0.f;
#pragma unroll
      for (int k = 0; k < N; ++k) { sc[k] = __expf(sc[k] - m); l += sc[k]; }
      float rl = 1.f / l;

      f16x2 acc2[8];
#pragma unroll
      for (int f = 0; f < 8; ++f) acc2[f] = f16x2{(_Float16)0.f, (_Float16)0.f};
#pragma unroll
      for (int k = 0; k < N; ++k) {
        f16x2 pp = f16x2{(_Float16)sc[k], (_Float16)sc[k]};
        const uint4 va = *(const uint4*)&s.Vh[(kb + k) * SK + ho];
        const uint4 vb = *(const uint4*)&s.Vh[(kb + k) * SK + ho + 8];
        acc2[0] += pp * u2f(va.x);
        acc2[1] += pp * u2f(va.y);
        acc2[2] += pp * u2f(va.z);
        acc2[3] += pp * u2f(va.w);
        acc2[4] += pp * u2f(vb.x);
        acc2[5] += pp * u2f(vb.y);
        acc2[6] += pp * u2f(vb.z);
        acc2[7] += pp * u2f(vb.w);
      }
      unsigned* op = (unsigned*)&s.Qh[r * SK + ho];
#pragma unroll
      for (int j = 0; j < 8; ++j)
        op[j] = pkh2((float)acc2[j][0] * rl, (float)acc2[j][1] * rl);
    }
    __syncthreads();

    // ---- O-proj (fdot2) + residual + LN: thread = (row, e-quad), 2 iters ----
#pragma unroll 1
    for (int it = 0; it < 2; ++it) {
      int rl = it * 32 + (tid >> 3);
      int qd = tid & 7, e0 = qd * 4;
      if (rl < SR) {
        const unsigned* opk = (const unsigned*)&s.Qh[rl * SK];
        unsigned r0u = s.Esh[rl * SEH + (e0 >> 1)];
        unsigned r1u = s.Esh[rl * SEH + (e0 >> 1) + 1];
        h2 ra = u2h(r0u), rb = u2h(r1u);
        float res[4] = { (float)ra[0], (float)ra[1], (float)rb[0], (float)rb[1] };
        float o[4], s1 = 0.f, s2 = 0.f;
#pragma unroll
        for (int j = 0; j < 4; ++j) {
          int e = e0 + j;
          float a = s.bos[e] + res[j];
#pragma unroll
          for (int d2 = 0; d2 < D / 2; ++d2)
            a = __builtin_amdgcn_fdot2(u2h(opk[d2]), u2h(s.woh[d2 * D + e]), a, false);
          o[j] = a; s1 += a; s2 += a * a;
        }
        s1 += __shfl_xor(s1, 1, 64); s2 += __shfl_xor(s2, 1, 64);
        s1 += __shfl_xor(s1, 2, 64); s2 += __shfl_xor(s2, 2, 64);
        s1 += __shfl_xor(s1, 4, 64); s2 += __shfl_xor(s2, 4, 64);
        float mu  = s1 * (1.f / D);
        float var = s2 * (1.f / D) - mu * mu;
        float rr = rsqrtf(var + 1e-5f);
        int b = b0 + rl / N, n = rl % N;
        uint2 ou;
        ou.x = pk2((o[0]-mu)*rr*s.gs[e0]+s.bbs[e0],    (o[1]-mu)*rr*s.gs[e0+1]+s.bbs[e0+1]);
        ou.y = pk2((o[2]-mu)*rr*s.gs[e0+2]+s.bbs[e0+2],(o[3]-mu)*rr*s.gs[e0+3]+s.bbs[e0+3]);
        *(uint2*)&Sn[(((size_t)b * T + t) * N + n) * D + e0] = ou;
      }
    }
  }
}

// ---------------------------------------------------------------------------
// attnt v13: causal-bounded chunk unroll (measured R31: ~70us, VGPR 44).
// ---------------------------------------------------------------------------
__global__ __launch_bounds__(256) void attnt_kernel(
    const bf16* __restrict__ Qt, const bf16* __restrict__ Kt,
    const bf16* __restrict__ Vt, const bf16* __restrict__ E,
    const float* __restrict__ tm_Wo, const float* __restrict__ tm_bo,
    const float* __restrict__ ln_g, const float* __restrict__ ln_b,
    bf16* __restrict__ Tn) {
  int bn = blockIdx.x;
  int n  = bn % N, b = bn / N;
  __shared__ __align__(16) __fp16 Klh[T * SK];        // 9600 B
  __shared__ __align__(16) __fp16 Vlh[T * SK];        // 9600 B
  __shared__ __align__(16) __fp16 Qlh[CH2 * SK];      // 2400 B
  __shared__ __align__(16) unsigned Olh[CH2 * SOH];   // packed f16 O, 2400 B
  __shared__ unsigned woh[(D / 2) * D];               // packed Wol, 2048 B
  __shared__ float bol[D], gl[D], bbl[D];
  int tid = threadIdx.x;

  const bf16* Kg = Kt + (size_t)bn * T * D;
  const bf16* Vg = Vt + (size_t)bn * T * D;
  const bf16* Qg = Qt + (size_t)bn * T * D;
  for (int i = tid; i < T * 4; i += 256) {
    int r = i >> 2, p = i & 3;
    uint4 ku = *(const uint4*)&Kg[r * D + p * 8];
    uint4 kh;
    kh.x = pkh2(blo(ku.x), bhi(ku.x));
    kh.y = pkh2(blo(ku.y), bhi(ku.y));
    kh.z = pkh2(blo(ku.z), bhi(ku.z));
    kh.w = pkh2(blo(ku.w), bhi(ku.w));
    *(uint4*)&Klh[r * SK + p * 8] = kh;
    uint4 vu = *(const uint4*)&Vg[r * D + p * 8];
    uint4 vh;
    vh.x = pkh2(blo(vu.x), bhi(vu.x));
    vh.y = pkh2(blo(vu.y), bhi(vu.y));
    vh.z = pkh2(blo(vu.z), bhi(vu.z));
    vh.w = pkh2(blo(vu.w), bhi(vu.w));
    *(uint4*)&Vlh[r * SK + p * 8] = vh;
  }
  {
    const float* wg = tm_Wo + (size_t)n * D * D;
    for (int i = tid; i < (D / 2) * D; i += 256) {
      int d2 = i >> 5, e = i & 31;
      woh[i] = pkh2(wg[(2 * d2) * D + e], wg[(2 * d2 + 1) * D + e]);
    }
  }
  if (tid < D) {
    bol[tid] = tm_bo[n * D + tid];
    gl[tid]  = ln_g[tid];
    bbl[tid] = ln_b[tid];
  }
  __syncthreads();

#pragma unroll
  for (int c = 0; c < 4; ++c) {
    const int JM = (CH2 * (c + 1) + 3) >> 2;   // 8,15,23,30 (compile-time)
    if (tid < CH2 * 4) {
      int r = tid >> 2, p = tid & 3;
      uint4 qu = *(const uint4*)&Qg[(CH2 * c + r) * D + p * 8];
      uint4 qh;
      qh.x = pkh2(blo(qu.x), bhi(qu.x));
      qh.y = pkh2(blo(qu.y), bhi(qu.y));
      qh.z = pkh2(blo(qu.z), bhi(qu.z));
      qh.w = pkh2(blo(qu.w), bhi(qu.w));
      *(uint4*)&Qlh[r * SK + p * 8] = qh;
    }
    __syncthreads();   // Qlh ready; prior O-proj done -> Olh safe to overwrite

    {
      int task = tid >> 2, sl = tid & 3;
      if (task < 2 * CH2) {
        int rl = task >> 1, h = task & 1, ho = h * FD;
        int rg = CH2 * c + rl;
        uint4 q0 = *(const uint4*)&Qlh[rl * SK + ho];
        uint4 q1 = *(const uint4*)&Qlh[rl * SK + ho + 8];
        unsigned qh[8] = { q0.x, q0.y, q0.z, q0.w, q1.x, q1.y, q1.z, q1.w };

        float sc[NJ];
        float mx = -3e38f;
#pragma unroll
        for (int j = 0; j < JM; ++j) {
          int k = 4 * j + sl;
          sc[j] = -3e38f;
          if (k <= rg) {
            const uint4 ka = *(const uint4*)&Klh[k * SK + ho];
            const uint4 kb = *(const uint4*)&Klh[k * SK + ho + 8];
            float s0 = __builtin_amdgcn_fdot2(u2h(qh[0]), u2h(ka.x), 0.f, false);
            float s1 = __builtin_amdgcn_fdot2(u2h(qh[1]), u2h(ka.y), 0.f, false);
            float s2 = __builtin_amdgcn_fdot2(u2h(qh[2]), u2h(ka.z), 0.f, false);
            float s3 = __builtin_amdgcn_fdot2(u2h(qh[3]), u2h(ka.w), 0.f, false);
            s0 = __builtin_amdgcn_fdot2(u2h(qh[4]), u2h(kb.x), s0, false);
            s1 = __builtin_amdgcn_fdot2(u2h(qh[5]), u2h(kb.y), s1, false);
            s2 = __builtin_amdgcn_fdot2(u2h(qh[6]), u2h(kb.z), s2, false);
            s3 = __builtin_amdgcn_fdot2(u2h(qh[7]), u2h(kb.w), s3, false);
            float s = ((s0 + s1) + (s2 + s3)) * SCALE;
            sc[j] = s;
            mx = fmaxf(mx, s);
          }
        }
        mx = fmaxf(mx, __shfl_xor(mx, 1, 64));
        mx = fmaxf(mx, __shfl_xor(mx, 2, 64));
        float l = 0.f;
#pragma unroll
        for (int j = 0; j < JM; ++j) {
          sc[j] = __expf(sc[j] - mx);   // invalid slots: exp(-inf) = 0
          l += sc[j];
        }
        l += __shfl_xor(l, 1, 64);
        l += __shfl_xor(l, 2, 64);
        float rli = 1.f / l;

        f16x2 acc2[8];
#pragma unroll
        for (int f = 0; f < 8; ++f) acc2[f] = f16x2{(_Float16)0.f, (_Float16)0.f};
#pragma unroll
        for (int j = 0; j < JM; ++j) {
          int k = 4 * j + sl;
          if (k <= rg) {
            f16x2 pp = f16x2{(_Float16)sc[j], (_Float16)sc[j]};
            const uint4 va = *(const uint4*)&Vlh[k * SK + ho];
            const uint4 vb = *(const uint4*)&Vlh[k * SK + ho + 8];
            acc2[0] += pp * u2f(va.x);
            acc2[1] += pp * u2f(va.y);
            acc2[2] += pp * u2f(va.z);
            acc2[3] += pp * u2f(va.w);
            acc2[4] += pp * u2f(vb.x);
            acc2[5] += pp * u2f(vb.y);
            acc2[6] += pp * u2f(vb.z);
            acc2[7] += pp * u2f(vb.w);
          }
        }
#pragma unroll
        for (int f = 0; f < 8; ++f) {
          unsigned u = *reinterpret_cast<unsigned*>(&acc2[f]);
          unsigned u1 = __shfl_xor(u, 1, 64);
          acc2[f] += u2f(u1);
          u = *reinterpret_cast<unsigned*>(&acc2[f]);
          unsigned u2_ = __shfl_xor(u, 2, 64);
          acc2[f] += u2f(u2_);
        }
        if (sl == 0) {
#pragma unroll
          for (int j = 0; j < 8; ++j)
            Olh[rl * SOH + h * 8 + j] =
                pkh2((float)acc2[j][0] * rli, (float)acc2[j][1] * rli);
        }
      }
    }
    __syncthreads();

    // ---- O-proj (fdot2) + residual + LN: thread = (row, e-quad) ----
    {
      int rl = tid >> 3, q = tid & 7, e0 = q * 4;
      if (rl < CH2) {
        int rg = CH2 * c + rl;
        size_t rowo = ((size_t)(b * T + rg) * N + n) * D;
        uint2 eu = *(const uint2*)&E[rowo + e0];
        float res[4] = { blo(eu.x), bhi(eu.x), blo(eu.y), bhi(eu.y) };
        float o[4], s1 = 0.f, s2 = 0.f;
#pragma unroll
        for (int j = 0; j < 4; ++j) {
          int e = e0 + j;
          float a = bol[e] + res[j];
#pragma unroll
          for (int d2 = 0; d2 < D / 2; ++d2)
            a = __builtin_amdgcn_fdot2(u2h(Olh[rl * SOH + d2]),
                                       u2h(woh[d2 * D + e]), a, false);
          o[j] = a; s1 += a; s2 += a * a;
        }
        s1 += __shfl_xor(s1, 1, 64); s2 += __shfl_xor(s2, 1, 64);
        s1 += __shfl_xor(s1, 2, 64); s2 += __shfl_xor(s2, 2, 64);
        s1 += __shfl_xor(s1, 4, 64); s2 += __shfl_xor(s2, 4, 64);
        float mu  = s1 * (1.f / D);
        float var = s2 * (1.f / D) - mu * mu;
        float r = rsqrtf(var + 1e-5f);
        uint2 ou;
        ou.x = pk2((o[0]-mu)*r*gl[e0]+bbl[e0],    (o[1]-mu)*r*gl[e0+1]+bbl[e0+1]);
        ou.y = pk2((o[2]-mu)*r*gl[e0+2]+bbl[e0+2],(o[3]-mu)*r*gl[e0+3]+bbl[e0+3]);
        *(uint2*)&Tn[rowo + e0] = ou;
      }
    }
  }
}

// ---------------------------------------------------------------------------
// ff v3: packed-f16 fdot2 gemvs (measured R26: ~-24us/dispatch).
// ---------------------------------------------------------------------------
__global__ __launch_bounds__(256) void ff_kernel(
    const bf16* __restrict__ Tn, const bf16* __restrict__ Sn,
    const float* __restrict__ W1, const float* __restrict__ b1,
    const float* __restrict__ W2, const float* __restrict__ b2,
    const float* __restrict__ ln_g, const float* __restrict__ ln_b,
    bf16* __restrict__ E) {
  __shared__ unsigned w1h[(D / 2) * FF];   // 1024 uints, 4KB
  __shared__ unsigned w2h[(FF / 2) * D];   // 1024 uints, 4KB
  __shared__ float bb1[FF], bb2[D], gs[D], bbs[D];
  __shared__ unsigned tslp[FR][D / 2 + 1]; // 32 x 17 (stride 17: conflict-free)
  __shared__ unsigned hlp[FR][FF / 2 + 1]; // 32 x 33 (stride 33: conflict-free)
  int tid = threadIdx.x;
  int r0 = blockIdx.x * FR;
  for (int i = tid; i < (D / 2) * FF; i += 256) {
    int d2 = i / FF, jj = i % FF;
    w1h[i] = pkh2(W1[(2 * d2) * FF + jj], W1[(2 * d2 + 1) * FF + jj]);
  }
  for (int i = tid; i < (FF / 2) * D; i += 256) {
    int k2 = i / D, e = i % D;
    w2h[i] = pkh2(W2[(2 * k2) * D + e], W2[(2 * k2 + 1) * D + e]);
  }
  if (tid < FF) bb1[tid] = b1[tid];
  if (tid < D) { bb2[tid] = b2[tid]; gs[tid] = ln_g[tid]; bbs[tid] = ln_b[tid]; }
  int r = tid >> 3, s = tid & 7;
  {
    const bf16* tp = Tn + ((size_t)(r0 + r)) * D + s * 4;
    const bf16* sp = Sn + ((size_t)(r0 + r)) * D + s * 4;
    uint2 tu = *(const uint2*)tp;
    uint2 su = *(const uint2*)sp;
    float t0 = blo(tu.x) + blo(su.x);
    float t1 = bhi(tu.x) + bhi(su.x);
    float t2 = blo(tu.y) + blo(su.y);
    float t3 = bhi(tu.y) + bhi(su.y);
    tslp[r][s * 2]     = pkh2(t0, t1);
    tslp[r][s * 2 + 1] = pkh2(t2, t3);
  }
  __syncthreads();
  // pass1: 8 hidden units per lane via fdot2
  {
    float hh[8];
#pragma unroll
    for (int j = 0; j < 8; ++j) {
      int jj = s * 8 + j;
      float a = bb1[jj];
#pragma unroll
      for (int d2 = 0; d2 < D / 2; ++d2)
        a = __builtin_amdgcn_fdot2(u2h(tslp[r][d2]), u2h(w1h[d2 * FF + jj]), a, false);
      hh[j] = fmaxf(a, 0.f);
    }
#pragma unroll
    for (int j = 0; j < 4; ++j)
      hlp[r][s * 4 + j] = pkh2(hh[2 * j], hh[2 * j + 1]);
  }
  __syncthreads();
  // pass2: 4 outputs per lane via fdot2 + LN (3-level shfl reduce)
  {
    float x[4];
    float s1 = 0.f, s2 = 0.f;
#pragma unroll
    for (int j4 = 0; j4 < 4; ++j4) {
      int e = s * 4 + j4;
      h2 tv = u2h(tslp[r][e >> 1]);
      float a = bb2[e] + (float)tv[j4 & 1];   // s*4 even -> e&1 == j4&1
#pragma unroll
      for (int k2 = 0; k2 < FF / 2; ++k2)
        a = __builtin_amdgcn_fdot2(u2h(hlp[r][k2]), u2h(w2h[k2 * D + e]), a, false);
      x[j4] = a; s1 += a; s2 += a * a;
    }
    s1 += __shfl_xor(s1, 1, 64); s2 += __shfl_xor(s2, 1, 64);
    s1 += __shfl_xor(s1, 2, 64); s2 += __shfl_xor(s2, 2, 64);
    s1 += __shfl_xor(s1, 4, 64); s2 += __shfl_xor(s2, 4, 64);
    float mu  = s1 * (1.f / D);
    float var = s2 * (1.f / D) - mu * mu;
    float rr = rsqrtf(var + 1e-5f);
    int e0 = s * 4;
    uint2 ou;
    ou.x = pk2((x[0]-mu)*rr*gs[e0]+bbs[e0],    (x[1]-mu)*rr*gs[e0+1]+bbs[e0+1]);
    ou.y = pk2((x[2]-mu)*rr*gs[e0+2]+bbs[e0+2],(x[3]-mu)*rr*gs[e0+3]+bbs[e0+3]);
    *(uint2*)&E[((size_t)(r0 + r)) * D + e0] = ou;
  }
}

// ---------------------------------------------------------------------------
// out = E@op_W + op_b + X   (f32 out)
// ---------------------------------------------------------------------------
__global__ __launch_bounds__(256) void out_kernel(
    const bf16* __restrict__ E, const float* __restrict__ op_W,
    const float* __restrict__ op_b, const float* __restrict__ X,
    float* __restrict__ out) {
  int idx = blockIdx.x * 256 + threadIdx.x;
  if (idx >= B * T * N * M) return;
  int m  = idx % M;
  int n  = (idx / M) % N;
  int bt = idx / (M * N);
  float acc = op_b[n * M + m];
  const bf16* e = E + ((size_t)bt * N + n) * D;
#pragma unroll
  for (int d = 0; d < D; ++d) acc += b2f(e[d]) * op_W[(n * D + d) * M + m];
  acc += X[idx];
  out[idx] = acc;
}

// ---------------------------------------------------------------------------
extern "C" void kernel_launch(void* const* d_in, const int* in_sizes, int n_in,
                              void* d_out, int out_size, void* d_ws, size_t ws_size,
                              hipStream_t stream) {
  const float* X     = (const float*)d_in[0];
  const float* pe    = (const float*)d_in[1];
  const float* E_W   = (const float*)d_in[2];
  const float* E_b   = (const float*)d_in[3];
  const float* tq_W  = (const float*)d_in[4];
  const float* tq_b  = (const float*)d_in[5];
  const float* tk_W  = (const float*)d_in[6];
  const float* tk_b  = (const float*)d_in[7];
  const float* tv_W  = (const float*)d_in[8];
  const float* tv_b  = (const float*)d_in[9];
  const float* tm_Wq = (const float*)d_in[10];
  const float* tm_bq = (const float*)d_in[11];
  const float* tm_Wk = (const float*)d_in[12];
  const float* tm_bk = (const float*)d_in[13];
  const float* tm_Wv = (const float*)d_in[14];
  const float* tm_bv = (const float*)d_in[15];
  const float* tm_Wo = (const float*)d_in[16];
  const float* tm_bo = (const float*)d_in[17];
  const float* sq_W  = (const float*)d_in[18];
  const float* sq_b  = (const float*)d_in[19];
  const float* sk_W  = (const float*)d_in[20];
  const float* sk_b  = (const float*)d_in[21];
  const float* sv_W  = (const float*)d_in[22];
  const float* sv_b  = (const float*)d_in[23];
  const float* sm_Wq = (const float*)d_in[24];
  const float* sm_bq = (const float*)d_in[25];
  const float* sm_Wk = (const float*)d_in[26];
  const float* sm_bk = (const float*)d_in[27];
  const float* sm_Wv = (const float*)d_in[28];
  const float* sm_bv = (const float*)d_in[29];
  const float* sm_Wo = (const float*)d_in[30];
  const float* sm_bo = (const float*)d_in[31];
  const float* ff1_W = (const float*)d_in[32];
  const float* ff1_b = (const float*)d_in[33];
  const float* ff2_W = (const float*)d_in[34];
  const float* ff2_b = (const float*)d_in[35];
  const float* ln_g  = (const float*)d_in[36];
  const float* ln_b  = (const float*)d_in[37];
  const float* op_W  = (const float*)d_in[38];
  const float* op_b  = (const float*)d_in[39];
  float* out = (float*)d_out;

  float* WtC = (float*)d_ws;                         // 3*N*D*D
  float* btC = WtC + 3 * N * D * D;                  // 3*N*D
  float* WsC = btC + 3 * N * D;                      // 3*T*D*D
  float* bsC = WsC + 3 * T * D * D;                  // 3*T*D
  size_t act = (size_t)B * T * N * D;
  bf16* Ebuf = (bf16*)(bsC + 3 * T * D);
  bf16* Tn   = Ebuf + act;
  bf16* Qt   = Tn + act;
  bf16* Kt   = Qt + act;
  bf16* Vt   = Kt + act;

  size_t floats_bytes = (size_t)(3 * N * D * D + 3 * N * D +
                                 3 * T * D * D + 3 * T * D) * sizeof(float);
  size_t need6 = floats_bytes + 6 * act * sizeof(bf16);
  bool concurrent = (ws_size >= need6);
  bf16* Sn = concurrent ? (Vt + act) : Qt;   // 6th buffer, or serial-safe alias

  compose3_kernel<<<3 * N, 256, 0, stream>>>(
      tq_W, tq_b, tm_Wq, tm_bq, tk_W, tk_b, tm_Wk, tm_bk,
      tv_W, tv_b, tm_Wv, tm_bv, WtC, btC, N);
  compose3_kernel<<<3 * T, 256, 0, stream>>>(
      sq_W, sq_b, sm_Wq, sm_bq, sk_W, sk_b, sm_Wk, sm_bk,
      sv_W, sv_b, sm_Wv, sm_bv, WsC, bsC, T);

  embed_kernel<<<(B * T * N * D) / 256, 256, 0, stream>>>(X, pe, E_W, E_b, Ebuf);

  for (int l = 0; l < L; ++l) {
    if (concurrent) {
      // qkvt ∥ spatial in one launch (role-split blocks), then attnt, ff.
      qs_fused_kernel<<<QG + SG, 256, 0, stream>>>(
          Ebuf, WtC, btC, Qt, Kt, Vt,
          WsC, bsC, sm_Wo, sm_bo, ln_g, ln_b, Sn, QG);
      attnt_kernel<<<B * N, 256, 0, stream>>>(Qt, Kt, Vt, Ebuf, tm_Wo, tm_bo, ln_g, ln_b, Tn);
    } else {
      // serial fallback (R31 schedule): qkvt, attnt, spatial (Sn aliases Qt).
      qs_fused_kernel<<<QG, 256, 0, stream>>>(
          Ebuf, WtC, btC, Qt, Kt, Vt,
          WsC, bsC, sm_Wo, sm_bo, ln_g, ln_b, Sn, QG);
      attnt_kernel<<<B * N, 256, 0, stream>>>(Qt, Kt, Vt, Ebuf, tm_Wo, tm_bo, ln_g, ln_b, Tn);
      qs_fused_kernel<<<SG, 256, 0, stream>>>(
          Ebuf, WtC, btC, Qt, Kt, Vt,
          WsC, bsC, sm_Wo, sm_bo, ln_g, ln_b, Sn, 0);
    }
    ff_kernel<<<(B * T * N) / FR, 256, 0, stream>>>(Tn, Sn, ff1_W, ff1_b, ff2_W, ff2_b, ln_g, ln_b, Ebuf);
  }

  out_kernel<<<(B * T * N * M + 255) / 256, 256, 0, stream>>>(Ebuf, op_W, op_b, X, out);
}

// Round 33
// 414.518 us; speedup vs baseline: 2.2105x; 1.0199x over previous
//
#include <hip/hip_runtime.h>
#include <hip/hip_bf16.h>

typedef __hip_bfloat16 bf16;
typedef __fp16 h2 __attribute__((ext_vector_type(2)));      // matches amdgcn builtin 'V2h'
typedef _Float16 f16x2 __attribute__((ext_vector_type(2))); // arithmetic (v_pk_*_f16)

constexpr int B  = 64, T = 120, N = 24, M = 3, D = 32;
constexpr int NH = 2, FD = 16, FF = 64, L = 3;
constexpr float SCALE = 0.25f;   // 1/sqrt(FD)
constexpr int SK  = 40;          // f16 LDS stride (80B rows) — attnt & spatial
constexpr int SOH = 20;          // attnt packed-f16 O stride (uints, 80B)
constexpr int CH2 = 30;          // attnt rows per chunk: 4 x 30 = 120 exactly
constexpr int NJ  = 30;          // max keys per lane slice (120/4)
constexpr int QR  = 64;          // qkvt rows per block (4 lanes/row)
constexpr int QCH = (B * T) / QR;// qkvt chunks = 120
constexpr int QEH = 20;          // qkvt packed-f16 Es stride (uints, 80B)
constexpr int BG  = 2;           // spatial batches per block
constexpr int SR  = N * BG;      // spatial rows per block = 48
constexpr int SEH = 20;          // spatial packed-f16 Es stride (uints, 80B)
constexpr int FR  = 32;          // ff rows per block (8 lanes/row)
constexpr int QG  = N * QCH;     // qkvt blocks = 2880
constexpr int AG  = B * N;       // attnt role blocks = 1536
constexpr int SG  = T * (B / BG);// spatial role blocks = 3840

__device__ __forceinline__ float b2f(bf16 x) { return __bfloat162float(x); }
__device__ __forceinline__ float blo(unsigned u) { return __uint_as_float(u << 16); }
__device__ __forceinline__ float bhi(unsigned u) { return __uint_as_float(u & 0xffff0000u); }
__device__ __forceinline__ unsigned pk2(float a, float b) {
  bf16 x = __float2bfloat16(a), y = __float2bfloat16(b);
  unsigned short ux = *reinterpret_cast<unsigned short*>(&x);
  unsigned short uy = *reinterpret_cast<unsigned short*>(&y);
  return (unsigned)ux | ((unsigned)uy << 16);
}
__device__ __forceinline__ unsigned pkh2(float a, float b) {
  h2 r = __builtin_amdgcn_cvt_pkrtz(a, b);     // v_cvt_pkrtz_f16_f32
  return *reinterpret_cast<unsigned*>(&r);
}
__device__ __forceinline__ h2 u2h(unsigned u) { return *reinterpret_cast<h2*>(&u); }
__device__ __forceinline__ f16x2 u2f(unsigned u) { return *reinterpret_cast<f16x2*>(&u); }

// ---------------------------------------------------------------------------
// Compose q/k/v chained linears: grid = 3*U blocks.  Wc = W1@W2, bc = b1@W2+b2.
// ---------------------------------------------------------------------------
__global__ __launch_bounds__(256) void compose3_kernel(
    const float* __restrict__ W1q, const float* __restrict__ b1q,
    const float* __restrict__ W2q, const float* __restrict__ b2q,
    const float* __restrict__ W1k, const float* __restrict__ b1k,
    const float* __restrict__ W2k, const float* __restrict__ b2k,
    const float* __restrict__ W1v, const float* __restrict__ b1v,
    const float* __restrict__ W2v, const float* __restrict__ b2v,
    float* __restrict__ Wc, float* __restrict__ bc, int U) {
  int fam = blockIdx.x / U;
  int n   = blockIdx.x % U;
  const float* W1 = (fam == 0) ? W1q : (fam == 1) ? W1k : W1v;
  const float* b1 = (fam == 0) ? b1q : (fam == 1) ? b1k : b1v;
  const float* W2 = (fam == 0) ? W2q : (fam == 1) ? W2k : W2v;
  const float* b2 = (fam == 0) ? b2q : (fam == 1) ? b2k : b2v;
  const float* w1 = W1 + n * D * D;
  const float* w2 = W2 + n * D * D;
  float* wc  = Wc + (size_t)(fam * U + n) * D * D;
  float* bcp = bc + (fam * U + n) * D;
  __shared__ float s1[D * D], s2[D * D];
  for (int i = threadIdx.x; i < D * D; i += 256) { s1[i] = w1[i]; s2[i] = w2[i]; }
  __syncthreads();
  for (int i = threadIdx.x; i < D * D; i += 256) {
    int d = i >> 5, f = i & 31;
    float acc = 0.f;
#pragma unroll
    for (int e = 0; e < D; ++e) acc += s1[d * D + e] * s2[e * D + f];
    wc[i] = acc;
  }
  if (threadIdx.x < D) {
    int f = threadIdx.x;
    float acc = b2[n * D + f];
#pragma unroll
    for (int e = 0; e < D; ++e) acc += b1[n * D + e] * s2[e * D + f];
    bcp[f] = acc;
  }
}

// ---------------------------------------------------------------------------
// E[b,t,n,d] = X@E_W + E_b + pe   (bf16 out)
// ---------------------------------------------------------------------------
__global__ __launch_bounds__(256) void embed_kernel(
    const float* __restrict__ X, const float* __restrict__ pe,
    const float* __restrict__ E_W, const float* __restrict__ E_b,
    bf16* __restrict__ E) {
  int idx = blockIdx.x * 256 + threadIdx.x;
  if (idx >= B * T * N * D) return;
  int d = idx & 31;
  int n = (idx >> 5) % N;
  int bt = idx / (D * N);
  int t = bt % T;
  const float* x = X + bt * (N * M) + n * M;
  float acc = E_b[n * D + d] + pe[t * D + d];
#pragma unroll
  for (int m = 0; m < M; ++m) acc += x[m] * E_W[(n * M + m) * D + d];
  E[idx] = __float2bfloat16(acc);
}

// ---------------------------------------------------------------------------
// qkvt v3: packed-f16 fdot2 gemv (measured R27: -17us/dispatch).
// ---------------------------------------------------------------------------
__global__ __launch_bounds__(256) void qkvt_kernel(
    const bf16* __restrict__ E, const float* __restrict__ WtC,
    const float* __restrict__ btC,
    bf16* __restrict__ Qt, bf16* __restrict__ Kt, bf16* __restrict__ Vt) {
  int n     = blockIdx.x / QCH;
  int chunk = blockIdx.x % QCH;
  __shared__ unsigned whh[3 * (D / 2) * D];        // 1536 uints, 6 KB
  __shared__ float bsh[3 * D];
  __shared__ __align__(16) unsigned Esp[QR * QEH]; // packed f16 Es, 5 KB
  int tid = threadIdx.x;
  for (int i = tid; i < 3 * (D / 2) * D; i += 256) {
    int fam = i / ((D / 2) * D);
    int idx = i % ((D / 2) * D);
    int d2 = idx >> 5, j = idx & 31;
    const float* wg = WtC + (size_t)(fam * N + n) * D * D;
    whh[i] = pkh2(wg[(2 * d2) * D + j], wg[(2 * d2 + 1) * D + j]);
  }
  if (tid < 3 * D) {
    int fam = tid >> 5, e = tid & 31;
    bsh[tid] = btC[(fam * N + n) * D + e];
  }
  {
    int row = tid >> 2, p = tid & 3;
    const bf16* er = E + ((size_t)(chunk * QR + row) * N + n) * D;
    uint4 u = *(const uint4*)&er[p * 8];
    uint4 o;
    o.x = pkh2(blo(u.x), bhi(u.x));
    o.y = pkh2(blo(u.y), bhi(u.y));
    o.z = pkh2(blo(u.z), bhi(u.z));
    o.w = pkh2(blo(u.w), bhi(u.w));
    *(uint4*)&Esp[row * QEH + p * 4] = o;
  }
  __syncthreads();

  int row = tid >> 2, q = tid & 3;
  int grow = chunk * QR + row;          // b*T + t
  int b = grow / T, t = grow % T;
  unsigned xp[D / 2];
#pragma unroll
  for (int d2 = 0; d2 < D / 2; ++d2) xp[d2] = Esp[row * QEH + d2];
  size_t dsto = (((size_t)b * N + n) * T + t) * D + q * 8;
  bf16* dsts[3] = { Qt + dsto, Kt + dsto, Vt + dsto };
#pragma unroll
  for (int fam = 0; fam < 3; ++fam) {
    const unsigned* wf = whh + fam * (D / 2) * D;
    const float* bi = bsh + fam * D;
    float a[8];
#pragma unroll
    for (int j = 0; j < 8; ++j) a[j] = bi[q * 8 + j];
#pragma unroll
    for (int d2 = 0; d2 < D / 2; ++d2) {
      h2 x = u2h(xp[d2]);
#pragma unroll
      for (int j = 0; j < 8; ++j)
        a[j] = __builtin_amdgcn_fdot2(x, u2h(wf[d2 * D + q * 8 + j]), a[j], false);
    }
    uint4 o;
    o.x = pk2(a[0], a[1]); o.y = pk2(a[2], a[3]);
    o.z = pk2(a[4], a[5]); o.w = pk2(a[6], a[7]);
    *(uint4*)dsts[fam] = o;
  }
}

// ---------------------------------------------------------------------------
// as_fused: role-split blocks — [0, ablocks) run attnt v13, rest run spatial
// v5.  spatial (E-only dep) hides under attnt (Q/K/V dep).  LDS union 26.6KB
// -> 6 blocks/CU for both roles.  Serial fallback = two partial launches.
// ---------------------------------------------------------------------------
struct ASmemA {
  __fp16 Klh[T * SK];              // 9600 B
  __fp16 Vlh[T * SK];              // 9600 B
  __fp16 Qlh[CH2 * SK];            // 2400 B
  unsigned Olh[CH2 * SOH];         // 2400 B
  unsigned woh[(D / 2) * D];       // 2048 B
  float bol[D], gl[D], bbl[D];     // 384 B  -> 26432 B
};
struct ASmemS {
  unsigned Wh[3 * (D / 2) * D];    // 6144 B
  unsigned woh[(D / 2) * D];       // 2048 B
  float bqs[D], bks[D], bvs[D], bos[D], gs[D], bbs[D];  // 768 B
  unsigned Esh[SR * SEH];          // 3840 B
  __fp16 Qh[SR * SK];              // 3840 B (O overwrites)
  __fp16 Kh[SR * SK];              // 3840 B
  __fp16 Vh[SR * SK];              // 3840 B  -> 24320 B
};
constexpr size_t AS_SMEM =
    sizeof(ASmemA) > sizeof(ASmemS) ? sizeof(ASmemA) : sizeof(ASmemS);

__global__ __launch_bounds__(256) void as_fused_kernel(
    const bf16* __restrict__ Qt, const bf16* __restrict__ Kt,
    const bf16* __restrict__ Vt, const bf16* __restrict__ E,
    const float* __restrict__ tm_Wo, const float* __restrict__ tm_bo,
    const float* __restrict__ WsC, const float* __restrict__ bsC,
    const float* __restrict__ sm_Wo, const float* __restrict__ sm_bo,
    const float* __restrict__ ln_g, const float* __restrict__ ln_b,
    bf16* __restrict__ Tn, bf16* __restrict__ Sn, int ablocks) {
  __shared__ __align__(16) char smem[AS_SMEM];
  int tid = threadIdx.x;

  if ((int)blockIdx.x < ablocks) {
    // ================= attnt role (v13) =================
    ASmemA& A = *reinterpret_cast<ASmemA*>(smem);
    int bn = blockIdx.x;
    int n  = bn % N, b = bn / N;

    const bf16* Kg = Kt + (size_t)bn * T * D;
    const bf16* Vg = Vt + (size_t)bn * T * D;
    const bf16* Qg = Qt + (size_t)bn * T * D;
    for (int i = tid; i < T * 4; i += 256) {
      int r = i >> 2, p = i & 3;
      uint4 ku = *(const uint4*)&Kg[r * D + p * 8];
      uint4 kh;
      kh.x = pkh2(blo(ku.x), bhi(ku.x));
      kh.y = pkh2(blo(ku.y), bhi(ku.y));
      kh.z = pkh2(blo(ku.z), bhi(ku.z));
      kh.w = pkh2(blo(ku.w), bhi(ku.w));
      *(uint4*)&A.Klh[r * SK + p * 8] = kh;
      uint4 vu = *(const uint4*)&Vg[r * D + p * 8];
      uint4 vh;
      vh.x = pkh2(blo(vu.x), bhi(vu.x));
      vh.y = pkh2(blo(vu.y), bhi(vu.y));
      vh.z = pkh2(blo(vu.z), bhi(vu.z));
      vh.w = pkh2(blo(vu.w), bhi(vu.w));
      *(uint4*)&A.Vlh[r * SK + p * 8] = vh;
    }
    {
      const float* wg = tm_Wo + (size_t)n * D * D;
      for (int i = tid; i < (D / 2) * D; i += 256) {
        int d2 = i >> 5, e = i & 31;
        A.woh[i] = pkh2(wg[(2 * d2) * D + e], wg[(2 * d2 + 1) * D + e]);
      }
    }
    if (tid < D) {
      A.bol[tid] = tm_bo[n * D + tid];
      A.gl[tid]  = ln_g[tid];
      A.bbl[tid] = ln_b[tid];
    }
    __syncthreads();

#pragma unroll
    for (int c = 0; c < 4; ++c) {
      const int JM = (CH2 * (c + 1) + 3) >> 2;   // 8,15,23,30 (compile-time)
      if (tid < CH2 * 4) {
        int r = tid >> 2, p = tid & 3;
        uint4 qu = *(const uint4*)&Qg[(CH2 * c + r) * D + p * 8];
        uint4 qh;
        qh.x = pkh2(blo(qu.x), bhi(qu.x));
        qh.y = pkh2(blo(qu.y), bhi(qu.y));
        qh.z = pkh2(blo(qu.z), bhi(qu.z));
        qh.w = pkh2(blo(qu.w), bhi(qu.w));
        *(uint4*)&A.Qlh[r * SK + p * 8] = qh;
      }
      __syncthreads();   // Qlh ready; prior O-proj done -> Olh safe to overwrite

      {
        int task = tid >> 2, sl = tid & 3;
        if (task < 2 * CH2) {
          int rl = task >> 1, h = task & 1, ho = h * FD;
          int rg = CH2 * c + rl;
          uint4 q0 = *(const uint4*)&A.Qlh[rl * SK + ho];
          uint4 q1 = *(const uint4*)&A.Qlh[rl * SK + ho + 8];
          unsigned qh[8] = { q0.x, q0.y, q0.z, q0.w, q1.x, q1.y, q1.z, q1.w };

          float sc[NJ];
          float mx = -3e38f;
#pragma unroll
          for (int j = 0; j < JM; ++j) {
            int k = 4 * j + sl;
            sc[j] = -3e38f;
            if (k <= rg) {
              const uint4 ka = *(const uint4*)&A.Klh[k * SK + ho];
              const uint4 kb = *(const uint4*)&A.Klh[k * SK + ho + 8];
              float s0 = __builtin_amdgcn_fdot2(u2h(qh[0]), u2h(ka.x), 0.f, false);
              float s1 = __builtin_amdgcn_fdot2(u2h(qh[1]), u2h(ka.y), 0.f, false);
              float s2 = __builtin_amdgcn_fdot2(u2h(qh[2]), u2h(ka.z), 0.f, false);
              float s3 = __builtin_amdgcn_fdot2(u2h(qh[3]), u2h(ka.w), 0.f, false);
              s0 = __builtin_amdgcn_fdot2(u2h(qh[4]), u2h(kb.x), s0, false);
              s1 = __builtin_amdgcn_fdot2(u2h(qh[5]), u2h(kb.y), s1, false);
              s2 = __builtin_amdgcn_fdot2(u2h(qh[6]), u2h(kb.z), s2, false);
              s3 = __builtin_amdgcn_fdot2(u2h(qh[7]), u2h(kb.w), s3, false);
              float s = ((s0 + s1) + (s2 + s3)) * SCALE;
              sc[j] = s;
              mx = fmaxf(mx, s);
            }
          }
          mx = fmaxf(mx, __shfl_xor(mx, 1, 64));
          mx = fmaxf(mx, __shfl_xor(mx, 2, 64));
          float l = 0.f;
#pragma unroll
          for (int j = 0; j < JM; ++j) {
            sc[j] = __expf(sc[j] - mx);   // invalid slots: exp(-inf) = 0
            l += sc[j];
          }
          l += __shfl_xor(l, 1, 64);
          l += __shfl_xor(l, 2, 64);
          float rli = 1.f / l;

          f16x2 acc2[8];
#pragma unroll
          for (int f = 0; f < 8; ++f) acc2[f] = f16x2{(_Float16)0.f, (_Float16)0.f};
#pragma unroll
          for (int j = 0; j < JM; ++j) {
            int k = 4 * j + sl;
            if (k <= rg) {
              f16x2 pp = f16x2{(_Float16)sc[j], (_Float16)sc[j]};
              const uint4 va = *(const uint4*)&A.Vlh[k * SK + ho];
              const uint4 vb = *(const uint4*)&A.Vlh[k * SK + ho + 8];
              acc2[0] += pp * u2f(va.x);
              acc2[1] += pp * u2f(va.y);
              acc2[2] += pp * u2f(va.z);
              acc2[3] += pp * u2f(va.w);
              acc2[4] += pp * u2f(vb.x);
              acc2[5] += pp * u2f(vb.y);
              acc2[6] += pp * u2f(vb.z);
              acc2[7] += pp * u2f(vb.w);
            }
          }
#pragma unroll
          for (int f = 0; f < 8; ++f) {
            unsigned u = *reinterpret_cast<unsigned*>(&acc2[f]);
            unsigned u1 = __shfl_xor(u, 1, 64);
            acc2[f] += u2f(u1);
            u = *reinterpret_cast<unsigned*>(&acc2[f]);
            unsigned u2_ = __shfl_xor(u, 2, 64);
            acc2[f] += u2f(u2_);
          }
          if (sl == 0) {
#pragma unroll
            for (int j = 0; j < 8; ++j)
              A.Olh[rl * SOH + h * 8 + j] =
                  pkh2((float)acc2[j][0] * rli, (float)acc2[j][1] * rli);
          }
        }
      }
      __syncthreads();

      // ---- O-proj (fdot2) + residual + LN: thread = (row, e-quad) ----
      {
        int rl = tid >> 3, q = tid & 7, e0 = q * 4;
        if (rl < CH2) {
          int rg = CH2 * c + rl;
          size_t rowo = ((size_t)(b * T + rg) * N + n) * D;
          uint2 eu = *(const uint2*)&E[rowo + e0];
          float res[4] = { blo(eu.x), bhi(eu.x), blo(eu.y), bhi(eu.y) };
          float o[4], s1 = 0.f, s2 = 0.f;
#pragma unroll
          for (int j = 0; j < 4; ++j) {
            int e = e0 + j;
            float a = A.bol[e] + res[j];
#pragma unroll
            for (int d2 = 0; d2 < D / 2; ++d2)
              a = __builtin_amdgcn_fdot2(u2h(A.Olh[rl * SOH + d2]),
                                         u2h(A.woh[d2 * D + e]), a, false);
            o[j] = a; s1 += a; s2 += a * a;
          }
          s1 += __shfl_xor(s1, 1, 64); s2 += __shfl_xor(s2, 1, 64);
          s1 += __shfl_xor(s1, 2, 64); s2 += __shfl_xor(s2, 2, 64);
          s1 += __shfl_xor(s1, 4, 64); s2 += __shfl_xor(s2, 4, 64);
          float mu  = s1 * (1.f / D);
          float var = s2 * (1.f / D) - mu * mu;
          float r = rsqrtf(var + 1e-5f);
          uint2 ou;
          ou.x = pk2((o[0]-mu)*r*A.gl[e0]+A.bbl[e0],    (o[1]-mu)*r*A.gl[e0+1]+A.bbl[e0+1]);
          ou.y = pk2((o[2]-mu)*r*A.gl[e0+2]+A.bbl[e0+2],(o[3]-mu)*r*A.gl[e0+3]+A.bbl[e0+3]);
          *(uint2*)&Tn[rowo + e0] = ou;
        }
      }
    }
  } else {
    // ================= spatial role (v5) =================
    ASmemS& s = *reinterpret_cast<ASmemS*>(smem);
    int sb = blockIdx.x - ablocks;
    int t  = sb >> 5;          // B/BG = 32 groups per t
    int bg = sb & 31;
    int b0 = bg * BG;

    for (int i = tid; i < 3 * (D / 2) * D; i += 256) {
      int fam = i / ((D / 2) * D);
      int idx = i % ((D / 2) * D);
      int d2 = idx >> 5, e = idx & 31;
      const float* wg = WsC + (size_t)(fam * T + t) * D * D;
      s.Wh[i] = pkh2(wg[(2 * d2) * D + e], wg[(2 * d2 + 1) * D + e]);
    }
    {
      const float* wg = sm_Wo + (size_t)t * D * D;
      for (int i = tid; i < (D / 2) * D; i += 256) {
        int d2 = i >> 5, e = i & 31;
        s.woh[i] = pkh2(wg[(2 * d2) * D + e], wg[(2 * d2 + 1) * D + e]);
      }
    }
    if (tid < D) {
      s.bqs[tid] = bsC[(0 * T + t) * D + tid];
      s.bks[tid] = bsC[(1 * T + t) * D + tid];
      s.bvs[tid] = bsC[(2 * T + t) * D + tid];
      s.bos[tid] = sm_bo[t * D + tid];
      s.gs[tid]  = ln_g[tid];
      s.bbs[tid] = ln_b[tid];
    }
    if (tid < SR * 4) {
      int r = tid >> 2, p = tid & 3;
      int b = b0 + r / N, n = r % N;
      uint4 u = *(const uint4*)&E[(((size_t)b * T + t) * N + n) * D + p * 8];
      uint4 o;
      o.x = pkh2(blo(u.x), bhi(u.x));
      o.y = pkh2(blo(u.y), bhi(u.y));
      o.z = pkh2(blo(u.z), bhi(u.z));
      o.w = pkh2(blo(u.w), bhi(u.w));
      *(uint4*)&s.Esh[r * SEH + p * 4] = o;
    }
    __syncthreads();

    // ---- QKV gemv (fdot2) -> packed-f16 Q/K/V ----
#pragma unroll 1
    for (int i = tid; i < SR * D; i += 256) {
      int r = i >> 5, e = i & 31;
      float aq = s.bqs[e], ak = s.bks[e], av = s.bvs[e];
#pragma unroll
      for (int d2 = 0; d2 < D / 2; ++d2) {
        h2 x = u2h(s.Esh[r * SEH + d2]);
        aq = __builtin_amdgcn_fdot2(x, u2h(s.Wh[0 * 512 + d2 * 32 + e]), aq, false);
        ak = __builtin_amdgcn_fdot2(x, u2h(s.Wh[1 * 512 + d2 * 32 + e]), ak, false);
        av = __builtin_amdgcn_fdot2(x, u2h(s.Wh[2 * 512 + d2 * 32 + e]), av, false);
      }
      s.Qh[r * SK + e] = (__fp16)aq;
      s.Kh[r * SK + e] = (__fp16)ak;
      s.Vh[r * SK + e] = (__fp16)av;
    }
    __syncthreads();

    // ---- attention (96 threads): fdot2 scores + pk_fma PV, O -> Q slot ----
    if (tid < SR * NH) {
      int r = tid >> 1, h = tid & 1, ho = h * FD;
      int kb = (r >= N) ? N : 0;
      uint4 q0 = *(const uint4*)&s.Qh[r * SK + ho];
      uint4 q1 = *(const uint4*)&s.Qh[r * SK + ho + 8];
      unsigned qh[8] = { q0.x, q0.y, q0.z, q0.w, q1.x, q1.y, q1.z, q1.w };
      float sc[N];
      float m = -1e30f;
#pragma unroll
      for (int k = 0; k < N; ++k) {
        const uint4 ka = *(const uint4*)&s.Kh[(kb + k) * SK + ho];
        const uint4 kc = *(const uint4*)&s.Kh[(kb + k) * SK + ho + 8];
        float s0 = __builtin_amdgcn_fdot2(u2h(qh[0]), u2h(ka.x), 0.f, false);
        float s1 = __builtin_amdgcn_fdot2(u2h(qh[1]), u2h(ka.y), 0.f, false);
        float s2 = __builtin_amdgcn_fdot2(u2h(qh[2]), u2h(ka.z), 0.f, false);
        float s3 = __builtin_amdgcn_fdot2(u2h(qh[3]), u2h(ka.w), 0.f, false);
        s0 = __builtin_amdgcn_fdot2(u2h(qh[4]), u2h(kc.x), s0, false);
        s1 = __builtin_amdgcn_fdot2(u2h(qh[5]), u2h(kc.y), s1, false);
        s2 = __builtin_amdgcn_fdot2(u2h(qh[6]), u2h(kc.z), s2, false);
        s3 = __builtin_amdgcn_fdot2(u2h(qh[7]), u2h(kc.w), s3, false);
        float sv = ((s0 + s1) + (s2 + s3)) * SCALE;
        sc[k] = sv;
        m = fmaxf(m, sv);
      }
      float l = 0.f;
#pragma unroll
      for (int k = 0; k < N; ++k) { sc[k] = __expf(sc[k] - m); l += sc[k]; }
      float rl = 1.f / l;

      f16x2 acc2[8];
#pragma unroll
      for (int f = 0; f < 8; ++f) acc2[f] = f16x2{(_Float16)0.f, (_Float16)0.f};
#pragma unroll
      for (int k = 0; k < N; ++k) {
        f16x2 pp = f16x2{(_Float16)sc[k], (_Float16)sc[k]};
        const uint4 va = *(const uint4*)&s.Vh[(kb + k) * SK + ho];
        const uint4 vb = *(const uint4*)&s.Vh[(kb + k) * SK + ho + 8];
        acc2[0] += pp * u2f(va.x);
        acc2[1] += pp * u2f(va.y);
        acc2[2] += pp * u2f(va.z);
        acc2[3] += pp * u2f(va.w);
        acc2[4] += pp * u2f(vb.x);
        acc2[5] += pp * u2f(vb.y);
        acc2[6] += pp * u2f(vb.z);
        acc2[7] += pp * u2f(vb.w);
      }
      unsigned* op = (unsigned*)&s.Qh[r * SK + ho];
#pragma unroll
      for (int j = 0; j < 8; ++j)
        op[j] = pkh2((float)acc2[j][0] * rl, (float)acc2[j][1] * rl);
    }
    __syncthreads();

    // ---- O-proj (fdot2) + residual + LN: thread = (row, e-quad), 2 iters ----
#pragma unroll 1
    for (int it = 0; it < 2; ++it) {
      int rl = it * 32 + (tid >> 3);
      int qd = tid & 7, e0 = qd * 4;
      if (rl < SR) {
        const unsigned* opk = (const unsigned*)&s.Qh[rl * SK];
        unsigned r0u = s.Esh[rl * SEH + (e0 >> 1)];
        unsigned r1u = s.Esh[rl * SEH + (e0 >> 1) + 1];
        h2 ra = u2h(r0u), rb = u2h(r1u);
        float res[4] = { (float)ra[0], (float)ra[1], (float)rb[0], (float)rb[1] };
        float o[4], s1 = 0.f, s2 = 0.f;
#pragma unroll
        for (int j = 0; j < 4; ++j) {
          int e = e0 + j;
          float a = s.bos[e] + res[j];
#pragma unroll
          for (int d2 = 0; d2 < D / 2; ++d2)
            a = __builtin_amdgcn_fdot2(u2h(opk[d2]), u2h(s.woh[d2 * D + e]), a, false);
          o[j] = a; s1 += a; s2 += a * a;
        }
        s1 += __shfl_xor(s1, 1, 64); s2 += __shfl_xor(s2, 1, 64);
        s1 += __shfl_xor(s1, 2, 64); s2 += __shfl_xor(s2, 2, 64);
        s1 += __shfl_xor(s1, 4, 64); s2 += __shfl_xor(s2, 4, 64);
        float mu  = s1 * (1.f / D);
        float var = s2 * (1.f / D) - mu * mu;
        float rr = rsqrtf(var + 1e-5f);
        int b = b0 + rl / N, n = rl % N;
        uint2 ou;
        ou.x = pk2((o[0]-mu)*rr*s.gs[e0]+s.bbs[e0],    (o[1]-mu)*rr*s.gs[e0+1]+s.bbs[e0+1]);
        ou.y = pk2((o[2]-mu)*rr*s.gs[e0+2]+s.bbs[e0+2],(o[3]-mu)*rr*s.gs[e0+3]+s.bbs[e0+3]);
        *(uint2*)&Sn[(((size_t)b * T + t) * N + n) * D + e0] = ou;
      }
    }
  }
}

// ---------------------------------------------------------------------------
// ff v3: packed-f16 fdot2 gemvs (measured R26: ~-24us/dispatch).
// ---------------------------------------------------------------------------
__global__ __launch_bounds__(256) void ff_kernel(
    const bf16* __restrict__ Tn, const bf16* __restrict__ Sn,
    const float* __restrict__ W1, const float* __restrict__ b1,
    const float* __restrict__ W2, const float* __restrict__ b2,
    const float* __restrict__ ln_g, const float* __restrict__ ln_b,
    bf16* __restrict__ E) {
  __shared__ unsigned w1h[(D / 2) * FF];   // 1024 uints, 4KB
  __shared__ unsigned w2h[(FF / 2) * D];   // 1024 uints, 4KB
  __shared__ float bb1[FF], bb2[D], gs[D], bbs[D];
  __shared__ unsigned tslp[FR][D / 2 + 1]; // 32 x 17 (stride 17: conflict-free)
  __shared__ unsigned hlp[FR][FF / 2 + 1]; // 32 x 33 (stride 33: conflict-free)
  int tid = threadIdx.x;
  int r0 = blockIdx.x * FR;
  for (int i = tid; i < (D / 2) * FF; i += 256) {
    int d2 = i / FF, jj = i % FF;
    w1h[i] = pkh2(W1[(2 * d2) * FF + jj], W1[(2 * d2 + 1) * FF + jj]);
  }
  for (int i = tid; i < (FF / 2) * D; i += 256) {
    int k2 = i / D, e = i % D;
    w2h[i] = pkh2(W2[(2 * k2) * D + e], W2[(2 * k2 + 1) * D + e]);
  }
  if (tid < FF) bb1[tid] = b1[tid];
  if (tid < D) { bb2[tid] = b2[tid]; gs[tid] = ln_g[tid]; bbs[tid] = ln_b[tid]; }
  int r = tid >> 3, s = tid & 7;
  {
    const bf16* tp = Tn + ((size_t)(r0 + r)) * D + s * 4;
    const bf16* sp = Sn + ((size_t)(r0 + r)) * D + s * 4;
    uint2 tu = *(const uint2*)tp;
    uint2 su = *(const uint2*)sp;
    float t0 = blo(tu.x) + blo(su.x);
    float t1 = bhi(tu.x) + bhi(su.x);
    float t2 = blo(tu.y) + blo(su.y);
    float t3 = bhi(tu.y) + bhi(su.y);
    tslp[r][s * 2]     = pkh2(t0, t1);
    tslp[r][s * 2 + 1] = pkh2(t2, t3);
  }
  __syncthreads();
  // pass1: 8 hidden units per lane via fdot2
  {
    float hh[8];
#pragma unroll
    for (int j = 0; j < 8; ++j) {
      int jj = s * 8 + j;
      float a = bb1[jj];
#pragma unroll
      for (int d2 = 0; d2 < D / 2; ++d2)
        a = __builtin_amdgcn_fdot2(u2h(tslp[r][d2]), u2h(w1h[d2 * FF + jj]), a, false);
      hh[j] = fmaxf(a, 0.f);
    }
#pragma unroll
    for (int j = 0; j < 4; ++j)
      hlp[r][s * 4 + j] = pkh2(hh[2 * j], hh[2 * j + 1]);
  }
  __syncthreads();
  // pass2: 4 outputs per lane via fdot2 + LN (3-level shfl reduce)
  {
    float x[4];
    float s1 = 0.f, s2 = 0.f;
#pragma unroll
    for (int j4 = 0; j4 < 4; ++j4) {
      int e = s * 4 + j4;
      h2 tv = u2h(tslp[r][e >> 1]);
      float a = bb2[e] + (float)tv[j4 & 1];   // s*4 even -> e&1 == j4&1
#pragma unroll
      for (int k2 = 0; k2 < FF / 2; ++k2)
        a = __builtin_amdgcn_fdot2(u2h(hlp[r][k2]), u2h(w2h[k2 * D + e]), a, false);
      x[j4] = a; s1 += a; s2 += a * a;
    }
    s1 += __shfl_xor(s1, 1, 64); s2 += __shfl_xor(s2, 1, 64);
    s1 += __shfl_xor(s1, 2, 64); s2 += __shfl_xor(s2, 2, 64);
    s1 += __shfl_xor(s1, 4, 64); s2 += __shfl_xor(s2, 4, 64);
    float mu  = s1 * (1.f / D);
    float var = s2 * (1.f / D) - mu * mu;
    float rr = rsqrtf(var + 1e-5f);
    int e0 = s * 4;
    uint2 ou;
    ou.x = pk2((x[0]-mu)*rr*gs[e0]+bbs[e0],    (x[1]-mu)*rr*gs[e0+1]+bbs[e0+1]);
    ou.y = pk2((x[2]-mu)*rr*gs[e0+2]+bbs[e0+2],(x[3]-mu)*rr*gs[e0+3]+bbs[e0+3]);
    *(uint2*)&E[((size_t)(r0 + r)) * D + e0] = ou;
  }
}

// ---------------------------------------------------------------------------
// out = E@op_W + op_b + X   (f32 out)
// ---------------------------------------------------------------------------
__global__ __launch_bounds__(256) void out_kernel(
    const bf16* __restrict__ E, const float* __restrict__ op_W,
    const float* __restrict__ op_b, const float* __restrict__ X,
    float* __restrict__ out) {
  int idx = blockIdx.x * 256 + threadIdx.x;
  if (idx >= B * T * N * M) return;
  int m  = idx % M;
  int n  = (idx / M) % N;
  int bt = idx / (M * N);
  float acc = op_b[n * M + m];
  const bf16* e = E + ((size_t)bt * N + n) * D;
#pragma unroll
  for (int d = 0; d < D; ++d) acc += b2f(e[d]) * op_W[(n * D + d) * M + m];
  acc += X[idx];
  out[idx] = acc;
}

// ---------------------------------------------------------------------------
extern "C" void kernel_launch(void* const* d_in, const int* in_sizes, int n_in,
                              void* d_out, int out_size, void* d_ws, size_t ws_size,
                              hipStream_t stream) {
  const float* X     = (const float*)d_in[0];
  const float* pe    = (const float*)d_in[1];
  const float* E_W   = (const float*)d_in[2];
  const float* E_b   = (const float*)d_in[3];
  const float* tq_W  = (const float*)d_in[4];
  const float* tq_b  = (const float*)d_in[5];
  const float* tk_W  = (const float*)d_in[6];
  const float* tk_b  = (const float*)d_in[7];
  const float* tv_W  = (const float*)d_in[8];
  const float* tv_b  = (const float*)d_in[9];
  const float* tm_Wq = (const float*)d_in[10];
  const float* tm_bq = (const float*)d_in[11];
  const float* tm_Wk = (const float*)d_in[12];
  const float* tm_bk = (const float*)d_in[13];
  const float* tm_Wv = (const float*)d_in[14];
  const float* tm_bv = (const float*)d_in[15];
  const float* tm_Wo = (const float*)d_in[16];
  const float* tm_bo = (const float*)d_in[17];
  const float* sq_W  = (const float*)d_in[18];
  const float* sq_b  = (const float*)d_in[19];
  const float* sk_W  = (const float*)d_in[20];
  const float* sk_b  = (const float*)d_in[21];
  const float* sv_W  = (const float*)d_in[22];
  const float* sv_b  = (const float*)d_in[23];
  const float* sm_Wq = (const float*)d_in[24];
  const float* sm_bq = (const float*)d_in[25];
  const float* sm_Wk = (const float*)d_in[26];
  const float* sm_bk = (const float*)d_in[27];
  const float* sm_Wv = (const float*)d_in[28];
  const float* sm_bv = (const float*)d_in[29];
  const float* sm_Wo = (const float*)d_in[30];
  const float* sm_bo = (const float*)d_in[31];
  const float* ff1_W = (const float*)d_in[32];
  const float* ff1_b = (const float*)d_in[33];
  const float* ff2_W = (const float*)d_in[34];
  const float* ff2_b = (const float*)d_in[35];
  const float* ln_g  = (const float*)d_in[36];
  const float* ln_b  = (const float*)d_in[37];
  const float* op_W  = (const float*)d_in[38];
  const float* op_b  = (const float*)d_in[39];
  float* out = (float*)d_out;

  float* WtC = (float*)d_ws;                         // 3*N*D*D
  float* btC = WtC + 3 * N * D * D;                  // 3*N*D
  float* WsC = btC + 3 * N * D;                      // 3*T*D*D
  float* bsC = WsC + 3 * T * D * D;                  // 3*T*D
  size_t act = (size_t)B * T * N * D;
  bf16* Ebuf = (bf16*)(bsC + 3 * T * D);
  bf16* Tn   = Ebuf + act;
  bf16* Qt   = Tn + act;
  bf16* Kt   = Qt + act;
  bf16* Vt   = Kt + act;

  size_t floats_bytes = (size_t)(3 * N * D * D + 3 * N * D +
                                 3 * T * D * D + 3 * T * D) * sizeof(float);
  size_t need6 = floats_bytes + 6 * act * sizeof(bf16);
  bool concurrent = (ws_size >= need6);
  bf16* Sn = concurrent ? (Vt + act) : Qt;   // 6th buffer, or serial-safe alias

  compose3_kernel<<<3 * N, 256, 0, stream>>>(
      tq_W, tq_b, tm_Wq, tm_bq, tk_W, tk_b, tm_Wk, tm_bk,
      tv_W, tv_b, tm_Wv, tm_bv, WtC, btC, N);
  compose3_kernel<<<3 * T, 256, 0, stream>>>(
      sq_W, sq_b, sm_Wq, sm_bq, sk_W, sk_b, sm_Wk, sm_bk,
      sv_W, sv_b, sm_Wv, sm_bv, WsC, bsC, T);

  embed_kernel<<<(B * T * N * D) / 256, 256, 0, stream>>>(X, pe, E_W, E_b, Ebuf);

  for (int l = 0; l < L; ++l) {
    qkvt_kernel<<<QG, 256, 0, stream>>>(Ebuf, WtC, btC, Qt, Kt, Vt);
    if (concurrent) {
      // attnt ∥ spatial in one launch: spatial hides under the longer attnt.
      as_fused_kernel<<<AG + SG, 256, 0, stream>>>(
          Qt, Kt, Vt, Ebuf, tm_Wo, tm_bo,
          WsC, bsC, sm_Wo, sm_bo, ln_g, ln_b, Tn, Sn, AG);
    } else {
      // serial fallback (R31 schedule): attnt, then spatial (Sn aliases Qt).
      as_fused_kernel<<<AG, 256, 0, stream>>>(
          Qt, Kt, Vt, Ebuf, tm_Wo, tm_bo,
          WsC, bsC, sm_Wo, sm_bo, ln_g, ln_b, Tn, Sn, AG);
      as_fused_kernel<<<SG, 256, 0, stream>>>(
          Qt, Kt, Vt, Ebuf, tm_Wo, tm_bo,
          WsC, bsC, sm_Wo, sm_bo, ln_g, ln_b, Tn, Sn, 0);
    }
    ff_kernel<<<(B * T * N) / FR, 256, 0, stream>>>(Tn, Sn, ff1_W, ff1_b, ff2_W, ff2_b, ln_g, ln_b, Ebuf);
  }

  out_kernel<<<(B * T * N * M + 255) / 256, 256, 0, stream>>>(Ebuf, op_W, op_b, X, out);
}

// Round 34
// 410.122 us; speedup vs baseline: 2.2342x; 1.0107x over previous
//
#include <hip/hip_runtime.h>
#include <hip/hip_bf16.h>

typedef __fp16 f16;
typedef __fp16 h2 __attribute__((ext_vector_type(2)));      // matches amdgcn builtin 'V2h'
typedef _Float16 f16x2 __attribute__((ext_vector_type(2))); // arithmetic (v_pk_*_f16)

constexpr int B  = 64, T = 120, N = 24, M = 3, D = 32;
constexpr int NH = 2, FD = 16, FF = 64, L = 3;
constexpr float SCALE = 0.25f;   // 1/sqrt(FD)
constexpr int SK  = 40;          // f16 LDS stride (80B rows) — attnt & spatial
constexpr int SOH = 20;          // attnt packed-f16 O stride (uints, 80B)
constexpr int CH2 = 30;          // attnt rows per chunk: 4 x 30 = 120 exactly
constexpr int NJ  = 30;          // max keys per lane slice (120/4)
constexpr int QR  = 64;          // qkvt rows per block (4 lanes/row)
constexpr int QCH = (B * T) / QR;// qkvt chunks = 120
constexpr int QEH = 20;          // qkvt packed-f16 Es stride (uints, 80B)
constexpr int BG  = 2;           // spatial batches per block
constexpr int SR  = N * BG;      // spatial rows per block = 48
constexpr int SEH = 20;          // spatial packed-f16 Es stride (uints, 80B)
constexpr int FR  = 32;          // ff rows per block (8 lanes/row)
constexpr int QG  = N * QCH;     // qkvt blocks = 2880
constexpr int AG  = B * N;       // attnt role blocks = 1536
constexpr int SG  = T * (B / BG);// spatial role blocks = 3840

__device__ __forceinline__ unsigned pkh2(float a, float b) {
  h2 r = __builtin_amdgcn_cvt_pkrtz(a, b);     // v_cvt_pkrtz_f16_f32
  return *reinterpret_cast<unsigned*>(&r);
}
__device__ __forceinline__ h2 u2h(unsigned u) { return *reinterpret_cast<h2*>(&u); }
__device__ __forceinline__ f16x2 u2f(unsigned u) { return *reinterpret_cast<f16x2*>(&u); }
__device__ __forceinline__ float hlo(unsigned u) { h2 v = u2h(u); return (float)v[0]; }
__device__ __forceinline__ float hhi(unsigned u) { h2 v = u2h(u); return (float)v[1]; }

// ---------------------------------------------------------------------------
// Compose q/k/v chained linears: grid = 3*U blocks.  Wc = W1@W2, bc = b1@W2+b2.
// ---------------------------------------------------------------------------
__global__ __launch_bounds__(256) void compose3_kernel(
    const float* __restrict__ W1q, const float* __restrict__ b1q,
    const float* __restrict__ W2q, const float* __restrict__ b2q,
    const float* __restrict__ W1k, const float* __restrict__ b1k,
    const float* __restrict__ W2k, const float* __restrict__ b2k,
    const float* __restrict__ W1v, const float* __restrict__ b1v,
    const float* __restrict__ W2v, const float* __restrict__ b2v,
    float* __restrict__ Wc, float* __restrict__ bc, int U) {
  int fam = blockIdx.x / U;
  int n   = blockIdx.x % U;
  const float* W1 = (fam == 0) ? W1q : (fam == 1) ? W1k : W1v;
  const float* b1 = (fam == 0) ? b1q : (fam == 1) ? b1k : b1v;
  const float* W2 = (fam == 0) ? W2q : (fam == 1) ? W2k : W2v;
  const float* b2 = (fam == 0) ? b2q : (fam == 1) ? b2k : b2v;
  const float* w1 = W1 + n * D * D;
  const float* w2 = W2 + n * D * D;
  float* wc  = Wc + (size_t)(fam * U + n) * D * D;
  float* bcp = bc + (fam * U + n) * D;
  __shared__ float s1[D * D], s2[D * D];
  for (int i = threadIdx.x; i < D * D; i += 256) { s1[i] = w1[i]; s2[i] = w2[i]; }
  __syncthreads();
  for (int i = threadIdx.x; i < D * D; i += 256) {
    int d = i >> 5, f = i & 31;
    float acc = 0.f;
#pragma unroll
    for (int e = 0; e < D; ++e) acc += s1[d * D + e] * s2[e * D + f];
    wc[i] = acc;
  }
  if (threadIdx.x < D) {
    int f = threadIdx.x;
    float acc = b2[n * D + f];
#pragma unroll
    for (int e = 0; e < D; ++e) acc += b1[n * D + e] * s2[e * D + f];
    bcp[f] = acc;
  }
}

// ---------------------------------------------------------------------------
// E[b,t,n,d] = X@E_W + E_b + pe   (f16 out)
// ---------------------------------------------------------------------------
__global__ __launch_bounds__(256) void embed_kernel(
    const float* __restrict__ X, const float* __restrict__ pe,
    const float* __restrict__ E_W, const float* __restrict__ E_b,
    f16* __restrict__ E) {
  int idx = blockIdx.x * 256 + threadIdx.x;
  if (idx >= B * T * N * D) return;
  int d = idx & 31;
  int n = (idx >> 5) % N;
  int bt = idx / (D * N);
  int t = bt % T;
  const float* x = X + bt * (N * M) + n * M;
  float acc = E_b[n * D + d] + pe[t * D + d];
#pragma unroll
  for (int m = 0; m < M; ++m) acc += x[m] * E_W[(n * M + m) * D + d];
  E[idx] = (f16)acc;
}

// ---------------------------------------------------------------------------
// qkvt v4 = v3 with f16 activations: Es staging is a pure uint4 copy (E is
// f16), outputs packed with single-op cvt_pkrtz.  Zero unpack/repack VALU.
// ---------------------------------------------------------------------------
__global__ __launch_bounds__(256) void qkvt_kernel(
    const f16* __restrict__ E, const float* __restrict__ WtC,
    const float* __restrict__ btC,
    f16* __restrict__ Qt, f16* __restrict__ Kt, f16* __restrict__ Vt) {
  int n     = blockIdx.x / QCH;
  int chunk = blockIdx.x % QCH;
  __shared__ unsigned whh[3 * (D / 2) * D];        // 1536 uints, 6 KB
  __shared__ float bsh[3 * D];
  __shared__ __align__(16) unsigned Esp[QR * QEH]; // packed f16 Es, 5 KB
  int tid = threadIdx.x;
  for (int i = tid; i < 3 * (D / 2) * D; i += 256) {
    int fam = i / ((D / 2) * D);
    int idx = i % ((D / 2) * D);
    int d2 = idx >> 5, j = idx & 31;
    const float* wg = WtC + (size_t)(fam * N + n) * D * D;
    whh[i] = pkh2(wg[(2 * d2) * D + j], wg[(2 * d2 + 1) * D + j]);
  }
  if (tid < 3 * D) {
    int fam = tid >> 5, e = tid & 31;
    bsh[tid] = btC[(fam * N + n) * D + e];
  }
  {
    int row = tid >> 2, p = tid & 3;
    const f16* er = E + ((size_t)(chunk * QR + row) * N + n) * D;
    *(uint4*)&Esp[row * QEH + p * 4] = *(const uint4*)&er[p * 8];
  }
  __syncthreads();

  int row = tid >> 2, q = tid & 3;
  int grow = chunk * QR + row;          // b*T + t
  int b = grow / T, t = grow % T;
  unsigned xp[D / 2];
#pragma unroll
  for (int d2 = 0; d2 < D / 2; ++d2) xp[d2] = Esp[row * QEH + d2];
  size_t dsto = (((size_t)b * N + n) * T + t) * D + q * 8;
  f16* dsts[3] = { Qt + dsto, Kt + dsto, Vt + dsto };
#pragma unroll
  for (int fam = 0; fam < 3; ++fam) {
    const unsigned* wf = whh + fam * (D / 2) * D;
    const float* bi = bsh + fam * D;
    float a[8];
#pragma unroll
    for (int j = 0; j < 8; ++j) a[j] = bi[q * 8 + j];
#pragma unroll
    for (int d2 = 0; d2 < D / 2; ++d2) {
      h2 x = u2h(xp[d2]);
#pragma unroll
      for (int j = 0; j < 8; ++j)
        a[j] = __builtin_amdgcn_fdot2(x, u2h(wf[d2 * D + q * 8 + j]), a[j], false);
    }
    uint4 o;
    o.x = pkh2(a[0], a[1]); o.y = pkh2(a[2], a[3]);
    o.z = pkh2(a[4], a[5]); o.w = pkh2(a[6], a[7]);
    *(uint4*)dsts[fam] = o;
  }
}

// ---------------------------------------------------------------------------
// as_fused v2: f16 activations — K/V/Q and Es staging are pure uint4 copies.
// Role-split: [0, ablocks) = attnt v13, rest = spatial v5.
// ---------------------------------------------------------------------------
struct ASmemA {
  f16 Klh[T * SK];                 // 9600 B
  f16 Vlh[T * SK];                 // 9600 B
  f16 Qlh[CH2 * SK];               // 2400 B
  unsigned Olh[CH2 * SOH];         // 2400 B
  unsigned woh[(D / 2) * D];       // 2048 B
  float bol[D], gl[D], bbl[D];     // 384 B  -> 26432 B
};
struct ASmemS {
  unsigned Wh[3 * (D / 2) * D];    // 6144 B
  unsigned woh[(D / 2) * D];       // 2048 B
  float bqs[D], bks[D], bvs[D], bos[D], gs[D], bbs[D];  // 768 B
  unsigned Esh[SR * SEH];          // 3840 B
  f16 Qh[SR * SK];                 // 3840 B (O overwrites)
  f16 Kh[SR * SK];                 // 3840 B
  f16 Vh[SR * SK];                 // 3840 B  -> 24320 B
};
constexpr size_t AS_SMEM =
    sizeof(ASmemA) > sizeof(ASmemS) ? sizeof(ASmemA) : sizeof(ASmemS);

__global__ __launch_bounds__(256) void as_fused_kernel(
    const f16* __restrict__ Qt, const f16* __restrict__ Kt,
    const f16* __restrict__ Vt, const f16* __restrict__ E,
    const float* __restrict__ tm_Wo, const float* __restrict__ tm_bo,
    const float* __restrict__ WsC, const float* __restrict__ bsC,
    const float* __restrict__ sm_Wo, const float* __restrict__ sm_bo,
    const float* __restrict__ ln_g, const float* __restrict__ ln_b,
    f16* __restrict__ Tn, f16* __restrict__ Sn, int ablocks) {
  __shared__ __align__(16) char smem[AS_SMEM];
  int tid = threadIdx.x;

  if ((int)blockIdx.x < ablocks) {
    // ================= attnt role (v13, f16 I/O) =================
    ASmemA& A = *reinterpret_cast<ASmemA*>(smem);
    int bn = blockIdx.x;
    int n  = bn % N, b = bn / N;

    const f16* Kg = Kt + (size_t)bn * T * D;
    const f16* Vg = Vt + (size_t)bn * T * D;
    const f16* Qg = Qt + (size_t)bn * T * D;
    for (int i = tid; i < T * 4; i += 256) {
      int r = i >> 2, p = i & 3;
      *(uint4*)&A.Klh[r * SK + p * 8] = *(const uint4*)&Kg[r * D + p * 8];
      *(uint4*)&A.Vlh[r * SK + p * 8] = *(const uint4*)&Vg[r * D + p * 8];
    }
    {
      const float* wg = tm_Wo + (size_t)n * D * D;
      for (int i = tid; i < (D / 2) * D; i += 256) {
        int d2 = i >> 5, e = i & 31;
        A.woh[i] = pkh2(wg[(2 * d2) * D + e], wg[(2 * d2 + 1) * D + e]);
      }
    }
    if (tid < D) {
      A.bol[tid] = tm_bo[n * D + tid];
      A.gl[tid]  = ln_g[tid];
      A.bbl[tid] = ln_b[tid];
    }
    __syncthreads();

#pragma unroll
    for (int c = 0; c < 4; ++c) {
      const int JM = (CH2 * (c + 1) + 3) >> 2;   // 8,15,23,30 (compile-time)
      if (tid < CH2 * 4) {
        int r = tid >> 2, p = tid & 3;
        *(uint4*)&A.Qlh[r * SK + p * 8] =
            *(const uint4*)&Qg[(CH2 * c + r) * D + p * 8];
      }
      __syncthreads();   // Qlh ready; prior O-proj done -> Olh safe to overwrite

      {
        int task = tid >> 2, sl = tid & 3;
        if (task < 2 * CH2) {
          int rl = task >> 1, h = task & 1, ho = h * FD;
          int rg = CH2 * c + rl;
          uint4 q0 = *(const uint4*)&A.Qlh[rl * SK + ho];
          uint4 q1 = *(const uint4*)&A.Qlh[rl * SK + ho + 8];
          unsigned qh[8] = { q0.x, q0.y, q0.z, q0.w, q1.x, q1.y, q1.z, q1.w };

          float sc[NJ];
          float mx = -3e38f;
#pragma unroll
          for (int j = 0; j < JM; ++j) {
            int k = 4 * j + sl;
            sc[j] = -3e38f;
            if (k <= rg) {
              const uint4 ka = *(const uint4*)&A.Klh[k * SK + ho];
              const uint4 kb = *(const uint4*)&A.Klh[k * SK + ho + 8];
              float s0 = __builtin_amdgcn_fdot2(u2h(qh[0]), u2h(ka.x), 0.f, false);
              float s1 = __builtin_amdgcn_fdot2(u2h(qh[1]), u2h(ka.y), 0.f, false);
              float s2 = __builtin_amdgcn_fdot2(u2h(qh[2]), u2h(ka.z), 0.f, false);
              float s3 = __builtin_amdgcn_fdot2(u2h(qh[3]), u2h(ka.w), 0.f, false);
              s0 = __builtin_amdgcn_fdot2(u2h(qh[4]), u2h(kb.x), s0, false);
              s1 = __builtin_amdgcn_fdot2(u2h(qh[5]), u2h(kb.y), s1, false);
              s2 = __builtin_amdgcn_fdot2(u2h(qh[6]), u2h(kb.z), s2, false);
              s3 = __builtin_amdgcn_fdot2(u2h(qh[7]), u2h(kb.w), s3, false);
              float s = ((s0 + s1) + (s2 + s3)) * SCALE;
              sc[j] = s;
              mx = fmaxf(mx, s);
            }
          }
          mx = fmaxf(mx, __shfl_xor(mx, 1, 64));
          mx = fmaxf(mx, __shfl_xor(mx, 2, 64));
          float l = 0.f;
#pragma unroll
          for (int j = 0; j < JM; ++j) {
            sc[j] = __expf(sc[j] - mx);   // invalid slots: exp(-inf) = 0
            l += sc[j];
          }
          l += __shfl_xor(l, 1, 64);
          l += __shfl_xor(l, 2, 64);
          float rli = 1.f / l;

          f16x2 acc2[8];
#pragma unroll
          for (int f = 0; f < 8; ++f) acc2[f] = f16x2{(_Float16)0.f, (_Float16)0.f};
#pragma unroll
          for (int j = 0; j < JM; ++j) {
            int k = 4 * j + sl;
            if (k <= rg) {
              f16x2 pp = f16x2{(_Float16)sc[j], (_Float16)sc[j]};
              const uint4 va = *(const uint4*)&A.Vlh[k * SK + ho];
              const uint4 vb = *(const uint4*)&A.Vlh[k * SK + ho + 8];
              acc2[0] += pp * u2f(va.x);
              acc2[1] += pp * u2f(va.y);
              acc2[2] += pp * u2f(va.z);
              acc2[3] += pp * u2f(va.w);
              acc2[4] += pp * u2f(vb.x);
              acc2[5] += pp * u2f(vb.y);
              acc2[6] += pp * u2f(vb.z);
              acc2[7] += pp * u2f(vb.w);
            }
          }
#pragma unroll
          for (int f = 0; f < 8; ++f) {
            unsigned u = *reinterpret_cast<unsigned*>(&acc2[f]);
            unsigned u1 = __shfl_xor(u, 1, 64);
            acc2[f] += u2f(u1);
            u = *reinterpret_cast<unsigned*>(&acc2[f]);
            unsigned u2_ = __shfl_xor(u, 2, 64);
            acc2[f] += u2f(u2_);
          }
          if (sl == 0) {
#pragma unroll
            for (int j = 0; j < 8; ++j)
              A.Olh[rl * SOH + h * 8 + j] =
                  pkh2((float)acc2[j][0] * rli, (float)acc2[j][1] * rli);
          }
        }
      }
      __syncthreads();

      // ---- O-proj (fdot2) + residual + LN: thread = (row, e-quad) ----
      {
        int rl = tid >> 3, q = tid & 7, e0 = q * 4;
        if (rl < CH2) {
          int rg = CH2 * c + rl;
          size_t rowo = ((size_t)(b * T + rg) * N + n) * D;
          uint2 eu = *(const uint2*)&E[rowo + e0];
          float res[4] = { hlo(eu.x), hhi(eu.x), hlo(eu.y), hhi(eu.y) };
          float o[4], s1 = 0.f, s2 = 0.f;
#pragma unroll
          for (int j = 0; j < 4; ++j) {
            int e = e0 + j;
            float a = A.bol[e] + res[j];
#pragma unroll
            for (int d2 = 0; d2 < D / 2; ++d2)
              a = __builtin_amdgcn_fdot2(u2h(A.Olh[rl * SOH + d2]),
                                         u2h(A.woh[d2 * D + e]), a, false);
            o[j] = a; s1 += a; s2 += a * a;
          }
          s1 += __shfl_xor(s1, 1, 64); s2 += __shfl_xor(s2, 1, 64);
          s1 += __shfl_xor(s1, 2, 64); s2 += __shfl_xor(s2, 2, 64);
          s1 += __shfl_xor(s1, 4, 64); s2 += __shfl_xor(s2, 4, 64);
          float mu  = s1 * (1.f / D);
          float var = s2 * (1.f / D) - mu * mu;
          float r = rsqrtf(var + 1e-5f);
          uint2 ou;
          ou.x = pkh2((o[0]-mu)*r*A.gl[e0]+A.bbl[e0],    (o[1]-mu)*r*A.gl[e0+1]+A.bbl[e0+1]);
          ou.y = pkh2((o[2]-mu)*r*A.gl[e0+2]+A.bbl[e0+2],(o[3]-mu)*r*A.gl[e0+3]+A.bbl[e0+3]);
          *(uint2*)&Tn[rowo + e0] = ou;
        }
      }
    }
  } else {
    // ================= spatial role (v5, f16 I/O) =================
    ASmemS& s = *reinterpret_cast<ASmemS*>(smem);
    int sb = blockIdx.x - ablocks;
    int t  = sb >> 5;          // B/BG = 32 groups per t
    int bg = sb & 31;
    int b0 = bg * BG;

    for (int i = tid; i < 3 * (D / 2) * D; i += 256) {
      int fam = i / ((D / 2) * D);
      int idx = i % ((D / 2) * D);
      int d2 = idx >> 5, e = idx & 31;
      const float* wg = WsC + (size_t)(fam * T + t) * D * D;
      s.Wh[i] = pkh2(wg[(2 * d2) * D + e], wg[(2 * d2 + 1) * D + e]);
    }
    {
      const float* wg = sm_Wo + (size_t)t * D * D;
      for (int i = tid; i < (D / 2) * D; i += 256) {
        int d2 = i >> 5, e = i & 31;
        s.woh[i] = pkh2(wg[(2 * d2) * D + e], wg[(2 * d2 + 1) * D + e]);
      }
    }
    if (tid < D) {
      s.bqs[tid] = bsC[(0 * T + t) * D + tid];
      s.bks[tid] = bsC[(1 * T + t) * D + tid];
      s.bvs[tid] = bsC[(2 * T + t) * D + tid];
      s.bos[tid] = sm_bo[t * D + tid];
      s.gs[tid]  = ln_g[tid];
      s.bbs[tid] = ln_b[tid];
    }
    if (tid < SR * 4) {
      int r = tid >> 2, p = tid & 3;
      int b = b0 + r / N, n = r % N;
      *(uint4*)&s.Esh[r * SEH + p * 4] =
          *(const uint4*)&E[(((size_t)b * T + t) * N + n) * D + p * 8];
    }
    __syncthreads();

    // ---- QKV gemv (fdot2) -> packed-f16 Q/K/V ----
#pragma unroll 1
    for (int i = tid; i < SR * D; i += 256) {
      int r = i >> 5, e = i & 31;
      float aq = s.bqs[e], ak = s.bks[e], av = s.bvs[e];
#pragma unroll
      for (int d2 = 0; d2 < D / 2; ++d2) {
        h2 x = u2h(s.Esh[r * SEH + d2]);
        aq = __builtin_amdgcn_fdot2(x, u2h(s.Wh[0 * 512 + d2 * 32 + e]), aq, false);
        ak = __builtin_amdgcn_fdot2(x, u2h(s.Wh[1 * 512 + d2 * 32 + e]), ak, false);
        av = __builtin_amdgcn_fdot2(x, u2h(s.Wh[2 * 512 + d2 * 32 + e]), av, false);
      }
      s.Qh[r * SK + e] = (f16)aq;
      s.Kh[r * SK + e] = (f16)ak;
      s.Vh[r * SK + e] = (f16)av;
    }
    __syncthreads();

    // ---- attention (96 threads): fdot2 scores + pk_fma PV, O -> Q slot ----
    if (tid < SR * NH) {
      int r = tid >> 1, h = tid & 1, ho = h * FD;
      int kb = (r >= N) ? N : 0;
      uint4 q0 = *(const uint4*)&s.Qh[r * SK + ho];
      uint4 q1 = *(const uint4*)&s.Qh[r * SK + ho + 8];
      unsigned qh[8] = { q0.x, q0.y, q0.z, q0.w, q1.x, q1.y, q1.z, q1.w };
      float sc[N];
      float m = -1e30f;
#pragma unroll
      for (int k = 0; k < N; ++k) {
        const uint4 ka = *(const uint4*)&s.Kh[(kb + k) * SK + ho];
        const uint4 kc = *(const uint4*)&s.Kh[(kb + k) * SK + ho + 8];
        float s0 = __builtin_amdgcn_fdot2(u2h(qh[0]), u2h(ka.x), 0.f, false);
        float s1 = __builtin_amdgcn_fdot2(u2h(qh[1]), u2h(ka.y), 0.f, false);
        float s2 = __builtin_amdgcn_fdot2(u2h(qh[2]), u2h(ka.z), 0.f, false);
        float s3 = __builtin_amdgcn_fdot2(u2h(qh[3]), u2h(ka.w), 0.f, false);
        s0 = __builtin_amdgcn_fdot2(u2h(qh[4]), u2h(kc.x), s0, false);
        s1 = __builtin_amdgcn_fdot2(u2h(qh[5]), u2h(kc.y), s1, false);
        s2 = __builtin_amdgcn_fdot2(u2h(qh[6]), u2h(kc.z), s2, false);
        s3 = __builtin_amdgcn_fdot2(u2h(qh[7]), u2h(kc.w), s3, false);
        float sv = ((s0 + s1) + (s2 + s3)) * SCALE;
        sc[k] = sv;
        m = fmaxf(m, sv);
      }
      float l = 0.f;
#pragma unroll
      for (int k = 0; k < N; ++k) { sc[k] = __expf(sc[k] - m); l += sc[k]; }
      float rl = 1.f / l;

      f16x2 acc2[8];
#pragma unroll
      for (int f = 0; f < 8; ++f) acc2[f] = f16x2{(_Float16)0.f, (_Float16)0.f};
#pragma unroll
      for (int k = 0; k < N; ++k) {
        f16x2 pp = f16x2{(_Float16)sc[k], (_Float16)sc[k]};
        const uint4 va = *(const uint4*)&s.Vh[(kb + k) * SK + ho];
        const uint4 vb = *(const uint4*)&s.Vh[(kb + k) * SK + ho + 8];
        acc2[0] += pp * u2f(va.x);
        acc2[1] += pp * u2f(va.y);
        acc2[2] += pp * u2f(va.z);
        acc2[3] += pp * u2f(va.w);
        acc2[4] += pp * u2f(vb.x);
        acc2[5] += pp * u2f(vb.y);
        acc2[6] += pp * u2f(vb.z);
        acc2[7] += pp * u2f(vb.w);
      }
      unsigned* op = (unsigned*)&s.Qh[r * SK + ho];
#pragma unroll
      for (int j = 0; j < 8; ++j)
        op[j] = pkh2((float)acc2[j][0] * rl, (float)acc2[j][1] * rl);
    }
    __syncthreads();

    // ---- O-proj (fdot2) + residual + LN: thread = (row, e-quad), 2 iters ----
#pragma unroll 1
    for (int it = 0; it < 2; ++it) {
      int rl = it * 32 + (tid >> 3);
      int qd = tid & 7, e0 = qd * 4;
      if (rl < SR) {
        const unsigned* opk = (const unsigned*)&s.Qh[rl * SK];
        unsigned r0u = s.Esh[rl * SEH + (e0 >> 1)];
        unsigned r1u = s.Esh[rl * SEH + (e0 >> 1) + 1];
        h2 ra = u2h(r0u), rb = u2h(r1u);
        float res[4] = { (float)ra[0], (float)ra[1], (float)rb[0], (float)rb[1] };
        float o[4], s1 = 0.f, s2 = 0.f;
#pragma unroll
        for (int j = 0; j < 4; ++j) {
          int e = e0 + j;
          float a = s.bos[e] + res[j];
#pragma unroll
          for (int d2 = 0; d2 < D / 2; ++d2)
            a = __builtin_amdgcn_fdot2(u2h(opk[d2]), u2h(s.woh[d2 * D + e]), a, false);
          o[j] = a; s1 += a; s2 += a * a;
        }
        s1 += __shfl_xor(s1, 1, 64); s2 += __shfl_xor(s2, 1, 64);
        s1 += __shfl_xor(s1, 2, 64); s2 += __shfl_xor(s2, 2, 64);
        s1 += __shfl_xor(s1, 4, 64); s2 += __shfl_xor(s2, 4, 64);
        float mu  = s1 * (1.f / D);
        float var = s2 * (1.f / D) - mu * mu;
        float rr = rsqrtf(var + 1e-5f);
        int b = b0 + rl / N, n = rl % N;
        uint2 ou;
        ou.x = pkh2((o[0]-mu)*rr*s.gs[e0]+s.bbs[e0],    (o[1]-mu)*rr*s.gs[e0+1]+s.bbs[e0+1]);
        ou.y = pkh2((o[2]-mu)*rr*s.gs[e0+2]+s.bbs[e0+2],(o[3]-mu)*rr*s.gs[e0+3]+s.bbs[e0+3]);
        *(uint2*)&Sn[(((size_t)b * T + t) * N + n) * D + e0] = ou;
      }
    }
  }
}

// ---------------------------------------------------------------------------
// ff v4 = v3 with f16 activations: ts = Tn+Sn via 2 packed v_pk_add_f16
// (was 8 unpacks + 4 adds + 2 packs); E write via cvt_pkrtz.
// ---------------------------------------------------------------------------
__global__ __launch_bounds__(256) void ff_kernel(
    const f16* __restrict__ Tn, const f16* __restrict__ Sn,
    const float* __restrict__ W1, const float* __restrict__ b1,
    const float* __restrict__ W2, const float* __restrict__ b2,
    const float* __restrict__ ln_g, const float* __restrict__ ln_b,
    f16* __restrict__ E) {
  __shared__ unsigned w1h[(D / 2) * FF];   // 1024 uints, 4KB
  __shared__ unsigned w2h[(FF / 2) * D];   // 1024 uints, 4KB
  __shared__ float bb1[FF], bb2[D], gs[D], bbs[D];
  __shared__ unsigned tslp[FR][D / 2 + 1]; // 32 x 17 (stride 17: conflict-free)
  __shared__ unsigned hlp[FR][FF / 2 + 1]; // 32 x 33 (stride 33: conflict-free)
  int tid = threadIdx.x;
  int r0 = blockIdx.x * FR;
  for (int i = tid; i < (D / 2) * FF; i += 256) {
    int d2 = i / FF, jj = i % FF;
    w1h[i] = pkh2(W1[(2 * d2) * FF + jj], W1[(2 * d2 + 1) * FF + jj]);
  }
  for (int i = tid; i < (FF / 2) * D; i += 256) {
    int k2 = i / D, e = i % D;
    w2h[i] = pkh2(W2[(2 * k2) * D + e], W2[(2 * k2 + 1) * D + e]);
  }
  if (tid < FF) bb1[tid] = b1[tid];
  if (tid < D) { bb2[tid] = b2[tid]; gs[tid] = ln_g[tid]; bbs[tid] = ln_b[tid]; }
  int r = tid >> 3, s = tid & 7;
  {
    const f16* tp = Tn + ((size_t)(r0 + r)) * D + s * 4;
    const f16* sp = Sn + ((size_t)(r0 + r)) * D + s * 4;
    uint2 tu = *(const uint2*)tp;
    uint2 su = *(const uint2*)sp;
    f16x2 a0 = u2f(tu.x) + u2f(su.x);
    f16x2 a1 = u2f(tu.y) + u2f(su.y);
    tslp[r][s * 2]     = *reinterpret_cast<unsigned*>(&a0);
    tslp[r][s * 2 + 1] = *reinterpret_cast<unsigned*>(&a1);
  }
  __syncthreads();
  // pass1: 8 hidden units per lane via fdot2
  {
    float hh[8];
#pragma unroll
    for (int j = 0; j < 8; ++j) {
      int jj = s * 8 + j;
      float a = bb1[jj];
#pragma unroll
      for (int d2 = 0; d2 < D / 2; ++d2)
        a = __builtin_amdgcn_fdot2(u2h(tslp[r][d2]), u2h(w1h[d2 * FF + jj]), a, false);
      hh[j] = fmaxf(a, 0.f);
    }
#pragma unroll
    for (int j = 0; j < 4; ++j)
      hlp[r][s * 4 + j] = pkh2(hh[2 * j], hh[2 * j + 1]);
  }
  __syncthreads();
  // pass2: 4 outputs per lane via fdot2 + LN (3-level shfl reduce)
  {
    float x[4];
    float s1 = 0.f, s2 = 0.f;
#pragma unroll
    for (int j4 = 0; j4 < 4; ++j4) {
      int e = s * 4 + j4;
      h2 tv = u2h(tslp[r][e >> 1]);
      float a = bb2[e] + (float)tv[j4 & 1];   // s*4 even -> e&1 == j4&1
#pragma unroll
      for (int k2 = 0; k2 < FF / 2; ++k2)
        a = __builtin_amdgcn_fdot2(u2h(hlp[r][k2]), u2h(w2h[k2 * D + e]), a, false);
      x[j4] = a; s1 += a; s2 += a * a;
    }
    s1 += __shfl_xor(s1, 1, 64); s2 += __shfl_xor(s2, 1, 64);
    s1 += __shfl_xor(s1, 2, 64); s2 += __shfl_xor(s2, 2, 64);
    s1 += __shfl_xor(s1, 4, 64); s2 += __shfl_xor(s2, 4, 64);
    float mu  = s1 * (1.f / D);
    float var = s2 * (1.f / D) - mu * mu;
    float rr = rsqrtf(var + 1e-5f);
    int e0 = s * 4;
    uint2 ou;
    ou.x = pkh2((x[0]-mu)*rr*gs[e0]+bbs[e0],    (x[1]-mu)*rr*gs[e0+1]+bbs[e0+1]);
    ou.y = pkh2((x[2]-mu)*rr*gs[e0+2]+bbs[e0+2],(x[3]-mu)*rr*gs[e0+3]+bbs[e0+3]);
    *(uint2*)&E[((size_t)(r0 + r)) * D + e0] = ou;
  }
}

// ---------------------------------------------------------------------------
// out = E@op_W + op_b + X   (f32 out)
// ---------------------------------------------------------------------------
__global__ __launch_bounds__(256) void out_kernel(
    const f16* __restrict__ E, const float* __restrict__ op_W,
    const float* __restrict__ op_b, const float* __restrict__ X,
    float* __restrict__ out) {
  int idx = blockIdx.x * 256 + threadIdx.x;
  if (idx >= B * T * N * M) return;
  int m  = idx % M;
  int n  = (idx / M) % N;
  int bt = idx / (M * N);
  float acc = op_b[n * M + m];
  const f16* e = E + ((size_t)bt * N + n) * D;
#pragma unroll
  for (int d = 0; d < D; ++d) acc += (float)e[d] * op_W[(n * D + d) * M + m];
  acc += X[idx];
  out[idx] = acc;
}

// ---------------------------------------------------------------------------
extern "C" void kernel_launch(void* const* d_in, const int* in_sizes, int n_in,
                              void* d_out, int out_size, void* d_ws, size_t ws_size,
                              hipStream_t stream) {
  const float* X     = (const float*)d_in[0];
  const float* pe    = (const float*)d_in[1];
  const float* E_W   = (const float*)d_in[2];
  const float* E_b   = (const float*)d_in[3];
  const float* tq_W  = (const float*)d_in[4];
  const float* tq_b  = (const float*)d_in[5];
  const float* tk_W  = (const float*)d_in[6];
  const float* tk_b  = (const float*)d_in[7];
  const float* tv_W  = (const float*)d_in[8];
  const float* tv_b  = (const float*)d_in[9];
  const float* tm_Wq = (const float*)d_in[10];
  const float* tm_bq = (const float*)d_in[11];
  const float* tm_Wk = (const float*)d_in[12];
  const float* tm_bk = (const float*)d_in[13];
  const float* tm_Wv = (const float*)d_in[14];
  const float* tm_bv = (const float*)d_in[15];
  const float* tm_Wo = (const float*)d_in[16];
  const float* tm_bo = (const float*)d_in[17];
  const float* sq_W  = (const float*)d_in[18];
  const float* sq_b  = (const float*)d_in[19];
  const float* sk_W  = (const float*)d_in[20];
  const float* sk_b  = (const float*)d_in[21];
  const float* sv_W  = (const float*)d_in[22];
  const float* sv_b  = (const float*)d_in[23];
  const float* sm_Wq = (const float*)d_in[24];
  const float* sm_bq = (const float*)d_in[25];
  const float* sm_Wk = (const float*)d_in[26];
  const float* sm_bk = (const float*)d_in[27];
  const float* sm_Wv = (const float*)d_in[28];
  const float* sm_bv = (const float*)d_in[29];
  const float* sm_Wo = (const float*)d_in[30];
  const float* sm_bo = (const float*)d_in[31];
  const float* ff1_W = (const float*)d_in[32];
  const float* ff1_b = (const float*)d_in[33];
  const float* ff2_W = (const float*)d_in[34];
  const float* ff2_b = (const float*)d_in[35];
  const float* ln_g  = (const float*)d_in[36];
  const float* ln_b  = (const float*)d_in[37];
  const float* op_W  = (const float*)d_in[38];
  const float* op_b  = (const float*)d_in[39];
  float* out = (float*)d_out;

  float* WtC = (float*)d_ws;                         // 3*N*D*D
  float* btC = WtC + 3 * N * D * D;                  // 3*N*D
  float* WsC = btC + 3 * N * D;                      // 3*T*D*D
  float* bsC = WsC + 3 * T * D * D;                  // 3*T*D
  size_t act = (size_t)B * T * N * D;
  f16* Ebuf = (f16*)(bsC + 3 * T * D);
  f16* Tn   = Ebuf + act;
  f16* Qt   = Tn + act;
  f16* Kt   = Qt + act;
  f16* Vt   = Kt + act;

  size_t floats_bytes = (size_t)(3 * N * D * D + 3 * N * D +
                                 3 * T * D * D + 3 * T * D) * sizeof(float);
  size_t need6 = floats_bytes + 6 * act * sizeof(f16);
  bool concurrent = (ws_size >= need6);
  f16* Sn = concurrent ? (Vt + act) : Qt;   // 6th buffer, or serial-safe alias

  compose3_kernel<<<3 * N, 256, 0, stream>>>(
      tq_W, tq_b, tm_Wq, tm_bq, tk_W, tk_b, tm_Wk, tm_bk,
      tv_W, tv_b, tm_Wv, tm_bv, WtC, btC, N);
  compose3_kernel<<<3 * T, 256, 0, stream>>>(
      sq_W, sq_b, sm_Wq, sm_bq, sk_W, sk_b, sm_Wk, sm_bk,
      sv_W, sv_b, sm_Wv, sm_bv, WsC, bsC, T);

  embed_kernel<<<(B * T * N * D) / 256, 256, 0, stream>>>(X, pe, E_W, E_b, Ebuf);

  for (int l = 0; l < L; ++l) {
    qkvt_kernel<<<QG, 256, 0, stream>>>(Ebuf, WtC, btC, Qt, Kt, Vt);
    if (concurrent) {
      // attnt ∥ spatial in one launch: spatial hides under the longer attnt.
      as_fused_kernel<<<AG + SG, 256, 0, stream>>>(
          Qt, Kt, Vt, Ebuf, tm_Wo, tm_bo,
          WsC, bsC, sm_Wo, sm_bo, ln_g, ln_b, Tn, Sn, AG);
    } else {
      // serial fallback (R31 schedule): attnt, then spatial (Sn aliases Qt).
      as_fused_kernel<<<AG, 256, 0, stream>>>(
          Qt, Kt, Vt, Ebuf, tm_Wo, tm_bo,
          WsC, bsC, sm_Wo, sm_bo, ln_g, ln_b, Tn, Sn, AG);
      as_fused_kernel<<<SG, 256, 0, stream>>>(
          Qt, Kt, Vt, Ebuf, tm_Wo, tm_bo,
          WsC, bsC, sm_Wo, sm_bo, ln_g, ln_b, Tn, Sn, 0);
    }
    ff_kernel<<<(B * T * N) / FR, 256, 0, stream>>>(Tn, Sn, ff1_W, ff1_b, ff2_W, ff2_b, ln_g, ln_b, Ebuf);
  }

  out_kernel<<<(B * T * N * M + 255) / 256, 256, 0, stream>>>(Ebuf, op_W, op_b, X, out);
}